// Round 2
// baseline (3148.320 us; speedup 1.0000x reference)
//
#include <hip/hip_runtime.h>
#include <hip/hip_bf16.h>

#define N_LAYERS 2
#define D_MODEL 1024
#define D_INNER 2048
#define D_STATE 16
#define D_CONV 4
#define DT_RANK 64
#define N_CLASSES 10
#define BB 4
#define LL 1024
#define BL (BB*LL)   // 4096 rows

// ---------------- LayerNorm (D=1024, one row per block, 256 thr) -------------
__global__ __launch_bounds__(256) void layernorm_k(const float* __restrict__ x,
    const float* __restrict__ w, const float* __restrict__ b,
    float* __restrict__ out) {
  const int row = blockIdx.x;
  const int t = threadIdx.x;
  const float4 v = *(const float4*)(x + (size_t)row * D_MODEL + t * 4);
  float s = v.x + v.y + v.z + v.w;
  float q = v.x*v.x + v.y*v.y + v.z*v.z + v.w*v.w;
  #pragma unroll
  for (int o = 32; o; o >>= 1) { s += __shfl_down(s, o); q += __shfl_down(q, o); }
  __shared__ float red[8];
  if ((t & 63) == 0) { red[t >> 6] = s; red[4 + (t >> 6)] = q; }
  __syncthreads();
  s = red[0] + red[1] + red[2] + red[3];
  q = red[4] + red[5] + red[6] + red[7];
  const float mean = s * (1.f / D_MODEL);
  const float var  = q * (1.f / D_MODEL) - mean * mean;
  const float rstd = rsqrtf(var + 1e-5f);
  const float4 wv = *(const float4*)(w + t * 4);
  const float4 bv = *(const float4*)(b + t * 4);
  float4 o4;
  o4.x = (v.x - mean) * rstd * wv.x + bv.x;
  o4.y = (v.y - mean) * rstd * wv.y + bv.y;
  o4.z = (v.z - mean) * rstd * wv.z + bv.z;
  o4.w = (v.w - mean) * rstd * wv.w + bv.w;
  *(float4*)(out + (size_t)row * D_MODEL + t * 4) = o4;
}

// ---------------- fp32 SGEMM NT: C[m,n] = sum_k A[m,k]*B[n,k] (+epilogue) ----
// EPI: 0 none; 1 softplus(acc + bias[n]); 2 acc + resid[m,n]
template<int BM, int BN, int BK, int TM, int TN, int EPI>
__global__ __launch_bounds__(256) void sgemm_nt(
    const float* __restrict__ A, const float* __restrict__ B,
    float* __restrict__ C, int M, int N, int K, int lda, int ldb, int ldc,
    const float* __restrict__ bias, const float* __restrict__ resid, int ldres) {
  constexpr int THREADS = 256;
  constexpr int NT = BN / TN;           // threads along n (fast)
  constexpr int K4 = BK / 4;
  constexpr int A_F4 = BM * BK / (THREADS * 4);
  constexpr int B_F4 = BN * BK / (THREADS * 4);
  static_assert((BM / TM) * (BN / TN) == THREADS, "thread shape");
  __shared__ float As[BK][BM + 4];
  __shared__ float Bs[BK][BN + 4];
  const int tid = threadIdx.x;
  const int m0 = blockIdx.y * BM;
  const int n0 = blockIdx.x * BN;
  const int tn = (tid % NT) * TN;
  const int tm = (tid / NT) * TM;
  float acc[TM][TN] = {};
  for (int k0 = 0; k0 < K; k0 += BK) {
    #pragma unroll
    for (int i = 0; i < A_F4; i++) {
      int li = tid + i * THREADS;
      int r = li / K4, c4 = li % K4;
      float4 v = *(const float4*)(A + (size_t)(m0 + r) * lda + k0 + c4 * 4);
      As[c4*4+0][r] = v.x; As[c4*4+1][r] = v.y; As[c4*4+2][r] = v.z; As[c4*4+3][r] = v.w;
    }
    #pragma unroll
    for (int i = 0; i < B_F4; i++) {
      int li = tid + i * THREADS;
      int r = li / K4, c4 = li % K4;
      float4 v = *(const float4*)(B + (size_t)(n0 + r) * ldb + k0 + c4 * 4);
      Bs[c4*4+0][r] = v.x; Bs[c4*4+1][r] = v.y; Bs[c4*4+2][r] = v.z; Bs[c4*4+3][r] = v.w;
    }
    __syncthreads();
    #pragma unroll
    for (int k = 0; k < BK; k++) {
      float a[TM], bf[TN];
      #pragma unroll
      for (int i = 0; i < TM; i++) a[i] = As[k][tm + i];
      #pragma unroll
      for (int j = 0; j < TN; j++) bf[j] = Bs[k][tn + j];
      #pragma unroll
      for (int i = 0; i < TM; i++)
        #pragma unroll
        for (int j = 0; j < TN; j++)
          acc[i][j] = fmaf(a[i], bf[j], acc[i][j]);
    }
    __syncthreads();
  }
  #pragma unroll
  for (int i = 0; i < TM; i++) {
    const int m = m0 + tm + i;
    #pragma unroll
    for (int j = 0; j < TN; j++) {
      const int n = n0 + tn + j;
      float v = acc[i][j];
      if constexpr (EPI == 1) {
        v += bias[n];
        v = (v > 20.f) ? v : log1pf(__expf(v));
      }
      if constexpr (EPI == 2) {
        v += resid[(size_t)m * ldres + n];
      }
      C[(size_t)m * ldc + n] = v;
    }
  }
}

// ---------------- causal depthwise conv (width 4) + SiLU --------------------
__global__ __launch_bounds__(256) void conv_silu_k(const float* __restrict__ xz,
    const float* __restrict__ cw, const float* __restrict__ cb,
    float* __restrict__ xc) {
  const int gid = blockIdx.x * 256 + threadIdx.x;   // B*L*D_INNER
  const int c = gid & (D_INNER - 1);
  const int l = (gid >> 11) & (LL - 1);
  const int b = gid >> 21;
  const float4 w = *(const float4*)(cw + c * 4);
  const float* base = xz + ((size_t)(b << 10) + l) * (2 * D_INNER) + c;
  float acc = cb[c];
  acc = fmaf(w.w, base[0], acc);
  if (l >= 1) acc = fmaf(w.z, base[-(2 * D_INNER)], acc);
  if (l >= 2) acc = fmaf(w.y, base[-2 * (2 * D_INNER)], acc);
  if (l >= 3) acc = fmaf(w.x, base[-3 * (2 * D_INNER)], acc);
  xc[gid] = acc / (1.f + __expf(-acc));
}

// ------- selective scan, lane per (b,c,n), fused SiLU(z) gate ----------------
// dty: in = dt, out = gated y (in-place; each 16-lane group owns channel c)
__global__ __launch_bounds__(256) void scan16_k(
    float* __restrict__ dty,
    const float* __restrict__ xc,
    const float* __restrict__ xdbl,
    const float* __restrict__ xz,
    const float* __restrict__ A_log, const float* __restrict__ Dp) {
  const int t = threadIdx.x;
  const int n = t & 15;                       // state index
  const int c = blockIdx.x * 16 + (t >> 4);   // channel
  const int b = blockIdx.y;
  const float Ac = -__expf(A_log[c * D_STATE + n]);
  const float Dv = Dp[c];
  const size_t rb = (size_t)b * LL;
  const float* dtp = dty + rb * D_INNER + c;
  const float* xcp = xc + rb * D_INNER + c;
  const float* bcp = xdbl + rb * 96 + DT_RANK + n;       // B at +0, C at +16
  const float* zp  = xz + rb * (size_t)(2 * D_INNER) + D_INNER + c;
  float* yp = dty + rb * D_INNER + c;

  float h = 0.f;
  float dtv = dtp[0];
  float xv  = xcp[0];
  float Bn  = bcp[0];
  float Cn  = bcp[D_STATE];
  for (int l = 0; l < LL; l++) {
    // software-pipelined prefetch (loads independent of recurrence)
    float dtv2 = 0.f, xv2 = 0.f, Bn2 = 0.f, Cn2 = 0.f;
    if (l + 1 < LL) {
      const size_t r1 = (size_t)(l + 1);
      dtv2 = dtp[r1 * D_INNER];
      xv2  = xcp[r1 * D_INNER];
      Bn2  = bcp[r1 * 96];
      Cn2  = bcp[r1 * 96 + D_STATE];
    }
    h = fmaf(__expf(dtv * Ac), h, (dtv * xv) * Bn);
    float y = h * Cn;
    y += __shfl_xor(y, 1, 16);
    y += __shfl_xor(y, 2, 16);
    y += __shfl_xor(y, 4, 16);
    y += __shfl_xor(y, 8, 16);
    if (n == 0) {
      const float z = zp[(size_t)l * 2 * D_INNER];
      yp[(size_t)l * D_INNER] =
          fmaf(xv, Dv, y) * (z / (1.f + __expf(-z)));
    }
    dtv = dtv2; xv = xv2; Bn = Bn2; Cn = Cn2;
  }
}

// ---------------- mean pool over L ------------------------------------------
__global__ __launch_bounds__(256) void pool_k(const float* __restrict__ h,
    float* __restrict__ pooled) {
  const int d = blockIdx.x * 256 + threadIdx.x;  // 0..1023
  const int b = blockIdx.y;
  float s = 0.f;
  for (int l = 0; l < LL; l++) s += h[((size_t)(b * LL + l)) * D_MODEL + d];
  pooled[b * D_MODEL + d] = s * (1.f / LL);
}

// ---------------- classifier head --------------------------------------------
__global__ __launch_bounds__(64) void head_k(const float* __restrict__ pooled,
    const float* __restrict__ hw, const float* __restrict__ hb,
    float* __restrict__ out) {
  const int b = blockIdx.x / N_CLASSES;
  const int j = blockIdx.x % N_CLASSES;
  float s = 0.f;
  for (int k = threadIdx.x; k < D_MODEL; k += 64)
    s = fmaf(pooled[b * D_MODEL + k], hw[j * D_MODEL + k], s);
  #pragma unroll
  for (int o = 32; o; o >>= 1) s += __shfl_down(s, o);
  if (threadIdx.x == 0) out[b * N_CLASSES + j] = s + hb[j];
}

extern "C" void kernel_launch(void* const* d_in, const int* in_sizes, int n_in,
                              void* d_out, int out_size, void* d_ws, size_t ws_size,
                              hipStream_t stream) {
  const float* x0    = (const float*)d_in[0];
  const float* ln1w  = (const float*)d_in[1];
  const float* ln1b  = (const float*)d_in[2];
  const float* inw   = (const float*)d_in[3];
  const float* convw = (const float*)d_in[4];
  const float* convb = (const float*)d_in[5];
  const float* xpw   = (const float*)d_in[6];
  const float* dtpw  = (const float*)d_in[7];
  const float* dtpb  = (const float*)d_in[8];
  const float* Alog  = (const float*)d_in[9];
  const float* Dp    = (const float*)d_in[10];
  const float* outw  = (const float*)d_in[11];
  const float* normw = (const float*)d_in[12];
  const float* normb = (const float*)d_in[13];
  const float* headw = (const float*)d_in[14];
  const float* headb = (const float*)d_in[15];

  float* ws = (float*)d_ws;
  float* X      = ws;                         // 4096*1024
  float* h      = X + (size_t)BL * D_MODEL;   // 4096*1024
  float* xz     = h + (size_t)BL * D_MODEL;   // 4096*4096
  float* xc     = xz + (size_t)BL * 2 * D_INNER;  // 4096*2048
  float* xdbl   = xc + (size_t)BL * D_INNER;  // 4096*96
  float* dty    = xdbl + (size_t)BL * 96;     // 4096*2048 (dt, then y in-place)
  float* pooled = dty + (size_t)BL * D_INNER; // 4*1024

  hipMemcpyAsync(X, x0, (size_t)BL * D_MODEL * sizeof(float),
                 hipMemcpyDeviceToDevice, stream);

  for (int layer = 0; layer < N_LAYERS; ++layer) {
    layernorm_k<<<BL, 256, 0, stream>>>(X, ln1w + layer * D_MODEL,
                                        ln1b + layer * D_MODEL, h);
    // xz = h @ in_w^T : M=4096 N=4096 K=1024
    sgemm_nt<128,128,16,8,8,0><<<dim3(4096/128, 4096/128), 256, 0, stream>>>(
        h, inw + (size_t)layer * 2 * D_INNER * D_MODEL, xz,
        BL, 2 * D_INNER, D_MODEL, D_MODEL, D_MODEL, 2 * D_INNER,
        nullptr, nullptr, 0);
    conv_silu_k<<<(BL * D_INNER) / 256, 256, 0, stream>>>(
        xz, convw + layer * D_INNER * D_CONV, convb + layer * D_INNER, xc);
    // x_dbl = xc @ xp_w^T : M=4096 N=96 K=2048
    sgemm_nt<128,32,32,8,2,0><<<dim3(96/32, 4096/128), 256, 0, stream>>>(
        xc, xpw + (size_t)layer * 96 * D_INNER, xdbl,
        BL, 96, D_INNER, D_INNER, D_INNER, 96, nullptr, nullptr, 0);
    // dt = softplus(dt_r @ dtp_w^T + dtp_b) : M=4096 N=2048 K=64 (lda=96)
    sgemm_nt<128,128,16,8,8,1><<<dim3(2048/128, 4096/128), 256, 0, stream>>>(
        xdbl, dtpw + (size_t)layer * D_INNER * DT_RANK, dty,
        BL, D_INNER, DT_RANK, 96, DT_RANK, D_INNER,
        dtpb + layer * D_INNER, nullptr, 0);
    // scan + fused SiLU(z) gate: lane per (b,c,n)
    scan16_k<<<dim3(D_INNER / 16, BB), 256, 0, stream>>>(
        dty, xc, xdbl, xz, Alog + (size_t)layer * D_INNER * D_STATE,
        Dp + layer * D_INNER);
    // X = X + y @ out_w^T : M=4096 N=1024 K=2048
    sgemm_nt<128,128,16,8,8,2><<<dim3(1024/128, 4096/128), 256, 0, stream>>>(
        dty, outw + (size_t)layer * D_MODEL * D_INNER, X,
        BL, D_MODEL, D_INNER, D_INNER, D_INNER, D_MODEL,
        nullptr, X, D_MODEL);
  }

  layernorm_k<<<BL, 256, 0, stream>>>(X, normw, normb, h);
  pool_k<<<dim3(D_MODEL / 256, BB), 256, 0, stream>>>(h, pooled);
  head_k<<<BB * N_CLASSES, 64, 0, stream>>>(pooled, headw, headb, (float*)d_out);
}

// Round 3
// 1976.252 us; speedup vs baseline: 1.5931x; 1.5931x over previous
//
#include <hip/hip_runtime.h>
#include <hip/hip_bf16.h>

#define N_LAYERS 2
#define D_MODEL 1024
#define D_INNER 2048
#define D_STATE 16
#define D_CONV 4
#define DT_RANK 64
#define N_CLASSES 10
#define BB 4
#define LL 1024
#define BL (BB*LL)   // 4096 rows
#define CH 16        // scan chunks per sequence
#define CLEN (LL/CH) // 64 steps per chunk

// ---------------- LayerNorm (D=1024, one row per block, 256 thr) -------------
__global__ __launch_bounds__(256) void layernorm_k(const float* __restrict__ x,
    const float* __restrict__ w, const float* __restrict__ b,
    float* __restrict__ out) {
  const int row = blockIdx.x;
  const int t = threadIdx.x;
  const float4 v = *(const float4*)(x + (size_t)row * D_MODEL + t * 4);
  float s = v.x + v.y + v.z + v.w;
  float q = v.x*v.x + v.y*v.y + v.z*v.z + v.w*v.w;
  #pragma unroll
  for (int o = 32; o; o >>= 1) { s += __shfl_down(s, o); q += __shfl_down(q, o); }
  __shared__ float red[8];
  if ((t & 63) == 0) { red[t >> 6] = s; red[4 + (t >> 6)] = q; }
  __syncthreads();
  s = red[0] + red[1] + red[2] + red[3];
  q = red[4] + red[5] + red[6] + red[7];
  const float mean = s * (1.f / D_MODEL);
  const float var  = q * (1.f / D_MODEL) - mean * mean;
  const float rstd = rsqrtf(var + 1e-5f);
  const float4 wv = *(const float4*)(w + t * 4);
  const float4 bv = *(const float4*)(b + t * 4);
  float4 o4;
  o4.x = (v.x - mean) * rstd * wv.x + bv.x;
  o4.y = (v.y - mean) * rstd * wv.y + bv.y;
  o4.z = (v.z - mean) * rstd * wv.z + bv.z;
  o4.w = (v.w - mean) * rstd * wv.w + bv.w;
  *(float4*)(out + (size_t)row * D_MODEL + t * 4) = o4;
}

// ---------------- fp32 SGEMM NT: C[m,n] = sum_k A[m,k]*B[n,k] (+epilogue) ----
// EPI: 0 none; 1 softplus(acc + bias[n]); 2 acc + resid[m,n]
template<int BM, int BN, int BK, int TM, int TN, int EPI>
__global__ __launch_bounds__(256) void sgemm_nt(
    const float* __restrict__ A, const float* __restrict__ B,
    float* __restrict__ C, int M, int N, int K, int lda, int ldb, int ldc,
    const float* __restrict__ bias, const float* __restrict__ resid, int ldres) {
  constexpr int THREADS = 256;
  constexpr int NT = BN / TN;           // threads along n (fast)
  constexpr int K4 = BK / 4;
  constexpr int A_F4 = BM * BK / (THREADS * 4);
  constexpr int B_F4 = BN * BK / (THREADS * 4);
  static_assert((BM / TM) * (BN / TN) == THREADS, "thread shape");
  __shared__ float As[BK][BM + 4];
  __shared__ float Bs[BK][BN + 4];
  const int tid = threadIdx.x;
  const int m0 = blockIdx.y * BM;
  const int n0 = blockIdx.x * BN;
  const int tn = (tid % NT) * TN;
  const int tm = (tid / NT) * TM;
  float acc[TM][TN] = {};
  for (int k0 = 0; k0 < K; k0 += BK) {
    #pragma unroll
    for (int i = 0; i < A_F4; i++) {
      int li = tid + i * THREADS;
      int r = li / K4, c4 = li % K4;
      float4 v = *(const float4*)(A + (size_t)(m0 + r) * lda + k0 + c4 * 4);
      As[c4*4+0][r] = v.x; As[c4*4+1][r] = v.y; As[c4*4+2][r] = v.z; As[c4*4+3][r] = v.w;
    }
    #pragma unroll
    for (int i = 0; i < B_F4; i++) {
      int li = tid + i * THREADS;
      int r = li / K4, c4 = li % K4;
      float4 v = *(const float4*)(B + (size_t)(n0 + r) * ldb + k0 + c4 * 4);
      Bs[c4*4+0][r] = v.x; Bs[c4*4+1][r] = v.y; Bs[c4*4+2][r] = v.z; Bs[c4*4+3][r] = v.w;
    }
    __syncthreads();
    #pragma unroll
    for (int k = 0; k < BK; k++) {
      float a[TM], bf[TN];
      #pragma unroll
      for (int i = 0; i < TM; i++) a[i] = As[k][tm + i];
      #pragma unroll
      for (int j = 0; j < TN; j++) bf[j] = Bs[k][tn + j];
      #pragma unroll
      for (int i = 0; i < TM; i++)
        #pragma unroll
        for (int j = 0; j < TN; j++)
          acc[i][j] = fmaf(a[i], bf[j], acc[i][j]);
    }
    __syncthreads();
  }
  #pragma unroll
  for (int i = 0; i < TM; i++) {
    const int m = m0 + tm + i;
    #pragma unroll
    for (int j = 0; j < TN; j++) {
      const int n = n0 + tn + j;
      float v = acc[i][j];
      if constexpr (EPI == 1) {
        v += bias[n];
        v = (v > 20.f) ? v : log1pf(__expf(v));
      }
      if constexpr (EPI == 2) {
        v += resid[(size_t)m * ldres + n];
      }
      C[(size_t)m * ldc + n] = v;
    }
  }
}

// ---------------- causal depthwise conv (width 4) + SiLU --------------------
__global__ __launch_bounds__(256) void conv_silu_k(const float* __restrict__ xz,
    const float* __restrict__ cw, const float* __restrict__ cb,
    float* __restrict__ xc) {
  const int gid = blockIdx.x * 256 + threadIdx.x;   // B*L*D_INNER
  const int c = gid & (D_INNER - 1);
  const int l = (gid >> 11) & (LL - 1);
  const int b = gid >> 21;
  const float4 w = *(const float4*)(cw + c * 4);
  const float* base = xz + ((size_t)(b << 10) + l) * (2 * D_INNER) + c;
  float acc = cb[c];
  acc = fmaf(w.w, base[0], acc);
  if (l >= 1) acc = fmaf(w.z, base[-(2 * D_INNER)], acc);
  if (l >= 2) acc = fmaf(w.y, base[-2 * (2 * D_INNER)], acc);
  if (l >= 3) acc = fmaf(w.x, base[-3 * (2 * D_INNER)], acc);
  xc[gid] = acc / (1.f + __expf(-acc));
}

// ------- chunked selective scan, pass 1: per-chunk free evolution -----------
// thread = (b, c, chunk k); h starts at 0; store h_end[16] and sum(dt).
__global__ __launch_bounds__(256) void scan_pass1_k(
    const float* __restrict__ dt, const float* __restrict__ xc,
    const float* __restrict__ xdbl, const float* __restrict__ A_log,
    float* __restrict__ hend, float* __restrict__ sumdt) {
  const int c = blockIdx.x * 256 + threadIdx.x;
  const int k = blockIdx.y;
  const int b = blockIdx.z;
  float Ac[D_STATE];
  #pragma unroll
  for (int n = 0; n < D_STATE; n++) Ac[n] = -__expf(A_log[c * D_STATE + n]);
  float h[D_STATE] = {};
  float sd = 0.f;
  const size_t r0 = (size_t)b * LL + (size_t)k * CLEN;
  const float* dtp = dt + r0 * D_INNER + c;
  const float* xcp = xc + r0 * D_INNER + c;
  const float* Bp  = xdbl + r0 * 96 + DT_RANK;

  float dtv = dtp[0];
  float xv  = xcp[0];
  float4 B0 = *(const float4*)(Bp + 0);
  float4 B1 = *(const float4*)(Bp + 4);
  float4 B2 = *(const float4*)(Bp + 8);
  float4 B3 = *(const float4*)(Bp + 12);
  for (int l = 0; l < CLEN; l++) {
    const int lp = (l + 1 < CLEN) ? l + 1 : l;   // safe redundant tail load
    const float dtv2 = dtp[(size_t)lp * D_INNER];
    const float xv2  = xcp[(size_t)lp * D_INNER];
    const float4 B0n = *(const float4*)(Bp + (size_t)lp * 96 + 0);
    const float4 B1n = *(const float4*)(Bp + (size_t)lp * 96 + 4);
    const float4 B2n = *(const float4*)(Bp + (size_t)lp * 96 + 8);
    const float4 B3n = *(const float4*)(Bp + (size_t)lp * 96 + 12);
    sd += dtv;
    const float dx = dtv * xv;
    const float Bv[D_STATE] = {B0.x,B0.y,B0.z,B0.w, B1.x,B1.y,B1.z,B1.w,
                               B2.x,B2.y,B2.z,B2.w, B3.x,B3.y,B3.z,B3.w};
    #pragma unroll
    for (int n = 0; n < D_STATE; n++)
      h[n] = fmaf(__expf(dtv * Ac[n]), h[n], dx * Bv[n]);
    dtv = dtv2; xv = xv2; B0 = B0n; B1 = B1n; B2 = B2n; B3 = B3n;
  }
  float* he = hend + (((size_t)(b * CH + k) * D_INNER + c) << 4);
  #pragma unroll
  for (int n = 0; n < D_STATE; n += 4)
    *(float4*)(he + n) = make_float4(h[n], h[n+1], h[n+2], h[n+3]);
  sumdt[(size_t)(b * CH + k) * D_INNER + c] = sd;
}

// ------- chunked scan fixup: in place hend -> h0 per chunk ------------------
// thread = (b, c, n); serial over 16 chunks. prod(dA over chunk)=exp(Ac*sumdt)
__global__ __launch_bounds__(256) void scan_fix_k(
    float* __restrict__ hend, const float* __restrict__ sumdt,
    const float* __restrict__ A_log) {
  const int gid = blockIdx.x * 256 + threadIdx.x;  // B*D_INNER*16
  const int n = gid & 15;
  const int c = (gid >> 4) & (D_INNER - 1);
  const int b = gid >> 15;
  const float Ac = -__expf(A_log[c * D_STATE + n]);
  float hrun = 0.f;
  for (int k = 0; k < CH; k++) {
    const size_t base = (size_t)(b * CH + k) * D_INNER + c;
    const float sd = sumdt[base];
    float* hp = hend + (base << 4) + n;
    const float tmp = *hp;
    *hp = hrun;                                   // h0 for chunk k
    hrun = fmaf(__expf(Ac * sd), hrun, tmp);      // h at end of chunk k
  }
}

// ------- chunked scan pass 3: replay with h0, emit gated y (in place) -------
__global__ __launch_bounds__(256) void scan_pass3_k(
    float* __restrict__ dty, const float* __restrict__ xc,
    const float* __restrict__ xdbl, const float* __restrict__ xz,
    const float* __restrict__ h0, const float* __restrict__ A_log,
    const float* __restrict__ Dp) {
  const int c = blockIdx.x * 256 + threadIdx.x;
  const int k = blockIdx.y;
  const int b = blockIdx.z;
  float Ac[D_STATE];
  #pragma unroll
  for (int n = 0; n < D_STATE; n++) Ac[n] = -__expf(A_log[c * D_STATE + n]);
  const float Dv = Dp[c];
  float h[D_STATE];
  const float* hp = h0 + (((size_t)(b * CH + k) * D_INNER + c) << 4);
  #pragma unroll
  for (int n = 0; n < D_STATE; n += 4) {
    const float4 v = *(const float4*)(hp + n);
    h[n] = v.x; h[n+1] = v.y; h[n+2] = v.z; h[n+3] = v.w;
  }
  const size_t r0 = (size_t)b * LL + (size_t)k * CLEN;
  float* dtp = dty + r0 * D_INNER + c;
  const float* xcp = xc + r0 * D_INNER + c;
  const float* Bp  = xdbl + r0 * 96 + DT_RANK;
  const float* zp  = xz + r0 * (size_t)(2 * D_INNER) + D_INNER + c;

  float dtv = dtp[0];
  float xv  = xcp[0];
  float zv  = zp[0];
  float4 B0 = *(const float4*)(Bp + 0);
  float4 B1 = *(const float4*)(Bp + 4);
  float4 B2 = *(const float4*)(Bp + 8);
  float4 B3 = *(const float4*)(Bp + 12);
  float4 C0 = *(const float4*)(Bp + 16);
  float4 C1 = *(const float4*)(Bp + 20);
  float4 C2 = *(const float4*)(Bp + 24);
  float4 C3 = *(const float4*)(Bp + 28);
  for (int l = 0; l < CLEN; l++) {
    const int lp = (l + 1 < CLEN) ? l + 1 : l;
    const float dtv2 = dtp[(size_t)lp * D_INNER];
    const float xv2  = xcp[(size_t)lp * D_INNER];
    const float zv2  = zp[(size_t)lp * 2 * D_INNER];
    const float4 B0n = *(const float4*)(Bp + (size_t)lp * 96 + 0);
    const float4 B1n = *(const float4*)(Bp + (size_t)lp * 96 + 4);
    const float4 B2n = *(const float4*)(Bp + (size_t)lp * 96 + 8);
    const float4 B3n = *(const float4*)(Bp + (size_t)lp * 96 + 12);
    const float4 C0n = *(const float4*)(Bp + (size_t)lp * 96 + 16);
    const float4 C1n = *(const float4*)(Bp + (size_t)lp * 96 + 20);
    const float4 C2n = *(const float4*)(Bp + (size_t)lp * 96 + 24);
    const float4 C3n = *(const float4*)(Bp + (size_t)lp * 96 + 28);
    const float dx = dtv * xv;
    const float Bv[D_STATE] = {B0.x,B0.y,B0.z,B0.w, B1.x,B1.y,B1.z,B1.w,
                               B2.x,B2.y,B2.z,B2.w, B3.x,B3.y,B3.z,B3.w};
    const float Cv[D_STATE] = {C0.x,C0.y,C0.z,C0.w, C1.x,C1.y,C1.z,C1.w,
                               C2.x,C2.y,C2.z,C2.w, C3.x,C3.y,C3.z,C3.w};
    float y = 0.f;
    #pragma unroll
    for (int n = 0; n < D_STATE; n++) {
      h[n] = fmaf(__expf(dtv * Ac[n]), h[n], dx * Bv[n]);
      y = fmaf(h[n], Cv[n], y);
    }
    y = fmaf(xv, Dv, y);
    dtp[(size_t)l * D_INNER] = y * (zv / (1.f + __expf(-zv)));
    dtv = dtv2; xv = xv2; zv = zv2;
    B0 = B0n; B1 = B1n; B2 = B2n; B3 = B3n;
    C0 = C0n; C1 = C1n; C2 = C2n; C3 = C3n;
  }
}

// ---------------- mean pool over L ------------------------------------------
__global__ __launch_bounds__(256) void pool_k(const float* __restrict__ h,
    float* __restrict__ pooled) {
  const int d = blockIdx.x * 256 + threadIdx.x;  // 0..1023
  const int b = blockIdx.y;
  float s = 0.f;
  for (int l = 0; l < LL; l++) s += h[((size_t)(b * LL + l)) * D_MODEL + d];
  pooled[b * D_MODEL + d] = s * (1.f / LL);
}

// ---------------- classifier head --------------------------------------------
__global__ __launch_bounds__(64) void head_k(const float* __restrict__ pooled,
    const float* __restrict__ hw, const float* __restrict__ hb,
    float* __restrict__ out) {
  const int b = blockIdx.x / N_CLASSES;
  const int j = blockIdx.x % N_CLASSES;
  float s = 0.f;
  for (int k = threadIdx.x; k < D_MODEL; k += 64)
    s = fmaf(pooled[b * D_MODEL + k], hw[j * D_MODEL + k], s);
  #pragma unroll
  for (int o = 32; o; o >>= 1) s += __shfl_down(s, o);
  if (threadIdx.x == 0) out[b * N_CLASSES + j] = s + hb[j];
}

extern "C" void kernel_launch(void* const* d_in, const int* in_sizes, int n_in,
                              void* d_out, int out_size, void* d_ws, size_t ws_size,
                              hipStream_t stream) {
  const float* x0    = (const float*)d_in[0];
  const float* ln1w  = (const float*)d_in[1];
  const float* ln1b  = (const float*)d_in[2];
  const float* inw   = (const float*)d_in[3];
  const float* convw = (const float*)d_in[4];
  const float* convb = (const float*)d_in[5];
  const float* xpw   = (const float*)d_in[6];
  const float* dtpw  = (const float*)d_in[7];
  const float* dtpb  = (const float*)d_in[8];
  const float* Alog  = (const float*)d_in[9];
  const float* Dp    = (const float*)d_in[10];
  const float* outw  = (const float*)d_in[11];
  const float* normw = (const float*)d_in[12];
  const float* normb = (const float*)d_in[13];
  const float* headw = (const float*)d_in[14];
  const float* headb = (const float*)d_in[15];

  float* ws = (float*)d_ws;
  float* X      = ws;                         // 4096*1024
  float* h      = X + (size_t)BL * D_MODEL;   // 4096*1024 (LN out; scan scratch)
  float* xz     = h + (size_t)BL * D_MODEL;   // 4096*4096
  float* xc     = xz + (size_t)BL * 2 * D_INNER;  // 4096*2048
  float* xdbl   = xc + (size_t)BL * D_INNER;  // 4096*96
  float* dty    = xdbl + (size_t)BL * 96;     // 4096*2048 (dt, then y in-place)
  float* pooled = dty + (size_t)BL * D_INNER; // 4*1024
  // scan scratch overlays h (free between in_proj GEMM and next layernorm):
  float* hend  = h;                           // B*CH*D_INNER*16 = 2,097,152
  float* sumdt = h + (size_t)BB * CH * D_INNER * D_STATE;  // 131,072

  hipMemcpyAsync(X, x0, (size_t)BL * D_MODEL * sizeof(float),
                 hipMemcpyDeviceToDevice, stream);

  for (int layer = 0; layer < N_LAYERS; ++layer) {
    layernorm_k<<<BL, 256, 0, stream>>>(X, ln1w + layer * D_MODEL,
                                        ln1b + layer * D_MODEL, h);
    // xz = h @ in_w^T : M=4096 N=4096 K=1024
    sgemm_nt<128,128,16,8,8,0><<<dim3(4096/128, 4096/128), 256, 0, stream>>>(
        h, inw + (size_t)layer * 2 * D_INNER * D_MODEL, xz,
        BL, 2 * D_INNER, D_MODEL, D_MODEL, D_MODEL, 2 * D_INNER,
        nullptr, nullptr, 0);
    conv_silu_k<<<(BL * D_INNER) / 256, 256, 0, stream>>>(
        xz, convw + layer * D_INNER * D_CONV, convb + layer * D_INNER, xc);
    // x_dbl = xc @ xp_w^T : M=4096 N=96 K=2048
    sgemm_nt<128,32,32,8,2,0><<<dim3(96/32, 4096/128), 256, 0, stream>>>(
        xc, xpw + (size_t)layer * 96 * D_INNER, xdbl,
        BL, 96, D_INNER, D_INNER, D_INNER, 96, nullptr, nullptr, 0);
    // dt = softplus(dt_r @ dtp_w^T + dtp_b) : M=4096 N=2048 K=64 (lda=96)
    sgemm_nt<128,128,16,8,8,1><<<dim3(2048/128, 4096/128), 256, 0, stream>>>(
        xdbl, dtpw + (size_t)layer * D_INNER * DT_RANK, dty,
        BL, D_INNER, DT_RANK, 96, DT_RANK, D_INNER,
        dtpb + layer * D_INNER, nullptr, 0);
    // chunked scan: pass1 (free chunk scan) -> fix (cross-chunk prefix)
    //               -> pass3 (replay + y + fused SiLU(z) gate)
    scan_pass1_k<<<dim3(D_INNER / 256, CH, BB), 256, 0, stream>>>(
        dty, xc, xdbl, Alog + (size_t)layer * D_INNER * D_STATE, hend, sumdt);
    scan_fix_k<<<(BB * D_INNER * D_STATE) / 256, 256, 0, stream>>>(
        hend, sumdt, Alog + (size_t)layer * D_INNER * D_STATE);
    scan_pass3_k<<<dim3(D_INNER / 256, CH, BB), 256, 0, stream>>>(
        dty, xc, xdbl, xz, hend, Alog + (size_t)layer * D_INNER * D_STATE,
        Dp + layer * D_INNER);
    // X = X + y @ out_w^T : M=4096 N=1024 K=2048
    sgemm_nt<128,128,16,8,8,2><<<dim3(1024/128, 4096/128), 256, 0, stream>>>(
        dty, outw + (size_t)layer * D_MODEL * D_INNER, X,
        BL, D_MODEL, D_INNER, D_INNER, D_INNER, D_MODEL,
        nullptr, X, D_MODEL);
  }

  layernorm_k<<<BL, 256, 0, stream>>>(X, normw, normb, h);
  pool_k<<<dim3(D_MODEL / 256, BB), 256, 0, stream>>>(h, pooled);
  head_k<<<BB * N_CLASSES, 64, 0, stream>>>(pooled, headw, headb, (float*)d_out);
}

// Round 4
// 1213.369 us; speedup vs baseline: 2.5947x; 1.6287x over previous
//
#include <hip/hip_runtime.h>
#include <hip/hip_bf16.h>

#define N_LAYERS 2
#define D_MODEL 1024
#define D_INNER 2048
#define D_STATE 16
#define D_CONV 4
#define DT_RANK 64
#define N_CLASSES 10
#define BB 4
#define LL 1024
#define BL (BB*LL)   // 4096 rows
#define CH 16        // scan chunks per sequence
#define CLEN (LL/CH) // 64 steps per chunk

typedef __attribute__((ext_vector_type(8))) short bf16x8;
typedef __attribute__((ext_vector_type(4))) float f32x4;

typedef const void __attribute__((address_space(1)))* gas_ptr;
typedef void __attribute__((address_space(3)))* las_ptr;
#define GLDS16(g, p) __builtin_amdgcn_global_load_lds((gas_ptr)(g), (las_ptr)(p), 16, 0, 0)

// ---- fp32 -> bf16 hi/lo split (RNE) -----------------------------------------
__device__ inline void split2(float x, unsigned short& hi, unsigned short& lo) {
  unsigned u = __float_as_uint(x);
  unsigned rh = (u + 0x7FFFu + ((u >> 16) & 1u)) & 0xFFFF0000u;
  hi = (unsigned short)(rh >> 16);
  float xl = x - __uint_as_float(rh);
  unsigned ul = __float_as_uint(xl);
  unsigned rl = (ul + 0x7FFFu + ((ul >> 16) & 1u)) & 0xFFFF0000u;
  lo = (unsigned short)(rl >> 16);
}

__global__ __launch_bounds__(256) void split_k(const float* __restrict__ in,
    unsigned short* __restrict__ hi, unsigned short* __restrict__ lo) {
  const int i = blockIdx.x * 256 + threadIdx.x;
  const float4 v = ((const float4*)in)[i];
  ushort4 h4, l4;
  split2(v.x, h4.x, l4.x); split2(v.y, h4.y, l4.y);
  split2(v.z, h4.z, l4.z); split2(v.w, h4.w, l4.w);
  ((ushort4*)hi)[i] = h4;
  ((ushort4*)lo)[i] = l4;
}

// ---------------- LayerNorm -> fp32 out ---------------------------------------
__global__ __launch_bounds__(256) void layernorm_k(const float* __restrict__ x,
    const float* __restrict__ w, const float* __restrict__ b,
    float* __restrict__ out) {
  const int row = blockIdx.x;
  const int t = threadIdx.x;
  const float4 v = *(const float4*)(x + (size_t)row * D_MODEL + t * 4);
  float s = v.x + v.y + v.z + v.w;
  float q = v.x*v.x + v.y*v.y + v.z*v.z + v.w*v.w;
  #pragma unroll
  for (int o = 32; o; o >>= 1) { s += __shfl_down(s, o); q += __shfl_down(q, o); }
  __shared__ float red[8];
  if ((t & 63) == 0) { red[t >> 6] = s; red[4 + (t >> 6)] = q; }
  __syncthreads();
  s = red[0] + red[1] + red[2] + red[3];
  q = red[4] + red[5] + red[6] + red[7];
  const float mean = s * (1.f / D_MODEL);
  const float var  = q * (1.f / D_MODEL) - mean * mean;
  const float rstd = rsqrtf(var + 1e-5f);
  const float4 wv = *(const float4*)(w + t * 4);
  const float4 bv = *(const float4*)(b + t * 4);
  float4 o4;
  o4.x = (v.x - mean) * rstd * wv.x + bv.x;
  o4.y = (v.y - mean) * rstd * wv.y + bv.y;
  o4.z = (v.z - mean) * rstd * wv.z + bv.z;
  o4.w = (v.w - mean) * rstd * wv.w + bv.w;
  *(float4*)(out + (size_t)row * D_MODEL + t * 4) = o4;
}

// ---------------- LayerNorm -> bf16 hi/lo out ---------------------------------
__global__ __launch_bounds__(256) void layernorm_split_k(const float* __restrict__ x,
    const float* __restrict__ w, const float* __restrict__ b,
    unsigned short* __restrict__ oh, unsigned short* __restrict__ ol) {
  const int row = blockIdx.x;
  const int t = threadIdx.x;
  const float4 v = *(const float4*)(x + (size_t)row * D_MODEL + t * 4);
  float s = v.x + v.y + v.z + v.w;
  float q = v.x*v.x + v.y*v.y + v.z*v.z + v.w*v.w;
  #pragma unroll
  for (int o = 32; o; o >>= 1) { s += __shfl_down(s, o); q += __shfl_down(q, o); }
  __shared__ float red[8];
  if ((t & 63) == 0) { red[t >> 6] = s; red[4 + (t >> 6)] = q; }
  __syncthreads();
  s = red[0] + red[1] + red[2] + red[3];
  q = red[4] + red[5] + red[6] + red[7];
  const float mean = s * (1.f / D_MODEL);
  const float var  = q * (1.f / D_MODEL) - mean * mean;
  const float rstd = rsqrtf(var + 1e-5f);
  const float4 wv = *(const float4*)(w + t * 4);
  const float4 bv = *(const float4*)(b + t * 4);
  float4 o4;
  o4.x = (v.x - mean) * rstd * wv.x + bv.x;
  o4.y = (v.y - mean) * rstd * wv.y + bv.y;
  o4.z = (v.z - mean) * rstd * wv.z + bv.z;
  o4.w = (v.w - mean) * rstd * wv.w + bv.w;
  ushort4 h4, l4;
  split2(o4.x, h4.x, l4.x); split2(o4.y, h4.y, l4.y);
  split2(o4.z, h4.z, l4.z); split2(o4.w, h4.w, l4.w);
  ((ushort4*)(oh + (size_t)row * D_MODEL))[t] = h4;
  ((ushort4*)(ol + (size_t)row * D_MODEL))[t] = l4;
}

// ---- split-bf16 MFMA GEMM NT: C[m,n] = sum_k A[m,k]*B[n,k] (+resid) ---------
// A = Ah+Al, B = Bh+Bl; computes Ah*Bh + Al*Bh + Ah*Bl (3 K-segments).
// 128x128 tile, BK=64, 4 waves, 4x4 16x16x32 fragments per wave.
template<int EPI>  // 0: C=acc ; 2: C=acc+resid
__global__ __launch_bounds__(256) void mfma_gemm_nt(
    const unsigned short* __restrict__ Ah, const unsigned short* __restrict__ Al,
    const unsigned short* __restrict__ Bh, const unsigned short* __restrict__ Bl,
    float* __restrict__ C, const float* __restrict__ resid,
    int M, int N, int K, int ldc) {
  __shared__ unsigned short As[128 * 64];
  __shared__ unsigned short Bs[128 * 64];
  const int tid = threadIdx.x;
  const int w = tid >> 6, l = tid & 63;
  const int wr = w >> 1, wc = w & 1;
  const int m0 = blockIdx.y * 128, n0 = blockIdx.x * 128;
  const int srow = l >> 3;             // staging row within 8-row block
  const int scol = (l & 7) * 8;        // staging col (elements)
  const int fr = l & 15;               // fragment row
  const int fk = (l >> 4) * 8;         // fragment k offset
  f32x4 acc[4][4] = {};

  #pragma unroll 1
  for (int seg = 0; seg < 3; ++seg) {
    const unsigned short* Asrc = (seg == 1) ? Al : Ah;
    const unsigned short* Bsrc = (seg == 2) ? Bl : Bh;
    #pragma unroll 1
    for (int k0 = 0; k0 < K; k0 += 64) {
      __syncthreads();                  // previous compute done before overwrite
      #pragma unroll
      for (int it = 0; it < 4; ++it) {
        const int bi = it * 4 + w;      // 1 KB block id 0..15
        const int row = bi * 8 + srow;
        GLDS16(Asrc + (size_t)(m0 + row) * K + k0 + scol, &As[bi * 512 + l * 8]);
        GLDS16(Bsrc + (size_t)(n0 + row) * K + k0 + scol, &Bs[bi * 512 + l * 8]);
      }
      __syncthreads();                  // staging visible (vmcnt drained)
      #pragma unroll
      for (int kk = 0; kk < 64; kk += 32) {
        bf16x8 a[4], b[4];
        #pragma unroll
        for (int f = 0; f < 4; ++f)
          a[f] = *(const bf16x8*)&As[(wr * 64 + f * 16 + fr) * 64 + kk + fk];
        #pragma unroll
        for (int f = 0; f < 4; ++f)
          b[f] = *(const bf16x8*)&Bs[(wc * 64 + f * 16 + fr) * 64 + kk + fk];
        #pragma unroll
        for (int i = 0; i < 4; ++i)
          #pragma unroll
          for (int j = 0; j < 4; ++j)
            acc[i][j] = __builtin_amdgcn_mfma_f32_16x16x32_bf16(
                a[i], b[j], acc[i][j], 0, 0, 0);
      }
    }
  }
  const int orow = (l >> 4) * 4;
  const int ocol = l & 15;
  #pragma unroll
  for (int i = 0; i < 4; ++i)
    #pragma unroll
    for (int j = 0; j < 4; ++j)
      #pragma unroll
      for (int r = 0; r < 4; ++r) {
        const int m = m0 + wr * 64 + i * 16 + orow + r;
        const int n = n0 + wc * 64 + j * 16 + ocol;
        float v = acc[i][j][r];
        if constexpr (EPI == 2) v += resid[(size_t)m * ldc + n];
        C[(size_t)m * ldc + n] = v;
      }
}

// ---------------- fp32 SGEMM NT (small GEMMs) --------------------------------
// EPI: 0 none; 1 softplus(acc + bias[n])
template<int BM, int BN, int BK, int TM, int TN, int EPI>
__global__ __launch_bounds__(256) void sgemm_nt(
    const float* __restrict__ A, const float* __restrict__ B,
    float* __restrict__ C, int M, int N, int K, int lda, int ldb, int ldc,
    const float* __restrict__ bias) {
  constexpr int THREADS = 256;
  constexpr int NT = BN / TN;
  constexpr int K4 = BK / 4;
  constexpr int A_F4 = BM * BK / (THREADS * 4);
  constexpr int B_F4 = BN * BK / (THREADS * 4);
  static_assert((BM / TM) * (BN / TN) == THREADS, "thread shape");
  __shared__ float As[BK][BM + 4];
  __shared__ float Bs[BK][BN + 4];
  const int tid = threadIdx.x;
  const int m0 = blockIdx.y * BM;
  const int n0 = blockIdx.x * BN;
  const int tn = (tid % NT) * TN;
  const int tm = (tid / NT) * TM;
  float acc[TM][TN] = {};
  for (int k0 = 0; k0 < K; k0 += BK) {
    #pragma unroll
    for (int i = 0; i < A_F4; i++) {
      int li = tid + i * THREADS;
      int r = li / K4, c4 = li % K4;
      float4 v = *(const float4*)(A + (size_t)(m0 + r) * lda + k0 + c4 * 4);
      As[c4*4+0][r] = v.x; As[c4*4+1][r] = v.y; As[c4*4+2][r] = v.z; As[c4*4+3][r] = v.w;
    }
    #pragma unroll
    for (int i = 0; i < B_F4; i++) {
      int li = tid + i * THREADS;
      int r = li / K4, c4 = li % K4;
      float4 v = *(const float4*)(B + (size_t)(n0 + r) * ldb + k0 + c4 * 4);
      Bs[c4*4+0][r] = v.x; Bs[c4*4+1][r] = v.y; Bs[c4*4+2][r] = v.z; Bs[c4*4+3][r] = v.w;
    }
    __syncthreads();
    #pragma unroll
    for (int k = 0; k < BK; k++) {
      float a[TM], bf[TN];
      #pragma unroll
      for (int i = 0; i < TM; i++) a[i] = As[k][tm + i];
      #pragma unroll
      for (int j = 0; j < TN; j++) bf[j] = Bs[k][tn + j];
      #pragma unroll
      for (int i = 0; i < TM; i++)
        #pragma unroll
        for (int j = 0; j < TN; j++)
          acc[i][j] = fmaf(a[i], bf[j], acc[i][j]);
    }
    __syncthreads();
  }
  #pragma unroll
  for (int i = 0; i < TM; i++) {
    const int m = m0 + tm + i;
    #pragma unroll
    for (int j = 0; j < TN; j++) {
      const int n = n0 + tn + j;
      float v = acc[i][j];
      if constexpr (EPI == 1) {
        v += bias[n];
        v = (v > 20.f) ? v : log1pf(__expf(v));
      }
      C[(size_t)m * ldc + n] = v;
    }
  }
}

// ---------------- causal depthwise conv (width 4) + SiLU --------------------
__global__ __launch_bounds__(256) void conv_silu_k(const float* __restrict__ xz,
    const float* __restrict__ cw, const float* __restrict__ cb,
    float* __restrict__ xc) {
  const int gid = blockIdx.x * 256 + threadIdx.x;
  const int c = gid & (D_INNER - 1);
  const int l = (gid >> 11) & (LL - 1);
  const int b = gid >> 21;
  const float4 w = *(const float4*)(cw + c * 4);
  const float* base = xz + ((size_t)(b << 10) + l) * (2 * D_INNER) + c;
  float acc = cb[c];
  acc = fmaf(w.w, base[0], acc);
  if (l >= 1) acc = fmaf(w.z, base[-(2 * D_INNER)], acc);
  if (l >= 2) acc = fmaf(w.y, base[-2 * (2 * D_INNER)], acc);
  if (l >= 3) acc = fmaf(w.x, base[-3 * (2 * D_INNER)], acc);
  xc[gid] = acc / (1.f + __expf(-acc));
}

// ------- chunked selective scan, pass 1 --------------------------------------
__global__ __launch_bounds__(256) void scan_pass1_k(
    const float* __restrict__ dt, const float* __restrict__ xc,
    const float* __restrict__ xdbl, const float* __restrict__ A_log,
    float* __restrict__ hend, float* __restrict__ sumdt) {
  const int c = blockIdx.x * 256 + threadIdx.x;
  const int k = blockIdx.y;
  const int b = blockIdx.z;
  float Ac[D_STATE];
  #pragma unroll
  for (int n = 0; n < D_STATE; n++) Ac[n] = -__expf(A_log[c * D_STATE + n]);
  float h[D_STATE] = {};
  float sd = 0.f;
  const size_t r0 = (size_t)b * LL + (size_t)k * CLEN;
  const float* dtp = dt + r0 * D_INNER + c;
  const float* xcp = xc + r0 * D_INNER + c;
  const float* Bp  = xdbl + r0 * 96 + DT_RANK;

  float dtv = dtp[0];
  float xv  = xcp[0];
  float4 B0 = *(const float4*)(Bp + 0);
  float4 B1 = *(const float4*)(Bp + 4);
  float4 B2 = *(const float4*)(Bp + 8);
  float4 B3 = *(const float4*)(Bp + 12);
  for (int l = 0; l < CLEN; l++) {
    const int lp = (l + 1 < CLEN) ? l + 1 : l;
    const float dtv2 = dtp[(size_t)lp * D_INNER];
    const float xv2  = xcp[(size_t)lp * D_INNER];
    const float4 B0n = *(const float4*)(Bp + (size_t)lp * 96 + 0);
    const float4 B1n = *(const float4*)(Bp + (size_t)lp * 96 + 4);
    const float4 B2n = *(const float4*)(Bp + (size_t)lp * 96 + 8);
    const float4 B3n = *(const float4*)(Bp + (size_t)lp * 96 + 12);
    sd += dtv;
    const float dx = dtv * xv;
    const float Bv[D_STATE] = {B0.x,B0.y,B0.z,B0.w, B1.x,B1.y,B1.z,B1.w,
                               B2.x,B2.y,B2.z,B2.w, B3.x,B3.y,B3.z,B3.w};
    #pragma unroll
    for (int n = 0; n < D_STATE; n++)
      h[n] = fmaf(__expf(dtv * Ac[n]), h[n], dx * Bv[n]);
    dtv = dtv2; xv = xv2; B0 = B0n; B1 = B1n; B2 = B2n; B3 = B3n;
  }
  float* he = hend + (((size_t)(b * CH + k) * D_INNER + c) << 4);
  #pragma unroll
  for (int n = 0; n < D_STATE; n += 4)
    *(float4*)(he + n) = make_float4(h[n], h[n+1], h[n+2], h[n+3]);
  sumdt[(size_t)(b * CH + k) * D_INNER + c] = sd;
}

// ------- chunked scan fixup ---------------------------------------------------
__global__ __launch_bounds__(256) void scan_fix_k(
    float* __restrict__ hend, const float* __restrict__ sumdt,
    const float* __restrict__ A_log) {
  const int gid = blockIdx.x * 256 + threadIdx.x;
  const int n = gid & 15;
  const int c = (gid >> 4) & (D_INNER - 1);
  const int b = gid >> 15;
  const float Ac = -__expf(A_log[c * D_STATE + n]);
  float hrun = 0.f;
  for (int k = 0; k < CH; k++) {
    const size_t base = (size_t)(b * CH + k) * D_INNER + c;
    const float sd = sumdt[base];
    float* hp = hend + (base << 4) + n;
    const float tmp = *hp;
    *hp = hrun;
    hrun = fmaf(__expf(Ac * sd), hrun, tmp);
  }
}

// ------- chunked scan pass 3: replay, gate, emit y as bf16 hi/lo -------------
__global__ __launch_bounds__(256) void scan_pass3_k(
    const float* __restrict__ dt, const float* __restrict__ xc,
    const float* __restrict__ xdbl, const float* __restrict__ xz,
    const float* __restrict__ h0, const float* __restrict__ A_log,
    const float* __restrict__ Dp,
    unsigned short* __restrict__ yh, unsigned short* __restrict__ yl) {
  const int c = blockIdx.x * 256 + threadIdx.x;
  const int k = blockIdx.y;
  const int b = blockIdx.z;
  float Ac[D_STATE];
  #pragma unroll
  for (int n = 0; n < D_STATE; n++) Ac[n] = -__expf(A_log[c * D_STATE + n]);
  const float Dv = Dp[c];
  float h[D_STATE];
  const float* hp = h0 + (((size_t)(b * CH + k) * D_INNER + c) << 4);
  #pragma unroll
  for (int n = 0; n < D_STATE; n += 4) {
    const float4 v = *(const float4*)(hp + n);
    h[n] = v.x; h[n+1] = v.y; h[n+2] = v.z; h[n+3] = v.w;
  }
  const size_t r0 = (size_t)b * LL + (size_t)k * CLEN;
  const float* dtp = dt + r0 * D_INNER + c;
  const float* xcp = xc + r0 * D_INNER + c;
  const float* Bp  = xdbl + r0 * 96 + DT_RANK;
  const float* zp  = xz + r0 * (size_t)(2 * D_INNER) + D_INNER + c;
  unsigned short* yhp = yh + r0 * D_INNER + c;
  unsigned short* ylp = yl + r0 * D_INNER + c;

  float dtv = dtp[0];
  float xv  = xcp[0];
  float zv  = zp[0];
  float4 B0 = *(const float4*)(Bp + 0);
  float4 B1 = *(const float4*)(Bp + 4);
  float4 B2 = *(const float4*)(Bp + 8);
  float4 B3 = *(const float4*)(Bp + 12);
  float4 C0 = *(const float4*)(Bp + 16);
  float4 C1 = *(const float4*)(Bp + 20);
  float4 C2 = *(const float4*)(Bp + 24);
  float4 C3 = *(const float4*)(Bp + 28);
  for (int l = 0; l < CLEN; l++) {
    const int lp = (l + 1 < CLEN) ? l + 1 : l;
    const float dtv2 = dtp[(size_t)lp * D_INNER];
    const float xv2  = xcp[(size_t)lp * D_INNER];
    const float zv2  = zp[(size_t)lp * 2 * D_INNER];
    const float4 B0n = *(const float4*)(Bp + (size_t)lp * 96 + 0);
    const float4 B1n = *(const float4*)(Bp + (size_t)lp * 96 + 4);
    const float4 B2n = *(const float4*)(Bp + (size_t)lp * 96 + 8);
    const float4 B3n = *(const float4*)(Bp + (size_t)lp * 96 + 12);
    const float4 C0n = *(const float4*)(Bp + (size_t)lp * 96 + 16);
    const float4 C1n = *(const float4*)(Bp + (size_t)lp * 96 + 20);
    const float4 C2n = *(const float4*)(Bp + (size_t)lp * 96 + 24);
    const float4 C3n = *(const float4*)(Bp + (size_t)lp * 96 + 28);
    const float dx = dtv * xv;
    const float Bv[D_STATE] = {B0.x,B0.y,B0.z,B0.w, B1.x,B1.y,B1.z,B1.w,
                               B2.x,B2.y,B2.z,B2.w, B3.x,B3.y,B3.z,B3.w};
    const float Cv[D_STATE] = {C0.x,C0.y,C0.z,C0.w, C1.x,C1.y,C1.z,C1.w,
                               C2.x,C2.y,C2.z,C2.w, C3.x,C3.y,C3.z,C3.w};
    float y = 0.f;
    #pragma unroll
    for (int n = 0; n < D_STATE; n++) {
      h[n] = fmaf(__expf(dtv * Ac[n]), h[n], dx * Bv[n]);
      y = fmaf(h[n], Cv[n], y);
    }
    y = fmaf(xv, Dv, y);
    y *= zv / (1.f + __expf(-zv));
    unsigned short uh, ul;
    split2(y, uh, ul);
    yhp[(size_t)l * D_INNER] = uh;
    ylp[(size_t)l * D_INNER] = ul;
    dtv = dtv2; xv = xv2; zv = zv2;
    B0 = B0n; B1 = B1n; B2 = B2n; B3 = B3n;
    C0 = C0n; C1 = C1n; C2 = C2n; C3 = C3n;
  }
}

// ---------------- mean pool over L ------------------------------------------
__global__ __launch_bounds__(256) void pool_k(const float* __restrict__ h,
    float* __restrict__ pooled) {
  const int d = blockIdx.x * 256 + threadIdx.x;
  const int b = blockIdx.y;
  float s = 0.f;
  for (int l = 0; l < LL; l++) s += h[((size_t)(b * LL + l)) * D_MODEL + d];
  pooled[b * D_MODEL + d] = s * (1.f / LL);
}

// ---------------- classifier head --------------------------------------------
__global__ __launch_bounds__(64) void head_k(const float* __restrict__ pooled,
    const float* __restrict__ hw, const float* __restrict__ hb,
    float* __restrict__ out) {
  const int b = blockIdx.x / N_CLASSES;
  const int j = blockIdx.x % N_CLASSES;
  float s = 0.f;
  for (int k = threadIdx.x; k < D_MODEL; k += 64)
    s = fmaf(pooled[b * D_MODEL + k], hw[j * D_MODEL + k], s);
  #pragma unroll
  for (int o = 32; o; o >>= 1) s += __shfl_down(s, o);
  if (threadIdx.x == 0) out[b * N_CLASSES + j] = s + hb[j];
}

extern "C" void kernel_launch(void* const* d_in, const int* in_sizes, int n_in,
                              void* d_out, int out_size, void* d_ws, size_t ws_size,
                              hipStream_t stream) {
  const float* x0    = (const float*)d_in[0];
  const float* ln1w  = (const float*)d_in[1];
  const float* ln1b  = (const float*)d_in[2];
  const float* inw   = (const float*)d_in[3];
  const float* convw = (const float*)d_in[4];
  const float* convb = (const float*)d_in[5];
  const float* xpw   = (const float*)d_in[6];
  const float* dtpw  = (const float*)d_in[7];
  const float* dtpb  = (const float*)d_in[8];
  const float* Alog  = (const float*)d_in[9];
  const float* Dp    = (const float*)d_in[10];
  const float* outw  = (const float*)d_in[11];
  const float* normw = (const float*)d_in[12];
  const float* normb = (const float*)d_in[13];
  const float* headw = (const float*)d_in[14];
  const float* headb = (const float*)d_in[15];

  float* ws = (float*)d_ws;
  size_t f = 0;
  float* X      = ws + f; f += (size_t)BL * D_MODEL;        // 4M
  float* xz     = ws + f; f += (size_t)BL * 2 * D_INNER;    // 16M
  float* xc     = ws + f; f += (size_t)BL * D_INNER;        // 8M
  float* xdbl   = ws + f; f += (size_t)BL * 96;             // 0.375M
  float* dty    = ws + f; f += (size_t)BL * D_INNER;        // 8M (dt; final-LN scratch)
  float* pooled = ws + f; f += 4096;
  float* hend   = ws + f; f += (size_t)BB * CH * D_INNER * D_STATE;  // 2M
  float* sumdt  = ws + f; f += (size_t)BB * CH * D_INNER;            // 0.125M
  unsigned short* hh  = (unsigned short*)(ws + f); f += (size_t)BL * D_MODEL / 2;
  unsigned short* hl  = (unsigned short*)(ws + f); f += (size_t)BL * D_MODEL / 2;
  unsigned short* yh  = (unsigned short*)(ws + f); f += (size_t)BL * D_INNER / 2;
  unsigned short* yl  = (unsigned short*)(ws + f); f += (size_t)BL * D_INNER / 2;
  unsigned short* wih = (unsigned short*)(ws + f); f += (size_t)2 * D_INNER * D_MODEL / 2;
  unsigned short* wil = (unsigned short*)(ws + f); f += (size_t)2 * D_INNER * D_MODEL / 2;
  unsigned short* woh = (unsigned short*)(ws + f); f += (size_t)D_MODEL * D_INNER / 2;
  unsigned short* wol = (unsigned short*)(ws + f); f += (size_t)D_MODEL * D_INNER / 2;

  hipMemcpyAsync(X, x0, (size_t)BL * D_MODEL * sizeof(float),
                 hipMemcpyDeviceToDevice, stream);

  for (int layer = 0; layer < N_LAYERS; ++layer) {
    // LayerNorm -> bf16 hi/lo A-operand
    layernorm_split_k<<<BL, 256, 0, stream>>>(X, ln1w + layer * D_MODEL,
                                              ln1b + layer * D_MODEL, hh, hl);
    // split weights for this layer
    split_k<<<(2 * D_INNER * D_MODEL) / 1024, 256, 0, stream>>>(
        inw + (size_t)layer * 2 * D_INNER * D_MODEL, wih, wil);
    split_k<<<(D_MODEL * D_INNER) / 1024, 256, 0, stream>>>(
        outw + (size_t)layer * D_MODEL * D_INNER, woh, wol);
    // xz = h @ in_w^T : M=4096 N=4096 K=1024 (split-bf16 MFMA)
    mfma_gemm_nt<0><<<dim3(4096 / 128, 4096 / 128), 256, 0, stream>>>(
        hh, hl, wih, wil, xz, nullptr, BL, 2 * D_INNER, D_MODEL, 2 * D_INNER);
    conv_silu_k<<<(BL * D_INNER) / 256, 256, 0, stream>>>(
        xz, convw + layer * D_INNER * D_CONV, convb + layer * D_INNER, xc);
    // x_dbl = xc @ xp_w^T : M=4096 N=96 K=2048 (fp32)
    sgemm_nt<128,32,32,8,2,0><<<dim3(96 / 32, 4096 / 128), 256, 0, stream>>>(
        xc, xpw + (size_t)layer * 96 * D_INNER, xdbl,
        BL, 96, D_INNER, D_INNER, D_INNER, 96, nullptr);
    // dt = softplus(dt_r @ dtp_w^T + dtp_b) : M=4096 N=2048 K=64 (fp32)
    sgemm_nt<128,128,16,8,8,1><<<dim3(2048 / 128, 4096 / 128), 256, 0, stream>>>(
        xdbl, dtpw + (size_t)layer * D_INNER * DT_RANK, dty,
        BL, D_INNER, DT_RANK, 96, DT_RANK, D_INNER,
        dtpb + layer * D_INNER);
    // chunked scan
    scan_pass1_k<<<dim3(D_INNER / 256, CH, BB), 256, 0, stream>>>(
        dty, xc, xdbl, Alog + (size_t)layer * D_INNER * D_STATE, hend, sumdt);
    scan_fix_k<<<(BB * D_INNER * D_STATE) / 256, 256, 0, stream>>>(
        hend, sumdt, Alog + (size_t)layer * D_INNER * D_STATE);
    scan_pass3_k<<<dim3(D_INNER / 256, CH, BB), 256, 0, stream>>>(
        dty, xc, xdbl, xz, hend, Alog + (size_t)layer * D_INNER * D_STATE,
        Dp + layer * D_INNER, yh, yl);
    // X = X + y @ out_w^T : M=4096 N=1024 K=2048 (split-bf16 MFMA, in-place)
    mfma_gemm_nt<2><<<dim3(1024 / 128, 4096 / 128), 256, 0, stream>>>(
        yh, yl, woh, wol, X, X, BL, D_MODEL, D_INNER, D_MODEL);
  }

  layernorm_k<<<BL, 256, 0, stream>>>(X, normw, normb, dty);
  pool_k<<<dim3(D_MODEL / 256, BB), 256, 0, stream>>>(dty, pooled);
  head_k<<<BB * N_CLASSES, 64, 0, stream>>>(pooled, headw, headb, (float*)d_out);
}

// Round 5
// 1049.413 us; speedup vs baseline: 3.0001x; 1.1562x over previous
//
#include <hip/hip_runtime.h>
#include <hip/hip_bf16.h>

#define N_LAYERS 2
#define D_MODEL 1024
#define D_INNER 2048
#define D_STATE 16
#define D_CONV 4
#define DT_RANK 64
#define N_CLASSES 10
#define BB 4
#define LL 1024
#define BL (BB*LL)   // 4096 rows
#define CH 16        // scan chunks per sequence
#define CLEN (LL/CH) // 64 steps per chunk

typedef __attribute__((ext_vector_type(8))) short bf16x8;
typedef __attribute__((ext_vector_type(4))) float f32x4;

typedef const void __attribute__((address_space(1)))* gas_ptr;
typedef void __attribute__((address_space(3)))* las_ptr;
#define GLDS16(g, p) __builtin_amdgcn_global_load_lds((gas_ptr)(g), (las_ptr)(p), 16, 0, 0)

// ---- fp32 -> bf16 hi/lo split (RNE) -----------------------------------------
__device__ inline void split2(float x, unsigned short& hi, unsigned short& lo) {
  unsigned u = __float_as_uint(x);
  unsigned rh = (u + 0x7FFFu + ((u >> 16) & 1u)) & 0xFFFF0000u;
  hi = (unsigned short)(rh >> 16);
  float xl = x - __uint_as_float(rh);
  unsigned ul = __float_as_uint(xl);
  unsigned rl = (ul + 0x7FFFu + ((ul >> 16) & 1u)) & 0xFFFF0000u;
  lo = (unsigned short)(rl >> 16);
}

__device__ inline unsigned short rnd_bf16(float x) {
  unsigned u = __float_as_uint(x);
  return (unsigned short)((u + 0x7FFFu + ((u >> 16) & 1u)) >> 16);
}

// round weights to bf16 (hi only)
__global__ __launch_bounds__(256) void round_k(const float* __restrict__ in,
    unsigned short* __restrict__ hi) {
  const int i = blockIdx.x * 256 + threadIdx.x;
  const float4 v = ((const float4*)in)[i];
  ushort4 h4;
  h4.x = rnd_bf16(v.x); h4.y = rnd_bf16(v.y);
  h4.z = rnd_bf16(v.z); h4.w = rnd_bf16(v.w);
  ((ushort4*)hi)[i] = h4;
}

// ---------------- LayerNorm -> fp32 out ---------------------------------------
__global__ __launch_bounds__(256) void layernorm_k(const float* __restrict__ x,
    const float* __restrict__ w, const float* __restrict__ b,
    float* __restrict__ out) {
  const int row = blockIdx.x;
  const int t = threadIdx.x;
  const float4 v = *(const float4*)(x + (size_t)row * D_MODEL + t * 4);
  float s = v.x + v.y + v.z + v.w;
  float q = v.x*v.x + v.y*v.y + v.z*v.z + v.w*v.w;
  #pragma unroll
  for (int o = 32; o; o >>= 1) { s += __shfl_down(s, o); q += __shfl_down(q, o); }
  __shared__ float red[8];
  if ((t & 63) == 0) { red[t >> 6] = s; red[4 + (t >> 6)] = q; }
  __syncthreads();
  s = red[0] + red[1] + red[2] + red[3];
  q = red[4] + red[5] + red[6] + red[7];
  const float mean = s * (1.f / D_MODEL);
  const float var  = q * (1.f / D_MODEL) - mean * mean;
  const float rstd = rsqrtf(var + 1e-5f);
  const float4 wv = *(const float4*)(w + t * 4);
  const float4 bv = *(const float4*)(b + t * 4);
  float4 o4;
  o4.x = (v.x - mean) * rstd * wv.x + bv.x;
  o4.y = (v.y - mean) * rstd * wv.y + bv.y;
  o4.z = (v.z - mean) * rstd * wv.z + bv.z;
  o4.w = (v.w - mean) * rstd * wv.w + bv.w;
  *(float4*)(out + (size_t)row * D_MODEL + t * 4) = o4;
}

// ---------------- LayerNorm -> bf16 hi/lo out ---------------------------------
__global__ __launch_bounds__(256) void layernorm_split_k(const float* __restrict__ x,
    const float* __restrict__ w, const float* __restrict__ b,
    unsigned short* __restrict__ oh, unsigned short* __restrict__ ol) {
  const int row = blockIdx.x;
  const int t = threadIdx.x;
  const float4 v = *(const float4*)(x + (size_t)row * D_MODEL + t * 4);
  float s = v.x + v.y + v.z + v.w;
  float q = v.x*v.x + v.y*v.y + v.z*v.z + v.w*v.w;
  #pragma unroll
  for (int o = 32; o; o >>= 1) { s += __shfl_down(s, o); q += __shfl_down(q, o); }
  __shared__ float red[8];
  if ((t & 63) == 0) { red[t >> 6] = s; red[4 + (t >> 6)] = q; }
  __syncthreads();
  s = red[0] + red[1] + red[2] + red[3];
  q = red[4] + red[5] + red[6] + red[7];
  const float mean = s * (1.f / D_MODEL);
  const float var  = q * (1.f / D_MODEL) - mean * mean;
  const float rstd = rsqrtf(var + 1e-5f);
  const float4 wv = *(const float4*)(w + t * 4);
  const float4 bv = *(const float4*)(b + t * 4);
  float4 o4;
  o4.x = (v.x - mean) * rstd * wv.x + bv.x;
  o4.y = (v.y - mean) * rstd * wv.y + bv.y;
  o4.z = (v.z - mean) * rstd * wv.z + bv.z;
  o4.w = (v.w - mean) * rstd * wv.w + bv.w;
  ushort4 h4, l4;
  split2(o4.x, h4.x, l4.x); split2(o4.y, h4.y, l4.y);
  split2(o4.z, h4.z, l4.z); split2(o4.w, h4.w, l4.w);
  ((ushort4*)(oh + (size_t)row * D_MODEL))[t] = h4;
  ((ushort4*)(ol + (size_t)row * D_MODEL))[t] = l4;
}

// ---- split-bf16 MFMA GEMM NT: C[m,n] = sum_k A[m,k]*B[n,k] (+resid) ---------
// A = Ah+Al (hi/lo bf16), B = Bh (bf16); computes Ah*Bh + Al*Bh (2 K-segments).
// Dropped (A-Ah-Al)*B + A*(B-Bh) ~ 2^-9 rel: measured final absmax ~1e-5 vs
// 8.7e-4 threshold. 128x128 tile, BK=64, 4 waves, 4x4 16x16x32 fragments.
template<int EPI>  // 0: C=acc ; 2: C=acc+resid
__global__ __launch_bounds__(256) void mfma_gemm_nt(
    const unsigned short* __restrict__ Ah, const unsigned short* __restrict__ Al,
    const unsigned short* __restrict__ Bh,
    float* __restrict__ C, const float* __restrict__ resid,
    int M, int N, int K, int ldc) {
  __shared__ unsigned short As[128 * 64];
  __shared__ unsigned short Bs[128 * 64];
  const int tid = threadIdx.x;
  const int w = tid >> 6, l = tid & 63;
  const int wr = w >> 1, wc = w & 1;
  const int m0 = blockIdx.y * 128, n0 = blockIdx.x * 128;
  const int srow = l >> 3;             // staging row within 8-row block
  const int scol = (l & 7) * 8;        // staging col (elements)
  const int fr = l & 15;               // fragment row
  const int fk = (l >> 4) * 8;         // fragment k offset
  f32x4 acc[4][4] = {};

  #pragma unroll 1
  for (int seg = 0; seg < 2; ++seg) {
    const unsigned short* Asrc = (seg == 1) ? Al : Ah;
    #pragma unroll 1
    for (int k0 = 0; k0 < K; k0 += 64) {
      __syncthreads();                  // previous compute done before overwrite
      #pragma unroll
      for (int it = 0; it < 4; ++it) {
        const int bi = it * 4 + w;      // 1 KB block id 0..15
        const int row = bi * 8 + srow;
        GLDS16(Asrc + (size_t)(m0 + row) * K + k0 + scol, &As[bi * 512 + l * 8]);
        GLDS16(Bh + (size_t)(n0 + row) * K + k0 + scol, &Bs[bi * 512 + l * 8]);
      }
      __syncthreads();                  // staging visible (vmcnt drained)
      #pragma unroll
      for (int kk = 0; kk < 64; kk += 32) {
        bf16x8 a[4], b[4];
        #pragma unroll
        for (int f = 0; f < 4; ++f)
          a[f] = *(const bf16x8*)&As[(wr * 64 + f * 16 + fr) * 64 + kk + fk];
        #pragma unroll
        for (int f = 0; f < 4; ++f)
          b[f] = *(const bf16x8*)&Bs[(wc * 64 + f * 16 + fr) * 64 + kk + fk];
        #pragma unroll
        for (int i = 0; i < 4; ++i)
          #pragma unroll
          for (int j = 0; j < 4; ++j)
            acc[i][j] = __builtin_amdgcn_mfma_f32_16x16x32_bf16(
                a[i], b[j], acc[i][j], 0, 0, 0);
      }
    }
  }
  const int orow = (l >> 4) * 4;
  const int ocol = l & 15;
  #pragma unroll
  for (int i = 0; i < 4; ++i)
    #pragma unroll
    for (int j = 0; j < 4; ++j)
      #pragma unroll
      for (int r = 0; r < 4; ++r) {
        const int m = m0 + wr * 64 + i * 16 + orow + r;
        const int n = n0 + wc * 64 + j * 16 + ocol;
        float v = acc[i][j][r];
        if constexpr (EPI == 2) v += resid[(size_t)m * ldc + n];
        C[(size_t)m * ldc + n] = v;
      }
}

// ---------------- fp32 SGEMM NT (small GEMMs) --------------------------------
// EPI: 0 none; 1 softplus(acc + bias[n])
template<int BM, int BN, int BK, int TM, int TN, int EPI>
__global__ __launch_bounds__(256) void sgemm_nt(
    const float* __restrict__ A, const float* __restrict__ B,
    float* __restrict__ C, int M, int N, int K, int lda, int ldb, int ldc,
    const float* __restrict__ bias) {
  constexpr int THREADS = 256;
  constexpr int NT = BN / TN;
  constexpr int K4 = BK / 4;
  constexpr int A_F4 = BM * BK / (THREADS * 4);
  constexpr int B_F4 = BN * BK / (THREADS * 4);
  static_assert((BM / TM) * (BN / TN) == THREADS, "thread shape");
  __shared__ float As[BK][BM + 4];
  __shared__ float Bs[BK][BN + 4];
  const int tid = threadIdx.x;
  const int m0 = blockIdx.y * BM;
  const int n0 = blockIdx.x * BN;
  const int tn = (tid % NT) * TN;
  const int tm = (tid / NT) * TM;
  float acc[TM][TN] = {};
  for (int k0 = 0; k0 < K; k0 += BK) {
    #pragma unroll
    for (int i = 0; i < A_F4; i++) {
      int li = tid + i * THREADS;
      int r = li / K4, c4 = li % K4;
      float4 v = *(const float4*)(A + (size_t)(m0 + r) * lda + k0 + c4 * 4);
      As[c4*4+0][r] = v.x; As[c4*4+1][r] = v.y; As[c4*4+2][r] = v.z; As[c4*4+3][r] = v.w;
    }
    #pragma unroll
    for (int i = 0; i < B_F4; i++) {
      int li = tid + i * THREADS;
      int r = li / K4, c4 = li % K4;
      float4 v = *(const float4*)(B + (size_t)(n0 + r) * ldb + k0 + c4 * 4);
      Bs[c4*4+0][r] = v.x; Bs[c4*4+1][r] = v.y; Bs[c4*4+2][r] = v.z; Bs[c4*4+3][r] = v.w;
    }
    __syncthreads();
    #pragma unroll
    for (int k = 0; k < BK; k++) {
      float a[TM], bf[TN];
      #pragma unroll
      for (int i = 0; i < TM; i++) a[i] = As[k][tm + i];
      #pragma unroll
      for (int j = 0; j < TN; j++) bf[j] = Bs[k][tn + j];
      #pragma unroll
      for (int i = 0; i < TM; i++)
        #pragma unroll
        for (int j = 0; j < TN; j++)
          acc[i][j] = fmaf(a[i], bf[j], acc[i][j]);
    }
    __syncthreads();
  }
  #pragma unroll
  for (int i = 0; i < TM; i++) {
    const int m = m0 + tm + i;
    #pragma unroll
    for (int j = 0; j < TN; j++) {
      const int n = n0 + tn + j;
      float v = acc[i][j];
      if constexpr (EPI == 1) {
        v += bias[n];
        v = (v > 20.f) ? v : log1pf(__expf(v));
      }
      C[(size_t)m * ldc + n] = v;
    }
  }
}

// ---------------- causal depthwise conv (width 4) + SiLU --------------------
__global__ __launch_bounds__(256) void conv_silu_k(const float* __restrict__ xz,
    const float* __restrict__ cw, const float* __restrict__ cb,
    float* __restrict__ xc) {
  const int gid = blockIdx.x * 256 + threadIdx.x;
  const int c = gid & (D_INNER - 1);
  const int l = (gid >> 11) & (LL - 1);
  const int b = gid >> 21;
  const float4 w = *(const float4*)(cw + c * 4);
  const float* base = xz + ((size_t)(b << 10) + l) * (2 * D_INNER) + c;
  float acc = cb[c];
  acc = fmaf(w.w, base[0], acc);
  if (l >= 1) acc = fmaf(w.z, base[-(2 * D_INNER)], acc);
  if (l >= 2) acc = fmaf(w.y, base[-2 * (2 * D_INNER)], acc);
  if (l >= 3) acc = fmaf(w.x, base[-3 * (2 * D_INNER)], acc);
  xc[gid] = acc / (1.f + __expf(-acc));
}

// ------- chunked selective scan, pass 1 --------------------------------------
__global__ __launch_bounds__(256) void scan_pass1_k(
    const float* __restrict__ dt, const float* __restrict__ xc,
    const float* __restrict__ xdbl, const float* __restrict__ A_log,
    float* __restrict__ hend, float* __restrict__ sumdt) {
  const int c = blockIdx.x * 256 + threadIdx.x;
  const int k = blockIdx.y;
  const int b = blockIdx.z;
  float Ac[D_STATE];
  #pragma unroll
  for (int n = 0; n < D_STATE; n++) Ac[n] = -__expf(A_log[c * D_STATE + n]);
  float h[D_STATE] = {};
  float sd = 0.f;
  const size_t r0 = (size_t)b * LL + (size_t)k * CLEN;
  const float* dtp = dt + r0 * D_INNER + c;
  const float* xcp = xc + r0 * D_INNER + c;
  const float* Bp  = xdbl + r0 * 96 + DT_RANK;

  float dtv = dtp[0];
  float xv  = xcp[0];
  float4 B0 = *(const float4*)(Bp + 0);
  float4 B1 = *(const float4*)(Bp + 4);
  float4 B2 = *(const float4*)(Bp + 8);
  float4 B3 = *(const float4*)(Bp + 12);
  for (int l = 0; l < CLEN; l++) {
    const int lp = (l + 1 < CLEN) ? l + 1 : l;
    const float dtv2 = dtp[(size_t)lp * D_INNER];
    const float xv2  = xcp[(size_t)lp * D_INNER];
    const float4 B0n = *(const float4*)(Bp + (size_t)lp * 96 + 0);
    const float4 B1n = *(const float4*)(Bp + (size_t)lp * 96 + 4);
    const float4 B2n = *(const float4*)(Bp + (size_t)lp * 96 + 8);
    const float4 B3n = *(const float4*)(Bp + (size_t)lp * 96 + 12);
    sd += dtv;
    const float dx = dtv * xv;
    const float Bv[D_STATE] = {B0.x,B0.y,B0.z,B0.w, B1.x,B1.y,B1.z,B1.w,
                               B2.x,B2.y,B2.z,B2.w, B3.x,B3.y,B3.z,B3.w};
    #pragma unroll
    for (int n = 0; n < D_STATE; n++)
      h[n] = fmaf(__expf(dtv * Ac[n]), h[n], dx * Bv[n]);
    dtv = dtv2; xv = xv2; B0 = B0n; B1 = B1n; B2 = B2n; B3 = B3n;
  }
  float* he = hend + (((size_t)(b * CH + k) * D_INNER + c) << 4);
  #pragma unroll
  for (int n = 0; n < D_STATE; n += 4)
    *(float4*)(he + n) = make_float4(h[n], h[n+1], h[n+2], h[n+3]);
  sumdt[(size_t)(b * CH + k) * D_INNER + c] = sd;
}

// ------- chunked scan fixup ---------------------------------------------------
__global__ __launch_bounds__(256) void scan_fix_k(
    float* __restrict__ hend, const float* __restrict__ sumdt,
    const float* __restrict__ A_log) {
  const int gid = blockIdx.x * 256 + threadIdx.x;
  const int n = gid & 15;
  const int c = (gid >> 4) & (D_INNER - 1);
  const int b = gid >> 15;
  const float Ac = -__expf(A_log[c * D_STATE + n]);
  float hrun = 0.f;
  for (int k = 0; k < CH; k++) {
    const size_t base = (size_t)(b * CH + k) * D_INNER + c;
    const float sd = sumdt[base];
    float* hp = hend + (base << 4) + n;
    const float tmp = *hp;
    *hp = hrun;
    hrun = fmaf(__expf(Ac * sd), hrun, tmp);
  }
}

// ------- chunked scan pass 3: replay, gate, emit y as bf16 hi/lo -------------
__global__ __launch_bounds__(256) void scan_pass3_k(
    const float* __restrict__ dt, const float* __restrict__ xc,
    const float* __restrict__ xdbl, const float* __restrict__ xz,
    const float* __restrict__ h0, const float* __restrict__ A_log,
    const float* __restrict__ Dp,
    unsigned short* __restrict__ yh, unsigned short* __restrict__ yl) {
  const int c = blockIdx.x * 256 + threadIdx.x;
  const int k = blockIdx.y;
  const int b = blockIdx.z;
  float Ac[D_STATE];
  #pragma unroll
  for (int n = 0; n < D_STATE; n++) Ac[n] = -__expf(A_log[c * D_STATE + n]);
  const float Dv = Dp[c];
  float h[D_STATE];
  const float* hp = h0 + (((size_t)(b * CH + k) * D_INNER + c) << 4);
  #pragma unroll
  for (int n = 0; n < D_STATE; n += 4) {
    const float4 v = *(const float4*)(hp + n);
    h[n] = v.x; h[n+1] = v.y; h[n+2] = v.z; h[n+3] = v.w;
  }
  const size_t r0 = (size_t)b * LL + (size_t)k * CLEN;
  const float* dtp = dt + r0 * D_INNER + c;
  const float* xcp = xc + r0 * D_INNER + c;
  const float* Bp  = xdbl + r0 * 96 + DT_RANK;
  const float* zp  = xz + r0 * (size_t)(2 * D_INNER) + D_INNER + c;
  unsigned short* yhp = yh + r0 * D_INNER + c;
  unsigned short* ylp = yl + r0 * D_INNER + c;

  float dtv = dtp[0];
  float xv  = xcp[0];
  float zv  = zp[0];
  float4 B0 = *(const float4*)(Bp + 0);
  float4 B1 = *(const float4*)(Bp + 4);
  float4 B2 = *(const float4*)(Bp + 8);
  float4 B3 = *(const float4*)(Bp + 12);
  float4 C0 = *(const float4*)(Bp + 16);
  float4 C1 = *(const float4*)(Bp + 20);
  float4 C2 = *(const float4*)(Bp + 24);
  float4 C3 = *(const float4*)(Bp + 28);
  for (int l = 0; l < CLEN; l++) {
    const int lp = (l + 1 < CLEN) ? l + 1 : l;
    const float dtv2 = dtp[(size_t)lp * D_INNER];
    const float xv2  = xcp[(size_t)lp * D_INNER];
    const float zv2  = zp[(size_t)lp * 2 * D_INNER];
    const float4 B0n = *(const float4*)(Bp + (size_t)lp * 96 + 0);
    const float4 B1n = *(const float4*)(Bp + (size_t)lp * 96 + 4);
    const float4 B2n = *(const float4*)(Bp + (size_t)lp * 96 + 8);
    const float4 B3n = *(const float4*)(Bp + (size_t)lp * 96 + 12);
    const float4 C0n = *(const float4*)(Bp + (size_t)lp * 96 + 16);
    const float4 C1n = *(const float4*)(Bp + (size_t)lp * 96 + 20);
    const float4 C2n = *(const float4*)(Bp + (size_t)lp * 96 + 24);
    const float4 C3n = *(const float4*)(Bp + (size_t)lp * 96 + 28);
    const float dx = dtv * xv;
    const float Bv[D_STATE] = {B0.x,B0.y,B0.z,B0.w, B1.x,B1.y,B1.z,B1.w,
                               B2.x,B2.y,B2.z,B2.w, B3.x,B3.y,B3.z,B3.w};
    const float Cv[D_STATE] = {C0.x,C0.y,C0.z,C0.w, C1.x,C1.y,C1.z,C1.w,
                               C2.x,C2.y,C2.z,C2.w, C3.x,C3.y,C3.z,C3.w};
    float y = 0.f;
    #pragma unroll
    for (int n = 0; n < D_STATE; n++) {
      h[n] = fmaf(__expf(dtv * Ac[n]), h[n], dx * Bv[n]);
      y = fmaf(h[n], Cv[n], y);
    }
    y = fmaf(xv, Dv, y);
    y *= zv / (1.f + __expf(-zv));
    unsigned short uh, ul;
    split2(y, uh, ul);
    yhp[(size_t)l * D_INNER] = uh;
    ylp[(size_t)l * D_INNER] = ul;
    dtv = dtv2; xv = xv2; zv = zv2;
    B0 = B0n; B1 = B1n; B2 = B2n; B3 = B3n;
    C0 = C0n; C1 = C1n; C2 = C2n; C3 = C3n;
  }
}

// ---------------- mean pool over L ------------------------------------------
__global__ __launch_bounds__(256) void pool_k(const float* __restrict__ h,
    float* __restrict__ pooled) {
  const int d = blockIdx.x * 256 + threadIdx.x;
  const int b = blockIdx.y;
  float s = 0.f;
  for (int l = 0; l < LL; l++) s += h[((size_t)(b * LL + l)) * D_MODEL + d];
  pooled[b * D_MODEL + d] = s * (1.f / LL);
}

// ---------------- classifier head --------------------------------------------
__global__ __launch_bounds__(64) void head_k(const float* __restrict__ pooled,
    const float* __restrict__ hw, const float* __restrict__ hb,
    float* __restrict__ out) {
  const int b = blockIdx.x / N_CLASSES;
  const int j = blockIdx.x % N_CLASSES;
  float s = 0.f;
  for (int k = threadIdx.x; k < D_MODEL; k += 64)
    s = fmaf(pooled[b * D_MODEL + k], hw[j * D_MODEL + k], s);
  #pragma unroll
  for (int o = 32; o; o >>= 1) s += __shfl_down(s, o);
  if (threadIdx.x == 0) out[b * N_CLASSES + j] = s + hb[j];
}

extern "C" void kernel_launch(void* const* d_in, const int* in_sizes, int n_in,
                              void* d_out, int out_size, void* d_ws, size_t ws_size,
                              hipStream_t stream) {
  const float* x0    = (const float*)d_in[0];
  const float* ln1w  = (const float*)d_in[1];
  const float* ln1b  = (const float*)d_in[2];
  const float* inw   = (const float*)d_in[3];
  const float* convw = (const float*)d_in[4];
  const float* convb = (const float*)d_in[5];
  const float* xpw   = (const float*)d_in[6];
  const float* dtpw  = (const float*)d_in[7];
  const float* dtpb  = (const float*)d_in[8];
  const float* Alog  = (const float*)d_in[9];
  const float* Dp    = (const float*)d_in[10];
  const float* outw  = (const float*)d_in[11];
  const float* normw = (const float*)d_in[12];
  const float* normb = (const float*)d_in[13];
  const float* headw = (const float*)d_in[14];
  const float* headb = (const float*)d_in[15];

  float* ws = (float*)d_ws;
  size_t f = 0;
  float* X      = ws + f; f += (size_t)BL * D_MODEL;        // 4M
  float* xz     = ws + f; f += (size_t)BL * 2 * D_INNER;    // 16M
  float* xc     = ws + f; f += (size_t)BL * D_INNER;        // 8M
  float* xdbl   = ws + f; f += (size_t)BL * 96;             // 0.375M
  float* dty    = ws + f; f += (size_t)BL * D_INNER;        // 8M (dt; final-LN scratch)
  float* pooled = ws + f; f += 4096;
  float* hend   = ws + f; f += (size_t)BB * CH * D_INNER * D_STATE;  // 2M
  float* sumdt  = ws + f; f += (size_t)BB * CH * D_INNER;            // 0.125M
  unsigned short* hh  = (unsigned short*)(ws + f); f += (size_t)BL * D_MODEL / 2;
  unsigned short* hl  = (unsigned short*)(ws + f); f += (size_t)BL * D_MODEL / 2;
  unsigned short* yh  = (unsigned short*)(ws + f); f += (size_t)BL * D_INNER / 2;
  unsigned short* yl  = (unsigned short*)(ws + f); f += (size_t)BL * D_INNER / 2;
  unsigned short* wih = (unsigned short*)(ws + f); f += (size_t)2 * D_INNER * D_MODEL / 2;
  unsigned short* woh = (unsigned short*)(ws + f); f += (size_t)D_MODEL * D_INNER / 2;

  hipMemcpyAsync(X, x0, (size_t)BL * D_MODEL * sizeof(float),
                 hipMemcpyDeviceToDevice, stream);

  for (int layer = 0; layer < N_LAYERS; ++layer) {
    // LayerNorm -> bf16 hi/lo A-operand
    layernorm_split_k<<<BL, 256, 0, stream>>>(X, ln1w + layer * D_MODEL,
                                              ln1b + layer * D_MODEL, hh, hl);
    // round weights to bf16 (hi only) for this layer
    round_k<<<(2 * D_INNER * D_MODEL) / 1024, 256, 0, stream>>>(
        inw + (size_t)layer * 2 * D_INNER * D_MODEL, wih);
    round_k<<<(D_MODEL * D_INNER) / 1024, 256, 0, stream>>>(
        outw + (size_t)layer * D_MODEL * D_INNER, woh);
    // xz = h @ in_w^T : M=4096 N=4096 K=1024 (2-term split-bf16 MFMA)
    mfma_gemm_nt<0><<<dim3(4096 / 128, 4096 / 128), 256, 0, stream>>>(
        hh, hl, wih, xz, nullptr, BL, 2 * D_INNER, D_MODEL, 2 * D_INNER);
    conv_silu_k<<<(BL * D_INNER) / 256, 256, 0, stream>>>(
        xz, convw + layer * D_INNER * D_CONV, convb + layer * D_INNER, xc);
    // x_dbl = xc @ xp_w^T : M=4096 N=96 K=2048 (fp32)
    sgemm_nt<128,32,32,8,2,0><<<dim3(96 / 32, 4096 / 128), 256, 0, stream>>>(
        xc, xpw + (size_t)layer * 96 * D_INNER, xdbl,
        BL, 96, D_INNER, D_INNER, D_INNER, 96, nullptr);
    // dt = softplus(dt_r @ dtp_w^T + dtp_b) : M=4096 N=2048 K=64 (fp32)
    sgemm_nt<128,128,16,8,8,1><<<dim3(2048 / 128, 4096 / 128), 256, 0, stream>>>(
        xdbl, dtpw + (size_t)layer * D_INNER * DT_RANK, dty,
        BL, D_INNER, DT_RANK, 96, DT_RANK, D_INNER,
        dtpb + layer * D_INNER);
    // chunked scan
    scan_pass1_k<<<dim3(D_INNER / 256, CH, BB), 256, 0, stream>>>(
        dty, xc, xdbl, Alog + (size_t)layer * D_INNER * D_STATE, hend, sumdt);
    scan_fix_k<<<(BB * D_INNER * D_STATE) / 256, 256, 0, stream>>>(
        hend, sumdt, Alog + (size_t)layer * D_INNER * D_STATE);
    scan_pass3_k<<<dim3(D_INNER / 256, CH, BB), 256, 0, stream>>>(
        dty, xc, xdbl, xz, hend, Alog + (size_t)layer * D_INNER * D_STATE,
        Dp + layer * D_INNER, yh, yl);
    // X = X + y @ out_w^T : M=4096 N=1024 K=2048 (2-term split-bf16 MFMA)
    mfma_gemm_nt<2><<<dim3(1024 / 128, 4096 / 128), 256, 0, stream>>>(
        yh, yl, woh, X, X, BL, D_MODEL, D_INNER, D_MODEL);
  }

  layernorm_k<<<BL, 256, 0, stream>>>(X, normw, normb, dty);
  pool_k<<<dim3(D_MODEL / 256, BB), 256, 0, stream>>>(dty, pooled);
  head_k<<<BB * N_CLASSES, 64, 0, stream>>>(pooled, headw, headb, (float*)d_out);
}

// Round 6
// 903.110 us; speedup vs baseline: 3.4861x; 1.1620x over previous
//
#include <hip/hip_runtime.h>
#include <hip/hip_bf16.h>

#define N_LAYERS 2
#define D_MODEL 1024
#define D_INNER 2048
#define D_STATE 16
#define D_CONV 4
#define DT_RANK 64
#define N_CLASSES 10
#define BB 4
#define LL 1024
#define BL (BB*LL)   // 4096 rows
#define CH 16        // scan chunks per sequence
#define CLEN (LL/CH) // 64 steps per chunk
#define KS 8         // split-K segments for x_proj

typedef __attribute__((ext_vector_type(8))) short bf16x8;
typedef __attribute__((ext_vector_type(4))) float f32x4;

typedef const void __attribute__((address_space(1)))* gas_ptr;
typedef void __attribute__((address_space(3)))* las_ptr;
#define GLDS16(g, p) __builtin_amdgcn_global_load_lds((gas_ptr)(g), (las_ptr)(p), 16, 0, 0)

// ---- fp32 -> bf16 hi/lo split (RNE) -----------------------------------------
__device__ inline void split2(float x, unsigned short& hi, unsigned short& lo) {
  unsigned u = __float_as_uint(x);
  unsigned rh = (u + 0x7FFFu + ((u >> 16) & 1u)) & 0xFFFF0000u;
  hi = (unsigned short)(rh >> 16);
  float xl = x - __uint_as_float(rh);
  unsigned ul = __float_as_uint(xl);
  unsigned rl = (ul + 0x7FFFu + ((ul >> 16) & 1u)) & 0xFFFF0000u;
  lo = (unsigned short)(rl >> 16);
}

__device__ inline unsigned short rnd_bf16(float x) {
  unsigned u = __float_as_uint(x);
  return (unsigned short)((u + 0x7FFFu + ((u >> 16) & 1u)) >> 16);
}

// round weights to bf16 (hi only)
__global__ __launch_bounds__(256) void round_k(const float* __restrict__ in,
    unsigned short* __restrict__ hi) {
  const int i = blockIdx.x * 256 + threadIdx.x;
  const float4 v = ((const float4*)in)[i];
  ushort4 h4;
  h4.x = rnd_bf16(v.x); h4.y = rnd_bf16(v.y);
  h4.z = rnd_bf16(v.z); h4.w = rnd_bf16(v.w);
  ((ushort4*)hi)[i] = h4;
}

// ---------------- LayerNorm -> fp32 out ---------------------------------------
__global__ __launch_bounds__(256) void layernorm_k(const float* __restrict__ x,
    const float* __restrict__ w, const float* __restrict__ b,
    float* __restrict__ out) {
  const int row = blockIdx.x;
  const int t = threadIdx.x;
  const float4 v = *(const float4*)(x + (size_t)row * D_MODEL + t * 4);
  float s = v.x + v.y + v.z + v.w;
  float q = v.x*v.x + v.y*v.y + v.z*v.z + v.w*v.w;
  #pragma unroll
  for (int o = 32; o; o >>= 1) { s += __shfl_down(s, o); q += __shfl_down(q, o); }
  __shared__ float red[8];
  if ((t & 63) == 0) { red[t >> 6] = s; red[4 + (t >> 6)] = q; }
  __syncthreads();
  s = red[0] + red[1] + red[2] + red[3];
  q = red[4] + red[5] + red[6] + red[7];
  const float mean = s * (1.f / D_MODEL);
  const float var  = q * (1.f / D_MODEL) - mean * mean;
  const float rstd = rsqrtf(var + 1e-5f);
  const float4 wv = *(const float4*)(w + t * 4);
  const float4 bv = *(const float4*)(b + t * 4);
  float4 o4;
  o4.x = (v.x - mean) * rstd * wv.x + bv.x;
  o4.y = (v.y - mean) * rstd * wv.y + bv.y;
  o4.z = (v.z - mean) * rstd * wv.z + bv.z;
  o4.w = (v.w - mean) * rstd * wv.w + bv.w;
  *(float4*)(out + (size_t)row * D_MODEL + t * 4) = o4;
}

// ---------------- LayerNorm -> bf16 hi/lo out ---------------------------------
__global__ __launch_bounds__(256) void layernorm_split_k(const float* __restrict__ x,
    const float* __restrict__ w, const float* __restrict__ b,
    unsigned short* __restrict__ oh, unsigned short* __restrict__ ol) {
  const int row = blockIdx.x;
  const int t = threadIdx.x;
  const float4 v = *(const float4*)(x + (size_t)row * D_MODEL + t * 4);
  float s = v.x + v.y + v.z + v.w;
  float q = v.x*v.x + v.y*v.y + v.z*v.z + v.w*v.w;
  #pragma unroll
  for (int o = 32; o; o >>= 1) { s += __shfl_down(s, o); q += __shfl_down(q, o); }
  __shared__ float red[8];
  if ((t & 63) == 0) { red[t >> 6] = s; red[4 + (t >> 6)] = q; }
  __syncthreads();
  s = red[0] + red[1] + red[2] + red[3];
  q = red[4] + red[5] + red[6] + red[7];
  const float mean = s * (1.f / D_MODEL);
  const float var  = q * (1.f / D_MODEL) - mean * mean;
  const float rstd = rsqrtf(var + 1e-5f);
  const float4 wv = *(const float4*)(w + t * 4);
  const float4 bv = *(const float4*)(b + t * 4);
  float4 o4;
  o4.x = (v.x - mean) * rstd * wv.x + bv.x;
  o4.y = (v.y - mean) * rstd * wv.y + bv.y;
  o4.z = (v.z - mean) * rstd * wv.z + bv.z;
  o4.w = (v.w - mean) * rstd * wv.w + bv.w;
  ushort4 h4, l4;
  split2(o4.x, h4.x, l4.x); split2(o4.y, h4.y, l4.y);
  split2(o4.z, h4.z, l4.z); split2(o4.w, h4.w, l4.w);
  ((ushort4*)(oh + (size_t)row * D_MODEL))[t] = h4;
  ((ushort4*)(ol + (size_t)row * D_MODEL))[t] = l4;
}

// ---- split-bf16 MFMA GEMM NT: C[m,n] = sum_k A[m,k]*B[n,k] (+resid) ---------
// A = Ah+Al (hi/lo bf16), B = Bh (bf16); computes Ah*Bh + Al*Bh (2 K-segments).
template<int EPI>  // 0: C=acc ; 2: C=acc+resid
__global__ __launch_bounds__(256) void mfma_gemm_nt(
    const unsigned short* __restrict__ Ah, const unsigned short* __restrict__ Al,
    const unsigned short* __restrict__ Bh,
    float* __restrict__ C, const float* __restrict__ resid,
    int M, int N, int K, int ldc) {
  __shared__ unsigned short As[128 * 64];
  __shared__ unsigned short Bs[128 * 64];
  const int tid = threadIdx.x;
  const int w = tid >> 6, l = tid & 63;
  const int wr = w >> 1, wc = w & 1;
  const int m0 = blockIdx.y * 128, n0 = blockIdx.x * 128;
  const int srow = l >> 3;             // staging row within 8-row block
  const int scol = (l & 7) * 8;        // staging col (elements)
  const int fr = l & 15;               // fragment row
  const int fk = (l >> 4) * 8;         // fragment k offset
  f32x4 acc[4][4] = {};

  #pragma unroll 1
  for (int seg = 0; seg < 2; ++seg) {
    const unsigned short* Asrc = (seg == 1) ? Al : Ah;
    #pragma unroll 1
    for (int k0 = 0; k0 < K; k0 += 64) {
      __syncthreads();                  // previous compute done before overwrite
      #pragma unroll
      for (int it = 0; it < 4; ++it) {
        const int bi = it * 4 + w;      // 1 KB block id 0..15
        const int row = bi * 8 + srow;
        GLDS16(Asrc + (size_t)(m0 + row) * K + k0 + scol, &As[bi * 512 + l * 8]);
        GLDS16(Bh + (size_t)(n0 + row) * K + k0 + scol, &Bs[bi * 512 + l * 8]);
      }
      __syncthreads();                  // staging visible (vmcnt drained)
      #pragma unroll
      for (int kk = 0; kk < 64; kk += 32) {
        bf16x8 a[4], b[4];
        #pragma unroll
        for (int f = 0; f < 4; ++f)
          a[f] = *(const bf16x8*)&As[(wr * 64 + f * 16 + fr) * 64 + kk + fk];
        #pragma unroll
        for (int f = 0; f < 4; ++f)
          b[f] = *(const bf16x8*)&Bs[(wc * 64 + f * 16 + fr) * 64 + kk + fk];
        #pragma unroll
        for (int i = 0; i < 4; ++i)
          #pragma unroll
          for (int j = 0; j < 4; ++j)
            acc[i][j] = __builtin_amdgcn_mfma_f32_16x16x32_bf16(
                a[i], b[j], acc[i][j], 0, 0, 0);
      }
    }
  }
  const int orow = (l >> 4) * 4;
  const int ocol = l & 15;
  #pragma unroll
  for (int i = 0; i < 4; ++i)
    #pragma unroll
    for (int j = 0; j < 4; ++j)
      #pragma unroll
      for (int r = 0; r < 4; ++r) {
        const int m = m0 + wr * 64 + i * 16 + orow + r;
        const int n = n0 + wc * 64 + j * 16 + ocol;
        float v = acc[i][j][r];
        if constexpr (EPI == 2) v += resid[(size_t)m * ldc + n];
        C[(size_t)m * ldc + n] = v;
      }
}

// ---------------- fp32 SGEMM NT (small GEMMs) --------------------------------
// EPI: 0 none; 1 softplus(acc + bias[n])
template<int BM, int BN, int BK, int TM, int TN, int EPI>
__global__ __launch_bounds__(256) void sgemm_nt(
    const float* __restrict__ A, const float* __restrict__ B,
    float* __restrict__ C, int M, int N, int K, int lda, int ldb, int ldc,
    const float* __restrict__ bias) {
  constexpr int THREADS = 256;
  constexpr int NT = BN / TN;
  constexpr int K4 = BK / 4;
  constexpr int A_F4 = BM * BK / (THREADS * 4);
  constexpr int B_F4 = BN * BK / (THREADS * 4);
  static_assert((BM / TM) * (BN / TN) == THREADS, "thread shape");
  __shared__ float As[BK][BM + 4];
  __shared__ float Bs[BK][BN + 4];
  const int tid = threadIdx.x;
  const int m0 = blockIdx.y * BM;
  const int n0 = blockIdx.x * BN;
  const int tn = (tid % NT) * TN;
  const int tm = (tid / NT) * TM;
  float acc[TM][TN] = {};
  for (int k0 = 0; k0 < K; k0 += BK) {
    #pragma unroll
    for (int i = 0; i < A_F4; i++) {
      int li = tid + i * THREADS;
      int r = li / K4, c4 = li % K4;
      float4 v = *(const float4*)(A + (size_t)(m0 + r) * lda + k0 + c4 * 4);
      As[c4*4+0][r] = v.x; As[c4*4+1][r] = v.y; As[c4*4+2][r] = v.z; As[c4*4+3][r] = v.w;
    }
    #pragma unroll
    for (int i = 0; i < B_F4; i++) {
      int li = tid + i * THREADS;
      int r = li / K4, c4 = li % K4;
      float4 v = *(const float4*)(B + (size_t)(n0 + r) * ldb + k0 + c4 * 4);
      Bs[c4*4+0][r] = v.x; Bs[c4*4+1][r] = v.y; Bs[c4*4+2][r] = v.z; Bs[c4*4+3][r] = v.w;
    }
    __syncthreads();
    #pragma unroll
    for (int k = 0; k < BK; k++) {
      float a[TM], bf[TN];
      #pragma unroll
      for (int i = 0; i < TM; i++) a[i] = As[k][tm + i];
      #pragma unroll
      for (int j = 0; j < TN; j++) bf[j] = Bs[k][tn + j];
      #pragma unroll
      for (int i = 0; i < TM; i++)
        #pragma unroll
        for (int j = 0; j < TN; j++)
          acc[i][j] = fmaf(a[i], bf[j], acc[i][j]);
    }
    __syncthreads();
  }
  #pragma unroll
  for (int i = 0; i < TM; i++) {
    const int m = m0 + tm + i;
    #pragma unroll
    for (int j = 0; j < TN; j++) {
      const int n = n0 + tn + j;
      float v = acc[i][j];
      if constexpr (EPI == 1) {
        v += bias[n];
        v = (v > 20.f) ? v : log1pf(__expf(v));
      }
      C[(size_t)m * ldc + n] = v;
    }
  }
}

// ---- x_proj split-K: part[kz][m][n] = sum_{k in seg kz} xc[m,k]*xpw[n,k] ----
// M=4096, N=96, K=2048, KS=8 segments of 256. BM=64 BN=32 BK=32 TM=4 TN=2.
__global__ __launch_bounds__(256) void sgemm_splitk_k(
    const float* __restrict__ A, const float* __restrict__ B,
    float* __restrict__ part) {
  __shared__ float As[32][64 + 4];
  __shared__ float Bs[32][32 + 4];
  const int tid = threadIdx.x;
  const int n0 = blockIdx.x * 32;
  const int m0 = blockIdx.y * 64;
  const int kz = blockIdx.z;
  const int tn = (tid & 15) * 2;
  const int tm = (tid >> 4) * 4;
  float acc[4][2] = {};
  for (int kb = 0; kb < 256; kb += 32) {
    const int k0 = kz * 256 + kb;
    #pragma unroll
    for (int i = 0; i < 2; i++) {
      int li = tid + i * 256;          // 512 float4 slots for A (64x32)
      int r = li >> 3, c4 = li & 7;
      float4 v = *(const float4*)(A + (size_t)(m0 + r) * D_INNER + k0 + c4 * 4);
      As[c4*4+0][r] = v.x; As[c4*4+1][r] = v.y;
      As[c4*4+2][r] = v.z; As[c4*4+3][r] = v.w;
    }
    {
      int r = tid >> 3, c4 = tid & 7;  // 256 float4 slots for B (32x32)
      float4 v = *(const float4*)(B + (size_t)(n0 + r) * D_INNER + k0 + c4 * 4);
      Bs[c4*4+0][r] = v.x; Bs[c4*4+1][r] = v.y;
      Bs[c4*4+2][r] = v.z; Bs[c4*4+3][r] = v.w;
    }
    __syncthreads();
    #pragma unroll
    for (int k = 0; k < 32; k++) {
      float a[4], bf[2];
      #pragma unroll
      for (int i = 0; i < 4; i++) a[i] = As[k][tm + i];
      bf[0] = Bs[k][tn]; bf[1] = Bs[k][tn + 1];
      #pragma unroll
      for (int i = 0; i < 4; i++) {
        acc[i][0] = fmaf(a[i], bf[0], acc[i][0]);
        acc[i][1] = fmaf(a[i], bf[1], acc[i][1]);
      }
    }
    __syncthreads();
  }
  float* p = part + (size_t)kz * BL * 96;
  #pragma unroll
  for (int i = 0; i < 4; i++) {
    const int m = m0 + tm + i;
    p[(size_t)m * 96 + n0 + tn]     = acc[i][0];
    p[(size_t)m * 96 + n0 + tn + 1] = acc[i][1];
  }
}

// fixed-order deterministic reduce of the KS partials -> xdbl
__global__ __launch_bounds__(256) void xproj_reduce_k(
    const float* __restrict__ part, float* __restrict__ out) {
  const int i = blockIdx.x * 256 + threadIdx.x;   // over BL*96
  float s = 0.f;
  #pragma unroll
  for (int k = 0; k < KS; k++) s += part[(size_t)k * BL * 96 + i];
  out[i] = s;
}

// ---------------- causal depthwise conv (width 4) + SiLU --------------------
__global__ __launch_bounds__(256) void conv_silu_k(const float* __restrict__ xz,
    const float* __restrict__ cw, const float* __restrict__ cb,
    float* __restrict__ xc) {
  const int gid = blockIdx.x * 256 + threadIdx.x;
  const int c = gid & (D_INNER - 1);
  const int l = (gid >> 11) & (LL - 1);
  const int b = gid >> 21;
  const float4 w = *(const float4*)(cw + c * 4);
  const float* base = xz + ((size_t)(b << 10) + l) * (2 * D_INNER) + c;
  float acc = cb[c];
  acc = fmaf(w.w, base[0], acc);
  if (l >= 1) acc = fmaf(w.z, base[-(2 * D_INNER)], acc);
  if (l >= 2) acc = fmaf(w.y, base[-2 * (2 * D_INNER)], acc);
  if (l >= 3) acc = fmaf(w.x, base[-3 * (2 * D_INNER)], acc);
  xc[gid] = acc / (1.f + __expf(-acc));
}

// ------- chunked selective scan, pass 1 --------------------------------------
__global__ __launch_bounds__(256) void scan_pass1_k(
    const float* __restrict__ dt, const float* __restrict__ xc,
    const float* __restrict__ xdbl, const float* __restrict__ A_log,
    float* __restrict__ hend, float* __restrict__ sumdt) {
  const int c = blockIdx.x * 256 + threadIdx.x;
  const int k = blockIdx.y;
  const int b = blockIdx.z;
  float Ac[D_STATE];
  #pragma unroll
  for (int n = 0; n < D_STATE; n++) Ac[n] = -__expf(A_log[c * D_STATE + n]);
  float h[D_STATE] = {};
  float sd = 0.f;
  const size_t r0 = (size_t)b * LL + (size_t)k * CLEN;
  const float* dtp = dt + r0 * D_INNER + c;
  const float* xcp = xc + r0 * D_INNER + c;
  const float* Bp  = xdbl + r0 * 96 + DT_RANK;

  float dtv = dtp[0];
  float xv  = xcp[0];
  float4 B0 = *(const float4*)(Bp + 0);
  float4 B1 = *(const float4*)(Bp + 4);
  float4 B2 = *(const float4*)(Bp + 8);
  float4 B3 = *(const float4*)(Bp + 12);
  for (int l = 0; l < CLEN; l++) {
    const int lp = (l + 1 < CLEN) ? l + 1 : l;
    const float dtv2 = dtp[(size_t)lp * D_INNER];
    const float xv2  = xcp[(size_t)lp * D_INNER];
    const float4 B0n = *(const float4*)(Bp + (size_t)lp * 96 + 0);
    const float4 B1n = *(const float4*)(Bp + (size_t)lp * 96 + 4);
    const float4 B2n = *(const float4*)(Bp + (size_t)lp * 96 + 8);
    const float4 B3n = *(const float4*)(Bp + (size_t)lp * 96 + 12);
    sd += dtv;
    const float dx = dtv * xv;
    const float Bv[D_STATE] = {B0.x,B0.y,B0.z,B0.w, B1.x,B1.y,B1.z,B1.w,
                               B2.x,B2.y,B2.z,B2.w, B3.x,B3.y,B3.z,B3.w};
    #pragma unroll
    for (int n = 0; n < D_STATE; n++)
      h[n] = fmaf(__expf(dtv * Ac[n]), h[n], dx * Bv[n]);
    dtv = dtv2; xv = xv2; B0 = B0n; B1 = B1n; B2 = B2n; B3 = B3n;
  }
  float* he = hend + (((size_t)(b * CH + k) * D_INNER + c) << 4);
  #pragma unroll
  for (int n = 0; n < D_STATE; n += 4)
    *(float4*)(he + n) = make_float4(h[n], h[n+1], h[n+2], h[n+3]);
  sumdt[(size_t)(b * CH + k) * D_INNER + c] = sd;
}

// ------- chunked scan fixup ---------------------------------------------------
__global__ __launch_bounds__(256) void scan_fix_k(
    float* __restrict__ hend, const float* __restrict__ sumdt,
    const float* __restrict__ A_log) {
  const int gid = blockIdx.x * 256 + threadIdx.x;
  const int n = gid & 15;
  const int c = (gid >> 4) & (D_INNER - 1);
  const int b = gid >> 15;
  const float Ac = -__expf(A_log[c * D_STATE + n]);
  float hrun = 0.f;
  for (int k = 0; k < CH; k++) {
    const size_t base = (size_t)(b * CH + k) * D_INNER + c;
    const float sd = sumdt[base];
    float* hp = hend + (base << 4) + n;
    const float tmp = *hp;
    *hp = hrun;
    hrun = fmaf(__expf(Ac * sd), hrun, tmp);
  }
}

// ------- chunked scan pass 3: replay, gate, emit y as bf16 hi/lo -------------
__global__ __launch_bounds__(256) void scan_pass3_k(
    const float* __restrict__ dt, const float* __restrict__ xc,
    const float* __restrict__ xdbl, const float* __restrict__ xz,
    const float* __restrict__ h0, const float* __restrict__ A_log,
    const float* __restrict__ Dp,
    unsigned short* __restrict__ yh, unsigned short* __restrict__ yl) {
  const int c = blockIdx.x * 256 + threadIdx.x;
  const int k = blockIdx.y;
  const int b = blockIdx.z;
  float Ac[D_STATE];
  #pragma unroll
  for (int n = 0; n < D_STATE; n++) Ac[n] = -__expf(A_log[c * D_STATE + n]);
  const float Dv = Dp[c];
  float h[D_STATE];
  const float* hp = h0 + (((size_t)(b * CH + k) * D_INNER + c) << 4);
  #pragma unroll
  for (int n = 0; n < D_STATE; n += 4) {
    const float4 v = *(const float4*)(hp + n);
    h[n] = v.x; h[n+1] = v.y; h[n+2] = v.z; h[n+3] = v.w;
  }
  const size_t r0 = (size_t)b * LL + (size_t)k * CLEN;
  const float* dtp = dt + r0 * D_INNER + c;
  const float* xcp = xc + r0 * D_INNER + c;
  const float* Bp  = xdbl + r0 * 96 + DT_RANK;
  const float* zp  = xz + r0 * (size_t)(2 * D_INNER) + D_INNER + c;
  unsigned short* yhp = yh + r0 * D_INNER + c;
  unsigned short* ylp = yl + r0 * D_INNER + c;

  float dtv = dtp[0];
  float xv  = xcp[0];
  float zv  = zp[0];
  float4 B0 = *(const float4*)(Bp + 0);
  float4 B1 = *(const float4*)(Bp + 4);
  float4 B2 = *(const float4*)(Bp + 8);
  float4 B3 = *(const float4*)(Bp + 12);
  float4 C0 = *(const float4*)(Bp + 16);
  float4 C1 = *(const float4*)(Bp + 20);
  float4 C2 = *(const float4*)(Bp + 24);
  float4 C3 = *(const float4*)(Bp + 28);
  for (int l = 0; l < CLEN; l++) {
    const int lp = (l + 1 < CLEN) ? l + 1 : l;
    const float dtv2 = dtp[(size_t)lp * D_INNER];
    const float xv2  = xcp[(size_t)lp * D_INNER];
    const float zv2  = zp[(size_t)lp * 2 * D_INNER];
    const float4 B0n = *(const float4*)(Bp + (size_t)lp * 96 + 0);
    const float4 B1n = *(const float4*)(Bp + (size_t)lp * 96 + 4);
    const float4 B2n = *(const float4*)(Bp + (size_t)lp * 96 + 8);
    const float4 B3n = *(const float4*)(Bp + (size_t)lp * 96 + 12);
    const float4 C0n = *(const float4*)(Bp + (size_t)lp * 96 + 16);
    const float4 C1n = *(const float4*)(Bp + (size_t)lp * 96 + 20);
    const float4 C2n = *(const float4*)(Bp + (size_t)lp * 96 + 24);
    const float4 C3n = *(const float4*)(Bp + (size_t)lp * 96 + 28);
    const float dx = dtv * xv;
    const float Bv[D_STATE] = {B0.x,B0.y,B0.z,B0.w, B1.x,B1.y,B1.z,B1.w,
                               B2.x,B2.y,B2.z,B2.w, B3.x,B3.y,B3.z,B3.w};
    const float Cv[D_STATE] = {C0.x,C0.y,C0.z,C0.w, C1.x,C1.y,C1.z,C1.w,
                               C2.x,C2.y,C2.z,C2.w, C3.x,C3.y,C3.z,C3.w};
    float y = 0.f;
    #pragma unroll
    for (int n = 0; n < D_STATE; n++) {
      h[n] = fmaf(__expf(dtv * Ac[n]), h[n], dx * Bv[n]);
      y = fmaf(h[n], Cv[n], y);
    }
    y = fmaf(xv, Dv, y);
    y *= zv / (1.f + __expf(-zv));
    unsigned short uh, ul;
    split2(y, uh, ul);
    yhp[(size_t)l * D_INNER] = uh;
    ylp[(size_t)l * D_INNER] = ul;
    dtv = dtv2; xv = xv2; zv = zv2;
    B0 = B0n; B1 = B1n; B2 = B2n; B3 = B3n;
    C0 = C0n; C1 = C1n; C2 = C2n; C3 = C3n;
  }
}

// ---------------- mean pool over L ------------------------------------------
__global__ __launch_bounds__(256) void pool_k(const float* __restrict__ h,
    float* __restrict__ pooled) {
  const int d = blockIdx.x * 256 + threadIdx.x;
  const int b = blockIdx.y;
  float s = 0.f;
  for (int l = 0; l < LL; l++) s += h[((size_t)(b * LL + l)) * D_MODEL + d];
  pooled[b * D_MODEL + d] = s * (1.f / LL);
}

// ---------------- classifier head --------------------------------------------
__global__ __launch_bounds__(64) void head_k(const float* __restrict__ pooled,
    const float* __restrict__ hw, const float* __restrict__ hb,
    float* __restrict__ out) {
  const int b = blockIdx.x / N_CLASSES;
  const int j = blockIdx.x % N_CLASSES;
  float s = 0.f;
  for (int k = threadIdx.x; k < D_MODEL; k += 64)
    s = fmaf(pooled[b * D_MODEL + k], hw[j * D_MODEL + k], s);
  #pragma unroll
  for (int o = 32; o; o >>= 1) s += __shfl_down(s, o);
  if (threadIdx.x == 0) out[b * N_CLASSES + j] = s + hb[j];
}

extern "C" void kernel_launch(void* const* d_in, const int* in_sizes, int n_in,
                              void* d_out, int out_size, void* d_ws, size_t ws_size,
                              hipStream_t stream) {
  const float* x0    = (const float*)d_in[0];
  const float* ln1w  = (const float*)d_in[1];
  const float* ln1b  = (const float*)d_in[2];
  const float* inw   = (const float*)d_in[3];
  const float* convw = (const float*)d_in[4];
  const float* convb = (const float*)d_in[5];
  const float* xpw   = (const float*)d_in[6];
  const float* dtpw  = (const float*)d_in[7];
  const float* dtpb  = (const float*)d_in[8];
  const float* Alog  = (const float*)d_in[9];
  const float* Dp    = (const float*)d_in[10];
  const float* outw  = (const float*)d_in[11];
  const float* normw = (const float*)d_in[12];
  const float* normb = (const float*)d_in[13];
  const float* headw = (const float*)d_in[14];
  const float* headb = (const float*)d_in[15];

  float* ws = (float*)d_ws;
  size_t f = 0;
  float* X      = ws + f; f += (size_t)BL * D_MODEL;        // 4M
  float* xz     = ws + f; f += (size_t)BL * 2 * D_INNER;    // 16M
  float* xc     = ws + f; f += (size_t)BL * D_INNER;        // 8M
  float* xdbl   = ws + f; f += (size_t)BL * 96;             // 0.375M
  float* dty    = ws + f; f += (size_t)BL * D_INNER;        // 8M (dt; final-LN scratch)
  float* pooled = ws + f; f += 4096;
  float* hend   = ws + f; f += (size_t)BB * CH * D_INNER * D_STATE;  // 2M
  float* sumdt  = ws + f; f += (size_t)BB * CH * D_INNER;            // 0.125M
  float* xpart  = ws + f; f += (size_t)KS * BL * 96;                 // 3.15M
  unsigned short* hh  = (unsigned short*)(ws + f); f += (size_t)BL * D_MODEL / 2;
  unsigned short* hl  = (unsigned short*)(ws + f); f += (size_t)BL * D_MODEL / 2;
  unsigned short* yh  = (unsigned short*)(ws + f); f += (size_t)BL * D_INNER / 2;
  unsigned short* yl  = (unsigned short*)(ws + f); f += (size_t)BL * D_INNER / 2;
  unsigned short* wih = (unsigned short*)(ws + f); f += (size_t)2 * D_INNER * D_MODEL / 2;
  unsigned short* woh = (unsigned short*)(ws + f); f += (size_t)D_MODEL * D_INNER / 2;

  hipMemcpyAsync(X, x0, (size_t)BL * D_MODEL * sizeof(float),
                 hipMemcpyDeviceToDevice, stream);

  for (int layer = 0; layer < N_LAYERS; ++layer) {
    // LayerNorm -> bf16 hi/lo A-operand
    layernorm_split_k<<<BL, 256, 0, stream>>>(X, ln1w + layer * D_MODEL,
                                              ln1b + layer * D_MODEL, hh, hl);
    // round weights to bf16 (hi only) for this layer
    round_k<<<(2 * D_INNER * D_MODEL) / 1024, 256, 0, stream>>>(
        inw + (size_t)layer * 2 * D_INNER * D_MODEL, wih);
    round_k<<<(D_MODEL * D_INNER) / 1024, 256, 0, stream>>>(
        outw + (size_t)layer * D_MODEL * D_INNER, woh);
    // xz = h @ in_w^T : M=4096 N=4096 K=1024 (2-term split-bf16 MFMA)
    mfma_gemm_nt<0><<<dim3(4096 / 128, 4096 / 128), 256, 0, stream>>>(
        hh, hl, wih, xz, nullptr, BL, 2 * D_INNER, D_MODEL, 2 * D_INNER);
    conv_silu_k<<<(BL * D_INNER) / 256, 256, 0, stream>>>(
        xz, convw + layer * D_INNER * D_CONV, convb + layer * D_INNER, xc);
    // x_dbl = xc @ xp_w^T : M=4096 N=96 K=2048 (fp32 split-K + reduce)
    sgemm_splitk_k<<<dim3(96 / 32, 4096 / 64, KS), 256, 0, stream>>>(
        xc, xpw + (size_t)layer * 96 * D_INNER, xpart);
    xproj_reduce_k<<<(BL * 96) / 256, 256, 0, stream>>>(xpart, xdbl);
    // dt = softplus(dt_r @ dtp_w^T + dtp_b) : M=4096 N=2048 K=64 (fp32)
    sgemm_nt<128,128,16,8,8,1><<<dim3(2048 / 128, 4096 / 128), 256, 0, stream>>>(
        xdbl, dtpw + (size_t)layer * D_INNER * DT_RANK, dty,
        BL, D_INNER, DT_RANK, 96, DT_RANK, D_INNER,
        dtpb + layer * D_INNER);
    // chunked scan
    scan_pass1_k<<<dim3(D_INNER / 256, CH, BB), 256, 0, stream>>>(
        dty, xc, xdbl, Alog + (size_t)layer * D_INNER * D_STATE, hend, sumdt);
    scan_fix_k<<<(BB * D_INNER * D_STATE) / 256, 256, 0, stream>>>(
        hend, sumdt, Alog + (size_t)layer * D_INNER * D_STATE);
    scan_pass3_k<<<dim3(D_INNER / 256, CH, BB), 256, 0, stream>>>(
        dty, xc, xdbl, xz, hend, Alog + (size_t)layer * D_INNER * D_STATE,
        Dp + layer * D_INNER, yh, yl);
    // X = X + y @ out_w^T : M=4096 N=1024 K=2048 (2-term split-bf16 MFMA)
    mfma_gemm_nt<2><<<dim3(1024 / 128, 4096 / 128), 256, 0, stream>>>(
        yh, yl, woh, X, X, BL, D_MODEL, D_INNER, D_MODEL);
  }

  layernorm_k<<<BL, 256, 0, stream>>>(X, normw, normb, dty);
  pool_k<<<dim3(D_MODEL / 256, BB), 256, 0, stream>>>(dty, pooled);
  head_k<<<BB * N_CLASSES, 64, 0, stream>>>(pooled, headw, headb, (float*)d_out);
}

// Round 7
// 812.853 us; speedup vs baseline: 3.8732x; 1.1110x over previous
//
#include <hip/hip_runtime.h>
#include <hip/hip_bf16.h>

#define N_LAYERS 2
#define D_MODEL 1024
#define D_INNER 2048
#define D_STATE 16
#define D_CONV 4
#define DT_RANK 64
#define N_CLASSES 10
#define BB 4
#define LL 1024
#define BL (BB*LL)   // 4096 rows
#define CH 16        // scan chunks per sequence
#define CLEN (LL/CH) // 64 steps per chunk
#define KS 8         // split-K segments for x_proj
#define KSO 4        // split-K segments for out_proj

typedef __attribute__((ext_vector_type(8))) short bf16x8;
typedef __attribute__((ext_vector_type(4))) float f32x4;

typedef const void __attribute__((address_space(1)))* gas_ptr;
typedef void __attribute__((address_space(3)))* las_ptr;
#define GLDS16(g, p) __builtin_amdgcn_global_load_lds((gas_ptr)(g), (las_ptr)(p), 16, 0, 0)

// ---- fp32 -> bf16 hi/lo split (RNE) -----------------------------------------
__device__ inline void split2(float x, unsigned short& hi, unsigned short& lo) {
  unsigned u = __float_as_uint(x);
  unsigned rh = (u + 0x7FFFu + ((u >> 16) & 1u)) & 0xFFFF0000u;
  hi = (unsigned short)(rh >> 16);
  float xl = x - __uint_as_float(rh);
  unsigned ul = __float_as_uint(xl);
  unsigned rl = (ul + 0x7FFFu + ((ul >> 16) & 1u)) & 0xFFFF0000u;
  lo = (unsigned short)(rl >> 16);
}

__device__ inline unsigned short rnd_bf16(float x) {
  unsigned u = __float_as_uint(x);
  return (unsigned short)((u + 0x7FFFu + ((u >> 16) & 1u)) >> 16);
}

// round weights to bf16 (hi only)
__global__ __launch_bounds__(256) void round_k(const float* __restrict__ in,
    unsigned short* __restrict__ hi) {
  const int i = blockIdx.x * 256 + threadIdx.x;
  const float4 v = ((const float4*)in)[i];
  ushort4 h4;
  h4.x = rnd_bf16(v.x); h4.y = rnd_bf16(v.y);
  h4.z = rnd_bf16(v.z); h4.w = rnd_bf16(v.w);
  ((ushort4*)hi)[i] = h4;
}

// ---------------- LayerNorm -> fp32 out ---------------------------------------
__global__ __launch_bounds__(256) void layernorm_k(const float* __restrict__ x,
    const float* __restrict__ w, const float* __restrict__ b,
    float* __restrict__ out) {
  const int row = blockIdx.x;
  const int t = threadIdx.x;
  const float4 v = *(const float4*)(x + (size_t)row * D_MODEL + t * 4);
  float s = v.x + v.y + v.z + v.w;
  float q = v.x*v.x + v.y*v.y + v.z*v.z + v.w*v.w;
  #pragma unroll
  for (int o = 32; o; o >>= 1) { s += __shfl_down(s, o); q += __shfl_down(q, o); }
  __shared__ float red[8];
  if ((t & 63) == 0) { red[t >> 6] = s; red[4 + (t >> 6)] = q; }
  __syncthreads();
  s = red[0] + red[1] + red[2] + red[3];
  q = red[4] + red[5] + red[6] + red[7];
  const float mean = s * (1.f / D_MODEL);
  const float var  = q * (1.f / D_MODEL) - mean * mean;
  const float rstd = rsqrtf(var + 1e-5f);
  const float4 wv = *(const float4*)(w + t * 4);
  const float4 bv = *(const float4*)(b + t * 4);
  float4 o4;
  o4.x = (v.x - mean) * rstd * wv.x + bv.x;
  o4.y = (v.y - mean) * rstd * wv.y + bv.y;
  o4.z = (v.z - mean) * rstd * wv.z + bv.z;
  o4.w = (v.w - mean) * rstd * wv.w + bv.w;
  *(float4*)(out + (size_t)row * D_MODEL + t * 4) = o4;
}

// ---------------- LayerNorm -> bf16 hi/lo out ---------------------------------
__global__ __launch_bounds__(256) void layernorm_split_k(const float* __restrict__ x,
    const float* __restrict__ w, const float* __restrict__ b,
    unsigned short* __restrict__ oh, unsigned short* __restrict__ ol) {
  const int row = blockIdx.x;
  const int t = threadIdx.x;
  const float4 v = *(const float4*)(x + (size_t)row * D_MODEL + t * 4);
  float s = v.x + v.y + v.z + v.w;
  float q = v.x*v.x + v.y*v.y + v.z*v.z + v.w*v.w;
  #pragma unroll
  for (int o = 32; o; o >>= 1) { s += __shfl_down(s, o); q += __shfl_down(q, o); }
  __shared__ float red[8];
  if ((t & 63) == 0) { red[t >> 6] = s; red[4 + (t >> 6)] = q; }
  __syncthreads();
  s = red[0] + red[1] + red[2] + red[3];
  q = red[4] + red[5] + red[6] + red[7];
  const float mean = s * (1.f / D_MODEL);
  const float var  = q * (1.f / D_MODEL) - mean * mean;
  const float rstd = rsqrtf(var + 1e-5f);
  const float4 wv = *(const float4*)(w + t * 4);
  const float4 bv = *(const float4*)(b + t * 4);
  float4 o4;
  o4.x = (v.x - mean) * rstd * wv.x + bv.x;
  o4.y = (v.y - mean) * rstd * wv.y + bv.y;
  o4.z = (v.z - mean) * rstd * wv.z + bv.z;
  o4.w = (v.w - mean) * rstd * wv.w + bv.w;
  ushort4 h4, l4;
  split2(o4.x, h4.x, l4.x); split2(o4.y, h4.y, l4.y);
  split2(o4.z, h4.z, l4.z); split2(o4.w, h4.w, l4.w);
  ((ushort4*)(oh + (size_t)row * D_MODEL))[t] = h4;
  ((ushort4*)(ol + (size_t)row * D_MODEL))[t] = l4;
}

// ---- split-bf16 MFMA GEMM NT (merged hi/lo K-loop, optional split-K) --------
// C[m,n] = sum_k (Ah+Al)[m,k]*Bh[n,k]. Per K-step stages Ah,Al,Bh (48 KB LDS)
// and issues 32 MFMA into one acc — halves barriers & B-fetch vs seg-loop.
// EPI 0: direct store (KSEG==1). EPI 1: store to partials at C+kz*M*ldc.
template<int EPI, int KSEG>
__global__ __launch_bounds__(256) void mfma_gemm_nt(
    const unsigned short* __restrict__ Ah, const unsigned short* __restrict__ Al,
    const unsigned short* __restrict__ Bh,
    float* __restrict__ C, int M, int N, int K, int ldc) {
  __shared__ unsigned short As[2][128 * 64];
  __shared__ unsigned short Bs[128 * 64];
  const int tid = threadIdx.x;
  const int w = tid >> 6, l = tid & 63;
  const int wr = w >> 1, wc = w & 1;
  const int m0 = blockIdx.y * 128, n0 = blockIdx.x * 128;
  const int kz = (KSEG > 1) ? blockIdx.z : 0;
  const int kbeg = kz * (K / KSEG);
  const int kend = kbeg + K / KSEG;
  const int srow = l >> 3;             // staging row within 8-row block
  const int scol = (l & 7) * 8;        // staging col (elements)
  const int fr = l & 15;               // fragment row
  const int fk = (l >> 4) * 8;         // fragment k offset
  f32x4 acc[4][4] = {};

  #pragma unroll 1
  for (int k0 = kbeg; k0 < kend; k0 += 64) {
    __syncthreads();                  // previous compute done before overwrite
    #pragma unroll
    for (int it = 0; it < 4; ++it) {
      const int bi = it * 4 + w;      // 1 KB block id 0..15
      const int row = bi * 8 + srow;
      GLDS16(Ah + (size_t)(m0 + row) * K + k0 + scol, &As[0][bi * 512 + l * 8]);
      GLDS16(Al + (size_t)(m0 + row) * K + k0 + scol, &As[1][bi * 512 + l * 8]);
      GLDS16(Bh + (size_t)(n0 + row) * K + k0 + scol, &Bs[bi * 512 + l * 8]);
    }
    __syncthreads();                  // staging visible (vmcnt drained)
    #pragma unroll
    for (int kk = 0; kk < 64; kk += 32) {
      bf16x8 b[4], ah[4], al[4];
      #pragma unroll
      for (int f = 0; f < 4; ++f)
        b[f] = *(const bf16x8*)&Bs[(wc * 64 + f * 16 + fr) * 64 + kk + fk];
      #pragma unroll
      for (int f = 0; f < 4; ++f)
        ah[f] = *(const bf16x8*)&As[0][(wr * 64 + f * 16 + fr) * 64 + kk + fk];
      #pragma unroll
      for (int f = 0; f < 4; ++f)
        al[f] = *(const bf16x8*)&As[1][(wr * 64 + f * 16 + fr) * 64 + kk + fk];
      #pragma unroll
      for (int i = 0; i < 4; ++i)
        #pragma unroll
        for (int j = 0; j < 4; ++j)
          acc[i][j] = __builtin_amdgcn_mfma_f32_16x16x32_bf16(
              ah[i], b[j], acc[i][j], 0, 0, 0);
      #pragma unroll
      for (int i = 0; i < 4; ++i)
        #pragma unroll
        for (int j = 0; j < 4; ++j)
          acc[i][j] = __builtin_amdgcn_mfma_f32_16x16x32_bf16(
              al[i], b[j], acc[i][j], 0, 0, 0);
    }
  }
  float* Cw = (EPI == 1) ? C + (size_t)kz * M * ldc : C;
  const int orow = (l >> 4) * 4;
  const int ocol = l & 15;
  #pragma unroll
  for (int i = 0; i < 4; ++i)
    #pragma unroll
    for (int j = 0; j < 4; ++j)
      #pragma unroll
      for (int r = 0; r < 4; ++r) {
        const int m = m0 + wr * 64 + i * 16 + orow + r;
        const int n = n0 + wc * 64 + j * 16 + ocol;
        Cw[(size_t)m * ldc + n] = acc[i][j][r];
      }
}

// fixed-order reduce of out_proj partials + residual -> X (float4 lanes)
__global__ __launch_bounds__(256) void outproj_reduce_k(
    const float* __restrict__ part, float* __restrict__ X) {
  const int i = blockIdx.x * 256 + threadIdx.x;   // over BL*D_MODEL/4
  float4 s = ((const float4*)X)[i];
  #pragma unroll
  for (int k = 0; k < KSO; k++) {
    const float4 p = ((const float4*)(part + (size_t)k * BL * D_MODEL))[i];
    s.x += p.x; s.y += p.y; s.z += p.z; s.w += p.w;
  }
  ((float4*)X)[i] = s;
}

// ---------------- fp32 SGEMM NT (dt GEMM) -------------------------------------
// EPI: 0 none; 1 softplus(acc + bias[n])
template<int BM, int BN, int BK, int TM, int TN, int EPI>
__global__ __launch_bounds__(256) void sgemm_nt(
    const float* __restrict__ A, const float* __restrict__ B,
    float* __restrict__ C, int M, int N, int K, int lda, int ldb, int ldc,
    const float* __restrict__ bias) {
  constexpr int THREADS = 256;
  constexpr int NT = BN / TN;
  constexpr int K4 = BK / 4;
  constexpr int A_F4 = BM * BK / (THREADS * 4);
  constexpr int B_F4 = BN * BK / (THREADS * 4);
  static_assert((BM / TM) * (BN / TN) == THREADS, "thread shape");
  __shared__ float As[BK][BM + 4];
  __shared__ float Bs[BK][BN + 4];
  const int tid = threadIdx.x;
  const int m0 = blockIdx.y * BM;
  const int n0 = blockIdx.x * BN;
  const int tn = (tid % NT) * TN;
  const int tm = (tid / NT) * TM;
  float acc[TM][TN] = {};
  for (int k0 = 0; k0 < K; k0 += BK) {
    #pragma unroll
    for (int i = 0; i < A_F4; i++) {
      int li = tid + i * THREADS;
      int r = li / K4, c4 = li % K4;
      float4 v = *(const float4*)(A + (size_t)(m0 + r) * lda + k0 + c4 * 4);
      As[c4*4+0][r] = v.x; As[c4*4+1][r] = v.y; As[c4*4+2][r] = v.z; As[c4*4+3][r] = v.w;
    }
    #pragma unroll
    for (int i = 0; i < B_F4; i++) {
      int li = tid + i * THREADS;
      int r = li / K4, c4 = li % K4;
      float4 v = *(const float4*)(B + (size_t)(n0 + r) * ldb + k0 + c4 * 4);
      Bs[c4*4+0][r] = v.x; Bs[c4*4+1][r] = v.y; Bs[c4*4+2][r] = v.z; Bs[c4*4+3][r] = v.w;
    }
    __syncthreads();
    #pragma unroll
    for (int k = 0; k < BK; k++) {
      float a[TM], bf[TN];
      #pragma unroll
      for (int i = 0; i < TM; i++) a[i] = As[k][tm + i];
      #pragma unroll
      for (int j = 0; j < TN; j++) bf[j] = Bs[k][tn + j];
      #pragma unroll
      for (int i = 0; i < TM; i++)
        #pragma unroll
        for (int j = 0; j < TN; j++)
          acc[i][j] = fmaf(a[i], bf[j], acc[i][j]);
    }
    __syncthreads();
  }
  #pragma unroll
  for (int i = 0; i < TM; i++) {
    const int m = m0 + tm + i;
    #pragma unroll
    for (int j = 0; j < TN; j++) {
      const int n = n0 + tn + j;
      float v = acc[i][j];
      if constexpr (EPI == 1) {
        v += bias[n];
        v = (v > 20.f) ? v : log1pf(__expf(v));
      }
      C[(size_t)m * ldc + n] = v;
    }
  }
}

// ---- x_proj split-K: part[kz][m][n] = sum_{k in seg kz} xc[m,k]*xpw[n,k] ----
__global__ __launch_bounds__(256) void sgemm_splitk_k(
    const float* __restrict__ A, const float* __restrict__ B,
    float* __restrict__ part) {
  __shared__ float As[32][64 + 4];
  __shared__ float Bs[32][32 + 4];
  const int tid = threadIdx.x;
  const int n0 = blockIdx.x * 32;
  const int m0 = blockIdx.y * 64;
  const int kz = blockIdx.z;
  const int tn = (tid & 15) * 2;
  const int tm = (tid >> 4) * 4;
  float acc[4][2] = {};
  for (int kb = 0; kb < 256; kb += 32) {
    const int k0 = kz * 256 + kb;
    #pragma unroll
    for (int i = 0; i < 2; i++) {
      int li = tid + i * 256;          // 512 float4 slots for A (64x32)
      int r = li >> 3, c4 = li & 7;
      float4 v = *(const float4*)(A + (size_t)(m0 + r) * D_INNER + k0 + c4 * 4);
      As[c4*4+0][r] = v.x; As[c4*4+1][r] = v.y;
      As[c4*4+2][r] = v.z; As[c4*4+3][r] = v.w;
    }
    {
      int r = tid >> 3, c4 = tid & 7;  // 256 float4 slots for B (32x32)
      float4 v = *(const float4*)(B + (size_t)(n0 + r) * D_INNER + k0 + c4 * 4);
      Bs[c4*4+0][r] = v.x; Bs[c4*4+1][r] = v.y;
      Bs[c4*4+2][r] = v.z; Bs[c4*4+3][r] = v.w;
    }
    __syncthreads();
    #pragma unroll
    for (int k = 0; k < 32; k++) {
      float a[4], bf[2];
      #pragma unroll
      for (int i = 0; i < 4; i++) a[i] = As[k][tm + i];
      bf[0] = Bs[k][tn]; bf[1] = Bs[k][tn + 1];
      #pragma unroll
      for (int i = 0; i < 4; i++) {
        acc[i][0] = fmaf(a[i], bf[0], acc[i][0]);
        acc[i][1] = fmaf(a[i], bf[1], acc[i][1]);
      }
    }
    __syncthreads();
  }
  float* p = part + (size_t)kz * BL * 96;
  #pragma unroll
  for (int i = 0; i < 4; i++) {
    const int m = m0 + tm + i;
    p[(size_t)m * 96 + n0 + tn]     = acc[i][0];
    p[(size_t)m * 96 + n0 + tn + 1] = acc[i][1];
  }
}

// fixed-order deterministic reduce of the KS partials -> xdbl
__global__ __launch_bounds__(256) void xproj_reduce_k(
    const float* __restrict__ part, float* __restrict__ out) {
  const int i = blockIdx.x * 256 + threadIdx.x;   // over BL*96
  float s = 0.f;
  #pragma unroll
  for (int k = 0; k < KS; k++) s += part[(size_t)k * BL * 96 + i];
  out[i] = s;
}

// ---------------- causal depthwise conv (width 4) + SiLU --------------------
__global__ __launch_bounds__(256) void conv_silu_k(const float* __restrict__ xz,
    const float* __restrict__ cw, const float* __restrict__ cb,
    float* __restrict__ xc) {
  const int gid = blockIdx.x * 256 + threadIdx.x;
  const int c = gid & (D_INNER - 1);
  const int l = (gid >> 11) & (LL - 1);
  const int b = gid >> 21;
  const float4 w = *(const float4*)(cw + c * 4);
  const float* base = xz + ((size_t)(b << 10) + l) * (2 * D_INNER) + c;
  float acc = cb[c];
  acc = fmaf(w.w, base[0], acc);
  if (l >= 1) acc = fmaf(w.z, base[-(2 * D_INNER)], acc);
  if (l >= 2) acc = fmaf(w.y, base[-2 * (2 * D_INNER)], acc);
  if (l >= 3) acc = fmaf(w.x, base[-3 * (2 * D_INNER)], acc);
  xc[gid] = acc / (1.f + __expf(-acc));
}

// ------- chunked selective scan, pass 1 --------------------------------------
__global__ __launch_bounds__(256) void scan_pass1_k(
    const float* __restrict__ dt, const float* __restrict__ xc,
    const float* __restrict__ xdbl, const float* __restrict__ A_log,
    float* __restrict__ hend, float* __restrict__ sumdt) {
  const int c = blockIdx.x * 256 + threadIdx.x;
  const int k = blockIdx.y;
  const int b = blockIdx.z;
  float Ac[D_STATE];
  #pragma unroll
  for (int n = 0; n < D_STATE; n++) Ac[n] = -__expf(A_log[c * D_STATE + n]);
  float h[D_STATE] = {};
  float sd = 0.f;
  const size_t r0 = (size_t)b * LL + (size_t)k * CLEN;
  const float* dtp = dt + r0 * D_INNER + c;
  const float* xcp = xc + r0 * D_INNER + c;
  const float* Bp  = xdbl + r0 * 96 + DT_RANK;

  float dtv = dtp[0];
  float xv  = xcp[0];
  float4 B0 = *(const float4*)(Bp + 0);
  float4 B1 = *(const float4*)(Bp + 4);
  float4 B2 = *(const float4*)(Bp + 8);
  float4 B3 = *(const float4*)(Bp + 12);
  for (int l = 0; l < CLEN; l++) {
    const int lp = (l + 1 < CLEN) ? l + 1 : l;
    const float dtv2 = dtp[(size_t)lp * D_INNER];
    const float xv2  = xcp[(size_t)lp * D_INNER];
    const float4 B0n = *(const float4*)(Bp + (size_t)lp * 96 + 0);
    const float4 B1n = *(const float4*)(Bp + (size_t)lp * 96 + 4);
    const float4 B2n = *(const float4*)(Bp + (size_t)lp * 96 + 8);
    const float4 B3n = *(const float4*)(Bp + (size_t)lp * 96 + 12);
    sd += dtv;
    const float dx = dtv * xv;
    const float Bv[D_STATE] = {B0.x,B0.y,B0.z,B0.w, B1.x,B1.y,B1.z,B1.w,
                               B2.x,B2.y,B2.z,B2.w, B3.x,B3.y,B3.z,B3.w};
    #pragma unroll
    for (int n = 0; n < D_STATE; n++)
      h[n] = fmaf(__expf(dtv * Ac[n]), h[n], dx * Bv[n]);
    dtv = dtv2; xv = xv2; B0 = B0n; B1 = B1n; B2 = B2n; B3 = B3n;
  }
  float* he = hend + (((size_t)(b * CH + k) * D_INNER + c) << 4);
  #pragma unroll
  for (int n = 0; n < D_STATE; n += 4)
    *(float4*)(he + n) = make_float4(h[n], h[n+1], h[n+2], h[n+3]);
  sumdt[(size_t)(b * CH + k) * D_INNER + c] = sd;
}

// ------- chunked scan fixup ---------------------------------------------------
__global__ __launch_bounds__(256) void scan_fix_k(
    float* __restrict__ hend, const float* __restrict__ sumdt,
    const float* __restrict__ A_log) {
  const int gid = blockIdx.x * 256 + threadIdx.x;
  const int n = gid & 15;
  const int c = (gid >> 4) & (D_INNER - 1);
  const int b = gid >> 15;
  const float Ac = -__expf(A_log[c * D_STATE + n]);
  float hrun = 0.f;
  for (int k = 0; k < CH; k++) {
    const size_t base = (size_t)(b * CH + k) * D_INNER + c;
    const float sd = sumdt[base];
    float* hp = hend + (base << 4) + n;
    const float tmp = *hp;
    *hp = hrun;
    hrun = fmaf(__expf(Ac * sd), hrun, tmp);
  }
}

// ------- chunked scan pass 3: replay, gate, emit y as bf16 hi/lo -------------
__global__ __launch_bounds__(256) void scan_pass3_k(
    const float* __restrict__ dt, const float* __restrict__ xc,
    const float* __restrict__ xdbl, const float* __restrict__ xz,
    const float* __restrict__ h0, const float* __restrict__ A_log,
    const float* __restrict__ Dp,
    unsigned short* __restrict__ yh, unsigned short* __restrict__ yl) {
  const int c = blockIdx.x * 256 + threadIdx.x;
  const int k = blockIdx.y;
  const int b = blockIdx.z;
  float Ac[D_STATE];
  #pragma unroll
  for (int n = 0; n < D_STATE; n++) Ac[n] = -__expf(A_log[c * D_STATE + n]);
  const float Dv = Dp[c];
  float h[D_STATE];
  const float* hp = h0 + (((size_t)(b * CH + k) * D_INNER + c) << 4);
  #pragma unroll
  for (int n = 0; n < D_STATE; n += 4) {
    const float4 v = *(const float4*)(hp + n);
    h[n] = v.x; h[n+1] = v.y; h[n+2] = v.z; h[n+3] = v.w;
  }
  const size_t r0 = (size_t)b * LL + (size_t)k * CLEN;
  const float* dtp = dt + r0 * D_INNER + c;
  const float* xcp = xc + r0 * D_INNER + c;
  const float* Bp  = xdbl + r0 * 96 + DT_RANK;
  const float* zp  = xz + r0 * (size_t)(2 * D_INNER) + D_INNER + c;
  unsigned short* yhp = yh + r0 * D_INNER + c;
  unsigned short* ylp = yl + r0 * D_INNER + c;

  float dtv = dtp[0];
  float xv  = xcp[0];
  float zv  = zp[0];
  float4 B0 = *(const float4*)(Bp + 0);
  float4 B1 = *(const float4*)(Bp + 4);
  float4 B2 = *(const float4*)(Bp + 8);
  float4 B3 = *(const float4*)(Bp + 12);
  float4 C0 = *(const float4*)(Bp + 16);
  float4 C1 = *(const float4*)(Bp + 20);
  float4 C2 = *(const float4*)(Bp + 24);
  float4 C3 = *(const float4*)(Bp + 28);
  for (int l = 0; l < CLEN; l++) {
    const int lp = (l + 1 < CLEN) ? l + 1 : l;
    const float dtv2 = dtp[(size_t)lp * D_INNER];
    const float xv2  = xcp[(size_t)lp * D_INNER];
    const float zv2  = zp[(size_t)lp * 2 * D_INNER];
    const float4 B0n = *(const float4*)(Bp + (size_t)lp * 96 + 0);
    const float4 B1n = *(const float4*)(Bp + (size_t)lp * 96 + 4);
    const float4 B2n = *(const float4*)(Bp + (size_t)lp * 96 + 8);
    const float4 B3n = *(const float4*)(Bp + (size_t)lp * 96 + 12);
    const float4 C0n = *(const float4*)(Bp + (size_t)lp * 96 + 16);
    const float4 C1n = *(const float4*)(Bp + (size_t)lp * 96 + 20);
    const float4 C2n = *(const float4*)(Bp + (size_t)lp * 96 + 24);
    const float4 C3n = *(const float4*)(Bp + (size_t)lp * 96 + 28);
    const float dx = dtv * xv;
    const float Bv[D_STATE] = {B0.x,B0.y,B0.z,B0.w, B1.x,B1.y,B1.z,B1.w,
                               B2.x,B2.y,B2.z,B2.w, B3.x,B3.y,B3.z,B3.w};
    const float Cv[D_STATE] = {C0.x,C0.y,C0.z,C0.w, C1.x,C1.y,C1.z,C1.w,
                               C2.x,C2.y,C2.z,C2.w, C3.x,C3.y,C3.z,C3.w};
    float y = 0.f;
    #pragma unroll
    for (int n = 0; n < D_STATE; n++) {
      h[n] = fmaf(__expf(dtv * Ac[n]), h[n], dx * Bv[n]);
      y = fmaf(h[n], Cv[n], y);
    }
    y = fmaf(xv, Dv, y);
    y *= zv / (1.f + __expf(-zv));
    unsigned short uh, ul;
    split2(y, uh, ul);
    yhp[(size_t)l * D_INNER] = uh;
    ylp[(size_t)l * D_INNER] = ul;
    dtv = dtv2; xv = xv2; zv = zv2;
    B0 = B0n; B1 = B1n; B2 = B2n; B3 = B3n;
    C0 = C0n; C1 = C1n; C2 = C2n; C3 = C3n;
  }
}

// ---------------- mean pool over L ------------------------------------------
__global__ __launch_bounds__(256) void pool_k(const float* __restrict__ h,
    float* __restrict__ pooled) {
  const int d = blockIdx.x * 256 + threadIdx.x;
  const int b = blockIdx.y;
  float s = 0.f;
  for (int l = 0; l < LL; l++) s += h[((size_t)(b * LL + l)) * D_MODEL + d];
  pooled[b * D_MODEL + d] = s * (1.f / LL);
}

// ---------------- classifier head --------------------------------------------
__global__ __launch_bounds__(64) void head_k(const float* __restrict__ pooled,
    const float* __restrict__ hw, const float* __restrict__ hb,
    float* __restrict__ out) {
  const int b = blockIdx.x / N_CLASSES;
  const int j = blockIdx.x % N_CLASSES;
  float s = 0.f;
  for (int k = threadIdx.x; k < D_MODEL; k += 64)
    s = fmaf(pooled[b * D_MODEL + k], hw[j * D_MODEL + k], s);
  #pragma unroll
  for (int o = 32; o; o >>= 1) s += __shfl_down(s, o);
  if (threadIdx.x == 0) out[b * N_CLASSES + j] = s + hb[j];
}

extern "C" void kernel_launch(void* const* d_in, const int* in_sizes, int n_in,
                              void* d_out, int out_size, void* d_ws, size_t ws_size,
                              hipStream_t stream) {
  const float* x0    = (const float*)d_in[0];
  const float* ln1w  = (const float*)d_in[1];
  const float* ln1b  = (const float*)d_in[2];
  const float* inw   = (const float*)d_in[3];
  const float* convw = (const float*)d_in[4];
  const float* convb = (const float*)d_in[5];
  const float* xpw   = (const float*)d_in[6];
  const float* dtpw  = (const float*)d_in[7];
  const float* dtpb  = (const float*)d_in[8];
  const float* Alog  = (const float*)d_in[9];
  const float* Dp    = (const float*)d_in[10];
  const float* outw  = (const float*)d_in[11];
  const float* normw = (const float*)d_in[12];
  const float* normb = (const float*)d_in[13];
  const float* headw = (const float*)d_in[14];
  const float* headb = (const float*)d_in[15];

  float* ws = (float*)d_ws;
  size_t f = 0;
  float* X      = ws + f; f += (size_t)BL * D_MODEL;        // 4M
  float* xz     = ws + f; f += (size_t)BL * 2 * D_INNER;    // 16M
  float* xc     = ws + f; f += (size_t)BL * D_INNER;        // 8M
  float* xdbl   = ws + f; f += (size_t)BL * 96;             // 0.375M
  float* dty    = ws + f; f += (size_t)BL * D_INNER;        // 8M (dt; final-LN scratch)
  float* pooled = ws + f; f += 4096;
  float* hend   = ws + f; f += (size_t)BB * CH * D_INNER * D_STATE;  // 2M
  float* sumdt  = ws + f; f += (size_t)BB * CH * D_INNER;            // 0.125M
  float* xpart  = ws + f; f += (size_t)KS * BL * 96;                 // 3.15M
  unsigned short* hh  = (unsigned short*)(ws + f); f += (size_t)BL * D_MODEL / 2;
  unsigned short* hl  = (unsigned short*)(ws + f); f += (size_t)BL * D_MODEL / 2;
  unsigned short* yh  = (unsigned short*)(ws + f); f += (size_t)BL * D_INNER / 2;
  unsigned short* yl  = (unsigned short*)(ws + f); f += (size_t)BL * D_INNER / 2;
  unsigned short* wih = (unsigned short*)(ws + f); f += (size_t)2 * D_INNER * D_MODEL / 2;
  unsigned short* woh = (unsigned short*)(ws + f); f += (size_t)D_MODEL * D_INNER / 2;
  // out_proj split-K partials overlay xz (dead between scan_pass3 and next in_proj)
  float* opart = xz;   // KSO * BL * D_MODEL = 16M floats == sizeof(xz)

  hipMemcpyAsync(X, x0, (size_t)BL * D_MODEL * sizeof(float),
                 hipMemcpyDeviceToDevice, stream);

  for (int layer = 0; layer < N_LAYERS; ++layer) {
    // LayerNorm -> bf16 hi/lo A-operand
    layernorm_split_k<<<BL, 256, 0, stream>>>(X, ln1w + layer * D_MODEL,
                                              ln1b + layer * D_MODEL, hh, hl);
    // round weights to bf16 (hi only) for this layer
    round_k<<<(2 * D_INNER * D_MODEL) / 1024, 256, 0, stream>>>(
        inw + (size_t)layer * 2 * D_INNER * D_MODEL, wih);
    round_k<<<(D_MODEL * D_INNER) / 1024, 256, 0, stream>>>(
        outw + (size_t)layer * D_MODEL * D_INNER, woh);
    // xz = h @ in_w^T : M=4096 N=4096 K=1024 (merged hi/lo MFMA)
    mfma_gemm_nt<0, 1><<<dim3(4096 / 128, 4096 / 128), 256, 0, stream>>>(
        hh, hl, wih, xz, BL, 2 * D_INNER, D_MODEL, 2 * D_INNER);
    conv_silu_k<<<(BL * D_INNER) / 256, 256, 0, stream>>>(
        xz, convw + layer * D_INNER * D_CONV, convb + layer * D_INNER, xc);
    // x_dbl = xc @ xp_w^T : M=4096 N=96 K=2048 (fp32 split-K + reduce)
    sgemm_splitk_k<<<dim3(96 / 32, 4096 / 64, KS), 256, 0, stream>>>(
        xc, xpw + (size_t)layer * 96 * D_INNER, xpart);
    xproj_reduce_k<<<(BL * 96) / 256, 256, 0, stream>>>(xpart, xdbl);
    // dt = softplus(dt_r @ dtp_w^T + dtp_b) : M=4096 N=2048 K=64 (fp32)
    sgemm_nt<128,128,16,8,8,1><<<dim3(2048 / 128, 4096 / 128), 256, 0, stream>>>(
        xdbl, dtpw + (size_t)layer * D_INNER * DT_RANK, dty,
        BL, D_INNER, DT_RANK, 96, DT_RANK, D_INNER,
        dtpb + layer * D_INNER);
    // chunked scan
    scan_pass1_k<<<dim3(D_INNER / 256, CH, BB), 256, 0, stream>>>(
        dty, xc, xdbl, Alog + (size_t)layer * D_INNER * D_STATE, hend, sumdt);
    scan_fix_k<<<(BB * D_INNER * D_STATE) / 256, 256, 0, stream>>>(
        hend, sumdt, Alog + (size_t)layer * D_INNER * D_STATE);
    scan_pass3_k<<<dim3(D_INNER / 256, CH, BB), 256, 0, stream>>>(
        dty, xc, xdbl, xz, hend, Alog + (size_t)layer * D_INNER * D_STATE,
        Dp + layer * D_INNER, yh, yl);
    // y @ out_w^T : M=4096 N=1024 K=2048, split-K=4 partials (overlay xz)
    mfma_gemm_nt<1, KSO><<<dim3(1024 / 128, 4096 / 128, KSO), 256, 0, stream>>>(
        yh, yl, woh, opart, BL, D_MODEL, D_INNER, D_MODEL);
    // X += sum_k partials (fixed order, deterministic)
    outproj_reduce_k<<<(BL * D_MODEL / 4) / 256, 256, 0, stream>>>(opart, X);
  }

  layernorm_k<<<BL, 256, 0, stream>>>(X, normw, normb, dty);
  pool_k<<<dim3(D_MODEL / 256, BB), 256, 0, stream>>>(dty, pooled);
  head_k<<<BB * N_CLASSES, 64, 0, stream>>>(pooled, headw, headb, (float*)d_out);
}

// Round 8
// 756.550 us; speedup vs baseline: 4.1614x; 1.0744x over previous
//
#include <hip/hip_runtime.h>
#include <hip/hip_bf16.h>

#define N_LAYERS 2
#define D_MODEL 1024
#define D_INNER 2048
#define D_STATE 16
#define D_CONV 4
#define DT_RANK 64
#define N_CLASSES 10
#define BB 4
#define LL 1024
#define BL (BB*LL)   // 4096 rows
#define CH 32        // scan chunks per sequence
#define CLEN (LL/CH) // 32 steps per chunk
#define KS 8         // split-K segments for x_proj
#define KSO 2        // split-K segments for out_proj

typedef __attribute__((ext_vector_type(8))) short bf16x8;
typedef __attribute__((ext_vector_type(4))) float f32x4;

typedef const void __attribute__((address_space(1)))* gas_ptr;
typedef void __attribute__((address_space(3)))* las_ptr;
#define GLDS16(g, p) __builtin_amdgcn_global_load_lds((gas_ptr)(g), (las_ptr)(p), 16, 0, 0)

// ---- fp32 -> bf16 hi/lo split (RNE) -----------------------------------------
__device__ inline void split2(float x, unsigned short& hi, unsigned short& lo) {
  unsigned u = __float_as_uint(x);
  unsigned rh = (u + 0x7FFFu + ((u >> 16) & 1u)) & 0xFFFF0000u;
  hi = (unsigned short)(rh >> 16);
  float xl = x - __uint_as_float(rh);
  unsigned ul = __float_as_uint(xl);
  unsigned rl = (ul + 0x7FFFu + ((ul >> 16) & 1u)) & 0xFFFF0000u;
  lo = (unsigned short)(rl >> 16);
}

__device__ inline unsigned short rnd_bf16(float x) {
  unsigned u = __float_as_uint(x);
  return (unsigned short)((u + 0x7FFFu + ((u >> 16) & 1u)) >> 16);
}

// round weights to bf16 (hi only)
__global__ __launch_bounds__(256) void round_k(const float* __restrict__ in,
    unsigned short* __restrict__ hi) {
  const int i = blockIdx.x * 256 + threadIdx.x;
  const float4 v = ((const float4*)in)[i];
  ushort4 h4;
  h4.x = rnd_bf16(v.x); h4.y = rnd_bf16(v.y);
  h4.z = rnd_bf16(v.z); h4.w = rnd_bf16(v.w);
  ((ushort4*)hi)[i] = h4;
}

// ---------------- LayerNorm -> fp32 out ---------------------------------------
__global__ __launch_bounds__(256) void layernorm_k(const float* __restrict__ x,
    const float* __restrict__ w, const float* __restrict__ b,
    float* __restrict__ out) {
  const int row = blockIdx.x;
  const int t = threadIdx.x;
  const float4 v = *(const float4*)(x + (size_t)row * D_MODEL + t * 4);
  float s = v.x + v.y + v.z + v.w;
  float q = v.x*v.x + v.y*v.y + v.z*v.z + v.w*v.w;
  #pragma unroll
  for (int o = 32; o; o >>= 1) { s += __shfl_down(s, o); q += __shfl_down(q, o); }
  __shared__ float red[8];
  if ((t & 63) == 0) { red[t >> 6] = s; red[4 + (t >> 6)] = q; }
  __syncthreads();
  s = red[0] + red[1] + red[2] + red[3];
  q = red[4] + red[5] + red[6] + red[7];
  const float mean = s * (1.f / D_MODEL);
  const float var  = q * (1.f / D_MODEL) - mean * mean;
  const float rstd = rsqrtf(var + 1e-5f);
  const float4 wv = *(const float4*)(w + t * 4);
  const float4 bv = *(const float4*)(b + t * 4);
  float4 o4;
  o4.x = (v.x - mean) * rstd * wv.x + bv.x;
  o4.y = (v.y - mean) * rstd * wv.y + bv.y;
  o4.z = (v.z - mean) * rstd * wv.z + bv.z;
  o4.w = (v.w - mean) * rstd * wv.w + bv.w;
  *(float4*)(out + (size_t)row * D_MODEL + t * 4) = o4;
}

// ---------------- LayerNorm -> bf16 hi/lo out ---------------------------------
__global__ __launch_bounds__(256) void layernorm_split_k(const float* __restrict__ x,
    const float* __restrict__ w, const float* __restrict__ b,
    unsigned short* __restrict__ oh, unsigned short* __restrict__ ol) {
  const int row = blockIdx.x;
  const int t = threadIdx.x;
  const float4 v = *(const float4*)(x + (size_t)row * D_MODEL + t * 4);
  float s = v.x + v.y + v.z + v.w;
  float q = v.x*v.x + v.y*v.y + v.z*v.z + v.w*v.w;
  #pragma unroll
  for (int o = 32; o; o >>= 1) { s += __shfl_down(s, o); q += __shfl_down(q, o); }
  __shared__ float red[8];
  if ((t & 63) == 0) { red[t >> 6] = s; red[4 + (t >> 6)] = q; }
  __syncthreads();
  s = red[0] + red[1] + red[2] + red[3];
  q = red[4] + red[5] + red[6] + red[7];
  const float mean = s * (1.f / D_MODEL);
  const float var  = q * (1.f / D_MODEL) - mean * mean;
  const float rstd = rsqrtf(var + 1e-5f);
  const float4 wv = *(const float4*)(w + t * 4);
  const float4 bv = *(const float4*)(b + t * 4);
  float4 o4;
  o4.x = (v.x - mean) * rstd * wv.x + bv.x;
  o4.y = (v.y - mean) * rstd * wv.y + bv.y;
  o4.z = (v.z - mean) * rstd * wv.z + bv.z;
  o4.w = (v.w - mean) * rstd * wv.w + bv.w;
  ushort4 h4, l4;
  split2(o4.x, h4.x, l4.x); split2(o4.y, h4.y, l4.y);
  split2(o4.z, h4.z, l4.z); split2(o4.w, h4.w, l4.w);
  ((ushort4*)(oh + (size_t)row * D_MODEL))[t] = h4;
  ((ushort4*)(ol + (size_t)row * D_MODEL))[t] = l4;
}

// ---- split-bf16 MFMA GEMM NT (merged hi/lo K-loop, optional split-K) --------
// C[m,n] = sum_k (Ah+Al)[m,k]*Bh[n,k]. Per K-step stages Ah,Al,Bh (48 KB LDS)
// and issues 32 MFMA into one acc. EPI 0: direct store; 1: partials.
template<int EPI, int KSEG>
__global__ __launch_bounds__(256) void mfma_gemm_nt(
    const unsigned short* __restrict__ Ah, const unsigned short* __restrict__ Al,
    const unsigned short* __restrict__ Bh,
    float* __restrict__ C, int M, int N, int K, int ldc) {
  __shared__ unsigned short As[2][128 * 64];
  __shared__ unsigned short Bs[128 * 64];
  const int tid = threadIdx.x;
  const int w = tid >> 6, l = tid & 63;
  const int wr = w >> 1, wc = w & 1;
  const int m0 = blockIdx.y * 128, n0 = blockIdx.x * 128;
  const int kz = (KSEG > 1) ? blockIdx.z : 0;
  const int kbeg = kz * (K / KSEG);
  const int kend = kbeg + K / KSEG;
  const int srow = l >> 3;             // staging row within 8-row block
  const int scol = (l & 7) * 8;        // staging col (elements)
  const int fr = l & 15;               // fragment row
  const int fk = (l >> 4) * 8;         // fragment k offset
  f32x4 acc[4][4] = {};

  #pragma unroll 1
  for (int k0 = kbeg; k0 < kend; k0 += 64) {
    __syncthreads();                  // previous compute done before overwrite
    #pragma unroll
    for (int it = 0; it < 4; ++it) {
      const int bi = it * 4 + w;      // 1 KB block id 0..15
      const int row = bi * 8 + srow;
      GLDS16(Ah + (size_t)(m0 + row) * K + k0 + scol, &As[0][bi * 512 + l * 8]);
      GLDS16(Al + (size_t)(m0 + row) * K + k0 + scol, &As[1][bi * 512 + l * 8]);
      GLDS16(Bh + (size_t)(n0 + row) * K + k0 + scol, &Bs[bi * 512 + l * 8]);
    }
    __syncthreads();                  // staging visible (vmcnt drained)
    #pragma unroll
    for (int kk = 0; kk < 64; kk += 32) {
      bf16x8 b[4], ah[4], al[4];
      #pragma unroll
      for (int f = 0; f < 4; ++f)
        b[f] = *(const bf16x8*)&Bs[(wc * 64 + f * 16 + fr) * 64 + kk + fk];
      #pragma unroll
      for (int f = 0; f < 4; ++f)
        ah[f] = *(const bf16x8*)&As[0][(wr * 64 + f * 16 + fr) * 64 + kk + fk];
      #pragma unroll
      for (int f = 0; f < 4; ++f)
        al[f] = *(const bf16x8*)&As[1][(wr * 64 + f * 16 + fr) * 64 + kk + fk];
      #pragma unroll
      for (int i = 0; i < 4; ++i)
        #pragma unroll
        for (int j = 0; j < 4; ++j)
          acc[i][j] = __builtin_amdgcn_mfma_f32_16x16x32_bf16(
              ah[i], b[j], acc[i][j], 0, 0, 0);
      #pragma unroll
      for (int i = 0; i < 4; ++i)
        #pragma unroll
        for (int j = 0; j < 4; ++j)
          acc[i][j] = __builtin_amdgcn_mfma_f32_16x16x32_bf16(
              al[i], b[j], acc[i][j], 0, 0, 0);
    }
  }
  float* Cw = (EPI == 1) ? C + (size_t)kz * M * ldc : C;
  const int orow = (l >> 4) * 4;
  const int ocol = l & 15;
  #pragma unroll
  for (int i = 0; i < 4; ++i)
    #pragma unroll
    for (int j = 0; j < 4; ++j)
      #pragma unroll
      for (int r = 0; r < 4; ++r) {
        const int m = m0 + wr * 64 + i * 16 + orow + r;
        const int n = n0 + wc * 64 + j * 16 + ocol;
        Cw[(size_t)m * ldc + n] = acc[i][j][r];
      }
}

// fixed-order reduce of out_proj partials + residual -> X (float4 lanes)
__global__ __launch_bounds__(256) void outproj_reduce_k(
    const float* __restrict__ part, float* __restrict__ X) {
  const int i = blockIdx.x * 256 + threadIdx.x;   // over BL*D_MODEL/4
  float4 s = ((const float4*)X)[i];
  #pragma unroll
  for (int k = 0; k < KSO; k++) {
    const float4 p = ((const float4*)(part + (size_t)k * BL * D_MODEL))[i];
    s.x += p.x; s.y += p.y; s.z += p.z; s.w += p.w;
  }
  ((float4*)X)[i] = s;
}

// ---------------- fp32 SGEMM NT (dt GEMM) -------------------------------------
// EPI: 0 none; 1 softplus(acc + bias[n])
template<int BM, int BN, int BK, int TM, int TN, int EPI>
__global__ __launch_bounds__(256) void sgemm_nt(
    const float* __restrict__ A, const float* __restrict__ B,
    float* __restrict__ C, int M, int N, int K, int lda, int ldb, int ldc,
    const float* __restrict__ bias) {
  constexpr int THREADS = 256;
  constexpr int NT = BN / TN;
  constexpr int K4 = BK / 4;
  constexpr int A_F4 = BM * BK / (THREADS * 4);
  constexpr int B_F4 = BN * BK / (THREADS * 4);
  static_assert((BM / TM) * (BN / TN) == THREADS, "thread shape");
  __shared__ float As[BK][BM + 4];
  __shared__ float Bs[BK][BN + 4];
  const int tid = threadIdx.x;
  const int m0 = blockIdx.y * BM;
  const int n0 = blockIdx.x * BN;
  const int tn = (tid % NT) * TN;
  const int tm = (tid / NT) * TM;
  float acc[TM][TN] = {};
  for (int k0 = 0; k0 < K; k0 += BK) {
    #pragma unroll
    for (int i = 0; i < A_F4; i++) {
      int li = tid + i * THREADS;
      int r = li / K4, c4 = li % K4;
      float4 v = *(const float4*)(A + (size_t)(m0 + r) * lda + k0 + c4 * 4);
      As[c4*4+0][r] = v.x; As[c4*4+1][r] = v.y; As[c4*4+2][r] = v.z; As[c4*4+3][r] = v.w;
    }
    #pragma unroll
    for (int i = 0; i < B_F4; i++) {
      int li = tid + i * THREADS;
      int r = li / K4, c4 = li % K4;
      float4 v = *(const float4*)(B + (size_t)(n0 + r) * ldb + k0 + c4 * 4);
      Bs[c4*4+0][r] = v.x; Bs[c4*4+1][r] = v.y; Bs[c4*4+2][r] = v.z; Bs[c4*4+3][r] = v.w;
    }
    __syncthreads();
    #pragma unroll
    for (int k = 0; k < BK; k++) {
      float a[TM], bf[TN];
      #pragma unroll
      for (int i = 0; i < TM; i++) a[i] = As[k][tm + i];
      #pragma unroll
      for (int j = 0; j < TN; j++) bf[j] = Bs[k][tn + j];
      #pragma unroll
      for (int i = 0; i < TM; i++)
        #pragma unroll
        for (int j = 0; j < TN; j++)
          acc[i][j] = fmaf(a[i], bf[j], acc[i][j]);
    }
    __syncthreads();
  }
  #pragma unroll
  for (int i = 0; i < TM; i++) {
    const int m = m0 + tm + i;
    #pragma unroll
    for (int j = 0; j < TN; j++) {
      const int n = n0 + tn + j;
      float v = acc[i][j];
      if constexpr (EPI == 1) {
        v += bias[n];
        v = (v > 20.f) ? v : log1pf(__expf(v));
      }
      C[(size_t)m * ldc + n] = v;
    }
  }
}

// ---- x_proj split-K: part[kz][m][n] = sum_{k in seg kz} xc[m,k]*xpw[n,k] ----
__global__ __launch_bounds__(256) void sgemm_splitk_k(
    const float* __restrict__ A, const float* __restrict__ B,
    float* __restrict__ part) {
  __shared__ float As[32][64 + 4];
  __shared__ float Bs[32][32 + 4];
  const int tid = threadIdx.x;
  const int n0 = blockIdx.x * 32;
  const int m0 = blockIdx.y * 64;
  const int kz = blockIdx.z;
  const int tn = (tid & 15) * 2;
  const int tm = (tid >> 4) * 4;
  float acc[4][2] = {};
  for (int kb = 0; kb < 256; kb += 32) {
    const int k0 = kz * 256 + kb;
    #pragma unroll
    for (int i = 0; i < 2; i++) {
      int li = tid + i * 256;          // 512 float4 slots for A (64x32)
      int r = li >> 3, c4 = li & 7;
      float4 v = *(const float4*)(A + (size_t)(m0 + r) * D_INNER + k0 + c4 * 4);
      As[c4*4+0][r] = v.x; As[c4*4+1][r] = v.y;
      As[c4*4+2][r] = v.z; As[c4*4+3][r] = v.w;
    }
    {
      int r = tid >> 3, c4 = tid & 7;  // 256 float4 slots for B (32x32)
      float4 v = *(const float4*)(B + (size_t)(n0 + r) * D_INNER + k0 + c4 * 4);
      Bs[c4*4+0][r] = v.x; Bs[c4*4+1][r] = v.y;
      Bs[c4*4+2][r] = v.z; Bs[c4*4+3][r] = v.w;
    }
    __syncthreads();
    #pragma unroll
    for (int k = 0; k < 32; k++) {
      float a[4], bf[2];
      #pragma unroll
      for (int i = 0; i < 4; i++) a[i] = As[k][tm + i];
      bf[0] = Bs[k][tn]; bf[1] = Bs[k][tn + 1];
      #pragma unroll
      for (int i = 0; i < 4; i++) {
        acc[i][0] = fmaf(a[i], bf[0], acc[i][0]);
        acc[i][1] = fmaf(a[i], bf[1], acc[i][1]);
      }
    }
    __syncthreads();
  }
  float* p = part + (size_t)kz * BL * 96;
  #pragma unroll
  for (int i = 0; i < 4; i++) {
    const int m = m0 + tm + i;
    p[(size_t)m * 96 + n0 + tn]     = acc[i][0];
    p[(size_t)m * 96 + n0 + tn + 1] = acc[i][1];
  }
}

// fixed-order deterministic reduce of the KS partials -> xdbl
__global__ __launch_bounds__(256) void xproj_reduce_k(
    const float* __restrict__ part, float* __restrict__ out) {
  const int i = blockIdx.x * 256 + threadIdx.x;   // over BL*96
  float s = 0.f;
  #pragma unroll
  for (int k = 0; k < KS; k++) s += part[(size_t)k * BL * 96 + i];
  out[i] = s;
}

// ------ causal depthwise conv (width 4) + SiLU, 4 channels/thread -----------
__global__ __launch_bounds__(256) void conv_silu_k(const float* __restrict__ xz,
    const float* __restrict__ cw, const float* __restrict__ cb,
    float* __restrict__ xc) {
  const int gid = blockIdx.x * 256 + threadIdx.x;   // BL * D_INNER/4
  const int c4 = (gid & (D_INNER / 4 - 1)) << 2;
  const int row = gid >> 9;                         // b*LL + l
  const int l = row & (LL - 1);
  const float* base = xz + (size_t)row * (2 * D_INNER) + c4;
  const float4 w0 = *(const float4*)(cw + (c4 + 0) * 4);
  const float4 w1 = *(const float4*)(cw + (c4 + 1) * 4);
  const float4 w2 = *(const float4*)(cw + (c4 + 2) * 4);
  const float4 w3 = *(const float4*)(cw + (c4 + 3) * 4);
  float4 acc = *(const float4*)(cb + c4);
  float4 xv = *(const float4*)base;
  acc.x = fmaf(w0.w, xv.x, acc.x); acc.y = fmaf(w1.w, xv.y, acc.y);
  acc.z = fmaf(w2.w, xv.z, acc.z); acc.w = fmaf(w3.w, xv.w, acc.w);
  if (l >= 1) {
    xv = *(const float4*)(base - 2 * D_INNER);
    acc.x = fmaf(w0.z, xv.x, acc.x); acc.y = fmaf(w1.z, xv.y, acc.y);
    acc.z = fmaf(w2.z, xv.z, acc.z); acc.w = fmaf(w3.z, xv.w, acc.w);
  }
  if (l >= 2) {
    xv = *(const float4*)(base - 4 * D_INNER);
    acc.x = fmaf(w0.y, xv.x, acc.x); acc.y = fmaf(w1.y, xv.y, acc.y);
    acc.z = fmaf(w2.y, xv.z, acc.z); acc.w = fmaf(w3.y, xv.w, acc.w);
  }
  if (l >= 3) {
    xv = *(const float4*)(base - 6 * D_INNER);
    acc.x = fmaf(w0.x, xv.x, acc.x); acc.y = fmaf(w1.x, xv.y, acc.y);
    acc.z = fmaf(w2.x, xv.z, acc.z); acc.w = fmaf(w3.x, xv.w, acc.w);
  }
  acc.x = acc.x / (1.f + __expf(-acc.x));
  acc.y = acc.y / (1.f + __expf(-acc.y));
  acc.z = acc.z / (1.f + __expf(-acc.z));
  acc.w = acc.w / (1.f + __expf(-acc.w));
  *(float4*)(xc + (size_t)row * D_INNER + c4) = acc;
}

// ------- chunked selective scan, pass 1 --------------------------------------
__global__ __launch_bounds__(256) void scan_pass1_k(
    const float* __restrict__ dt, const float* __restrict__ xc,
    const float* __restrict__ xdbl, const float* __restrict__ A_log,
    float* __restrict__ hend, float* __restrict__ sumdt) {
  const int c = blockIdx.x * 256 + threadIdx.x;
  const int k = blockIdx.y;
  const int b = blockIdx.z;
  float Ac[D_STATE];
  #pragma unroll
  for (int n = 0; n < D_STATE; n++) Ac[n] = -__expf(A_log[c * D_STATE + n]);
  float h[D_STATE] = {};
  float sd = 0.f;
  const size_t r0 = (size_t)b * LL + (size_t)k * CLEN;
  const float* dtp = dt + r0 * D_INNER + c;
  const float* xcp = xc + r0 * D_INNER + c;
  const float* Bp  = xdbl + r0 * 96 + DT_RANK;

  float dtv = dtp[0];
  float xv  = xcp[0];
  float4 B0 = *(const float4*)(Bp + 0);
  float4 B1 = *(const float4*)(Bp + 4);
  float4 B2 = *(const float4*)(Bp + 8);
  float4 B3 = *(const float4*)(Bp + 12);
  for (int l = 0; l < CLEN; l++) {
    const int lp = (l + 1 < CLEN) ? l + 1 : l;
    const float dtv2 = dtp[(size_t)lp * D_INNER];
    const float xv2  = xcp[(size_t)lp * D_INNER];
    const float4 B0n = *(const float4*)(Bp + (size_t)lp * 96 + 0);
    const float4 B1n = *(const float4*)(Bp + (size_t)lp * 96 + 4);
    const float4 B2n = *(const float4*)(Bp + (size_t)lp * 96 + 8);
    const float4 B3n = *(const float4*)(Bp + (size_t)lp * 96 + 12);
    sd += dtv;
    const float dx = dtv * xv;
    const float Bv[D_STATE] = {B0.x,B0.y,B0.z,B0.w, B1.x,B1.y,B1.z,B1.w,
                               B2.x,B2.y,B2.z,B2.w, B3.x,B3.y,B3.z,B3.w};
    #pragma unroll
    for (int n = 0; n < D_STATE; n++)
      h[n] = fmaf(__expf(dtv * Ac[n]), h[n], dx * Bv[n]);
    dtv = dtv2; xv = xv2; B0 = B0n; B1 = B1n; B2 = B2n; B3 = B3n;
  }
  float* he = hend + (((size_t)(b * CH + k) * D_INNER + c) << 4);
  #pragma unroll
  for (int n = 0; n < D_STATE; n += 4)
    *(float4*)(he + n) = make_float4(h[n], h[n+1], h[n+2], h[n+3]);
  sumdt[(size_t)(b * CH + k) * D_INNER + c] = sd;
}

// ------- chunked scan fixup ---------------------------------------------------
__global__ __launch_bounds__(256) void scan_fix_k(
    float* __restrict__ hend, const float* __restrict__ sumdt,
    const float* __restrict__ A_log) {
  const int gid = blockIdx.x * 256 + threadIdx.x;
  const int n = gid & 15;
  const int c = (gid >> 4) & (D_INNER - 1);
  const int b = gid >> 15;
  const float Ac = -__expf(A_log[c * D_STATE + n]);
  float hrun = 0.f;
  for (int k = 0; k < CH; k++) {
    const size_t base = (size_t)(b * CH + k) * D_INNER + c;
    const float sd = sumdt[base];
    float* hp = hend + (base << 4) + n;
    const float tmp = *hp;
    *hp = hrun;
    hrun = fmaf(__expf(Ac * sd), hrun, tmp);
  }
}

// ------- chunked scan pass 3: replay, gate, emit y as bf16 hi/lo -------------
__global__ __launch_bounds__(256) void scan_pass3_k(
    const float* __restrict__ dt, const float* __restrict__ xc,
    const float* __restrict__ xdbl, const float* __restrict__ xz,
    const float* __restrict__ h0, const float* __restrict__ A_log,
    const float* __restrict__ Dp,
    unsigned short* __restrict__ yh, unsigned short* __restrict__ yl) {
  const int c = blockIdx.x * 256 + threadIdx.x;
  const int k = blockIdx.y;
  const int b = blockIdx.z;
  float Ac[D_STATE];
  #pragma unroll
  for (int n = 0; n < D_STATE; n++) Ac[n] = -__expf(A_log[c * D_STATE + n]);
  const float Dv = Dp[c];
  float h[D_STATE];
  const float* hp = h0 + (((size_t)(b * CH + k) * D_INNER + c) << 4);
  #pragma unroll
  for (int n = 0; n < D_STATE; n += 4) {
    const float4 v = *(const float4*)(hp + n);
    h[n] = v.x; h[n+1] = v.y; h[n+2] = v.z; h[n+3] = v.w;
  }
  const size_t r0 = (size_t)b * LL + (size_t)k * CLEN;
  const float* dtp = dt + r0 * D_INNER + c;
  const float* xcp = xc + r0 * D_INNER + c;
  const float* Bp  = xdbl + r0 * 96 + DT_RANK;
  const float* zp  = xz + r0 * (size_t)(2 * D_INNER) + D_INNER + c;
  unsigned short* yhp = yh + r0 * D_INNER + c;
  unsigned short* ylp = yl + r0 * D_INNER + c;

  float dtv = dtp[0];
  float xv  = xcp[0];
  float zv  = zp[0];
  float4 B0 = *(const float4*)(Bp + 0);
  float4 B1 = *(const float4*)(Bp + 4);
  float4 B2 = *(const float4*)(Bp + 8);
  float4 B3 = *(const float4*)(Bp + 12);
  float4 C0 = *(const float4*)(Bp + 16);
  float4 C1 = *(const float4*)(Bp + 20);
  float4 C2 = *(const float4*)(Bp + 24);
  float4 C3 = *(const float4*)(Bp + 28);
  for (int l = 0; l < CLEN; l++) {
    const int lp = (l + 1 < CLEN) ? l + 1 : l;
    const float dtv2 = dtp[(size_t)lp * D_INNER];
    const float xv2  = xcp[(size_t)lp * D_INNER];
    const float zv2  = zp[(size_t)lp * 2 * D_INNER];
    const float4 B0n = *(const float4*)(Bp + (size_t)lp * 96 + 0);
    const float4 B1n = *(const float4*)(Bp + (size_t)lp * 96 + 4);
    const float4 B2n = *(const float4*)(Bp + (size_t)lp * 96 + 8);
    const float4 B3n = *(const float4*)(Bp + (size_t)lp * 96 + 12);
    const float4 C0n = *(const float4*)(Bp + (size_t)lp * 96 + 16);
    const float4 C1n = *(const float4*)(Bp + (size_t)lp * 96 + 20);
    const float4 C2n = *(const float4*)(Bp + (size_t)lp * 96 + 24);
    const float4 C3n = *(const float4*)(Bp + (size_t)lp * 96 + 28);
    const float dx = dtv * xv;
    const float Bv[D_STATE] = {B0.x,B0.y,B0.z,B0.w, B1.x,B1.y,B1.z,B1.w,
                               B2.x,B2.y,B2.z,B2.w, B3.x,B3.y,B3.z,B3.w};
    const float Cv[D_STATE] = {C0.x,C0.y,C0.z,C0.w, C1.x,C1.y,C1.z,C1.w,
                               C2.x,C2.y,C2.z,C2.w, C3.x,C3.y,C3.z,C3.w};
    float y = 0.f;
    #pragma unroll
    for (int n = 0; n < D_STATE; n++) {
      h[n] = fmaf(__expf(dtv * Ac[n]), h[n], dx * Bv[n]);
      y = fmaf(h[n], Cv[n], y);
    }
    y = fmaf(xv, Dv, y);
    y *= zv / (1.f + __expf(-zv));
    unsigned short uh, ul;
    split2(y, uh, ul);
    yhp[(size_t)l * D_INNER] = uh;
    ylp[(size_t)l * D_INNER] = ul;
    dtv = dtv2; xv = xv2; zv = zv2;
    B0 = B0n; B1 = B1n; B2 = B2n; B3 = B3n;
    C0 = C0n; C1 = C1n; C2 = C2n; C3 = C3n;
  }
}

// ---------------- mean pool over L ------------------------------------------
__global__ __launch_bounds__(256) void pool_k(const float* __restrict__ h,
    float* __restrict__ pooled) {
  const int d = blockIdx.x * 256 + threadIdx.x;
  const int b = blockIdx.y;
  float s = 0.f;
  for (int l = 0; l < LL; l++) s += h[((size_t)(b * LL + l)) * D_MODEL + d];
  pooled[b * D_MODEL + d] = s * (1.f / LL);
}

// ---------------- classifier head --------------------------------------------
__global__ __launch_bounds__(64) void head_k(const float* __restrict__ pooled,
    const float* __restrict__ hw, const float* __restrict__ hb,
    float* __restrict__ out) {
  const int b = blockIdx.x / N_CLASSES;
  const int j = blockIdx.x % N_CLASSES;
  float s = 0.f;
  for (int k = threadIdx.x; k < D_MODEL; k += 64)
    s = fmaf(pooled[b * D_MODEL + k], hw[j * D_MODEL + k], s);
  #pragma unroll
  for (int o = 32; o; o >>= 1) s += __shfl_down(s, o);
  if (threadIdx.x == 0) out[b * N_CLASSES + j] = s + hb[j];
}

extern "C" void kernel_launch(void* const* d_in, const int* in_sizes, int n_in,
                              void* d_out, int out_size, void* d_ws, size_t ws_size,
                              hipStream_t stream) {
  const float* x0    = (const float*)d_in[0];
  const float* ln1w  = (const float*)d_in[1];
  const float* ln1b  = (const float*)d_in[2];
  const float* inw   = (const float*)d_in[3];
  const float* convw = (const float*)d_in[4];
  const float* convb = (const float*)d_in[5];
  const float* xpw   = (const float*)d_in[6];
  const float* dtpw  = (const float*)d_in[7];
  const float* dtpb  = (const float*)d_in[8];
  const float* Alog  = (const float*)d_in[9];
  const float* Dp    = (const float*)d_in[10];
  const float* outw  = (const float*)d_in[11];
  const float* normw = (const float*)d_in[12];
  const float* normb = (const float*)d_in[13];
  const float* headw = (const float*)d_in[14];
  const float* headb = (const float*)d_in[15];

  float* ws = (float*)d_ws;
  size_t f = 0;
  float* X      = ws + f; f += (size_t)BL * D_MODEL;        // 4.2M
  float* xz     = ws + f; f += (size_t)BL * 2 * D_INNER;    // 16.8M
  float* xc     = ws + f; f += (size_t)BL * D_INNER;        // 8.4M
  float* xdbl   = ws + f; f += (size_t)BL * 96;             // 0.39M
  float* dty    = ws + f; f += (size_t)BL * D_INNER;        // 8.4M
  float* pooled = ws + f; f += 4096;
  float* xpart  = ws + f; f += (size_t)KS * BL * 96;        // 3.15M
  unsigned short* hh  = (unsigned short*)(ws + f); f += (size_t)BL * D_MODEL / 2;
  unsigned short* hl  = (unsigned short*)(ws + f); f += (size_t)BL * D_MODEL / 2;
  unsigned short* yh  = (unsigned short*)(ws + f); f += (size_t)BL * D_INNER / 2;
  unsigned short* yl  = (unsigned short*)(ws + f); f += (size_t)BL * D_INNER / 2;
  unsigned short* wih = (unsigned short*)(ws + f); f += (size_t)2 * D_INNER * D_MODEL / 2;
  unsigned short* woh = (unsigned short*)(ws + f); f += (size_t)D_MODEL * D_INNER / 2;
  // Overlays (lifetime-disjoint):
  //  hend (BB*CH*D_INNER*16 = 4.19M) overlays hh+hl (dead after in_proj GEMM)
  //  sumdt (BB*CH*D_INNER = 0.26M) overlays xpart (dead after xproj_reduce)
  //  opart (KSO*BL*D_MODEL = 8.4M) overlays xz (dead after scan_pass3)
  float* hend  = (float*)hh;
  float* sumdt = xpart;
  float* opart = xz;

  hipMemcpyAsync(X, x0, (size_t)BL * D_MODEL * sizeof(float),
                 hipMemcpyDeviceToDevice, stream);

  for (int layer = 0; layer < N_LAYERS; ++layer) {
    // LayerNorm -> bf16 hi/lo A-operand
    layernorm_split_k<<<BL, 256, 0, stream>>>(X, ln1w + layer * D_MODEL,
                                              ln1b + layer * D_MODEL, hh, hl);
    // round weights to bf16 (hi only) for this layer
    round_k<<<(2 * D_INNER * D_MODEL) / 1024, 256, 0, stream>>>(
        inw + (size_t)layer * 2 * D_INNER * D_MODEL, wih);
    round_k<<<(D_MODEL * D_INNER) / 1024, 256, 0, stream>>>(
        outw + (size_t)layer * D_MODEL * D_INNER, woh);
    // xz = h @ in_w^T : M=4096 N=4096 K=1024 (merged hi/lo MFMA)
    mfma_gemm_nt<0, 1><<<dim3(4096 / 128, 4096 / 128), 256, 0, stream>>>(
        hh, hl, wih, xz, BL, 2 * D_INNER, D_MODEL, 2 * D_INNER);
    conv_silu_k<<<(BL * D_INNER / 4) / 256, 256, 0, stream>>>(
        xz, convw + layer * D_INNER * D_CONV, convb + layer * D_INNER, xc);
    // x_dbl = xc @ xp_w^T : M=4096 N=96 K=2048 (fp32 split-K + reduce)
    sgemm_splitk_k<<<dim3(96 / 32, 4096 / 64, KS), 256, 0, stream>>>(
        xc, xpw + (size_t)layer * 96 * D_INNER, xpart);
    xproj_reduce_k<<<(BL * 96) / 256, 256, 0, stream>>>(xpart, xdbl);
    // dt = softplus(dt_r @ dtp_w^T + dtp_b) : M=4096 N=2048 K=64 (fp32, 64² tile)
    sgemm_nt<64,64,64,4,4,1><<<dim3(2048 / 64, 4096 / 64), 256, 0, stream>>>(
        xdbl, dtpw + (size_t)layer * D_INNER * DT_RANK, dty,
        BL, D_INNER, DT_RANK, 96, DT_RANK, D_INNER,
        dtpb + layer * D_INNER);
    // chunked scan (CH=32)
    scan_pass1_k<<<dim3(D_INNER / 256, CH, BB), 256, 0, stream>>>(
        dty, xc, xdbl, Alog + (size_t)layer * D_INNER * D_STATE, hend, sumdt);
    scan_fix_k<<<(BB * D_INNER * D_STATE) / 256, 256, 0, stream>>>(
        hend, sumdt, Alog + (size_t)layer * D_INNER * D_STATE);
    scan_pass3_k<<<dim3(D_INNER / 256, CH, BB), 256, 0, stream>>>(
        dty, xc, xdbl, xz, hend, Alog + (size_t)layer * D_INNER * D_STATE,
        Dp + layer * D_INNER, yh, yl);
    // y @ out_w^T : M=4096 N=1024 K=2048, split-K=2 partials (overlay xz)
    mfma_gemm_nt<1, KSO><<<dim3(1024 / 128, 4096 / 128, KSO), 256, 0, stream>>>(
        yh, yl, woh, opart, BL, D_MODEL, D_INNER, D_MODEL);
    // X += sum_k partials (fixed order, deterministic)
    outproj_reduce_k<<<(BL * D_MODEL / 4) / 256, 256, 0, stream>>>(opart, X);
  }

  layernorm_k<<<BL, 256, 0, stream>>>(X, normw, normb, dty);
  pool_k<<<dim3(D_MODEL / 256, BB), 256, 0, stream>>>(dty, pooled);
  head_k<<<BB * N_CLASSES, 64, 0, stream>>>(pooled, headw, headb, (float*)d_out);
}

// Round 9
// 672.265 us; speedup vs baseline: 4.6832x; 1.1254x over previous
//
#include <hip/hip_runtime.h>
#include <hip/hip_bf16.h>

#define N_LAYERS 2
#define D_MODEL 1024
#define D_INNER 2048
#define D_STATE 16
#define D_CONV 4
#define DT_RANK 64
#define N_CLASSES 10
#define BB 4
#define LL 1024
#define BL (BB*LL)   // 4096 rows
#define CH 32        // scan chunks per sequence
#define CLEN (LL/CH) // 32 steps per chunk
#define KS 8         // split-K segments for x_proj
#define KSO 2        // split-K segments for out_proj

typedef __attribute__((ext_vector_type(8))) short bf16x8;
typedef __attribute__((ext_vector_type(4))) float f32x4;

typedef const void __attribute__((address_space(1)))* gas_ptr;
typedef void __attribute__((address_space(3)))* las_ptr;
#define GLDS16(g, p) __builtin_amdgcn_global_load_lds((gas_ptr)(g), (las_ptr)(p), 16, 0, 0)

__device__ inline unsigned short rnd_bf16(float x) {
  unsigned u = __float_as_uint(x);
  return (unsigned short)((u + 0x7FFFu + ((u >> 16) & 1u)) >> 16);
}

// round weights to bf16
__global__ __launch_bounds__(256) void round_k(const float* __restrict__ in,
    unsigned short* __restrict__ hi) {
  const int i = blockIdx.x * 256 + threadIdx.x;
  const float4 v = ((const float4*)in)[i];
  ushort4 h4;
  h4.x = rnd_bf16(v.x); h4.y = rnd_bf16(v.y);
  h4.z = rnd_bf16(v.z); h4.w = rnd_bf16(v.w);
  ((ushort4*)hi)[i] = h4;
}

// ---------------- LayerNorm -> fp32 out ---------------------------------------
__global__ __launch_bounds__(256) void layernorm_k(const float* __restrict__ x,
    const float* __restrict__ w, const float* __restrict__ b,
    float* __restrict__ out) {
  const int row = blockIdx.x;
  const int t = threadIdx.x;
  const float4 v = *(const float4*)(x + (size_t)row * D_MODEL + t * 4);
  float s = v.x + v.y + v.z + v.w;
  float q = v.x*v.x + v.y*v.y + v.z*v.z + v.w*v.w;
  #pragma unroll
  for (int o = 32; o; o >>= 1) { s += __shfl_down(s, o); q += __shfl_down(q, o); }
  __shared__ float red[8];
  if ((t & 63) == 0) { red[t >> 6] = s; red[4 + (t >> 6)] = q; }
  __syncthreads();
  s = red[0] + red[1] + red[2] + red[3];
  q = red[4] + red[5] + red[6] + red[7];
  const float mean = s * (1.f / D_MODEL);
  const float var  = q * (1.f / D_MODEL) - mean * mean;
  const float rstd = rsqrtf(var + 1e-5f);
  const float4 wv = *(const float4*)(w + t * 4);
  const float4 bv = *(const float4*)(b + t * 4);
  float4 o4;
  o4.x = (v.x - mean) * rstd * wv.x + bv.x;
  o4.y = (v.y - mean) * rstd * wv.y + bv.y;
  o4.z = (v.z - mean) * rstd * wv.z + bv.z;
  o4.w = (v.w - mean) * rstd * wv.w + bv.w;
  *(float4*)(out + (size_t)row * D_MODEL + t * 4) = o4;
}

// ---------------- LayerNorm -> bf16 out ---------------------------------------
__global__ __launch_bounds__(256) void layernorm_bf16_k(const float* __restrict__ x,
    const float* __restrict__ w, const float* __restrict__ b,
    unsigned short* __restrict__ oh) {
  const int row = blockIdx.x;
  const int t = threadIdx.x;
  const float4 v = *(const float4*)(x + (size_t)row * D_MODEL + t * 4);
  float s = v.x + v.y + v.z + v.w;
  float q = v.x*v.x + v.y*v.y + v.z*v.z + v.w*v.w;
  #pragma unroll
  for (int o = 32; o; o >>= 1) { s += __shfl_down(s, o); q += __shfl_down(q, o); }
  __shared__ float red[8];
  if ((t & 63) == 0) { red[t >> 6] = s; red[4 + (t >> 6)] = q; }
  __syncthreads();
  s = red[0] + red[1] + red[2] + red[3];
  q = red[4] + red[5] + red[6] + red[7];
  const float mean = s * (1.f / D_MODEL);
  const float var  = q * (1.f / D_MODEL) - mean * mean;
  const float rstd = rsqrtf(var + 1e-5f);
  const float4 wv = *(const float4*)(w + t * 4);
  const float4 bv = *(const float4*)(b + t * 4);
  ushort4 h4;
  h4.x = rnd_bf16((v.x - mean) * rstd * wv.x + bv.x);
  h4.y = rnd_bf16((v.y - mean) * rstd * wv.y + bv.y);
  h4.z = rnd_bf16((v.z - mean) * rstd * wv.z + bv.z);
  h4.w = rnd_bf16((v.w - mean) * rstd * wv.w + bv.w);
  ((ushort4*)(oh + (size_t)row * D_MODEL))[t] = h4;
}

// ---- bf16 MFMA GEMM NT (optional split-K) -----------------------------------
// C[m,n] = sum_k A[m,k]*B[n,k], bf16 inputs, fp32 acc.
// 128x128 tile, BK=64, 4 waves, 4x4 16x16x32 fragments, 32 KB LDS.
// EPI 0: direct store; 1: store to partials at C + kz*M*ldc.
template<int EPI, int KSEG>
__global__ __launch_bounds__(256) void mfma_gemm_nt(
    const unsigned short* __restrict__ Ah, const unsigned short* __restrict__ Bh,
    float* __restrict__ C, int M, int N, int K, int ldc) {
  __shared__ unsigned short As[128 * 64];
  __shared__ unsigned short Bs[128 * 64];
  const int tid = threadIdx.x;
  const int w = tid >> 6, l = tid & 63;
  const int wr = w >> 1, wc = w & 1;
  const int m0 = blockIdx.y * 128, n0 = blockIdx.x * 128;
  const int kz = (KSEG > 1) ? blockIdx.z : 0;
  const int kbeg = kz * (K / KSEG);
  const int kend = kbeg + K / KSEG;
  const int srow = l >> 3;             // staging row within 8-row block
  const int scol = (l & 7) * 8;        // staging col (elements)
  const int fr = l & 15;               // fragment row
  const int fk = (l >> 4) * 8;         // fragment k offset
  f32x4 acc[4][4] = {};

  #pragma unroll 1
  for (int k0 = kbeg; k0 < kend; k0 += 64) {
    __syncthreads();                  // previous compute done before overwrite
    #pragma unroll
    for (int it = 0; it < 4; ++it) {
      const int bi = it * 4 + w;      // 1 KB block id 0..15
      const int row = bi * 8 + srow;
      GLDS16(Ah + (size_t)(m0 + row) * K + k0 + scol, &As[bi * 512 + l * 8]);
      GLDS16(Bh + (size_t)(n0 + row) * K + k0 + scol, &Bs[bi * 512 + l * 8]);
    }
    __syncthreads();                  // staging visible (vmcnt drained)
    #pragma unroll
    for (int kk = 0; kk < 64; kk += 32) {
      bf16x8 a[4], b[4];
      #pragma unroll
      for (int f = 0; f < 4; ++f)
        b[f] = *(const bf16x8*)&Bs[(wc * 64 + f * 16 + fr) * 64 + kk + fk];
      #pragma unroll
      for (int f = 0; f < 4; ++f)
        a[f] = *(const bf16x8*)&As[(wr * 64 + f * 16 + fr) * 64 + kk + fk];
      #pragma unroll
      for (int i = 0; i < 4; ++i)
        #pragma unroll
        for (int j = 0; j < 4; ++j)
          acc[i][j] = __builtin_amdgcn_mfma_f32_16x16x32_bf16(
              a[i], b[j], acc[i][j], 0, 0, 0);
    }
  }
  float* Cw = (EPI == 1) ? C + (size_t)kz * M * ldc : C;
  const int orow = (l >> 4) * 4;
  const int ocol = l & 15;
  #pragma unroll
  for (int i = 0; i < 4; ++i)
    #pragma unroll
    for (int j = 0; j < 4; ++j)
      #pragma unroll
      for (int r = 0; r < 4; ++r) {
        const int m = m0 + wr * 64 + i * 16 + orow + r;
        const int n = n0 + wc * 64 + j * 16 + ocol;
        Cw[(size_t)m * ldc + n] = acc[i][j][r];
      }
}

// fixed-order reduce of out_proj partials + residual -> X (float4 lanes)
__global__ __launch_bounds__(256) void outproj_reduce_k(
    const float* __restrict__ part, float* __restrict__ X) {
  const int i = blockIdx.x * 256 + threadIdx.x;   // over BL*D_MODEL/4
  float4 s = ((const float4*)X)[i];
  #pragma unroll
  for (int k = 0; k < KSO; k++) {
    const float4 p = ((const float4*)(part + (size_t)k * BL * D_MODEL))[i];
    s.x += p.x; s.y += p.y; s.z += p.z; s.w += p.w;
  }
  ((float4*)X)[i] = s;
}

// ---------------- fp32 SGEMM NT (dt GEMM) -------------------------------------
// EPI: 0 none; 1 softplus(acc + bias[n])
template<int BM, int BN, int BK, int TM, int TN, int EPI>
__global__ __launch_bounds__(256) void sgemm_nt(
    const float* __restrict__ A, const float* __restrict__ B,
    float* __restrict__ C, int M, int N, int K, int lda, int ldb, int ldc,
    const float* __restrict__ bias) {
  constexpr int THREADS = 256;
  constexpr int NT = BN / TN;
  constexpr int K4 = BK / 4;
  constexpr int A_F4 = BM * BK / (THREADS * 4);
  constexpr int B_F4 = BN * BK / (THREADS * 4);
  static_assert((BM / TM) * (BN / TN) == THREADS, "thread shape");
  __shared__ float As[BK][BM + 4];
  __shared__ float Bs[BK][BN + 4];
  const int tid = threadIdx.x;
  const int m0 = blockIdx.y * BM;
  const int n0 = blockIdx.x * BN;
  const int tn = (tid % NT) * TN;
  const int tm = (tid / NT) * TM;
  float acc[TM][TN] = {};
  for (int k0 = 0; k0 < K; k0 += BK) {
    #pragma unroll
    for (int i = 0; i < A_F4; i++) {
      int li = tid + i * THREADS;
      int r = li / K4, c4 = li % K4;
      float4 v = *(const float4*)(A + (size_t)(m0 + r) * lda + k0 + c4 * 4);
      As[c4*4+0][r] = v.x; As[c4*4+1][r] = v.y; As[c4*4+2][r] = v.z; As[c4*4+3][r] = v.w;
    }
    #pragma unroll
    for (int i = 0; i < B_F4; i++) {
      int li = tid + i * THREADS;
      int r = li / K4, c4 = li % K4;
      float4 v = *(const float4*)(B + (size_t)(n0 + r) * ldb + k0 + c4 * 4);
      Bs[c4*4+0][r] = v.x; Bs[c4*4+1][r] = v.y; Bs[c4*4+2][r] = v.z; Bs[c4*4+3][r] = v.w;
    }
    __syncthreads();
    #pragma unroll
    for (int k = 0; k < BK; k++) {
      float a[TM], bf[TN];
      #pragma unroll
      for (int i = 0; i < TM; i++) a[i] = As[k][tm + i];
      #pragma unroll
      for (int j = 0; j < TN; j++) bf[j] = Bs[k][tn + j];
      #pragma unroll
      for (int i = 0; i < TM; i++)
        #pragma unroll
        for (int j = 0; j < TN; j++)
          acc[i][j] = fmaf(a[i], bf[j], acc[i][j]);
    }
    __syncthreads();
  }
  #pragma unroll
  for (int i = 0; i < TM; i++) {
    const int m = m0 + tm + i;
    #pragma unroll
    for (int j = 0; j < TN; j++) {
      const int n = n0 + tn + j;
      float v = acc[i][j];
      if constexpr (EPI == 1) {
        v += bias[n];
        v = (v > 20.f) ? v : log1pf(__expf(v));
      }
      C[(size_t)m * ldc + n] = v;
    }
  }
}

// ---- x_proj split-K: part[kz][m][n] = sum_{k in seg kz} xc[m,k]*xpw[n,k] ----
__global__ __launch_bounds__(256) void sgemm_splitk_k(
    const float* __restrict__ A, const float* __restrict__ B,
    float* __restrict__ part) {
  __shared__ float As[32][64 + 4];
  __shared__ float Bs[32][32 + 4];
  const int tid = threadIdx.x;
  const int n0 = blockIdx.x * 32;
  const int m0 = blockIdx.y * 64;
  const int kz = blockIdx.z;
  const int tn = (tid & 15) * 2;
  const int tm = (tid >> 4) * 4;
  float acc[4][2] = {};
  for (int kb = 0; kb < 256; kb += 32) {
    const int k0 = kz * 256 + kb;
    #pragma unroll
    for (int i = 0; i < 2; i++) {
      int li = tid + i * 256;          // 512 float4 slots for A (64x32)
      int r = li >> 3, c4 = li & 7;
      float4 v = *(const float4*)(A + (size_t)(m0 + r) * D_INNER + k0 + c4 * 4);
      As[c4*4+0][r] = v.x; As[c4*4+1][r] = v.y;
      As[c4*4+2][r] = v.z; As[c4*4+3][r] = v.w;
    }
    {
      int r = tid >> 3, c4 = tid & 7;  // 256 float4 slots for B (32x32)
      float4 v = *(const float4*)(B + (size_t)(n0 + r) * D_INNER + k0 + c4 * 4);
      Bs[c4*4+0][r] = v.x; Bs[c4*4+1][r] = v.y;
      Bs[c4*4+2][r] = v.z; Bs[c4*4+3][r] = v.w;
    }
    __syncthreads();
    #pragma unroll
    for (int k = 0; k < 32; k++) {
      float a[4], bf[2];
      #pragma unroll
      for (int i = 0; i < 4; i++) a[i] = As[k][tm + i];
      bf[0] = Bs[k][tn]; bf[1] = Bs[k][tn + 1];
      #pragma unroll
      for (int i = 0; i < 4; i++) {
        acc[i][0] = fmaf(a[i], bf[0], acc[i][0]);
        acc[i][1] = fmaf(a[i], bf[1], acc[i][1]);
      }
    }
    __syncthreads();
  }
  float* p = part + (size_t)kz * BL * 96;
  #pragma unroll
  for (int i = 0; i < 4; i++) {
    const int m = m0 + tm + i;
    p[(size_t)m * 96 + n0 + tn]     = acc[i][0];
    p[(size_t)m * 96 + n0 + tn + 1] = acc[i][1];
  }
}

// fixed-order deterministic reduce of the KS partials -> xdbl
__global__ __launch_bounds__(256) void xproj_reduce_k(
    const float* __restrict__ part, float* __restrict__ out) {
  const int i = blockIdx.x * 256 + threadIdx.x;   // over BL*96
  float s = 0.f;
  #pragma unroll
  for (int k = 0; k < KS; k++) s += part[(size_t)k * BL * 96 + i];
  out[i] = s;
}

// ------ causal depthwise conv (width 4) + SiLU, 4 channels/thread -----------
__global__ __launch_bounds__(256) void conv_silu_k(const float* __restrict__ xz,
    const float* __restrict__ cw, const float* __restrict__ cb,
    float* __restrict__ xc) {
  const int gid = blockIdx.x * 256 + threadIdx.x;   // BL * D_INNER/4
  const int c4 = (gid & (D_INNER / 4 - 1)) << 2;
  const int row = gid >> 9;                         // b*LL + l
  const int l = row & (LL - 1);
  const float* base = xz + (size_t)row * (2 * D_INNER) + c4;
  const float4 w0 = *(const float4*)(cw + (c4 + 0) * 4);
  const float4 w1 = *(const float4*)(cw + (c4 + 1) * 4);
  const float4 w2 = *(const float4*)(cw + (c4 + 2) * 4);
  const float4 w3 = *(const float4*)(cw + (c4 + 3) * 4);
  float4 acc = *(const float4*)(cb + c4);
  float4 xv = *(const float4*)base;
  acc.x = fmaf(w0.w, xv.x, acc.x); acc.y = fmaf(w1.w, xv.y, acc.y);
  acc.z = fmaf(w2.w, xv.z, acc.z); acc.w = fmaf(w3.w, xv.w, acc.w);
  if (l >= 1) {
    xv = *(const float4*)(base - 2 * D_INNER);
    acc.x = fmaf(w0.z, xv.x, acc.x); acc.y = fmaf(w1.z, xv.y, acc.y);
    acc.z = fmaf(w2.z, xv.z, acc.z); acc.w = fmaf(w3.z, xv.w, acc.w);
  }
  if (l >= 2) {
    xv = *(const float4*)(base - 4 * D_INNER);
    acc.x = fmaf(w0.y, xv.x, acc.x); acc.y = fmaf(w1.y, xv.y, acc.y);
    acc.z = fmaf(w2.y, xv.z, acc.z); acc.w = fmaf(w3.y, xv.w, acc.w);
  }
  if (l >= 3) {
    xv = *(const float4*)(base - 6 * D_INNER);
    acc.x = fmaf(w0.x, xv.x, acc.x); acc.y = fmaf(w1.x, xv.y, acc.y);
    acc.z = fmaf(w2.x, xv.z, acc.z); acc.w = fmaf(w3.x, xv.w, acc.w);
  }
  acc.x = acc.x / (1.f + __expf(-acc.x));
  acc.y = acc.y / (1.f + __expf(-acc.y));
  acc.z = acc.z / (1.f + __expf(-acc.z));
  acc.w = acc.w / (1.f + __expf(-acc.w));
  *(float4*)(xc + (size_t)row * D_INNER + c4) = acc;
}

// ------- chunked selective scan, pass 1 --------------------------------------
__global__ __launch_bounds__(256) void scan_pass1_k(
    const float* __restrict__ dt, const float* __restrict__ xc,
    const float* __restrict__ xdbl, const float* __restrict__ A_log,
    float* __restrict__ hend, float* __restrict__ sumdt) {
  const int c = blockIdx.x * 256 + threadIdx.x;
  const int k = blockIdx.y;
  const int b = blockIdx.z;
  float Ac[D_STATE];
  #pragma unroll
  for (int n = 0; n < D_STATE; n++) Ac[n] = -__expf(A_log[c * D_STATE + n]);
  float h[D_STATE] = {};
  float sd = 0.f;
  const size_t r0 = (size_t)b * LL + (size_t)k * CLEN;
  const float* dtp = dt + r0 * D_INNER + c;
  const float* xcp = xc + r0 * D_INNER + c;
  const float* Bp  = xdbl + r0 * 96 + DT_RANK;

  float dtv = dtp[0];
  float xv  = xcp[0];
  float4 B0 = *(const float4*)(Bp + 0);
  float4 B1 = *(const float4*)(Bp + 4);
  float4 B2 = *(const float4*)(Bp + 8);
  float4 B3 = *(const float4*)(Bp + 12);
  for (int l = 0; l < CLEN; l++) {
    const int lp = (l + 1 < CLEN) ? l + 1 : l;
    const float dtv2 = dtp[(size_t)lp * D_INNER];
    const float xv2  = xcp[(size_t)lp * D_INNER];
    const float4 B0n = *(const float4*)(Bp + (size_t)lp * 96 + 0);
    const float4 B1n = *(const float4*)(Bp + (size_t)lp * 96 + 4);
    const float4 B2n = *(const float4*)(Bp + (size_t)lp * 96 + 8);
    const float4 B3n = *(const float4*)(Bp + (size_t)lp * 96 + 12);
    sd += dtv;
    const float dx = dtv * xv;
    const float Bv[D_STATE] = {B0.x,B0.y,B0.z,B0.w, B1.x,B1.y,B1.z,B1.w,
                               B2.x,B2.y,B2.z,B2.w, B3.x,B3.y,B3.z,B3.w};
    #pragma unroll
    for (int n = 0; n < D_STATE; n++)
      h[n] = fmaf(__expf(dtv * Ac[n]), h[n], dx * Bv[n]);
    dtv = dtv2; xv = xv2; B0 = B0n; B1 = B1n; B2 = B2n; B3 = B3n;
  }
  float* he = hend + (((size_t)(b * CH + k) * D_INNER + c) << 4);
  #pragma unroll
  for (int n = 0; n < D_STATE; n += 4)
    *(float4*)(he + n) = make_float4(h[n], h[n+1], h[n+2], h[n+3]);
  sumdt[(size_t)(b * CH + k) * D_INNER + c] = sd;
}

// ------- chunked scan fixup ---------------------------------------------------
__global__ __launch_bounds__(256) void scan_fix_k(
    float* __restrict__ hend, const float* __restrict__ sumdt,
    const float* __restrict__ A_log) {
  const int gid = blockIdx.x * 256 + threadIdx.x;
  const int n = gid & 15;
  const int c = (gid >> 4) & (D_INNER - 1);
  const int b = gid >> 15;
  const float Ac = -__expf(A_log[c * D_STATE + n]);
  float hrun = 0.f;
  for (int k = 0; k < CH; k++) {
    const size_t base = (size_t)(b * CH + k) * D_INNER + c;
    const float sd = sumdt[base];
    float* hp = hend + (base << 4) + n;
    const float tmp = *hp;
    *hp = hrun;
    hrun = fmaf(__expf(Ac * sd), hrun, tmp);
  }
}

// ------- chunked scan pass 3: replay, gate, emit y as bf16 --------------------
__global__ __launch_bounds__(256) void scan_pass3_k(
    const float* __restrict__ dt, const float* __restrict__ xc,
    const float* __restrict__ xdbl, const float* __restrict__ xz,
    const float* __restrict__ h0, const float* __restrict__ A_log,
    const float* __restrict__ Dp, unsigned short* __restrict__ yh) {
  const int c = blockIdx.x * 256 + threadIdx.x;
  const int k = blockIdx.y;
  const int b = blockIdx.z;
  float Ac[D_STATE];
  #pragma unroll
  for (int n = 0; n < D_STATE; n++) Ac[n] = -__expf(A_log[c * D_STATE + n]);
  const float Dv = Dp[c];
  float h[D_STATE];
  const float* hp = h0 + (((size_t)(b * CH + k) * D_INNER + c) << 4);
  #pragma unroll
  for (int n = 0; n < D_STATE; n += 4) {
    const float4 v = *(const float4*)(hp + n);
    h[n] = v.x; h[n+1] = v.y; h[n+2] = v.z; h[n+3] = v.w;
  }
  const size_t r0 = (size_t)b * LL + (size_t)k * CLEN;
  const float* dtp = dt + r0 * D_INNER + c;
  const float* xcp = xc + r0 * D_INNER + c;
  const float* Bp  = xdbl + r0 * 96 + DT_RANK;
  const float* zp  = xz + r0 * (size_t)(2 * D_INNER) + D_INNER + c;
  unsigned short* yhp = yh + r0 * D_INNER + c;

  float dtv = dtp[0];
  float xv  = xcp[0];
  float zv  = zp[0];
  float4 B0 = *(const float4*)(Bp + 0);
  float4 B1 = *(const float4*)(Bp + 4);
  float4 B2 = *(const float4*)(Bp + 8);
  float4 B3 = *(const float4*)(Bp + 12);
  float4 C0 = *(const float4*)(Bp + 16);
  float4 C1 = *(const float4*)(Bp + 20);
  float4 C2 = *(const float4*)(Bp + 24);
  float4 C3 = *(const float4*)(Bp + 28);
  for (int l = 0; l < CLEN; l++) {
    const int lp = (l + 1 < CLEN) ? l + 1 : l;
    const float dtv2 = dtp[(size_t)lp * D_INNER];
    const float xv2  = xcp[(size_t)lp * D_INNER];
    const float zv2  = zp[(size_t)lp * 2 * D_INNER];
    const float4 B0n = *(const float4*)(Bp + (size_t)lp * 96 + 0);
    const float4 B1n = *(const float4*)(Bp + (size_t)lp * 96 + 4);
    const float4 B2n = *(const float4*)(Bp + (size_t)lp * 96 + 8);
    const float4 B3n = *(const float4*)(Bp + (size_t)lp * 96 + 12);
    const float4 C0n = *(const float4*)(Bp + (size_t)lp * 96 + 16);
    const float4 C1n = *(const float4*)(Bp + (size_t)lp * 96 + 20);
    const float4 C2n = *(const float4*)(Bp + (size_t)lp * 96 + 24);
    const float4 C3n = *(const float4*)(Bp + (size_t)lp * 96 + 28);
    const float dx = dtv * xv;
    const float Bv[D_STATE] = {B0.x,B0.y,B0.z,B0.w, B1.x,B1.y,B1.z,B1.w,
                               B2.x,B2.y,B2.z,B2.w, B3.x,B3.y,B3.z,B3.w};
    const float Cv[D_STATE] = {C0.x,C0.y,C0.z,C0.w, C1.x,C1.y,C1.z,C1.w,
                               C2.x,C2.y,C2.z,C2.w, C3.x,C3.y,C3.z,C3.w};
    float y = 0.f;
    #pragma unroll
    for (int n = 0; n < D_STATE; n++) {
      h[n] = fmaf(__expf(dtv * Ac[n]), h[n], dx * Bv[n]);
      y = fmaf(h[n], Cv[n], y);
    }
    y = fmaf(xv, Dv, y);
    y *= zv / (1.f + __expf(-zv));
    yhp[(size_t)l * D_INNER] = rnd_bf16(y);
    dtv = dtv2; xv = xv2; zv = zv2;
    B0 = B0n; B1 = B1n; B2 = B2n; B3 = B3n;
    C0 = C0n; C1 = C1n; C2 = C2n; C3 = C3n;
  }
}

// ---------------- mean pool over L ------------------------------------------
__global__ __launch_bounds__(256) void pool_k(const float* __restrict__ h,
    float* __restrict__ pooled) {
  const int d = blockIdx.x * 256 + threadIdx.x;
  const int b = blockIdx.y;
  float s = 0.f;
  for (int l = 0; l < LL; l++) s += h[((size_t)(b * LL + l)) * D_MODEL + d];
  pooled[b * D_MODEL + d] = s * (1.f / LL);
}

// ---------------- classifier head --------------------------------------------
__global__ __launch_bounds__(64) void head_k(const float* __restrict__ pooled,
    const float* __restrict__ hw, const float* __restrict__ hb,
    float* __restrict__ out) {
  const int b = blockIdx.x / N_CLASSES;
  const int j = blockIdx.x % N_CLASSES;
  float s = 0.f;
  for (int k = threadIdx.x; k < D_MODEL; k += 64)
    s = fmaf(pooled[b * D_MODEL + k], hw[j * D_MODEL + k], s);
  #pragma unroll
  for (int o = 32; o; o >>= 1) s += __shfl_down(s, o);
  if (threadIdx.x == 0) out[b * N_CLASSES + j] = s + hb[j];
}

extern "C" void kernel_launch(void* const* d_in, const int* in_sizes, int n_in,
                              void* d_out, int out_size, void* d_ws, size_t ws_size,
                              hipStream_t stream) {
  const float* x0    = (const float*)d_in[0];
  const float* ln1w  = (const float*)d_in[1];
  const float* ln1b  = (const float*)d_in[2];
  const float* inw   = (const float*)d_in[3];
  const float* convw = (const float*)d_in[4];
  const float* convb = (const float*)d_in[5];
  const float* xpw   = (const float*)d_in[6];
  const float* dtpw  = (const float*)d_in[7];
  const float* dtpb  = (const float*)d_in[8];
  const float* Alog  = (const float*)d_in[9];
  const float* Dp    = (const float*)d_in[10];
  const float* outw  = (const float*)d_in[11];
  const float* normw = (const float*)d_in[12];
  const float* normb = (const float*)d_in[13];
  const float* headw = (const float*)d_in[14];
  const float* headb = (const float*)d_in[15];

  float* ws = (float*)d_ws;
  size_t f = 0;
  float* X      = ws + f; f += (size_t)BL * D_MODEL;        // 4.19M
  float* xz     = ws + f; f += (size_t)BL * 2 * D_INNER;    // 16.8M
  float* xc     = ws + f; f += (size_t)BL * D_INNER;        // 8.4M
  float* xdbl   = ws + f; f += (size_t)BL * 96;             // 0.39M
  float* dty    = ws + f; f += (size_t)BL * D_INNER;        // 8.4M
  float* pooled = ws + f; f += 4096;
  float* xpart  = ws + f; f += (size_t)KS * BL * 96;        // 3.15M
  float* hend   = ws + f; f += (size_t)BB * CH * D_INNER * D_STATE;  // 4.19M
  unsigned short* hh  = (unsigned short*)(ws + f); f += (size_t)BL * D_MODEL / 2;
  unsigned short* yh  = (unsigned short*)(ws + f); f += (size_t)BL * D_INNER / 2;
  unsigned short* wih = (unsigned short*)(ws + f); f += (size_t)2 * D_INNER * D_MODEL / 2;
  unsigned short* woh = (unsigned short*)(ws + f); f += (size_t)D_MODEL * D_INNER / 2;
  // Overlays (lifetime-disjoint):
  //  sumdt (BB*CH*D_INNER = 0.26M) overlays xpart (dead after xproj_reduce)
  //  opart (KSO*BL*D_MODEL = 8.4M) overlays xz (written after scan_pass3's reads)
  float* sumdt = xpart;
  float* opart = xz;

  hipMemcpyAsync(X, x0, (size_t)BL * D_MODEL * sizeof(float),
                 hipMemcpyDeviceToDevice, stream);

  for (int layer = 0; layer < N_LAYERS; ++layer) {
    // LayerNorm -> bf16 A-operand
    layernorm_bf16_k<<<BL, 256, 0, stream>>>(X, ln1w + layer * D_MODEL,
                                             ln1b + layer * D_MODEL, hh);
    // round weights to bf16 for this layer
    round_k<<<(2 * D_INNER * D_MODEL) / 1024, 256, 0, stream>>>(
        inw + (size_t)layer * 2 * D_INNER * D_MODEL, wih);
    round_k<<<(D_MODEL * D_INNER) / 1024, 256, 0, stream>>>(
        outw + (size_t)layer * D_MODEL * D_INNER, woh);
    // xz = h @ in_w^T : M=4096 N=4096 K=1024 (bf16 MFMA)
    mfma_gemm_nt<0, 1><<<dim3(4096 / 128, 4096 / 128), 256, 0, stream>>>(
        hh, wih, xz, BL, 2 * D_INNER, D_MODEL, 2 * D_INNER);
    conv_silu_k<<<(BL * D_INNER / 4) / 256, 256, 0, stream>>>(
        xz, convw + layer * D_INNER * D_CONV, convb + layer * D_INNER, xc);
    // x_dbl = xc @ xp_w^T : M=4096 N=96 K=2048 (fp32 split-K + reduce)
    sgemm_splitk_k<<<dim3(96 / 32, 4096 / 64, KS), 256, 0, stream>>>(
        xc, xpw + (size_t)layer * 96 * D_INNER, xpart);
    xproj_reduce_k<<<(BL * 96) / 256, 256, 0, stream>>>(xpart, xdbl);
    // dt = softplus(dt_r @ dtp_w^T + dtp_b) : M=4096 N=2048 K=64 (fp32, 64² tile)
    sgemm_nt<64,64,64,4,4,1><<<dim3(2048 / 64, 4096 / 64), 256, 0, stream>>>(
        xdbl, dtpw + (size_t)layer * D_INNER * DT_RANK, dty,
        BL, D_INNER, DT_RANK, 96, DT_RANK, D_INNER,
        dtpb + layer * D_INNER);
    // chunked scan (CH=32)
    scan_pass1_k<<<dim3(D_INNER / 256, CH, BB), 256, 0, stream>>>(
        dty, xc, xdbl, Alog + (size_t)layer * D_INNER * D_STATE, hend, sumdt);
    scan_fix_k<<<(BB * D_INNER * D_STATE) / 256, 256, 0, stream>>>(
        hend, sumdt, Alog + (size_t)layer * D_INNER * D_STATE);
    scan_pass3_k<<<dim3(D_INNER / 256, CH, BB), 256, 0, stream>>>(
        dty, xc, xdbl, xz, hend, Alog + (size_t)layer * D_INNER * D_STATE,
        Dp + layer * D_INNER, yh);
    // y @ out_w^T : M=4096 N=1024 K=2048, split-K=2 partials (overlay xz)
    mfma_gemm_nt<1, KSO><<<dim3(1024 / 128, 4096 / 128, KSO), 256, 0, stream>>>(
        yh, woh, opart, BL, D_MODEL, D_INNER, D_MODEL);
    // X += sum_k partials (fixed order, deterministic)
    outproj_reduce_k<<<(BL * D_MODEL / 4) / 256, 256, 0, stream>>>(opart, X);
  }

  layernorm_k<<<BL, 256, 0, stream>>>(X, normw, normb, dty);
  pool_k<<<dim3(D_MODEL / 256, BB), 256, 0, stream>>>(dty, pooled);
  head_k<<<BB * N_CLASSES, 64, 0, stream>>>(pooled, headw, headb, (float*)d_out);
}

// Round 10
// 659.497 us; speedup vs baseline: 4.7738x; 1.0194x over previous
//
#include <hip/hip_runtime.h>
#include <hip/hip_bf16.h>

#define N_LAYERS 2
#define D_MODEL 1024
#define D_INNER 2048
#define D_STATE 16
#define D_CONV 4
#define DT_RANK 64
#define N_CLASSES 10
#define BB 4
#define LL 1024
#define BL (BB*LL)   // 4096 rows
#define CH 32        // scan chunks per sequence
#define CLEN (LL/CH) // 32 steps per chunk
#define KS 8         // split-K segments for x_proj
#define KSO 2        // split-K segments for out_proj

typedef __attribute__((ext_vector_type(8))) short bf16x8;
typedef __attribute__((ext_vector_type(4))) float f32x4;

typedef const void __attribute__((address_space(1)))* gas_ptr;
typedef void __attribute__((address_space(3)))* las_ptr;
#define GLDS16(g, p) __builtin_amdgcn_global_load_lds((gas_ptr)(g), (las_ptr)(p), 16, 0, 0)

__device__ inline unsigned short rnd_bf16(float x) {
  unsigned u = __float_as_uint(x);
  return (unsigned short)((u + 0x7FFFu + ((u >> 16) & 1u)) >> 16);
}
__device__ inline float b2f(unsigned short u) {
  return __uint_as_float(((unsigned)u) << 16);
}

// round weights to bf16 (both layers in one launch)
__global__ __launch_bounds__(256) void round_k(const float* __restrict__ in,
    unsigned short* __restrict__ hi) {
  const int i = blockIdx.x * 256 + threadIdx.x;
  const float4 v = ((const float4*)in)[i];
  ushort4 h4;
  h4.x = rnd_bf16(v.x); h4.y = rnd_bf16(v.y);
  h4.z = rnd_bf16(v.z); h4.w = rnd_bf16(v.w);
  ((ushort4*)hi)[i] = h4;
}

// ---------------- LayerNorm -> bf16 out ---------------------------------------
__global__ __launch_bounds__(256) void layernorm_bf16_k(const float* __restrict__ x,
    const float* __restrict__ w, const float* __restrict__ b,
    unsigned short* __restrict__ oh) {
  const int row = blockIdx.x;
  const int t = threadIdx.x;
  const float4 v = *(const float4*)(x + (size_t)row * D_MODEL + t * 4);
  float s = v.x + v.y + v.z + v.w;
  float q = v.x*v.x + v.y*v.y + v.z*v.z + v.w*v.w;
  #pragma unroll
  for (int o = 32; o; o >>= 1) { s += __shfl_down(s, o); q += __shfl_down(q, o); }
  __shared__ float red[8];
  if ((t & 63) == 0) { red[t >> 6] = s; red[4 + (t >> 6)] = q; }
  __syncthreads();
  s = red[0] + red[1] + red[2] + red[3];
  q = red[4] + red[5] + red[6] + red[7];
  const float mean = s * (1.f / D_MODEL);
  const float var  = q * (1.f / D_MODEL) - mean * mean;
  const float rstd = rsqrtf(var + 1e-5f);
  const float4 wv = *(const float4*)(w + t * 4);
  const float4 bv = *(const float4*)(b + t * 4);
  ushort4 h4;
  h4.x = rnd_bf16((v.x - mean) * rstd * wv.x + bv.x);
  h4.y = rnd_bf16((v.y - mean) * rstd * wv.y + bv.y);
  h4.z = rnd_bf16((v.z - mean) * rstd * wv.z + bv.z);
  h4.w = rnd_bf16((v.w - mean) * rstd * wv.w + bv.w);
  ((ushort4*)(oh + (size_t)row * D_MODEL))[t] = h4;
}

// ---- fused: X += sum(out_proj partials); then LayerNorm(X) -> next operand ---
// OUT 0: bf16 (next layer's hh). OUT 1: fp32 (final LN for pooling).
template<int OUT>
__global__ __launch_bounds__(256) void oreduce_ln_k(
    const float* __restrict__ part, float* __restrict__ X,
    const float* __restrict__ w, const float* __restrict__ b,
    void* __restrict__ out) {
  const int row = blockIdx.x;
  const int t = threadIdx.x;
  float4 v = *(const float4*)(X + (size_t)row * D_MODEL + t * 4);
  #pragma unroll
  for (int k = 0; k < KSO; k++) {
    const float4 p = *(const float4*)(part + (size_t)k * BL * D_MODEL
                                      + (size_t)row * D_MODEL + t * 4);
    v.x += p.x; v.y += p.y; v.z += p.z; v.w += p.w;
  }
  *(float4*)(X + (size_t)row * D_MODEL + t * 4) = v;   // residual for next layer
  float s = v.x + v.y + v.z + v.w;
  float q = v.x*v.x + v.y*v.y + v.z*v.z + v.w*v.w;
  #pragma unroll
  for (int o = 32; o; o >>= 1) { s += __shfl_down(s, o); q += __shfl_down(q, o); }
  __shared__ float red[8];
  if ((t & 63) == 0) { red[t >> 6] = s; red[4 + (t >> 6)] = q; }
  __syncthreads();
  s = red[0] + red[1] + red[2] + red[3];
  q = red[4] + red[5] + red[6] + red[7];
  const float mean = s * (1.f / D_MODEL);
  const float var  = q * (1.f / D_MODEL) - mean * mean;
  const float rstd = rsqrtf(var + 1e-5f);
  const float4 wv = *(const float4*)(w + t * 4);
  const float4 bv = *(const float4*)(b + t * 4);
  float4 o4;
  o4.x = (v.x - mean) * rstd * wv.x + bv.x;
  o4.y = (v.y - mean) * rstd * wv.y + bv.y;
  o4.z = (v.z - mean) * rstd * wv.z + bv.z;
  o4.w = (v.w - mean) * rstd * wv.w + bv.w;
  if constexpr (OUT == 0) {
    ushort4 h4;
    h4.x = rnd_bf16(o4.x); h4.y = rnd_bf16(o4.y);
    h4.z = rnd_bf16(o4.z); h4.w = rnd_bf16(o4.w);
    ((ushort4*)((unsigned short*)out + (size_t)row * D_MODEL))[t] = h4;
  } else {
    *(float4*)((float*)out + (size_t)row * D_MODEL + t * 4) = o4;
  }
}

// ---- bf16 MFMA GEMM NT (optional split-K) -----------------------------------
// C[m,n] = sum_k A[m,k]*B[n,k], bf16 inputs, fp32 acc.
// EPI 0: store bf16 to (unsigned short*)C; EPI 1: fp32 partials at C+kz*M*ldc.
template<int EPI, int KSEG>
__global__ __launch_bounds__(256) void mfma_gemm_nt(
    const unsigned short* __restrict__ Ah, const unsigned short* __restrict__ Bh,
    void* __restrict__ Cv, int M, int N, int K, int ldc) {
  __shared__ unsigned short As[128 * 64];
  __shared__ unsigned short Bs[128 * 64];
  const int tid = threadIdx.x;
  const int w = tid >> 6, l = tid & 63;
  const int wr = w >> 1, wc = w & 1;
  const int m0 = blockIdx.y * 128, n0 = blockIdx.x * 128;
  const int kz = (KSEG > 1) ? blockIdx.z : 0;
  const int kbeg = kz * (K / KSEG);
  const int kend = kbeg + K / KSEG;
  const int srow = l >> 3;             // staging row within 8-row block
  const int scol = (l & 7) * 8;        // staging col (elements)
  const int fr = l & 15;               // fragment row
  const int fk = (l >> 4) * 8;         // fragment k offset
  f32x4 acc[4][4] = {};

  #pragma unroll 1
  for (int k0 = kbeg; k0 < kend; k0 += 64) {
    __syncthreads();                  // previous compute done before overwrite
    #pragma unroll
    for (int it = 0; it < 4; ++it) {
      const int bi = it * 4 + w;      // 1 KB block id 0..15
      const int row = bi * 8 + srow;
      GLDS16(Ah + (size_t)(m0 + row) * K + k0 + scol, &As[bi * 512 + l * 8]);
      GLDS16(Bh + (size_t)(n0 + row) * K + k0 + scol, &Bs[bi * 512 + l * 8]);
    }
    __syncthreads();                  // staging visible (vmcnt drained)
    #pragma unroll
    for (int kk = 0; kk < 64; kk += 32) {
      bf16x8 a[4], b[4];
      #pragma unroll
      for (int f = 0; f < 4; ++f)
        b[f] = *(const bf16x8*)&Bs[(wc * 64 + f * 16 + fr) * 64 + kk + fk];
      #pragma unroll
      for (int f = 0; f < 4; ++f)
        a[f] = *(const bf16x8*)&As[(wr * 64 + f * 16 + fr) * 64 + kk + fk];
      #pragma unroll
      for (int i = 0; i < 4; ++i)
        #pragma unroll
        for (int j = 0; j < 4; ++j)
          acc[i][j] = __builtin_amdgcn_mfma_f32_16x16x32_bf16(
              a[i], b[j], acc[i][j], 0, 0, 0);
    }
  }
  const int orow = (l >> 4) * 4;
  const int ocol = l & 15;
  if constexpr (EPI == 0) {
    unsigned short* Cw = (unsigned short*)Cv;
    #pragma unroll
    for (int i = 0; i < 4; ++i)
      #pragma unroll
      for (int j = 0; j < 4; ++j)
        #pragma unroll
        for (int r = 0; r < 4; ++r) {
          const int m = m0 + wr * 64 + i * 16 + orow + r;
          const int n = n0 + wc * 64 + j * 16 + ocol;
          Cw[(size_t)m * ldc + n] = rnd_bf16(acc[i][j][r]);
        }
  } else {
    float* Cw = (float*)Cv + (size_t)kz * M * ldc;
    #pragma unroll
    for (int i = 0; i < 4; ++i)
      #pragma unroll
      for (int j = 0; j < 4; ++j)
        #pragma unroll
        for (int r = 0; r < 4; ++r) {
          const int m = m0 + wr * 64 + i * 16 + orow + r;
          const int n = n0 + wc * 64 + j * 16 + ocol;
          Cw[(size_t)m * ldc + n] = acc[i][j][r];
        }
  }
}

// ---------------- fp32 SGEMM NT (dt GEMM) -------------------------------------
// EPI: 0 none; 1 softplus(acc + bias[n])
template<int BM, int BN, int BK, int TM, int TN, int EPI>
__global__ __launch_bounds__(256) void sgemm_nt(
    const float* __restrict__ A, const float* __restrict__ B,
    float* __restrict__ C, int M, int N, int K, int lda, int ldb, int ldc,
    const float* __restrict__ bias) {
  constexpr int THREADS = 256;
  constexpr int NT = BN / TN;
  constexpr int K4 = BK / 4;
  constexpr int A_F4 = BM * BK / (THREADS * 4);
  constexpr int B_F4 = BN * BK / (THREADS * 4);
  static_assert((BM / TM) * (BN / TN) == THREADS, "thread shape");
  __shared__ float As[BK][BM + 4];
  __shared__ float Bs[BK][BN + 4];
  const int tid = threadIdx.x;
  const int m0 = blockIdx.y * BM;
  const int n0 = blockIdx.x * BN;
  const int tn = (tid % NT) * TN;
  const int tm = (tid / NT) * TM;
  float acc[TM][TN] = {};
  for (int k0 = 0; k0 < K; k0 += BK) {
    #pragma unroll
    for (int i = 0; i < A_F4; i++) {
      int li = tid + i * THREADS;
      int r = li / K4, c4 = li % K4;
      float4 v = *(const float4*)(A + (size_t)(m0 + r) * lda + k0 + c4 * 4);
      As[c4*4+0][r] = v.x; As[c4*4+1][r] = v.y; As[c4*4+2][r] = v.z; As[c4*4+3][r] = v.w;
    }
    #pragma unroll
    for (int i = 0; i < B_F4; i++) {
      int li = tid + i * THREADS;
      int r = li / K4, c4 = li % K4;
      float4 v = *(const float4*)(B + (size_t)(n0 + r) * ldb + k0 + c4 * 4);
      Bs[c4*4+0][r] = v.x; Bs[c4*4+1][r] = v.y; Bs[c4*4+2][r] = v.z; Bs[c4*4+3][r] = v.w;
    }
    __syncthreads();
    #pragma unroll
    for (int k = 0; k < BK; k++) {
      float a[TM], bf[TN];
      #pragma unroll
      for (int i = 0; i < TM; i++) a[i] = As[k][tm + i];
      #pragma unroll
      for (int j = 0; j < TN; j++) bf[j] = Bs[k][tn + j];
      #pragma unroll
      for (int i = 0; i < TM; i++)
        #pragma unroll
        for (int j = 0; j < TN; j++)
          acc[i][j] = fmaf(a[i], bf[j], acc[i][j]);
    }
    __syncthreads();
  }
  #pragma unroll
  for (int i = 0; i < TM; i++) {
    const int m = m0 + tm + i;
    #pragma unroll
    for (int j = 0; j < TN; j++) {
      const int n = n0 + tn + j;
      float v = acc[i][j];
      if constexpr (EPI == 1) {
        v += bias[n];
        v = (v > 20.f) ? v : log1pf(__expf(v));
      }
      C[(size_t)m * ldc + n] = v;
    }
  }
}

// ---- x_proj split-K: part[kz][m][n] = sum_{k in seg kz} xc[m,k]*xpw[n,k] ----
__global__ __launch_bounds__(256) void sgemm_splitk_k(
    const float* __restrict__ A, const float* __restrict__ B,
    float* __restrict__ part) {
  __shared__ float As[32][64 + 4];
  __shared__ float Bs[32][32 + 4];
  const int tid = threadIdx.x;
  const int n0 = blockIdx.x * 32;
  const int m0 = blockIdx.y * 64;
  const int kz = blockIdx.z;
  const int tn = (tid & 15) * 2;
  const int tm = (tid >> 4) * 4;
  float acc[4][2] = {};
  for (int kb = 0; kb < 256; kb += 32) {
    const int k0 = kz * 256 + kb;
    #pragma unroll
    for (int i = 0; i < 2; i++) {
      int li = tid + i * 256;          // 512 float4 slots for A (64x32)
      int r = li >> 3, c4 = li & 7;
      float4 v = *(const float4*)(A + (size_t)(m0 + r) * D_INNER + k0 + c4 * 4);
      As[c4*4+0][r] = v.x; As[c4*4+1][r] = v.y;
      As[c4*4+2][r] = v.z; As[c4*4+3][r] = v.w;
    }
    {
      int r = tid >> 3, c4 = tid & 7;  // 256 float4 slots for B (32x32)
      float4 v = *(const float4*)(B + (size_t)(n0 + r) * D_INNER + k0 + c4 * 4);
      Bs[c4*4+0][r] = v.x; Bs[c4*4+1][r] = v.y;
      Bs[c4*4+2][r] = v.z; Bs[c4*4+3][r] = v.w;
    }
    __syncthreads();
    #pragma unroll
    for (int k = 0; k < 32; k++) {
      float a[4], bf[2];
      #pragma unroll
      for (int i = 0; i < 4; i++) a[i] = As[k][tm + i];
      bf[0] = Bs[k][tn]; bf[1] = Bs[k][tn + 1];
      #pragma unroll
      for (int i = 0; i < 4; i++) {
        acc[i][0] = fmaf(a[i], bf[0], acc[i][0]);
        acc[i][1] = fmaf(a[i], bf[1], acc[i][1]);
      }
    }
    __syncthreads();
  }
  float* p = part + (size_t)kz * BL * 96;
  #pragma unroll
  for (int i = 0; i < 4; i++) {
    const int m = m0 + tm + i;
    p[(size_t)m * 96 + n0 + tn]     = acc[i][0];
    p[(size_t)m * 96 + n0 + tn + 1] = acc[i][1];
  }
}

// fixed-order deterministic reduce of the KS partials -> xdbl
__global__ __launch_bounds__(256) void xproj_reduce_k(
    const float* __restrict__ part, float* __restrict__ out) {
  const int i = blockIdx.x * 256 + threadIdx.x;   // over BL*96
  float s = 0.f;
  #pragma unroll
  for (int k = 0; k < KS; k++) s += part[(size_t)k * BL * 96 + i];
  out[i] = s;
}

// ------ causal depthwise conv (width 4) + SiLU, bf16 in / fp32 out -----------
__global__ __launch_bounds__(256) void conv_silu_k(
    const unsigned short* __restrict__ xz,
    const float* __restrict__ cw, const float* __restrict__ cb,
    float* __restrict__ xc) {
  const int gid = blockIdx.x * 256 + threadIdx.x;   // BL * D_INNER/4
  const int c4 = (gid & (D_INNER / 4 - 1)) << 2;
  const int row = gid >> 9;                         // b*LL + l
  const int l = row & (LL - 1);
  const unsigned short* base = xz + (size_t)row * (2 * D_INNER) + c4;
  const float4 w0 = *(const float4*)(cw + (c4 + 0) * 4);
  const float4 w1 = *(const float4*)(cw + (c4 + 1) * 4);
  const float4 w2 = *(const float4*)(cw + (c4 + 2) * 4);
  const float4 w3 = *(const float4*)(cw + (c4 + 3) * 4);
  float4 acc = *(const float4*)(cb + c4);
  ushort4 uv = *(const ushort4*)base;
  acc.x = fmaf(w0.w, b2f(uv.x), acc.x); acc.y = fmaf(w1.w, b2f(uv.y), acc.y);
  acc.z = fmaf(w2.w, b2f(uv.z), acc.z); acc.w = fmaf(w3.w, b2f(uv.w), acc.w);
  if (l >= 1) {
    uv = *(const ushort4*)(base - 2 * D_INNER);
    acc.x = fmaf(w0.z, b2f(uv.x), acc.x); acc.y = fmaf(w1.z, b2f(uv.y), acc.y);
    acc.z = fmaf(w2.z, b2f(uv.z), acc.z); acc.w = fmaf(w3.z, b2f(uv.w), acc.w);
  }
  if (l >= 2) {
    uv = *(const ushort4*)(base - 4 * D_INNER);
    acc.x = fmaf(w0.y, b2f(uv.x), acc.x); acc.y = fmaf(w1.y, b2f(uv.y), acc.y);
    acc.z = fmaf(w2.y, b2f(uv.z), acc.z); acc.w = fmaf(w3.y, b2f(uv.w), acc.w);
  }
  if (l >= 3) {
    uv = *(const ushort4*)(base - 6 * D_INNER);
    acc.x = fmaf(w0.x, b2f(uv.x), acc.x); acc.y = fmaf(w1.x, b2f(uv.y), acc.y);
    acc.z = fmaf(w2.x, b2f(uv.z), acc.z); acc.w = fmaf(w3.x, b2f(uv.w), acc.w);
  }
  acc.x = acc.x / (1.f + __expf(-acc.x));
  acc.y = acc.y / (1.f + __expf(-acc.y));
  acc.z = acc.z / (1.f + __expf(-acc.z));
  acc.w = acc.w / (1.f + __expf(-acc.w));
  *(float4*)(xc + (size_t)row * D_INNER + c4) = acc;
}

// ------- chunked selective scan, pass 1 --------------------------------------
__global__ __launch_bounds__(256) void scan_pass1_k(
    const float* __restrict__ dt, const float* __restrict__ xc,
    const float* __restrict__ xdbl, const float* __restrict__ A_log,
    float* __restrict__ hend, float* __restrict__ sumdt) {
  const int c = blockIdx.x * 256 + threadIdx.x;
  const int k = blockIdx.y;
  const int b = blockIdx.z;
  float Ac[D_STATE];
  #pragma unroll
  for (int n = 0; n < D_STATE; n++) Ac[n] = -__expf(A_log[c * D_STATE + n]);
  float h[D_STATE] = {};
  float sd = 0.f;
  const size_t r0 = (size_t)b * LL + (size_t)k * CLEN;
  const float* dtp = dt + r0 * D_INNER + c;
  const float* xcp = xc + r0 * D_INNER + c;
  const float* Bp  = xdbl + r0 * 96 + DT_RANK;

  float dtv = dtp[0];
  float xv  = xcp[0];
  float4 B0 = *(const float4*)(Bp + 0);
  float4 B1 = *(const float4*)(Bp + 4);
  float4 B2 = *(const float4*)(Bp + 8);
  float4 B3 = *(const float4*)(Bp + 12);
  for (int l = 0; l < CLEN; l++) {
    const int lp = (l + 1 < CLEN) ? l + 1 : l;
    const float dtv2 = dtp[(size_t)lp * D_INNER];
    const float xv2  = xcp[(size_t)lp * D_INNER];
    const float4 B0n = *(const float4*)(Bp + (size_t)lp * 96 + 0);
    const float4 B1n = *(const float4*)(Bp + (size_t)lp * 96 + 4);
    const float4 B2n = *(const float4*)(Bp + (size_t)lp * 96 + 8);
    const float4 B3n = *(const float4*)(Bp + (size_t)lp * 96 + 12);
    sd += dtv;
    const float dx = dtv * xv;
    const float Bv[D_STATE] = {B0.x,B0.y,B0.z,B0.w, B1.x,B1.y,B1.z,B1.w,
                               B2.x,B2.y,B2.z,B2.w, B3.x,B3.y,B3.z,B3.w};
    #pragma unroll
    for (int n = 0; n < D_STATE; n++)
      h[n] = fmaf(__expf(dtv * Ac[n]), h[n], dx * Bv[n]);
    dtv = dtv2; xv = xv2; B0 = B0n; B1 = B1n; B2 = B2n; B3 = B3n;
  }
  float* he = hend + (((size_t)(b * CH + k) * D_INNER + c) << 4);
  #pragma unroll
  for (int n = 0; n < D_STATE; n += 4)
    *(float4*)(he + n) = make_float4(h[n], h[n+1], h[n+2], h[n+3]);
  sumdt[(size_t)(b * CH + k) * D_INNER + c] = sd;
}

// ------- chunked scan fixup ---------------------------------------------------
__global__ __launch_bounds__(256) void scan_fix_k(
    float* __restrict__ hend, const float* __restrict__ sumdt,
    const float* __restrict__ A_log) {
  const int gid = blockIdx.x * 256 + threadIdx.x;
  const int n = gid & 15;
  const int c = (gid >> 4) & (D_INNER - 1);
  const int b = gid >> 15;
  const float Ac = -__expf(A_log[c * D_STATE + n]);
  float hrun = 0.f;
  for (int k = 0; k < CH; k++) {
    const size_t base = (size_t)(b * CH + k) * D_INNER + c;
    const float sd = sumdt[base];
    float* hp = hend + (base << 4) + n;
    const float tmp = *hp;
    *hp = hrun;
    hrun = fmaf(__expf(Ac * sd), hrun, tmp);
  }
}

// ------- chunked scan pass 3: replay, gate (bf16 z), emit y as bf16 ----------
__global__ __launch_bounds__(256) void scan_pass3_k(
    const float* __restrict__ dt, const float* __restrict__ xc,
    const float* __restrict__ xdbl, const unsigned short* __restrict__ xz,
    const float* __restrict__ h0, const float* __restrict__ A_log,
    const float* __restrict__ Dp, unsigned short* __restrict__ yh) {
  const int c = blockIdx.x * 256 + threadIdx.x;
  const int k = blockIdx.y;
  const int b = blockIdx.z;
  float Ac[D_STATE];
  #pragma unroll
  for (int n = 0; n < D_STATE; n++) Ac[n] = -__expf(A_log[c * D_STATE + n]);
  const float Dv = Dp[c];
  float h[D_STATE];
  const float* hp = h0 + (((size_t)(b * CH + k) * D_INNER + c) << 4);
  #pragma unroll
  for (int n = 0; n < D_STATE; n += 4) {
    const float4 v = *(const float4*)(hp + n);
    h[n] = v.x; h[n+1] = v.y; h[n+2] = v.z; h[n+3] = v.w;
  }
  const size_t r0 = (size_t)b * LL + (size_t)k * CLEN;
  const float* dtp = dt + r0 * D_INNER + c;
  const float* xcp = xc + r0 * D_INNER + c;
  const float* Bp  = xdbl + r0 * 96 + DT_RANK;
  const unsigned short* zp = xz + r0 * (size_t)(2 * D_INNER) + D_INNER + c;
  unsigned short* yhp = yh + r0 * D_INNER + c;

  float dtv = dtp[0];
  float xv  = xcp[0];
  float zv  = b2f(zp[0]);
  float4 B0 = *(const float4*)(Bp + 0);
  float4 B1 = *(const float4*)(Bp + 4);
  float4 B2 = *(const float4*)(Bp + 8);
  float4 B3 = *(const float4*)(Bp + 12);
  float4 C0 = *(const float4*)(Bp + 16);
  float4 C1 = *(const float4*)(Bp + 20);
  float4 C2 = *(const float4*)(Bp + 24);
  float4 C3 = *(const float4*)(Bp + 28);
  for (int l = 0; l < CLEN; l++) {
    const int lp = (l + 1 < CLEN) ? l + 1 : l;
    const float dtv2 = dtp[(size_t)lp * D_INNER];
    const float xv2  = xcp[(size_t)lp * D_INNER];
    const float zv2  = b2f(zp[(size_t)lp * 2 * D_INNER]);
    const float4 B0n = *(const float4*)(Bp + (size_t)lp * 96 + 0);
    const float4 B1n = *(const float4*)(Bp + (size_t)lp * 96 + 4);
    const float4 B2n = *(const float4*)(Bp + (size_t)lp * 96 + 8);
    const float4 B3n = *(const float4*)(Bp + (size_t)lp * 96 + 12);
    const float4 C0n = *(const float4*)(Bp + (size_t)lp * 96 + 16);
    const float4 C1n = *(const float4*)(Bp + (size_t)lp * 96 + 20);
    const float4 C2n = *(const float4*)(Bp + (size_t)lp * 96 + 24);
    const float4 C3n = *(const float4*)(Bp + (size_t)lp * 96 + 28);
    const float dx = dtv * xv;
    const float Bv[D_STATE] = {B0.x,B0.y,B0.z,B0.w, B1.x,B1.y,B1.z,B1.w,
                               B2.x,B2.y,B2.z,B2.w, B3.x,B3.y,B3.z,B3.w};
    const float Cv[D_STATE] = {C0.x,C0.y,C0.z,C0.w, C1.x,C1.y,C1.z,C1.w,
                               C2.x,C2.y,C2.z,C2.w, C3.x,C3.y,C3.z,C3.w};
    float y = 0.f;
    #pragma unroll
    for (int n = 0; n < D_STATE; n++) {
      h[n] = fmaf(__expf(dtv * Ac[n]), h[n], dx * Bv[n]);
      y = fmaf(h[n], Cv[n], y);
    }
    y = fmaf(xv, Dv, y);
    y *= zv / (1.f + __expf(-zv));
    yhp[(size_t)l * D_INNER] = rnd_bf16(y);
    dtv = dtv2; xv = xv2; zv = zv2;
    B0 = B0n; B1 = B1n; B2 = B2n; B3 = B3n;
    C0 = C0n; C1 = C1n; C2 = C2n; C3 = C3n;
  }
}

// ---------------- mean pool over L ------------------------------------------
__global__ __launch_bounds__(256) void pool_k(const float* __restrict__ h,
    float* __restrict__ pooled) {
  const int d = blockIdx.x * 256 + threadIdx.x;
  const int b = blockIdx.y;
  float s = 0.f;
  for (int l = 0; l < LL; l++) s += h[((size_t)(b * LL + l)) * D_MODEL + d];
  pooled[b * D_MODEL + d] = s * (1.f / LL);
}

// ---------------- classifier head --------------------------------------------
__global__ __launch_bounds__(64) void head_k(const float* __restrict__ pooled,
    const float* __restrict__ hw, const float* __restrict__ hb,
    float* __restrict__ out) {
  const int b = blockIdx.x / N_CLASSES;
  const int j = blockIdx.x % N_CLASSES;
  float s = 0.f;
  for (int k = threadIdx.x; k < D_MODEL; k += 64)
    s = fmaf(pooled[b * D_MODEL + k], hw[j * D_MODEL + k], s);
  #pragma unroll
  for (int o = 32; o; o >>= 1) s += __shfl_down(s, o);
  if (threadIdx.x == 0) out[b * N_CLASSES + j] = s + hb[j];
}

extern "C" void kernel_launch(void* const* d_in, const int* in_sizes, int n_in,
                              void* d_out, int out_size, void* d_ws, size_t ws_size,
                              hipStream_t stream) {
  const float* x0    = (const float*)d_in[0];
  const float* ln1w  = (const float*)d_in[1];
  const float* ln1b  = (const float*)d_in[2];
  const float* inw   = (const float*)d_in[3];
  const float* convw = (const float*)d_in[4];
  const float* convb = (const float*)d_in[5];
  const float* xpw   = (const float*)d_in[6];
  const float* dtpw  = (const float*)d_in[7];
  const float* dtpb  = (const float*)d_in[8];
  const float* Alog  = (const float*)d_in[9];
  const float* Dp    = (const float*)d_in[10];
  const float* outw  = (const float*)d_in[11];
  const float* normw = (const float*)d_in[12];
  const float* normb = (const float*)d_in[13];
  const float* headw = (const float*)d_in[14];
  const float* headb = (const float*)d_in[15];

  float* ws = (float*)d_ws;
  size_t f = 0;
  float* X      = ws + f; f += (size_t)BL * D_MODEL;        // 4.19M
  float* xzf    = ws + f; f += (size_t)BL * D_INNER;        // 8.4M floats (bf16 xz)
  float* xc     = ws + f; f += (size_t)BL * D_INNER;        // 8.4M
  float* xdbl   = ws + f; f += (size_t)BL * 96;             // 0.39M
  float* dty    = ws + f; f += (size_t)BL * D_INNER;        // 8.4M
  float* pooled = ws + f; f += 4096;
  float* xpart  = ws + f; f += (size_t)KS * BL * 96;        // 3.15M
  float* hend   = ws + f; f += (size_t)BB * CH * D_INNER * D_STATE;  // 4.19M
  float* opart  = ws + f; f += (size_t)KSO * BL * D_MODEL;  // 8.4M
  unsigned short* hh  = (unsigned short*)(ws + f); f += (size_t)BL * D_MODEL / 2;
  unsigned short* yh  = (unsigned short*)(ws + f); f += (size_t)BL * D_INNER / 2;
  unsigned short* wih = (unsigned short*)(ws + f);
  f += (size_t)N_LAYERS * 2 * D_INNER * D_MODEL / 2;
  unsigned short* woh = (unsigned short*)(ws + f);
  f += (size_t)N_LAYERS * D_MODEL * D_INNER / 2;
  unsigned short* xz = (unsigned short*)xzf;   // BL * 2*D_INNER bf16
  float* sumdt = xpart;   // overlay: dead after xproj_reduce, live in scan only

  hipMemcpyAsync(X, x0, (size_t)BL * D_MODEL * sizeof(float),
                 hipMemcpyDeviceToDevice, stream);
  // round all weights once (both layers)
  round_k<<<(N_LAYERS * 2 * D_INNER * D_MODEL) / 1024, 256, 0, stream>>>(inw, wih);
  round_k<<<(N_LAYERS * D_MODEL * D_INNER) / 1024, 256, 0, stream>>>(outw, woh);
  // layer-0 LayerNorm -> bf16 operand (reads x0 directly)
  layernorm_bf16_k<<<BL, 256, 0, stream>>>(x0, ln1w, ln1b, hh);

  for (int layer = 0; layer < N_LAYERS; ++layer) {
    const unsigned short* wi = wih + (size_t)layer * 2 * D_INNER * D_MODEL;
    const unsigned short* wo = woh + (size_t)layer * D_MODEL * D_INNER;
    // xz = h @ in_w^T : M=4096 N=4096 K=1024 (bf16 MFMA, bf16 out)
    mfma_gemm_nt<0, 1><<<dim3(4096 / 128, 4096 / 128), 256, 0, stream>>>(
        hh, wi, xz, BL, 2 * D_INNER, D_MODEL, 2 * D_INNER);
    conv_silu_k<<<(BL * D_INNER / 4) / 256, 256, 0, stream>>>(
        xz, convw + layer * D_INNER * D_CONV, convb + layer * D_INNER, xc);
    // x_dbl = xc @ xp_w^T : M=4096 N=96 K=2048 (fp32 split-K + reduce)
    sgemm_splitk_k<<<dim3(96 / 32, 4096 / 64, KS), 256, 0, stream>>>(
        xc, xpw + (size_t)layer * 96 * D_INNER, xpart);
    xproj_reduce_k<<<(BL * 96) / 256, 256, 0, stream>>>(xpart, xdbl);
    // dt = softplus(dt_r @ dtp_w^T + dtp_b) : M=4096 N=2048 K=64 (fp32)
    sgemm_nt<64,64,64,4,4,1><<<dim3(2048 / 64, 4096 / 64), 256, 0, stream>>>(
        xdbl, dtpw + (size_t)layer * D_INNER * DT_RANK, dty,
        BL, D_INNER, DT_RANK, 96, DT_RANK, D_INNER,
        dtpb + layer * D_INNER);
    // chunked scan (CH=32)
    scan_pass1_k<<<dim3(D_INNER / 256, CH, BB), 256, 0, stream>>>(
        dty, xc, xdbl, Alog + (size_t)layer * D_INNER * D_STATE, hend, sumdt);
    scan_fix_k<<<(BB * D_INNER * D_STATE) / 256, 256, 0, stream>>>(
        hend, sumdt, Alog + (size_t)layer * D_INNER * D_STATE);
    scan_pass3_k<<<dim3(D_INNER / 256, CH, BB), 256, 0, stream>>>(
        dty, xc, xdbl, xz, hend, Alog + (size_t)layer * D_INNER * D_STATE,
        Dp + layer * D_INNER, yh);
    // y @ out_w^T : M=4096 N=1024 K=2048, split-K=2 partials
    mfma_gemm_nt<1, KSO><<<dim3(1024 / 128, 4096 / 128, KSO), 256, 0, stream>>>(
        yh, wo, opart, BL, D_MODEL, D_INNER, D_MODEL);
    // fused: X += partials; LN(X) -> next operand (bf16) or final LN (fp32)
    if (layer + 1 < N_LAYERS) {
      oreduce_ln_k<0><<<BL, 256, 0, stream>>>(
          opart, X, ln1w + (layer + 1) * D_MODEL, ln1b + (layer + 1) * D_MODEL, hh);
    } else {
      oreduce_ln_k<1><<<BL, 256, 0, stream>>>(opart, X, normw, normb, dty);
    }
  }

  pool_k<<<dim3(D_MODEL / 256, BB), 256, 0, stream>>>(dty, pooled);
  head_k<<<BB * N_CLASSES, 64, 0, stream>>>(pooled, headw, headb, (float*)d_out);
}

// Round 11
// 609.389 us; speedup vs baseline: 5.1664x; 1.0822x over previous
//
#include <hip/hip_runtime.h>
#include <hip/hip_bf16.h>

#define N_LAYERS 2
#define D_MODEL 1024
#define D_INNER 2048
#define D_STATE 16
#define D_CONV 4
#define DT_RANK 64
#define N_CLASSES 10
#define BB 4
#define LL 1024
#define BL (BB*LL)   // 4096 rows
#define CH 32        // scan chunks per sequence
#define CLEN (LL/CH) // 32 steps per chunk
#define KS 8         // split-K segments for x_proj
#define KSO 2        // split-K segments for out_proj

typedef __attribute__((ext_vector_type(8))) short bf16x8;
typedef __attribute__((ext_vector_type(8))) unsigned short us8;
typedef __attribute__((ext_vector_type(4))) float f32x4;

typedef const void __attribute__((address_space(1)))* gas_ptr;
typedef void __attribute__((address_space(3)))* las_ptr;
#define GLDS16(g, p) __builtin_amdgcn_global_load_lds((gas_ptr)(g), (las_ptr)(p), 16, 0, 0)

__device__ inline unsigned short rnd_bf16(float x) {
  unsigned u = __float_as_uint(x);
  return (unsigned short)((u + 0x7FFFu + ((u >> 16) & 1u)) >> 16);
}
__device__ inline float b2f(unsigned short u) {
  return __uint_as_float(((unsigned)u) << 16);
}

// round weights to bf16 (both layers in one launch)
__global__ __launch_bounds__(256) void round_k(const float* __restrict__ in,
    unsigned short* __restrict__ hi) {
  const int i = blockIdx.x * 256 + threadIdx.x;
  const float4 v = ((const float4*)in)[i];
  ushort4 h4;
  h4.x = rnd_bf16(v.x); h4.y = rnd_bf16(v.y);
  h4.z = rnd_bf16(v.z); h4.w = rnd_bf16(v.w);
  ((ushort4*)hi)[i] = h4;
}

// ---------------- LayerNorm -> bf16 out ---------------------------------------
__global__ __launch_bounds__(256) void layernorm_bf16_k(const float* __restrict__ x,
    const float* __restrict__ w, const float* __restrict__ b,
    unsigned short* __restrict__ oh) {
  const int row = blockIdx.x;
  const int t = threadIdx.x;
  const float4 v = *(const float4*)(x + (size_t)row * D_MODEL + t * 4);
  float s = v.x + v.y + v.z + v.w;
  float q = v.x*v.x + v.y*v.y + v.z*v.z + v.w*v.w;
  #pragma unroll
  for (int o = 32; o; o >>= 1) { s += __shfl_down(s, o); q += __shfl_down(q, o); }
  __shared__ float red[8];
  if ((t & 63) == 0) { red[t >> 6] = s; red[4 + (t >> 6)] = q; }
  __syncthreads();
  s = red[0] + red[1] + red[2] + red[3];
  q = red[4] + red[5] + red[6] + red[7];
  const float mean = s * (1.f / D_MODEL);
  const float var  = q * (1.f / D_MODEL) - mean * mean;
  const float rstd = rsqrtf(var + 1e-5f);
  const float4 wv = *(const float4*)(w + t * 4);
  const float4 bv = *(const float4*)(b + t * 4);
  ushort4 h4;
  h4.x = rnd_bf16((v.x - mean) * rstd * wv.x + bv.x);
  h4.y = rnd_bf16((v.y - mean) * rstd * wv.y + bv.y);
  h4.z = rnd_bf16((v.z - mean) * rstd * wv.z + bv.z);
  h4.w = rnd_bf16((v.w - mean) * rstd * wv.w + bv.w);
  ((ushort4*)(oh + (size_t)row * D_MODEL))[t] = h4;
}

// ---- fused: Xout = Xin + sum(out_proj partials); then LayerNorm -> operand ---
// OUT 0: bf16 (next layer's hh). OUT 1: fp32 (final LN for pooling).
template<int OUT>
__global__ __launch_bounds__(256) void oreduce_ln_k(
    const float* __restrict__ part, const float* __restrict__ Xin,
    float* __restrict__ Xout,
    const float* __restrict__ w, const float* __restrict__ b,
    void* __restrict__ out) {
  const int row = blockIdx.x;
  const int t = threadIdx.x;
  float4 v = *(const float4*)(Xin + (size_t)row * D_MODEL + t * 4);
  #pragma unroll
  for (int k = 0; k < KSO; k++) {
    const float4 p = *(const float4*)(part + (size_t)k * BL * D_MODEL
                                      + (size_t)row * D_MODEL + t * 4);
    v.x += p.x; v.y += p.y; v.z += p.z; v.w += p.w;
  }
  *(float4*)(Xout + (size_t)row * D_MODEL + t * 4) = v;   // residual stream
  float s = v.x + v.y + v.z + v.w;
  float q = v.x*v.x + v.y*v.y + v.z*v.z + v.w*v.w;
  #pragma unroll
  for (int o = 32; o; o >>= 1) { s += __shfl_down(s, o); q += __shfl_down(q, o); }
  __shared__ float red[8];
  if ((t & 63) == 0) { red[t >> 6] = s; red[4 + (t >> 6)] = q; }
  __syncthreads();
  s = red[0] + red[1] + red[2] + red[3];
  q = red[4] + red[5] + red[6] + red[7];
  const float mean = s * (1.f / D_MODEL);
  const float var  = q * (1.f / D_MODEL) - mean * mean;
  const float rstd = rsqrtf(var + 1e-5f);
  const float4 wv = *(const float4*)(w + t * 4);
  const float4 bv = *(const float4*)(b + t * 4);
  float4 o4;
  o4.x = (v.x - mean) * rstd * wv.x + bv.x;
  o4.y = (v.y - mean) * rstd * wv.y + bv.y;
  o4.z = (v.z - mean) * rstd * wv.z + bv.z;
  o4.w = (v.w - mean) * rstd * wv.w + bv.w;
  if constexpr (OUT == 0) {
    ushort4 h4;
    h4.x = rnd_bf16(o4.x); h4.y = rnd_bf16(o4.y);
    h4.z = rnd_bf16(o4.z); h4.w = rnd_bf16(o4.w);
    ((ushort4*)((unsigned short*)out + (size_t)row * D_MODEL))[t] = h4;
  } else {
    *(float4*)((float*)out + (size_t)row * D_MODEL + t * 4) = o4;
  }
}

// ---- bf16 MFMA GEMM NT (optional split-K) -----------------------------------
// EPI 0: store bf16 to (unsigned short*)C; EPI 1: fp32 partials at C+kz*M*ldc.
template<int EPI, int KSEG>
__global__ __launch_bounds__(256) void mfma_gemm_nt(
    const unsigned short* __restrict__ Ah, const unsigned short* __restrict__ Bh,
    void* __restrict__ Cv, int M, int N, int K, int ldc) {
  __shared__ unsigned short As[128 * 64];
  __shared__ unsigned short Bs[128 * 64];
  const int tid = threadIdx.x;
  const int w = tid >> 6, l = tid & 63;
  const int wr = w >> 1, wc = w & 1;
  const int m0 = blockIdx.y * 128, n0 = blockIdx.x * 128;
  const int kz = (KSEG > 1) ? blockIdx.z : 0;
  const int kbeg = kz * (K / KSEG);
  const int kend = kbeg + K / KSEG;
  const int srow = l >> 3;             // staging row within 8-row block
  const int scol = (l & 7) * 8;        // staging col (elements)
  const int fr = l & 15;               // fragment row
  const int fk = (l >> 4) * 8;         // fragment k offset
  f32x4 acc[4][4] = {};

  #pragma unroll 1
  for (int k0 = kbeg; k0 < kend; k0 += 64) {
    __syncthreads();                  // previous compute done before overwrite
    #pragma unroll
    for (int it = 0; it < 4; ++it) {
      const int bi = it * 4 + w;      // 1 KB block id 0..15
      const int row = bi * 8 + srow;
      GLDS16(Ah + (size_t)(m0 + row) * K + k0 + scol, &As[bi * 512 + l * 8]);
      GLDS16(Bh + (size_t)(n0 + row) * K + k0 + scol, &Bs[bi * 512 + l * 8]);
    }
    __syncthreads();                  // staging visible (vmcnt drained)
    #pragma unroll
    for (int kk = 0; kk < 64; kk += 32) {
      bf16x8 a[4], b[4];
      #pragma unroll
      for (int f = 0; f < 4; ++f)
        b[f] = *(const bf16x8*)&Bs[(wc * 64 + f * 16 + fr) * 64 + kk + fk];
      #pragma unroll
      for (int f = 0; f < 4; ++f)
        a[f] = *(const bf16x8*)&As[(wr * 64 + f * 16 + fr) * 64 + kk + fk];
      #pragma unroll
      for (int i = 0; i < 4; ++i)
        #pragma unroll
        for (int j = 0; j < 4; ++j)
          acc[i][j] = __builtin_amdgcn_mfma_f32_16x16x32_bf16(
              a[i], b[j], acc[i][j], 0, 0, 0);
    }
  }
  const int orow = (l >> 4) * 4;
  const int ocol = l & 15;
  if constexpr (EPI == 0) {
    unsigned short* Cw = (unsigned short*)Cv;
    #pragma unroll
    for (int i = 0; i < 4; ++i)
      #pragma unroll
      for (int j = 0; j < 4; ++j)
        #pragma unroll
        for (int r = 0; r < 4; ++r) {
          const int m = m0 + wr * 64 + i * 16 + orow + r;
          const int n = n0 + wc * 64 + j * 16 + ocol;
          Cw[(size_t)m * ldc + n] = rnd_bf16(acc[i][j][r]);
        }
  } else {
    float* Cw = (float*)Cv + (size_t)kz * M * ldc;
    #pragma unroll
    for (int i = 0; i < 4; ++i)
      #pragma unroll
      for (int j = 0; j < 4; ++j)
        #pragma unroll
        for (int r = 0; r < 4; ++r) {
          const int m = m0 + wr * 64 + i * 16 + orow + r;
          const int n = n0 + wc * 64 + j * 16 + ocol;
          Cw[(size_t)m * ldc + n] = acc[i][j][r];
        }
  }
}

// ---------------- fp32 SGEMM NT (dt GEMM) -------------------------------------
// EPI: 0 none; 1 softplus(acc + bias[n])
template<int BM, int BN, int BK, int TM, int TN, int EPI>
__global__ __launch_bounds__(256) void sgemm_nt(
    const float* __restrict__ A, const float* __restrict__ B,
    float* __restrict__ C, int M, int N, int K, int lda, int ldb, int ldc,
    const float* __restrict__ bias) {
  constexpr int THREADS = 256;
  constexpr int NT = BN / TN;
  constexpr int K4 = BK / 4;
  constexpr int A_F4 = BM * BK / (THREADS * 4);
  constexpr int B_F4 = BN * BK / (THREADS * 4);
  static_assert((BM / TM) * (BN / TN) == THREADS, "thread shape");
  __shared__ float As[BK][BM + 4];
  __shared__ float Bs[BK][BN + 4];
  const int tid = threadIdx.x;
  const int m0 = blockIdx.y * BM;
  const int n0 = blockIdx.x * BN;
  const int tn = (tid % NT) * TN;
  const int tm = (tid / NT) * TM;
  float acc[TM][TN] = {};
  for (int k0 = 0; k0 < K; k0 += BK) {
    #pragma unroll
    for (int i = 0; i < A_F4; i++) {
      int li = tid + i * THREADS;
      int r = li / K4, c4 = li % K4;
      float4 v = *(const float4*)(A + (size_t)(m0 + r) * lda + k0 + c4 * 4);
      As[c4*4+0][r] = v.x; As[c4*4+1][r] = v.y; As[c4*4+2][r] = v.z; As[c4*4+3][r] = v.w;
    }
    #pragma unroll
    for (int i = 0; i < B_F4; i++) {
      int li = tid + i * THREADS;
      int r = li / K4, c4 = li % K4;
      float4 v = *(const float4*)(B + (size_t)(n0 + r) * ldb + k0 + c4 * 4);
      Bs[c4*4+0][r] = v.x; Bs[c4*4+1][r] = v.y; Bs[c4*4+2][r] = v.z; Bs[c4*4+3][r] = v.w;
    }
    __syncthreads();
    #pragma unroll
    for (int k = 0; k < BK; k++) {
      float a[TM], bf[TN];
      #pragma unroll
      for (int i = 0; i < TM; i++) a[i] = As[k][tm + i];
      #pragma unroll
      for (int j = 0; j < TN; j++) bf[j] = Bs[k][tn + j];
      #pragma unroll
      for (int i = 0; i < TM; i++)
        #pragma unroll
        for (int j = 0; j < TN; j++)
          acc[i][j] = fmaf(a[i], bf[j], acc[i][j]);
    }
    __syncthreads();
  }
  #pragma unroll
  for (int i = 0; i < TM; i++) {
    const int m = m0 + tm + i;
    #pragma unroll
    for (int j = 0; j < TN; j++) {
      const int n = n0 + tn + j;
      float v = acc[i][j];
      if constexpr (EPI == 1) {
        v += bias[n];
        v = (v > 20.f) ? v : log1pf(__expf(v));
      }
      C[(size_t)m * ldc + n] = v;
    }
  }
}

// ---- x_proj split-K (bf16 A): part[kz][m][n] = sum_seg xc[m,k]*xpw[n,k] -----
__global__ __launch_bounds__(256) void sgemm_splitk_k(
    const unsigned short* __restrict__ A, const float* __restrict__ B,
    float* __restrict__ part) {
  __shared__ float As[32][64 + 4];
  __shared__ float Bs[32][32 + 4];
  const int tid = threadIdx.x;
  const int n0 = blockIdx.x * 32;
  const int m0 = blockIdx.y * 64;
  const int kz = blockIdx.z;
  const int tn = (tid & 15) * 2;
  const int tm = (tid >> 4) * 4;
  float acc[4][2] = {};
  for (int kb = 0; kb < 256; kb += 32) {
    const int k0 = kz * 256 + kb;
    {
      // A: 64 rows x 32 k of bf16; 256 threads x 8 elems
      int r = tid >> 2, c8 = (tid & 3) * 8;
      us8 u = *(const us8*)(A + (size_t)(m0 + r) * D_INNER + k0 + c8);
      #pragma unroll
      for (int j = 0; j < 8; j++) As[c8 + j][r] = b2f((unsigned short)u[j]);
    }
    {
      int r = tid >> 3, c4 = tid & 7;  // 256 float4 slots for B (32x32)
      float4 v = *(const float4*)(B + (size_t)(n0 + r) * D_INNER + k0 + c4 * 4);
      Bs[c4*4+0][r] = v.x; Bs[c4*4+1][r] = v.y;
      Bs[c4*4+2][r] = v.z; Bs[c4*4+3][r] = v.w;
    }
    __syncthreads();
    #pragma unroll
    for (int k = 0; k < 32; k++) {
      float a[4], bf[2];
      #pragma unroll
      for (int i = 0; i < 4; i++) a[i] = As[k][tm + i];
      bf[0] = Bs[k][tn]; bf[1] = Bs[k][tn + 1];
      #pragma unroll
      for (int i = 0; i < 4; i++) {
        acc[i][0] = fmaf(a[i], bf[0], acc[i][0]);
        acc[i][1] = fmaf(a[i], bf[1], acc[i][1]);
      }
    }
    __syncthreads();
  }
  float* p = part + (size_t)kz * BL * 96;
  #pragma unroll
  for (int i = 0; i < 4; i++) {
    const int m = m0 + tm + i;
    p[(size_t)m * 96 + n0 + tn]     = acc[i][0];
    p[(size_t)m * 96 + n0 + tn + 1] = acc[i][1];
  }
}

// fixed-order deterministic reduce of the KS partials -> xdbl
__global__ __launch_bounds__(256) void xproj_reduce_k(
    const float* __restrict__ part, float* __restrict__ out) {
  const int i = blockIdx.x * 256 + threadIdx.x;   // over BL*96
  float s = 0.f;
  #pragma unroll
  for (int k = 0; k < KS; k++) s += part[(size_t)k * BL * 96 + i];
  out[i] = s;
}

// ------ causal depthwise conv + SiLU, bf16 in / bf16 out, 4 ch/thread --------
__global__ __launch_bounds__(256) void conv_silu_k(
    const unsigned short* __restrict__ xz,
    const float* __restrict__ cw, const float* __restrict__ cb,
    unsigned short* __restrict__ xc) {
  const int gid = blockIdx.x * 256 + threadIdx.x;   // BL * D_INNER/4
  const int c4 = (gid & (D_INNER / 4 - 1)) << 2;
  const int row = gid >> 9;                         // b*LL + l
  const int l = row & (LL - 1);
  const unsigned short* base = xz + (size_t)row * (2 * D_INNER) + c4;
  const float4 w0 = *(const float4*)(cw + (c4 + 0) * 4);
  const float4 w1 = *(const float4*)(cw + (c4 + 1) * 4);
  const float4 w2 = *(const float4*)(cw + (c4 + 2) * 4);
  const float4 w3 = *(const float4*)(cw + (c4 + 3) * 4);
  float4 acc = *(const float4*)(cb + c4);
  ushort4 uv = *(const ushort4*)base;
  acc.x = fmaf(w0.w, b2f(uv.x), acc.x); acc.y = fmaf(w1.w, b2f(uv.y), acc.y);
  acc.z = fmaf(w2.w, b2f(uv.z), acc.z); acc.w = fmaf(w3.w, b2f(uv.w), acc.w);
  if (l >= 1) {
    uv = *(const ushort4*)(base - 2 * D_INNER);
    acc.x = fmaf(w0.z, b2f(uv.x), acc.x); acc.y = fmaf(w1.z, b2f(uv.y), acc.y);
    acc.z = fmaf(w2.z, b2f(uv.z), acc.z); acc.w = fmaf(w3.z, b2f(uv.w), acc.w);
  }
  if (l >= 2) {
    uv = *(const ushort4*)(base - 4 * D_INNER);
    acc.x = fmaf(w0.y, b2f(uv.x), acc.x); acc.y = fmaf(w1.y, b2f(uv.y), acc.y);
    acc.z = fmaf(w2.y, b2f(uv.z), acc.z); acc.w = fmaf(w3.y, b2f(uv.w), acc.w);
  }
  if (l >= 3) {
    uv = *(const ushort4*)(base - 6 * D_INNER);
    acc.x = fmaf(w0.x, b2f(uv.x), acc.x); acc.y = fmaf(w1.x, b2f(uv.y), acc.y);
    acc.z = fmaf(w2.x, b2f(uv.z), acc.z); acc.w = fmaf(w3.x, b2f(uv.w), acc.w);
  }
  ushort4 o4;
  o4.x = rnd_bf16(acc.x / (1.f + __expf(-acc.x)));
  o4.y = rnd_bf16(acc.y / (1.f + __expf(-acc.y)));
  o4.z = rnd_bf16(acc.z / (1.f + __expf(-acc.z)));
  o4.w = rnd_bf16(acc.w / (1.f + __expf(-acc.w)));
  *(ushort4*)(xc + (size_t)row * D_INNER + c4) = o4;
}

// ------- chunked selective scan, pass 1 (bf16 xc) -----------------------------
__global__ __launch_bounds__(256) void scan_pass1_k(
    const float* __restrict__ dt, const unsigned short* __restrict__ xc,
    const float* __restrict__ xdbl, const float* __restrict__ A_log,
    float* __restrict__ hend, float* __restrict__ sumdt) {
  const int c = blockIdx.x * 256 + threadIdx.x;
  const int k = blockIdx.y;
  const int b = blockIdx.z;
  float Ac[D_STATE];
  #pragma unroll
  for (int n = 0; n < D_STATE; n++) Ac[n] = -__expf(A_log[c * D_STATE + n]);
  float h[D_STATE] = {};
  float sd = 0.f;
  const size_t r0 = (size_t)b * LL + (size_t)k * CLEN;
  const float* dtp = dt + r0 * D_INNER + c;
  const unsigned short* xcp = xc + r0 * D_INNER + c;
  const float* Bp  = xdbl + r0 * 96 + DT_RANK;

  float dtv = dtp[0];
  float xv  = b2f(xcp[0]);
  float4 B0 = *(const float4*)(Bp + 0);
  float4 B1 = *(const float4*)(Bp + 4);
  float4 B2 = *(const float4*)(Bp + 8);
  float4 B3 = *(const float4*)(Bp + 12);
  for (int l = 0; l < CLEN; l++) {
    const int lp = (l + 1 < CLEN) ? l + 1 : l;
    const float dtv2 = dtp[(size_t)lp * D_INNER];
    const float xv2  = b2f(xcp[(size_t)lp * D_INNER]);
    const float4 B0n = *(const float4*)(Bp + (size_t)lp * 96 + 0);
    const float4 B1n = *(const float4*)(Bp + (size_t)lp * 96 + 4);
    const float4 B2n = *(const float4*)(Bp + (size_t)lp * 96 + 8);
    const float4 B3n = *(const float4*)(Bp + (size_t)lp * 96 + 12);
    sd += dtv;
    const float dx = dtv * xv;
    const float Bv[D_STATE] = {B0.x,B0.y,B0.z,B0.w, B1.x,B1.y,B1.z,B1.w,
                               B2.x,B2.y,B2.z,B2.w, B3.x,B3.y,B3.z,B3.w};
    #pragma unroll
    for (int n = 0; n < D_STATE; n++)
      h[n] = fmaf(__expf(dtv * Ac[n]), h[n], dx * Bv[n]);
    dtv = dtv2; xv = xv2; B0 = B0n; B1 = B1n; B2 = B2n; B3 = B3n;
  }
  float* he = hend + (((size_t)(b * CH + k) * D_INNER + c) << 4);
  #pragma unroll
  for (int n = 0; n < D_STATE; n += 4)
    *(float4*)(he + n) = make_float4(h[n], h[n+1], h[n+2], h[n+3]);
  sumdt[(size_t)(b * CH + k) * D_INNER + c] = sd;
}

// ------- chunked scan fixup ---------------------------------------------------
__global__ __launch_bounds__(256) void scan_fix_k(
    float* __restrict__ hend, const float* __restrict__ sumdt,
    const float* __restrict__ A_log) {
  const int gid = blockIdx.x * 256 + threadIdx.x;
  const int n = gid & 15;
  const int c = (gid >> 4) & (D_INNER - 1);
  const int b = gid >> 15;
  const float Ac = -__expf(A_log[c * D_STATE + n]);
  float hrun = 0.f;
  for (int k = 0; k < CH; k++) {
    const size_t base = (size_t)(b * CH + k) * D_INNER + c;
    const float sd = sumdt[base];
    float* hp = hend + (base << 4) + n;
    const float tmp = *hp;
    *hp = hrun;
    hrun = fmaf(__expf(Ac * sd), hrun, tmp);
  }
}

// ------- chunked scan pass 3: replay, gate (bf16 z), emit y as bf16 ----------
__global__ __launch_bounds__(256) void scan_pass3_k(
    const float* __restrict__ dt, const unsigned short* __restrict__ xc,
    const float* __restrict__ xdbl, const unsigned short* __restrict__ xz,
    const float* __restrict__ h0, const float* __restrict__ A_log,
    const float* __restrict__ Dp, unsigned short* __restrict__ yh) {
  const int c = blockIdx.x * 256 + threadIdx.x;
  const int k = blockIdx.y;
  const int b = blockIdx.z;
  float Ac[D_STATE];
  #pragma unroll
  for (int n = 0; n < D_STATE; n++) Ac[n] = -__expf(A_log[c * D_STATE + n]);
  const float Dv = Dp[c];
  float h[D_STATE];
  const float* hp = h0 + (((size_t)(b * CH + k) * D_INNER + c) << 4);
  #pragma unroll
  for (int n = 0; n < D_STATE; n += 4) {
    const float4 v = *(const float4*)(hp + n);
    h[n] = v.x; h[n+1] = v.y; h[n+2] = v.z; h[n+3] = v.w;
  }
  const size_t r0 = (size_t)b * LL + (size_t)k * CLEN;
  const float* dtp = dt + r0 * D_INNER + c;
  const unsigned short* xcp = xc + r0 * D_INNER + c;
  const float* Bp  = xdbl + r0 * 96 + DT_RANK;
  const unsigned short* zp = xz + r0 * (size_t)(2 * D_INNER) + D_INNER + c;
  unsigned short* yhp = yh + r0 * D_INNER + c;

  float dtv = dtp[0];
  float xv  = b2f(xcp[0]);
  float zv  = b2f(zp[0]);
  float4 B0 = *(const float4*)(Bp + 0);
  float4 B1 = *(const float4*)(Bp + 4);
  float4 B2 = *(const float4*)(Bp + 8);
  float4 B3 = *(const float4*)(Bp + 12);
  float4 C0 = *(const float4*)(Bp + 16);
  float4 C1 = *(const float4*)(Bp + 20);
  float4 C2 = *(const float4*)(Bp + 24);
  float4 C3 = *(const float4*)(Bp + 28);
  for (int l = 0; l < CLEN; l++) {
    const int lp = (l + 1 < CLEN) ? l + 1 : l;
    const float dtv2 = dtp[(size_t)lp * D_INNER];
    const float xv2  = b2f(xcp[(size_t)lp * D_INNER]);
    const float zv2  = b2f(zp[(size_t)lp * 2 * D_INNER]);
    const float4 B0n = *(const float4*)(Bp + (size_t)lp * 96 + 0);
    const float4 B1n = *(const float4*)(Bp + (size_t)lp * 96 + 4);
    const float4 B2n = *(const float4*)(Bp + (size_t)lp * 96 + 8);
    const float4 B3n = *(const float4*)(Bp + (size_t)lp * 96 + 12);
    const float4 C0n = *(const float4*)(Bp + (size_t)lp * 96 + 16);
    const float4 C1n = *(const float4*)(Bp + (size_t)lp * 96 + 20);
    const float4 C2n = *(const float4*)(Bp + (size_t)lp * 96 + 24);
    const float4 C3n = *(const float4*)(Bp + (size_t)lp * 96 + 28);
    const float dx = dtv * xv;
    const float Bv[D_STATE] = {B0.x,B0.y,B0.z,B0.w, B1.x,B1.y,B1.z,B1.w,
                               B2.x,B2.y,B2.z,B2.w, B3.x,B3.y,B3.z,B3.w};
    const float Cv[D_STATE] = {C0.x,C0.y,C0.z,C0.w, C1.x,C1.y,C1.z,C1.w,
                               C2.x,C2.y,C2.z,C2.w, C3.x,C3.y,C3.z,C3.w};
    float y = 0.f;
    #pragma unroll
    for (int n = 0; n < D_STATE; n++) {
      h[n] = fmaf(__expf(dtv * Ac[n]), h[n], dx * Bv[n]);
      y = fmaf(h[n], Cv[n], y);
    }
    y = fmaf(xv, Dv, y);
    y *= zv / (1.f + __expf(-zv));
    yhp[(size_t)l * D_INNER] = rnd_bf16(y);
    dtv = dtv2; xv = xv2; zv = zv2;
    B0 = B0n; B1 = B1n; B2 = B2n; B3 = B3n;
    C0 = C0n; C1 = C1n; C2 = C2n; C3 = C3n;
  }
}

// ---------------- mean pool over L, two-stage ---------------------------------
__global__ __launch_bounds__(256) void pool1_k(const float* __restrict__ h,
    float* __restrict__ pp) {
  const int d = blockIdx.x * 256 + threadIdx.x;  // 0..1023
  const int b = blockIdx.y;
  const int seg = blockIdx.z;                    // 0..15
  float s = 0.f;
  const size_t base = (size_t)b * LL + (size_t)seg * 64;
  for (int l = 0; l < 64; l++) s += h[(base + l) * D_MODEL + d];
  pp[((size_t)(b * 16 + seg)) * D_MODEL + d] = s;
}
__global__ __launch_bounds__(256) void pool2_k(const float* __restrict__ pp,
    float* __restrict__ pooled) {
  const int d = blockIdx.x * 256 + threadIdx.x;
  const int b = blockIdx.y;
  float s = 0.f;
  #pragma unroll
  for (int k = 0; k < 16; k++) s += pp[((size_t)(b * 16 + k)) * D_MODEL + d];
  pooled[b * D_MODEL + d] = s * (1.f / LL);
}

// ---------------- classifier head --------------------------------------------
__global__ __launch_bounds__(64) void head_k(const float* __restrict__ pooled,
    const float* __restrict__ hw, const float* __restrict__ hb,
    float* __restrict__ out) {
  const int b = blockIdx.x / N_CLASSES;
  const int j = blockIdx.x % N_CLASSES;
  float s = 0.f;
  for (int k = threadIdx.x; k < D_MODEL; k += 64)
    s = fmaf(pooled[b * D_MODEL + k], hw[j * D_MODEL + k], s);
  #pragma unroll
  for (int o = 32; o; o >>= 1) s += __shfl_down(s, o);
  if (threadIdx.x == 0) out[b * N_CLASSES + j] = s + hb[j];
}

extern "C" void kernel_launch(void* const* d_in, const int* in_sizes, int n_in,
                              void* d_out, int out_size, void* d_ws, size_t ws_size,
                              hipStream_t stream) {
  const float* x0    = (const float*)d_in[0];
  const float* ln1w  = (const float*)d_in[1];
  const float* ln1b  = (const float*)d_in[2];
  const float* inw   = (const float*)d_in[3];
  const float* convw = (const float*)d_in[4];
  const float* convb = (const float*)d_in[5];
  const float* xpw   = (const float*)d_in[6];
  const float* dtpw  = (const float*)d_in[7];
  const float* dtpb  = (const float*)d_in[8];
  const float* Alog  = (const float*)d_in[9];
  const float* Dp    = (const float*)d_in[10];
  const float* outw  = (const float*)d_in[11];
  const float* normw = (const float*)d_in[12];
  const float* normb = (const float*)d_in[13];
  const float* headw = (const float*)d_in[14];
  const float* headb = (const float*)d_in[15];

  float* ws = (float*)d_ws;
  size_t f = 0;
  float* X      = ws + f; f += (size_t)BL * D_MODEL;        // residual stream
  float* xzf    = ws + f; f += (size_t)BL * D_INNER;        // bf16 xz (4096x4096)
  float* xdbl   = ws + f; f += (size_t)BL * 96;
  float* dty    = ws + f; f += (size_t)BL * D_INNER;        // fp32 dt / final-LN out
  float* pooled = ws + f; f += 4096;
  float* pooldp = ws + f; f += (size_t)16 * BB * D_MODEL;   // pool partials
  float* xpart  = ws + f; f += (size_t)KS * BL * 96;
  float* hend   = ws + f; f += (size_t)BB * CH * D_INNER * D_STATE;
  float* opart  = ws + f; f += (size_t)KSO * BL * D_MODEL;
  unsigned short* hh  = (unsigned short*)(ws + f); f += (size_t)BL * D_MODEL / 2;
  unsigned short* yh  = (unsigned short*)(ws + f); f += (size_t)BL * D_INNER / 2;
  unsigned short* xcb = (unsigned short*)(ws + f); f += (size_t)BL * D_INNER / 2;
  unsigned short* wih = (unsigned short*)(ws + f);
  f += (size_t)N_LAYERS * 2 * D_INNER * D_MODEL / 2;
  unsigned short* woh = (unsigned short*)(ws + f);
  f += (size_t)N_LAYERS * D_MODEL * D_INNER / 2;
  unsigned short* xz = (unsigned short*)xzf;   // BL * 2*D_INNER bf16
  float* sumdt = xpart;   // overlay: xpart dead after xproj_reduce

  // round all weights once (both layers)
  round_k<<<(N_LAYERS * 2 * D_INNER * D_MODEL) / 1024, 256, 0, stream>>>(inw, wih);
  round_k<<<(N_LAYERS * D_MODEL * D_INNER) / 1024, 256, 0, stream>>>(outw, woh);
  // layer-0 LayerNorm -> bf16 operand (reads x0 directly)
  layernorm_bf16_k<<<BL, 256, 0, stream>>>(x0, ln1w, ln1b, hh);

  for (int layer = 0; layer < N_LAYERS; ++layer) {
    const unsigned short* wi = wih + (size_t)layer * 2 * D_INNER * D_MODEL;
    const unsigned short* wo = woh + (size_t)layer * D_MODEL * D_INNER;
    // xz = h @ in_w^T : M=4096 N=4096 K=1024 (bf16 MFMA, bf16 out)
    mfma_gemm_nt<0, 1><<<dim3(4096 / 128, 4096 / 128), 256, 0, stream>>>(
        hh, wi, xz, BL, 2 * D_INNER, D_MODEL, 2 * D_INNER);
    conv_silu_k<<<(BL * D_INNER / 4) / 256, 256, 0, stream>>>(
        xz, convw + layer * D_INNER * D_CONV, convb + layer * D_INNER, xcb);
    // x_dbl = xc @ xp_w^T : M=4096 N=96 K=2048 (bf16 A, fp32 split-K + reduce)
    sgemm_splitk_k<<<dim3(96 / 32, 4096 / 64, KS), 256, 0, stream>>>(
        xcb, xpw + (size_t)layer * 96 * D_INNER, xpart);
    xproj_reduce_k<<<(BL * 96) / 256, 256, 0, stream>>>(xpart, xdbl);
    // dt = softplus(dt_r @ dtp_w^T + dtp_b) : M=4096 N=2048 K=64 (fp32)
    sgemm_nt<64,64,64,4,4,1><<<dim3(2048 / 64, 4096 / 64), 256, 0, stream>>>(
        xdbl, dtpw + (size_t)layer * D_INNER * DT_RANK, dty,
        BL, D_INNER, DT_RANK, 96, DT_RANK, D_INNER,
        dtpb + layer * D_INNER);
    // chunked scan (CH=32)
    scan_pass1_k<<<dim3(D_INNER / 256, CH, BB), 256, 0, stream>>>(
        dty, xcb, xdbl, Alog + (size_t)layer * D_INNER * D_STATE, hend, sumdt);
    scan_fix_k<<<(BB * D_INNER * D_STATE) / 256, 256, 0, stream>>>(
        hend, sumdt, Alog + (size_t)layer * D_INNER * D_STATE);
    scan_pass3_k<<<dim3(D_INNER / 256, CH, BB), 256, 0, stream>>>(
        dty, xcb, xdbl, xz, hend, Alog + (size_t)layer * D_INNER * D_STATE,
        Dp + layer * D_INNER, yh);
    // y @ out_w^T : M=4096 N=1024 K=2048, split-K=2 partials
    mfma_gemm_nt<1, KSO><<<dim3(1024 / 128, 4096 / 128, KSO), 256, 0, stream>>>(
        yh, wo, opart, BL, D_MODEL, D_INNER, D_MODEL);
    // fused: X = (layer0 ? x0 : X) + partials; LN -> next operand / final LN
    const float* Xin = (layer == 0) ? x0 : X;
    if (layer + 1 < N_LAYERS) {
      oreduce_ln_k<0><<<BL, 256, 0, stream>>>(
          opart, Xin, X, ln1w + (layer + 1) * D_MODEL,
          ln1b + (layer + 1) * D_MODEL, hh);
    } else {
      oreduce_ln_k<1><<<BL, 256, 0, stream>>>(opart, Xin, X, normw, normb, dty);
    }
  }

  pool1_k<<<dim3(D_MODEL / 256, BB, 16), 256, 0, stream>>>(dty, pooldp);
  pool2_k<<<dim3(D_MODEL / 256, BB), 256, 0, stream>>>(pooldp, pooled);
  head_k<<<BB * N_CLASSES, 64, 0, stream>>>(pooled, headw, headb, (float*)d_out);
}

// Round 12
// 603.200 us; speedup vs baseline: 5.2194x; 1.0103x over previous
//
#include <hip/hip_runtime.h>
#include <hip/hip_bf16.h>

#define N_LAYERS 2
#define D_MODEL 1024
#define D_INNER 2048
#define D_STATE 16
#define D_CONV 4
#define DT_RANK 64
#define N_CLASSES 10
#define BB 4
#define LL 1024
#define BL (BB*LL)   // 4096 rows
#define CH 32        // scan chunks per sequence
#define CLEN (LL/CH) // 32 steps per chunk
#define KS 8         // split-K segments for x_proj
#define KSO 2        // split-K segments for out_proj

typedef __attribute__((ext_vector_type(8))) short bf16x8;
typedef __attribute__((ext_vector_type(8))) unsigned short us8;
typedef __attribute__((ext_vector_type(4))) float f32x4;

typedef const void __attribute__((address_space(1)))* gas_ptr;
typedef void __attribute__((address_space(3)))* las_ptr;
#define GLDS16(g, p) __builtin_amdgcn_global_load_lds((gas_ptr)(g), (las_ptr)(p), 16, 0, 0)

__device__ inline unsigned short rnd_bf16(float x) {
  unsigned u = __float_as_uint(x);
  return (unsigned short)((u + 0x7FFFu + ((u >> 16) & 1u)) >> 16);
}
__device__ inline float b2f(unsigned short u) {
  return __uint_as_float(((unsigned)u) << 16);
}

// round weights to bf16 (both layers in one launch)
__global__ __launch_bounds__(256) void round_k(const float* __restrict__ in,
    unsigned short* __restrict__ hi) {
  const int i = blockIdx.x * 256 + threadIdx.x;
  const float4 v = ((const float4*)in)[i];
  ushort4 h4;
  h4.x = rnd_bf16(v.x); h4.y = rnd_bf16(v.y);
  h4.z = rnd_bf16(v.z); h4.w = rnd_bf16(v.w);
  ((ushort4*)hi)[i] = h4;
}

// ---------------- LayerNorm -> bf16 out ---------------------------------------
__global__ __launch_bounds__(256) void layernorm_bf16_k(const float* __restrict__ x,
    const float* __restrict__ w, const float* __restrict__ b,
    unsigned short* __restrict__ oh) {
  const int row = blockIdx.x;
  const int t = threadIdx.x;
  const float4 v = *(const float4*)(x + (size_t)row * D_MODEL + t * 4);
  float s = v.x + v.y + v.z + v.w;
  float q = v.x*v.x + v.y*v.y + v.z*v.z + v.w*v.w;
  #pragma unroll
  for (int o = 32; o; o >>= 1) { s += __shfl_down(s, o); q += __shfl_down(q, o); }
  __shared__ float red[8];
  if ((t & 63) == 0) { red[t >> 6] = s; red[4 + (t >> 6)] = q; }
  __syncthreads();
  s = red[0] + red[1] + red[2] + red[3];
  q = red[4] + red[5] + red[6] + red[7];
  const float mean = s * (1.f / D_MODEL);
  const float var  = q * (1.f / D_MODEL) - mean * mean;
  const float rstd = rsqrtf(var + 1e-5f);
  const float4 wv = *(const float4*)(w + t * 4);
  const float4 bv = *(const float4*)(b + t * 4);
  ushort4 h4;
  h4.x = rnd_bf16((v.x - mean) * rstd * wv.x + bv.x);
  h4.y = rnd_bf16((v.y - mean) * rstd * wv.y + bv.y);
  h4.z = rnd_bf16((v.z - mean) * rstd * wv.z + bv.z);
  h4.w = rnd_bf16((v.w - mean) * rstd * wv.w + bv.w);
  ((ushort4*)(oh + (size_t)row * D_MODEL))[t] = h4;
}

// ---- fused: Xout = Xin + sum(out_proj partials); then LayerNorm -> operand ---
// OUT 0: bf16 (next layer's hh). OUT 1: fp32 (final LN for pooling).
template<int OUT>
__global__ __launch_bounds__(256) void oreduce_ln_k(
    const float* __restrict__ part, const float* __restrict__ Xin,
    float* __restrict__ Xout,
    const float* __restrict__ w, const float* __restrict__ b,
    void* __restrict__ out) {
  const int row = blockIdx.x;
  const int t = threadIdx.x;
  float4 v = *(const float4*)(Xin + (size_t)row * D_MODEL + t * 4);
  #pragma unroll
  for (int k = 0; k < KSO; k++) {
    const float4 p = *(const float4*)(part + (size_t)k * BL * D_MODEL
                                      + (size_t)row * D_MODEL + t * 4);
    v.x += p.x; v.y += p.y; v.z += p.z; v.w += p.w;
  }
  *(float4*)(Xout + (size_t)row * D_MODEL + t * 4) = v;   // residual stream
  float s = v.x + v.y + v.z + v.w;
  float q = v.x*v.x + v.y*v.y + v.z*v.z + v.w*v.w;
  #pragma unroll
  for (int o = 32; o; o >>= 1) { s += __shfl_down(s, o); q += __shfl_down(q, o); }
  __shared__ float red[8];
  if ((t & 63) == 0) { red[t >> 6] = s; red[4 + (t >> 6)] = q; }
  __syncthreads();
  s = red[0] + red[1] + red[2] + red[3];
  q = red[4] + red[5] + red[6] + red[7];
  const float mean = s * (1.f / D_MODEL);
  const float var  = q * (1.f / D_MODEL) - mean * mean;
  const float rstd = rsqrtf(var + 1e-5f);
  const float4 wv = *(const float4*)(w + t * 4);
  const float4 bv = *(const float4*)(b + t * 4);
  float4 o4;
  o4.x = (v.x - mean) * rstd * wv.x + bv.x;
  o4.y = (v.y - mean) * rstd * wv.y + bv.y;
  o4.z = (v.z - mean) * rstd * wv.z + bv.z;
  o4.w = (v.w - mean) * rstd * wv.w + bv.w;
  if constexpr (OUT == 0) {
    ushort4 h4;
    h4.x = rnd_bf16(o4.x); h4.y = rnd_bf16(o4.y);
    h4.z = rnd_bf16(o4.z); h4.w = rnd_bf16(o4.w);
    ((ushort4*)((unsigned short*)out + (size_t)row * D_MODEL))[t] = h4;
  } else {
    *(float4*)((float*)out + (size_t)row * D_MODEL + t * 4) = o4;
  }
}

// ---- bf16 MFMA GEMM NT (optional split-K), XCD+supertile block swizzle ------
// EPI 0: store bf16 to (unsigned short*)C; EPI 1: fp32 partials at C+kz*M*ldc.
// Requires gridDim.x%8==0 and gridDim.y%8==0 (both call sites satisfy).
template<int EPI, int KSEG>
__global__ __launch_bounds__(256) void mfma_gemm_nt(
    const unsigned short* __restrict__ Ah, const unsigned short* __restrict__ Bh,
    void* __restrict__ Cv, int M, int N, int K, int ldc) {
  __shared__ unsigned short As[128 * 64];
  __shared__ unsigned short Bs[128 * 64];
  const int tid = threadIdx.x;
  const int w = tid >> 6, l = tid & 63;
  const int wr = w >> 1, wc = w & 1;
  // L2-locality remap: XCD chunking then 8x8 supertiles (bijective, nwg%8==0)
  const int nbx = gridDim.x;
  const int nwg = nbx * gridDim.y;
  int bid = blockIdx.y * nbx + blockIdx.x;
  bid = (bid & 7) * (nwg >> 3) + (bid >> 3);
  const int st = bid >> 6, wi = bid & 63;
  const int stpr = nbx >> 3;
  const int n0 = ((st % stpr) * 8 + (wi & 7)) * 128;
  const int m0 = ((st / stpr) * 8 + (wi >> 3)) * 128;
  const int kz = (KSEG > 1) ? blockIdx.z : 0;
  const int kbeg = kz * (K / KSEG);
  const int kend = kbeg + K / KSEG;
  const int srow = l >> 3;             // staging row within 8-row block
  const int scol = (l & 7) * 8;        // staging col (elements)
  const int fr = l & 15;               // fragment row
  const int fk = (l >> 4) * 8;         // fragment k offset
  f32x4 acc[4][4] = {};

  #pragma unroll 1
  for (int k0 = kbeg; k0 < kend; k0 += 64) {
    __syncthreads();                  // previous compute done before overwrite
    #pragma unroll
    for (int it = 0; it < 4; ++it) {
      const int bi = it * 4 + w;      // 1 KB block id 0..15
      const int row = bi * 8 + srow;
      GLDS16(Ah + (size_t)(m0 + row) * K + k0 + scol, &As[bi * 512 + l * 8]);
      GLDS16(Bh + (size_t)(n0 + row) * K + k0 + scol, &Bs[bi * 512 + l * 8]);
    }
    __syncthreads();                  // staging visible (vmcnt drained)
    #pragma unroll
    for (int kk = 0; kk < 64; kk += 32) {
      bf16x8 a[4], b[4];
      #pragma unroll
      for (int f = 0; f < 4; ++f)
        b[f] = *(const bf16x8*)&Bs[(wc * 64 + f * 16 + fr) * 64 + kk + fk];
      #pragma unroll
      for (int f = 0; f < 4; ++f)
        a[f] = *(const bf16x8*)&As[(wr * 64 + f * 16 + fr) * 64 + kk + fk];
      #pragma unroll
      for (int i = 0; i < 4; ++i)
        #pragma unroll
        for (int j = 0; j < 4; ++j)
          acc[i][j] = __builtin_amdgcn_mfma_f32_16x16x32_bf16(
              a[i], b[j], acc[i][j], 0, 0, 0);
    }
  }
  const int orow = (l >> 4) * 4;
  const int ocol = l & 15;
  if constexpr (EPI == 0) {
    unsigned short* Cw = (unsigned short*)Cv;
    #pragma unroll
    for (int i = 0; i < 4; ++i)
      #pragma unroll
      for (int j = 0; j < 4; ++j)
        #pragma unroll
        for (int r = 0; r < 4; ++r) {
          const int m = m0 + wr * 64 + i * 16 + orow + r;
          const int n = n0 + wc * 64 + j * 16 + ocol;
          Cw[(size_t)m * ldc + n] = rnd_bf16(acc[i][j][r]);
        }
  } else {
    float* Cw = (float*)Cv + (size_t)kz * M * ldc;
    #pragma unroll
    for (int i = 0; i < 4; ++i)
      #pragma unroll
      for (int j = 0; j < 4; ++j)
        #pragma unroll
        for (int r = 0; r < 4; ++r) {
          const int m = m0 + wr * 64 + i * 16 + orow + r;
          const int n = n0 + wc * 64 + j * 16 + ocol;
          Cw[(size_t)m * ldc + n] = acc[i][j][r];
        }
  }
}

// ---------------- fp32 SGEMM NT (dt GEMM) -------------------------------------
// EPI 1: softplus(acc + bias[n]) stored as bf16 to (unsigned short*)C.
template<int BM, int BN, int BK, int TM, int TN, int EPI>
__global__ __launch_bounds__(256) void sgemm_nt(
    const float* __restrict__ A, const float* __restrict__ B,
    void* __restrict__ Cv, int M, int N, int K, int lda, int ldb, int ldc,
    const float* __restrict__ bias) {
  constexpr int THREADS = 256;
  constexpr int NT = BN / TN;
  constexpr int K4 = BK / 4;
  constexpr int A_F4 = BM * BK / (THREADS * 4);
  constexpr int B_F4 = BN * BK / (THREADS * 4);
  static_assert((BM / TM) * (BN / TN) == THREADS, "thread shape");
  __shared__ float As[BK][BM + 4];
  __shared__ float Bs[BK][BN + 4];
  const int tid = threadIdx.x;
  const int m0 = blockIdx.y * BM;
  const int n0 = blockIdx.x * BN;
  const int tn = (tid % NT) * TN;
  const int tm = (tid / NT) * TM;
  float acc[TM][TN] = {};
  for (int k0 = 0; k0 < K; k0 += BK) {
    #pragma unroll
    for (int i = 0; i < A_F4; i++) {
      int li = tid + i * THREADS;
      int r = li / K4, c4 = li % K4;
      float4 v = *(const float4*)(A + (size_t)(m0 + r) * lda + k0 + c4 * 4);
      As[c4*4+0][r] = v.x; As[c4*4+1][r] = v.y; As[c4*4+2][r] = v.z; As[c4*4+3][r] = v.w;
    }
    #pragma unroll
    for (int i = 0; i < B_F4; i++) {
      int li = tid + i * THREADS;
      int r = li / K4, c4 = li % K4;
      float4 v = *(const float4*)(B + (size_t)(n0 + r) * ldb + k0 + c4 * 4);
      Bs[c4*4+0][r] = v.x; Bs[c4*4+1][r] = v.y; Bs[c4*4+2][r] = v.z; Bs[c4*4+3][r] = v.w;
    }
    __syncthreads();
    #pragma unroll
    for (int k = 0; k < BK; k++) {
      float a[TM], bf[TN];
      #pragma unroll
      for (int i = 0; i < TM; i++) a[i] = As[k][tm + i];
      #pragma unroll
      for (int j = 0; j < TN; j++) bf[j] = Bs[k][tn + j];
      #pragma unroll
      for (int i = 0; i < TM; i++)
        #pragma unroll
        for (int j = 0; j < TN; j++)
          acc[i][j] = fmaf(a[i], bf[j], acc[i][j]);
    }
    __syncthreads();
  }
  #pragma unroll
  for (int i = 0; i < TM; i++) {
    const int m = m0 + tm + i;
    #pragma unroll
    for (int j = 0; j < TN; j++) {
      const int n = n0 + tn + j;
      float v = acc[i][j];
      if constexpr (EPI == 1) {
        v += bias[n];
        v = (v > 20.f) ? v : log1pf(__expf(v));
        ((unsigned short*)Cv)[(size_t)m * ldc + n] = rnd_bf16(v);
      } else {
        ((float*)Cv)[(size_t)m * ldc + n] = v;
      }
    }
  }
}

// ---- x_proj split-K (bf16 A): part[kz][m][n] = sum_seg xc[m,k]*xpw[n,k] -----
__global__ __launch_bounds__(256) void sgemm_splitk_k(
    const unsigned short* __restrict__ A, const float* __restrict__ B,
    float* __restrict__ part) {
  __shared__ float As[32][64 + 4];
  __shared__ float Bs[32][32 + 4];
  const int tid = threadIdx.x;
  const int n0 = blockIdx.x * 32;
  const int m0 = blockIdx.y * 64;
  const int kz = blockIdx.z;
  const int tn = (tid & 15) * 2;
  const int tm = (tid >> 4) * 4;
  float acc[4][2] = {};
  for (int kb = 0; kb < 256; kb += 32) {
    const int k0 = kz * 256 + kb;
    {
      // A: 64 rows x 32 k of bf16; 256 threads x 8 elems
      int r = tid >> 2, c8 = (tid & 3) * 8;
      us8 u = *(const us8*)(A + (size_t)(m0 + r) * D_INNER + k0 + c8);
      #pragma unroll
      for (int j = 0; j < 8; j++) As[c8 + j][r] = b2f((unsigned short)u[j]);
    }
    {
      int r = tid >> 3, c4 = tid & 7;  // 256 float4 slots for B (32x32)
      float4 v = *(const float4*)(B + (size_t)(n0 + r) * D_INNER + k0 + c4 * 4);
      Bs[c4*4+0][r] = v.x; Bs[c4*4+1][r] = v.y;
      Bs[c4*4+2][r] = v.z; Bs[c4*4+3][r] = v.w;
    }
    __syncthreads();
    #pragma unroll
    for (int k = 0; k < 32; k++) {
      float a[4], bf[2];
      #pragma unroll
      for (int i = 0; i < 4; i++) a[i] = As[k][tm + i];
      bf[0] = Bs[k][tn]; bf[1] = Bs[k][tn + 1];
      #pragma unroll
      for (int i = 0; i < 4; i++) {
        acc[i][0] = fmaf(a[i], bf[0], acc[i][0]);
        acc[i][1] = fmaf(a[i], bf[1], acc[i][1]);
      }
    }
    __syncthreads();
  }
  float* p = part + (size_t)kz * BL * 96;
  #pragma unroll
  for (int i = 0; i < 4; i++) {
    const int m = m0 + tm + i;
    p[(size_t)m * 96 + n0 + tn]     = acc[i][0];
    p[(size_t)m * 96 + n0 + tn + 1] = acc[i][1];
  }
}

// fixed-order deterministic reduce of the KS partials -> xdbl
__global__ __launch_bounds__(256) void xproj_reduce_k(
    const float* __restrict__ part, float* __restrict__ out) {
  const int i = blockIdx.x * 256 + threadIdx.x;   // over BL*96
  float s = 0.f;
  #pragma unroll
  for (int k = 0; k < KS; k++) s += part[(size_t)k * BL * 96 + i];
  out[i] = s;
}

// ------ causal depthwise conv + SiLU, bf16 in / bf16 out, 4 ch/thread --------
__global__ __launch_bounds__(256) void conv_silu_k(
    const unsigned short* __restrict__ xz,
    const float* __restrict__ cw, const float* __restrict__ cb,
    unsigned short* __restrict__ xc) {
  const int gid = blockIdx.x * 256 + threadIdx.x;   // BL * D_INNER/4
  const int c4 = (gid & (D_INNER / 4 - 1)) << 2;
  const int row = gid >> 9;                         // b*LL + l
  const int l = row & (LL - 1);
  const unsigned short* base = xz + (size_t)row * (2 * D_INNER) + c4;
  const float4 w0 = *(const float4*)(cw + (c4 + 0) * 4);
  const float4 w1 = *(const float4*)(cw + (c4 + 1) * 4);
  const float4 w2 = *(const float4*)(cw + (c4 + 2) * 4);
  const float4 w3 = *(const float4*)(cw + (c4 + 3) * 4);
  float4 acc = *(const float4*)(cb + c4);
  ushort4 uv = *(const ushort4*)base;
  acc.x = fmaf(w0.w, b2f(uv.x), acc.x); acc.y = fmaf(w1.w, b2f(uv.y), acc.y);
  acc.z = fmaf(w2.w, b2f(uv.z), acc.z); acc.w = fmaf(w3.w, b2f(uv.w), acc.w);
  if (l >= 1) {
    uv = *(const ushort4*)(base - 2 * D_INNER);
    acc.x = fmaf(w0.z, b2f(uv.x), acc.x); acc.y = fmaf(w1.z, b2f(uv.y), acc.y);
    acc.z = fmaf(w2.z, b2f(uv.z), acc.z); acc.w = fmaf(w3.z, b2f(uv.w), acc.w);
  }
  if (l >= 2) {
    uv = *(const ushort4*)(base - 4 * D_INNER);
    acc.x = fmaf(w0.y, b2f(uv.x), acc.x); acc.y = fmaf(w1.y, b2f(uv.y), acc.y);
    acc.z = fmaf(w2.y, b2f(uv.z), acc.z); acc.w = fmaf(w3.y, b2f(uv.w), acc.w);
  }
  if (l >= 3) {
    uv = *(const ushort4*)(base - 6 * D_INNER);
    acc.x = fmaf(w0.x, b2f(uv.x), acc.x); acc.y = fmaf(w1.x, b2f(uv.y), acc.y);
    acc.z = fmaf(w2.x, b2f(uv.z), acc.z); acc.w = fmaf(w3.x, b2f(uv.w), acc.w);
  }
  ushort4 o4;
  o4.x = rnd_bf16(acc.x / (1.f + __expf(-acc.x)));
  o4.y = rnd_bf16(acc.y / (1.f + __expf(-acc.y)));
  o4.z = rnd_bf16(acc.z / (1.f + __expf(-acc.z)));
  o4.w = rnd_bf16(acc.w / (1.f + __expf(-acc.w)));
  *(ushort4*)(xc + (size_t)row * D_INNER + c4) = o4;
}

// ------- chunked selective scan, pass 1 (bf16 dt, bf16 xc) --------------------
__global__ __launch_bounds__(256) void scan_pass1_k(
    const unsigned short* __restrict__ dt, const unsigned short* __restrict__ xc,
    const float* __restrict__ xdbl, const float* __restrict__ A_log,
    float* __restrict__ hend, float* __restrict__ sumdt) {
  const int c = blockIdx.x * 256 + threadIdx.x;
  const int k = blockIdx.y;
  const int b = blockIdx.z;
  float Ac[D_STATE];
  #pragma unroll
  for (int n = 0; n < D_STATE; n++) Ac[n] = -__expf(A_log[c * D_STATE + n]);
  float h[D_STATE] = {};
  float sd = 0.f;
  const size_t r0 = (size_t)b * LL + (size_t)k * CLEN;
  const unsigned short* dtp = dt + r0 * D_INNER + c;
  const unsigned short* xcp = xc + r0 * D_INNER + c;
  const float* Bp  = xdbl + r0 * 96 + DT_RANK;

  float dtv = b2f(dtp[0]);
  float xv  = b2f(xcp[0]);
  float4 B0 = *(const float4*)(Bp + 0);
  float4 B1 = *(const float4*)(Bp + 4);
  float4 B2 = *(const float4*)(Bp + 8);
  float4 B3 = *(const float4*)(Bp + 12);
  for (int l = 0; l < CLEN; l++) {
    const int lp = (l + 1 < CLEN) ? l + 1 : l;
    const float dtv2 = b2f(dtp[(size_t)lp * D_INNER]);
    const float xv2  = b2f(xcp[(size_t)lp * D_INNER]);
    const float4 B0n = *(const float4*)(Bp + (size_t)lp * 96 + 0);
    const float4 B1n = *(const float4*)(Bp + (size_t)lp * 96 + 4);
    const float4 B2n = *(const float4*)(Bp + (size_t)lp * 96 + 8);
    const float4 B3n = *(const float4*)(Bp + (size_t)lp * 96 + 12);
    sd += dtv;
    const float dx = dtv * xv;
    const float Bv[D_STATE] = {B0.x,B0.y,B0.z,B0.w, B1.x,B1.y,B1.z,B1.w,
                               B2.x,B2.y,B2.z,B2.w, B3.x,B3.y,B3.z,B3.w};
    #pragma unroll
    for (int n = 0; n < D_STATE; n++)
      h[n] = fmaf(__expf(dtv * Ac[n]), h[n], dx * Bv[n]);
    dtv = dtv2; xv = xv2; B0 = B0n; B1 = B1n; B2 = B2n; B3 = B3n;
  }
  float* he = hend + (((size_t)(b * CH + k) * D_INNER + c) << 4);
  #pragma unroll
  for (int n = 0; n < D_STATE; n += 4)
    *(float4*)(he + n) = make_float4(h[n], h[n+1], h[n+2], h[n+3]);
  sumdt[(size_t)(b * CH + k) * D_INNER + c] = sd;
}

// ------- chunked scan fixup ---------------------------------------------------
__global__ __launch_bounds__(256) void scan_fix_k(
    float* __restrict__ hend, const float* __restrict__ sumdt,
    const float* __restrict__ A_log) {
  const int gid = blockIdx.x * 256 + threadIdx.x;
  const int n = gid & 15;
  const int c = (gid >> 4) & (D_INNER - 1);
  const int b = gid >> 15;
  const float Ac = -__expf(A_log[c * D_STATE + n]);
  float hrun = 0.f;
  for (int k = 0; k < CH; k++) {
    const size_t base = (size_t)(b * CH + k) * D_INNER + c;
    const float sd = sumdt[base];
    float* hp = hend + (base << 4) + n;
    const float tmp = *hp;
    *hp = hrun;
    hrun = fmaf(__expf(Ac * sd), hrun, tmp);
  }
}

// ------- chunked scan pass 3: replay, gate (bf16 z), emit y as bf16 ----------
__global__ __launch_bounds__(256) void scan_pass3_k(
    const unsigned short* __restrict__ dt, const unsigned short* __restrict__ xc,
    const float* __restrict__ xdbl, const unsigned short* __restrict__ xz,
    const float* __restrict__ h0, const float* __restrict__ A_log,
    const float* __restrict__ Dp, unsigned short* __restrict__ yh) {
  const int c = blockIdx.x * 256 + threadIdx.x;
  const int k = blockIdx.y;
  const int b = blockIdx.z;
  float Ac[D_STATE];
  #pragma unroll
  for (int n = 0; n < D_STATE; n++) Ac[n] = -__expf(A_log[c * D_STATE + n]);
  const float Dv = Dp[c];
  float h[D_STATE];
  const float* hp = h0 + (((size_t)(b * CH + k) * D_INNER + c) << 4);
  #pragma unroll
  for (int n = 0; n < D_STATE; n += 4) {
    const float4 v = *(const float4*)(hp + n);
    h[n] = v.x; h[n+1] = v.y; h[n+2] = v.z; h[n+3] = v.w;
  }
  const size_t r0 = (size_t)b * LL + (size_t)k * CLEN;
  const unsigned short* dtp = dt + r0 * D_INNER + c;
  const unsigned short* xcp = xc + r0 * D_INNER + c;
  const float* Bp  = xdbl + r0 * 96 + DT_RANK;
  const unsigned short* zp = xz + r0 * (size_t)(2 * D_INNER) + D_INNER + c;
  unsigned short* yhp = yh + r0 * D_INNER + c;

  float dtv = b2f(dtp[0]);
  float xv  = b2f(xcp[0]);
  float zv  = b2f(zp[0]);
  float4 B0 = *(const float4*)(Bp + 0);
  float4 B1 = *(const float4*)(Bp + 4);
  float4 B2 = *(const float4*)(Bp + 8);
  float4 B3 = *(const float4*)(Bp + 12);
  float4 C0 = *(const float4*)(Bp + 16);
  float4 C1 = *(const float4*)(Bp + 20);
  float4 C2 = *(const float4*)(Bp + 24);
  float4 C3 = *(const float4*)(Bp + 28);
  for (int l = 0; l < CLEN; l++) {
    const int lp = (l + 1 < CLEN) ? l + 1 : l;
    const float dtv2 = b2f(dtp[(size_t)lp * D_INNER]);
    const float xv2  = b2f(xcp[(size_t)lp * D_INNER]);
    const float zv2  = b2f(zp[(size_t)lp * 2 * D_INNER]);
    const float4 B0n = *(const float4*)(Bp + (size_t)lp * 96 + 0);
    const float4 B1n = *(const float4*)(Bp + (size_t)lp * 96 + 4);
    const float4 B2n = *(const float4*)(Bp + (size_t)lp * 96 + 8);
    const float4 B3n = *(const float4*)(Bp + (size_t)lp * 96 + 12);
    const float4 C0n = *(const float4*)(Bp + (size_t)lp * 96 + 16);
    const float4 C1n = *(const float4*)(Bp + (size_t)lp * 96 + 20);
    const float4 C2n = *(const float4*)(Bp + (size_t)lp * 96 + 24);
    const float4 C3n = *(const float4*)(Bp + (size_t)lp * 96 + 28);
    const float dx = dtv * xv;
    const float Bv[D_STATE] = {B0.x,B0.y,B0.z,B0.w, B1.x,B1.y,B1.z,B1.w,
                               B2.x,B2.y,B2.z,B2.w, B3.x,B3.y,B3.z,B3.w};
    const float Cv[D_STATE] = {C0.x,C0.y,C0.z,C0.w, C1.x,C1.y,C1.z,C1.w,
                               C2.x,C2.y,C2.z,C2.w, C3.x,C3.y,C3.z,C3.w};
    float y = 0.f;
    #pragma unroll
    for (int n = 0; n < D_STATE; n++) {
      h[n] = fmaf(__expf(dtv * Ac[n]), h[n], dx * Bv[n]);
      y = fmaf(h[n], Cv[n], y);
    }
    y = fmaf(xv, Dv, y);
    y *= zv / (1.f + __expf(-zv));
    yhp[(size_t)l * D_INNER] = rnd_bf16(y);
    dtv = dtv2; xv = xv2; zv = zv2;
    B0 = B0n; B1 = B1n; B2 = B2n; B3 = B3n;
    C0 = C0n; C1 = C1n; C2 = C2n; C3 = C3n;
  }
}

// ---------------- mean pool over L, two-stage ---------------------------------
__global__ __launch_bounds__(256) void pool1_k(const float* __restrict__ h,
    float* __restrict__ pp) {
  const int d = blockIdx.x * 256 + threadIdx.x;  // 0..1023
  const int b = blockIdx.y;
  const int seg = blockIdx.z;                    // 0..15
  float s = 0.f;
  const size_t base = (size_t)b * LL + (size_t)seg * 64;
  for (int l = 0; l < 64; l++) s += h[(base + l) * D_MODEL + d];
  pp[((size_t)(b * 16 + seg)) * D_MODEL + d] = s;
}
__global__ __launch_bounds__(256) void pool2_k(const float* __restrict__ pp,
    float* __restrict__ pooled) {
  const int d = blockIdx.x * 256 + threadIdx.x;
  const int b = blockIdx.y;
  float s = 0.f;
  #pragma unroll
  for (int k = 0; k < 16; k++) s += pp[((size_t)(b * 16 + k)) * D_MODEL + d];
  pooled[b * D_MODEL + d] = s * (1.f / LL);
}

// ---------------- classifier head --------------------------------------------
__global__ __launch_bounds__(64) void head_k(const float* __restrict__ pooled,
    const float* __restrict__ hw, const float* __restrict__ hb,
    float* __restrict__ out) {
  const int b = blockIdx.x / N_CLASSES;
  const int j = blockIdx.x % N_CLASSES;
  float s = 0.f;
  for (int k = threadIdx.x; k < D_MODEL; k += 64)
    s = fmaf(pooled[b * D_MODEL + k], hw[j * D_MODEL + k], s);
  #pragma unroll
  for (int o = 32; o; o >>= 1) s += __shfl_down(s, o);
  if (threadIdx.x == 0) out[b * N_CLASSES + j] = s + hb[j];
}

extern "C" void kernel_launch(void* const* d_in, const int* in_sizes, int n_in,
                              void* d_out, int out_size, void* d_ws, size_t ws_size,
                              hipStream_t stream) {
  const float* x0    = (const float*)d_in[0];
  const float* ln1w  = (const float*)d_in[1];
  const float* ln1b  = (const float*)d_in[2];
  const float* inw   = (const float*)d_in[3];
  const float* convw = (const float*)d_in[4];
  const float* convb = (const float*)d_in[5];
  const float* xpw   = (const float*)d_in[6];
  const float* dtpw  = (const float*)d_in[7];
  const float* dtpb  = (const float*)d_in[8];
  const float* Alog  = (const float*)d_in[9];
  const float* Dp    = (const float*)d_in[10];
  const float* outw  = (const float*)d_in[11];
  const float* normw = (const float*)d_in[12];
  const float* normb = (const float*)d_in[13];
  const float* headw = (const float*)d_in[14];
  const float* headb = (const float*)d_in[15];

  float* ws = (float*)d_ws;
  size_t f = 0;
  float* X      = ws + f; f += (size_t)BL * D_MODEL;        // residual stream
  float* xzf    = ws + f; f += (size_t)BL * D_INNER;        // bf16 xz (4096x4096)
  float* xdbl   = ws + f; f += (size_t)BL * 96;
  float* dty    = ws + f; f += (size_t)BL * D_INNER;        // bf16 dt / fp32 final-LN
  float* pooled = ws + f; f += 4096;
  float* pooldp = ws + f; f += (size_t)16 * BB * D_MODEL;   // pool partials
  float* xpart  = ws + f; f += (size_t)KS * BL * 96;
  float* hend   = ws + f; f += (size_t)BB * CH * D_INNER * D_STATE;
  float* opart  = ws + f; f += (size_t)KSO * BL * D_MODEL;
  unsigned short* hh  = (unsigned short*)(ws + f); f += (size_t)BL * D_MODEL / 2;
  unsigned short* yh  = (unsigned short*)(ws + f); f += (size_t)BL * D_INNER / 2;
  unsigned short* xcb = (unsigned short*)(ws + f); f += (size_t)BL * D_INNER / 2;
  unsigned short* wih = (unsigned short*)(ws + f);
  f += (size_t)N_LAYERS * 2 * D_INNER * D_MODEL / 2;
  unsigned short* woh = (unsigned short*)(ws + f);
  f += (size_t)N_LAYERS * D_MODEL * D_INNER / 2;
  unsigned short* xz  = (unsigned short*)xzf;   // BL * 2*D_INNER bf16
  unsigned short* dtb = (unsigned short*)dty;   // BL * D_INNER bf16 (dt)
  float* sumdt = xpart;   // overlay: xpart dead after xproj_reduce

  // round all weights once (both layers)
  round_k<<<(N_LAYERS * 2 * D_INNER * D_MODEL) / 1024, 256, 0, stream>>>(inw, wih);
  round_k<<<(N_LAYERS * D_MODEL * D_INNER) / 1024, 256, 0, stream>>>(outw, woh);
  // layer-0 LayerNorm -> bf16 operand (reads x0 directly)
  layernorm_bf16_k<<<BL, 256, 0, stream>>>(x0, ln1w, ln1b, hh);

  for (int layer = 0; layer < N_LAYERS; ++layer) {
    const unsigned short* wi = wih + (size_t)layer * 2 * D_INNER * D_MODEL;
    const unsigned short* wo = woh + (size_t)layer * D_MODEL * D_INNER;
    // xz = h @ in_w^T : M=4096 N=4096 K=1024 (bf16 MFMA, bf16 out, swizzled)
    mfma_gemm_nt<0, 1><<<dim3(4096 / 128, 4096 / 128), 256, 0, stream>>>(
        hh, wi, xz, BL, 2 * D_INNER, D_MODEL, 2 * D_INNER);
    conv_silu_k<<<(BL * D_INNER / 4) / 256, 256, 0, stream>>>(
        xz, convw + layer * D_INNER * D_CONV, convb + layer * D_INNER, xcb);
    // x_dbl = xc @ xp_w^T : M=4096 N=96 K=2048 (bf16 A, fp32 split-K + reduce)
    sgemm_splitk_k<<<dim3(96 / 32, 4096 / 64, KS), 256, 0, stream>>>(
        xcb, xpw + (size_t)layer * 96 * D_INNER, xpart);
    xproj_reduce_k<<<(BL * 96) / 256, 256, 0, stream>>>(xpart, xdbl);
    // dt = softplus(dt_r @ dtp_w^T + dtp_b) : M=4096 N=2048 K=64, bf16 out
    sgemm_nt<64,64,64,4,4,1><<<dim3(2048 / 64, 4096 / 64), 256, 0, stream>>>(
        xdbl, dtpw + (size_t)layer * D_INNER * DT_RANK, dtb,
        BL, D_INNER, DT_RANK, 96, DT_RANK, D_INNER,
        dtpb + layer * D_INNER);
    // chunked scan (CH=32)
    scan_pass1_k<<<dim3(D_INNER / 256, CH, BB), 256, 0, stream>>>(
        dtb, xcb, xdbl, Alog + (size_t)layer * D_INNER * D_STATE, hend, sumdt);
    scan_fix_k<<<(BB * D_INNER * D_STATE) / 256, 256, 0, stream>>>(
        hend, sumdt, Alog + (size_t)layer * D_INNER * D_STATE);
    scan_pass3_k<<<dim3(D_INNER / 256, CH, BB), 256, 0, stream>>>(
        dtb, xcb, xdbl, xz, hend, Alog + (size_t)layer * D_INNER * D_STATE,
        Dp + layer * D_INNER, yh);
    // y @ out_w^T : M=4096 N=1024 K=2048, split-K=2 partials (swizzled)
    mfma_gemm_nt<1, KSO><<<dim3(1024 / 128, 4096 / 128, KSO), 256, 0, stream>>>(
        yh, wo, opart, BL, D_MODEL, D_INNER, D_MODEL);
    // fused: X = (layer0 ? x0 : X) + partials; LN -> next operand / final LN
    const float* Xin = (layer == 0) ? x0 : X;
    if (layer + 1 < N_LAYERS) {
      oreduce_ln_k<0><<<BL, 256, 0, stream>>>(
          opart, Xin, X, ln1w + (layer + 1) * D_MODEL,
          ln1b + (layer + 1) * D_MODEL, hh);
    } else {
      oreduce_ln_k<1><<<BL, 256, 0, stream>>>(opart, Xin, X, normw, normb, dty);
    }
  }

  pool1_k<<<dim3(D_MODEL / 256, BB, 16), 256, 0, stream>>>(dty, pooldp);
  pool2_k<<<dim3(D_MODEL / 256, BB), 256, 0, stream>>>(pooldp, pooled);
  head_k<<<BB * N_CLASSES, 64, 0, stream>>>(pooled, headw, headb, (float*)d_out);
}

// Round 13
// 570.708 us; speedup vs baseline: 5.5165x; 1.0569x over previous
//
#include <hip/hip_runtime.h>
#include <hip/hip_bf16.h>

#define N_LAYERS 2
#define D_MODEL 1024
#define D_INNER 2048
#define D_STATE 16
#define D_CONV 4
#define DT_RANK 64
#define N_CLASSES 10
#define BB 4
#define LL 1024
#define BL (BB*LL)   // 4096 rows
#define CH 32        // scan chunks per sequence
#define CLEN (LL/CH) // 32 steps per chunk
#define KS 8         // split-K segments for x_proj
#define KSO 2        // split-K segments for out_proj

typedef __attribute__((ext_vector_type(8))) short bf16x8;
typedef __attribute__((ext_vector_type(8))) unsigned short us8;
typedef __attribute__((ext_vector_type(4))) float f32x4;

typedef const void __attribute__((address_space(1)))* gas_ptr;
typedef void __attribute__((address_space(3)))* las_ptr;
#define GLDS16(g, p) __builtin_amdgcn_global_load_lds((gas_ptr)(g), (las_ptr)(p), 16, 0, 0)

__device__ inline unsigned short rnd_bf16(float x) {
  unsigned u = __float_as_uint(x);
  return (unsigned short)((u + 0x7FFFu + ((u >> 16) & 1u)) >> 16);
}
__device__ inline float b2f(unsigned short u) {
  return __uint_as_float(((unsigned)u) << 16);
}

// round weights to bf16 (both layers in one launch)
__global__ __launch_bounds__(256) void round_k(const float* __restrict__ in,
    unsigned short* __restrict__ hi) {
  const int i = blockIdx.x * 256 + threadIdx.x;
  const float4 v = ((const float4*)in)[i];
  ushort4 h4;
  h4.x = rnd_bf16(v.x); h4.y = rnd_bf16(v.y);
  h4.z = rnd_bf16(v.z); h4.w = rnd_bf16(v.w);
  ((ushort4*)hi)[i] = h4;
}

// ---------------- LayerNorm -> bf16 out ---------------------------------------
__global__ __launch_bounds__(256) void layernorm_bf16_k(const float* __restrict__ x,
    const float* __restrict__ w, const float* __restrict__ b,
    unsigned short* __restrict__ oh) {
  const int row = blockIdx.x;
  const int t = threadIdx.x;
  const float4 v = *(const float4*)(x + (size_t)row * D_MODEL + t * 4);
  float s = v.x + v.y + v.z + v.w;
  float q = v.x*v.x + v.y*v.y + v.z*v.z + v.w*v.w;
  #pragma unroll
  for (int o = 32; o; o >>= 1) { s += __shfl_down(s, o); q += __shfl_down(q, o); }
  __shared__ float red[8];
  if ((t & 63) == 0) { red[t >> 6] = s; red[4 + (t >> 6)] = q; }
  __syncthreads();
  s = red[0] + red[1] + red[2] + red[3];
  q = red[4] + red[5] + red[6] + red[7];
  const float mean = s * (1.f / D_MODEL);
  const float var  = q * (1.f / D_MODEL) - mean * mean;
  const float rstd = rsqrtf(var + 1e-5f);
  const float4 wv = *(const float4*)(w + t * 4);
  const float4 bv = *(const float4*)(b + t * 4);
  ushort4 h4;
  h4.x = rnd_bf16((v.x - mean) * rstd * wv.x + bv.x);
  h4.y = rnd_bf16((v.y - mean) * rstd * wv.y + bv.y);
  h4.z = rnd_bf16((v.z - mean) * rstd * wv.z + bv.z);
  h4.w = rnd_bf16((v.w - mean) * rstd * wv.w + bv.w);
  ((ushort4*)(oh + (size_t)row * D_MODEL))[t] = h4;
}

// ---- fused: Xout = Xin + sum(out_proj partials); then LayerNorm -> operand ---
template<int OUT>
__global__ __launch_bounds__(256) void oreduce_ln_k(
    const float* __restrict__ part, const float* __restrict__ Xin,
    float* __restrict__ Xout,
    const float* __restrict__ w, const float* __restrict__ b,
    void* __restrict__ out) {
  const int row = blockIdx.x;
  const int t = threadIdx.x;
  float4 v = *(const float4*)(Xin + (size_t)row * D_MODEL + t * 4);
  #pragma unroll
  for (int k = 0; k < KSO; k++) {
    const float4 p = *(const float4*)(part + (size_t)k * BL * D_MODEL
                                      + (size_t)row * D_MODEL + t * 4);
    v.x += p.x; v.y += p.y; v.z += p.z; v.w += p.w;
  }
  *(float4*)(Xout + (size_t)row * D_MODEL + t * 4) = v;   // residual stream
  float s = v.x + v.y + v.z + v.w;
  float q = v.x*v.x + v.y*v.y + v.z*v.z + v.w*v.w;
  #pragma unroll
  for (int o = 32; o; o >>= 1) { s += __shfl_down(s, o); q += __shfl_down(q, o); }
  __shared__ float red[8];
  if ((t & 63) == 0) { red[t >> 6] = s; red[4 + (t >> 6)] = q; }
  __syncthreads();
  s = red[0] + red[1] + red[2] + red[3];
  q = red[4] + red[5] + red[6] + red[7];
  const float mean = s * (1.f / D_MODEL);
  const float var  = q * (1.f / D_MODEL) - mean * mean;
  const float rstd = rsqrtf(var + 1e-5f);
  const float4 wv = *(const float4*)(w + t * 4);
  const float4 bv = *(const float4*)(b + t * 4);
  float4 o4;
  o4.x = (v.x - mean) * rstd * wv.x + bv.x;
  o4.y = (v.y - mean) * rstd * wv.y + bv.y;
  o4.z = (v.z - mean) * rstd * wv.z + bv.z;
  o4.w = (v.w - mean) * rstd * wv.w + bv.w;
  if constexpr (OUT == 0) {
    ushort4 h4;
    h4.x = rnd_bf16(o4.x); h4.y = rnd_bf16(o4.y);
    h4.z = rnd_bf16(o4.z); h4.w = rnd_bf16(o4.w);
    ((ushort4*)((unsigned short*)out + (size_t)row * D_MODEL))[t] = h4;
  } else {
    *(float4*)((float*)out + (size_t)row * D_MODEL + t * 4) = o4;
  }
}

// ==== 256x256 bf16 MFMA GEMM NT — counted-vmcnt pipeline (in_proj only) ======
// 512 thr (8 waves 2Mx4N), BK=64, 128 KB LDS dbuf, prefetch dist 2 K-tiles,
// s_waitcnt vmcnt(8) (never 0 in loop), raw s_barrier, T2 read-swizzle
// (col8 ^= row&7) with inverse pre-applied to the global source. bf16 C out.
// Grid MUST be (16,16). M=N=4096 implied.
__global__ __launch_bounds__(512) void mfma_gemm256_nt(
    const unsigned short* __restrict__ A, const unsigned short* __restrict__ B,
    unsigned short* __restrict__ C, int K, int ldc) {
  __shared__ unsigned short S[65536];   // [buf:2][mat:2][256*64] bf16 = 128 KB
  const int tid = threadIdx.x;
  const int l = tid & 63;
  const int w = tid >> 6;
  const int wm = w >> 2, wn = w & 3;
  // XCD remap: XCD x gets a 4-row x 8-col panel of the 16x16 grid
  const int bid = blockIdx.y * 16 + blockIdx.x;
  const int x = bid & 7, v = bid >> 3;            // v in 0..31
  const int bx = (x & 1) * 8 + (v & 7);
  const int by = (x >> 1) * 4 + (v >> 3);
  const int m0 = by * 256, n0 = bx * 256;
  const int nkt = K >> 6;
  const int r8 = (tid >> 3) & 7;                  // staging row & 7
  const int c16s = (tid & 7) ^ r8;                // pre-swizzled source col16

  // stage one half-tile (mat: 0=A rows m0.., 1=B rows n0..; half: 0/1) of kt
  auto stage1 = [&](int kt, int mat, int half) {
    const unsigned short* base = (mat == 0) ? (A + (size_t)m0 * K)
                                            : (B + (size_t)n0 * K);
    unsigned short* dst = S + ((kt & 1) * 32768 + mat * 16384 + half * 8192);
    #pragma unroll
    for (int e = 0; e < 2; ++e) {
      const int row = half * 128 + e * 64 + (tid >> 3);
      GLDS16(base + (size_t)row * K + kt * 64 + c16s * 8,
             dst + e * 4096 + tid * 8);
    }
  };
  auto stage_full = [&](int kt) {
    stage1(kt, 0, 0); stage1(kt, 0, 1); stage1(kt, 1, 0); stage1(kt, 1, 1);
  };

  // prologue: stage K-tiles 0 and 1
  stage_full(0);
  if (nkt > 1) stage_full(1);

  f32x4 acc[8][4] = {};
  const int fr = l & 15;
  const int fk8 = l >> 4;                         // 0..3 (col8 within K-half)

  #pragma unroll 1
  for (int kt = 0; kt < nkt; ++kt) {
    if (kt + 1 < nkt) asm volatile("s_waitcnt vmcnt(8)" ::: "memory");
    else              asm volatile("s_waitcnt vmcnt(0)" ::: "memory");
    __builtin_amdgcn_s_barrier();
    __builtin_amdgcn_sched_barrier(0);
    const unsigned short* SA = S + (kt & 1) * 32768;
    const unsigned short* SB = SA + 16384;
    #pragma unroll
    for (int kk8 = 0; kk8 < 8; kk8 += 4) {        // kk = 0, 32
      bf16x8 av[8], bv[4];
      const int c8 = kk8 + fk8;
      #pragma unroll
      for (int i = 0; i < 8; ++i) {
        const int R = wm * 128 + i * 16 + fr;
        av[i] = *(const bf16x8*)&SA[R * 64 + ((c8 ^ (R & 7)) << 3)];
      }
      #pragma unroll
      for (int j = 0; j < 4; ++j) {
        const int R = wn * 64 + j * 16 + fr;
        bv[j] = *(const bf16x8*)&SB[R * 64 + ((c8 ^ (R & 7)) << 3)];
      }
      __builtin_amdgcn_s_setprio(1);
      #pragma unroll
      for (int i = 0; i < 8; ++i)
        #pragma unroll
        for (int j = 0; j < 4; ++j)
          acc[i][j] = __builtin_amdgcn_mfma_f32_16x16x32_bf16(
              av[i], bv[j], acc[i][j], 0, 0, 0);
      __builtin_amdgcn_s_setprio(0);
    }
    __builtin_amdgcn_s_barrier();                 // buf[kt&1] fully consumed
    __builtin_amdgcn_sched_barrier(0);
    if (kt + 2 < nkt) stage_full(kt + 2);         // overwrite just-freed buf
  }

  const int orow = (l >> 4) * 4, ocol = l & 15;
  #pragma unroll
  for (int i = 0; i < 8; ++i)
    #pragma unroll
    for (int j = 0; j < 4; ++j)
      #pragma unroll
      for (int r = 0; r < 4; ++r) {
        const int m = m0 + wm * 128 + i * 16 + orow + r;
        const int n = n0 + wn * 64 + j * 16 + ocol;
        C[(size_t)m * ldc + n] = rnd_bf16(acc[i][j][r]);
      }
}

// ---- bf16 MFMA GEMM NT 128² (split-K, out_proj) -----------------------------
template<int EPI, int KSEG>
__global__ __launch_bounds__(256) void mfma_gemm_nt(
    const unsigned short* __restrict__ Ah, const unsigned short* __restrict__ Bh,
    void* __restrict__ Cv, int M, int N, int K, int ldc) {
  __shared__ unsigned short As[128 * 64];
  __shared__ unsigned short Bs[128 * 64];
  const int tid = threadIdx.x;
  const int w = tid >> 6, l = tid & 63;
  const int wr = w >> 1, wc = w & 1;
  const int nbx = gridDim.x;
  const int nwg = nbx * gridDim.y;
  int bid = blockIdx.y * nbx + blockIdx.x;
  bid = (bid & 7) * (nwg >> 3) + (bid >> 3);
  const int st = bid >> 6, wi = bid & 63;
  const int stpr = (nbx >= 8) ? (nbx >> 3) : 1;
  int n0, m0;
  if (nbx >= 8) {
    n0 = ((st % stpr) * 8 + (wi & 7)) * 128;
    m0 = ((st / stpr) * 8 + (wi >> 3)) * 128;
  } else {
    n0 = (bid % nbx) * 128;
    m0 = (bid / nbx) * 128;
  }
  const int kz = (KSEG > 1) ? blockIdx.z : 0;
  const int kbeg = kz * (K / KSEG);
  const int kend = kbeg + K / KSEG;
  const int srow = l >> 3;
  const int scol = (l & 7) * 8;
  const int fr = l & 15;
  const int fk = (l >> 4) * 8;
  f32x4 acc[4][4] = {};

  #pragma unroll 1
  for (int k0 = kbeg; k0 < kend; k0 += 64) {
    __syncthreads();
    #pragma unroll
    for (int it = 0; it < 4; ++it) {
      const int bi = it * 4 + w;
      const int row = bi * 8 + srow;
      GLDS16(Ah + (size_t)(m0 + row) * K + k0 + scol, &As[bi * 512 + l * 8]);
      GLDS16(Bh + (size_t)(n0 + row) * K + k0 + scol, &Bs[bi * 512 + l * 8]);
    }
    __syncthreads();
    #pragma unroll
    for (int kk = 0; kk < 64; kk += 32) {
      bf16x8 a[4], b[4];
      #pragma unroll
      for (int f = 0; f < 4; ++f)
        b[f] = *(const bf16x8*)&Bs[(wc * 64 + f * 16 + fr) * 64 + kk + fk];
      #pragma unroll
      for (int f = 0; f < 4; ++f)
        a[f] = *(const bf16x8*)&As[(wr * 64 + f * 16 + fr) * 64 + kk + fk];
      #pragma unroll
      for (int i = 0; i < 4; ++i)
        #pragma unroll
        for (int j = 0; j < 4; ++j)
          acc[i][j] = __builtin_amdgcn_mfma_f32_16x16x32_bf16(
              a[i], b[j], acc[i][j], 0, 0, 0);
    }
  }
  const int orow = (l >> 4) * 4;
  const int ocol = l & 15;
  if constexpr (EPI == 0) {
    unsigned short* Cw = (unsigned short*)Cv;
    #pragma unroll
    for (int i = 0; i < 4; ++i)
      #pragma unroll
      for (int j = 0; j < 4; ++j)
        #pragma unroll
        for (int r = 0; r < 4; ++r) {
          const int m = m0 + wr * 64 + i * 16 + orow + r;
          const int n = n0 + wc * 64 + j * 16 + ocol;
          Cw[(size_t)m * ldc + n] = rnd_bf16(acc[i][j][r]);
        }
  } else {
    float* Cw = (float*)Cv + (size_t)kz * M * ldc;
    #pragma unroll
    for (int i = 0; i < 4; ++i)
      #pragma unroll
      for (int j = 0; j < 4; ++j)
        #pragma unroll
        for (int r = 0; r < 4; ++r) {
          const int m = m0 + wr * 64 + i * 16 + orow + r;
          const int n = n0 + wc * 64 + j * 16 + ocol;
          Cw[(size_t)m * ldc + n] = acc[i][j][r];
        }
  }
}

// ---------------- fp32 SGEMM NT (dt GEMM) -------------------------------------
template<int BM, int BN, int BK, int TM, int TN, int EPI>
__global__ __launch_bounds__(256) void sgemm_nt(
    const float* __restrict__ A, const float* __restrict__ B,
    void* __restrict__ Cv, int M, int N, int K, int lda, int ldb, int ldc,
    const float* __restrict__ bias) {
  constexpr int THREADS = 256;
  constexpr int NT = BN / TN;
  constexpr int K4 = BK / 4;
  constexpr int A_F4 = BM * BK / (THREADS * 4);
  constexpr int B_F4 = BN * BK / (THREADS * 4);
  static_assert((BM / TM) * (BN / TN) == THREADS, "thread shape");
  __shared__ float As[BK][BM + 4];
  __shared__ float Bs[BK][BN + 4];
  const int tid = threadIdx.x;
  const int m0 = blockIdx.y * BM;
  const int n0 = blockIdx.x * BN;
  const int tn = (tid % NT) * TN;
  const int tm = (tid / NT) * TM;
  float acc[TM][TN] = {};
  for (int k0 = 0; k0 < K; k0 += BK) {
    #pragma unroll
    for (int i = 0; i < A_F4; i++) {
      int li = tid + i * THREADS;
      int r = li / K4, c4 = li % K4;
      float4 v = *(const float4*)(A + (size_t)(m0 + r) * lda + k0 + c4 * 4);
      As[c4*4+0][r] = v.x; As[c4*4+1][r] = v.y; As[c4*4+2][r] = v.z; As[c4*4+3][r] = v.w;
    }
    #pragma unroll
    for (int i = 0; i < B_F4; i++) {
      int li = tid + i * THREADS;
      int r = li / K4, c4 = li % K4;
      float4 v = *(const float4*)(B + (size_t)(n0 + r) * ldb + k0 + c4 * 4);
      Bs[c4*4+0][r] = v.x; Bs[c4*4+1][r] = v.y; Bs[c4*4+2][r] = v.z; Bs[c4*4+3][r] = v.w;
    }
    __syncthreads();
    #pragma unroll
    for (int k = 0; k < BK; k++) {
      float a[TM], bf[TN];
      #pragma unroll
      for (int i = 0; i < TM; i++) a[i] = As[k][tm + i];
      #pragma unroll
      for (int j = 0; j < TN; j++) bf[j] = Bs[k][tn + j];
      #pragma unroll
      for (int i = 0; i < TM; i++)
        #pragma unroll
        for (int j = 0; j < TN; j++)
          acc[i][j] = fmaf(a[i], bf[j], acc[i][j]);
    }
    __syncthreads();
  }
  #pragma unroll
  for (int i = 0; i < TM; i++) {
    const int m = m0 + tm + i;
    #pragma unroll
    for (int j = 0; j < TN; j++) {
      const int n = n0 + tn + j;
      float v = acc[i][j];
      if constexpr (EPI == 1) {
        v += bias[n];
        v = (v > 20.f) ? v : log1pf(__expf(v));
        ((unsigned short*)Cv)[(size_t)m * ldc + n] = rnd_bf16(v);
      } else {
        ((float*)Cv)[(size_t)m * ldc + n] = v;
      }
    }
  }
}

// ---- x_proj split-K (bf16 A) ------------------------------------------------
__global__ __launch_bounds__(256) void sgemm_splitk_k(
    const unsigned short* __restrict__ A, const float* __restrict__ B,
    float* __restrict__ part) {
  __shared__ float As[32][64 + 4];
  __shared__ float Bs[32][32 + 4];
  const int tid = threadIdx.x;
  const int n0 = blockIdx.x * 32;
  const int m0 = blockIdx.y * 64;
  const int kz = blockIdx.z;
  const int tn = (tid & 15) * 2;
  const int tm = (tid >> 4) * 4;
  float acc[4][2] = {};
  for (int kb = 0; kb < 256; kb += 32) {
    const int k0 = kz * 256 + kb;
    {
      int r = tid >> 2, c8 = (tid & 3) * 8;
      us8 u = *(const us8*)(A + (size_t)(m0 + r) * D_INNER + k0 + c8);
      #pragma unroll
      for (int j = 0; j < 8; j++) As[c8 + j][r] = b2f((unsigned short)u[j]);
    }
    {
      int r = tid >> 3, c4 = tid & 7;
      float4 v = *(const float4*)(B + (size_t)(n0 + r) * D_INNER + k0 + c4 * 4);
      Bs[c4*4+0][r] = v.x; Bs[c4*4+1][r] = v.y;
      Bs[c4*4+2][r] = v.z; Bs[c4*4+3][r] = v.w;
    }
    __syncthreads();
    #pragma unroll
    for (int k = 0; k < 32; k++) {
      float a[4], bf[2];
      #pragma unroll
      for (int i = 0; i < 4; i++) a[i] = As[k][tm + i];
      bf[0] = Bs[k][tn]; bf[1] = Bs[k][tn + 1];
      #pragma unroll
      for (int i = 0; i < 4; i++) {
        acc[i][0] = fmaf(a[i], bf[0], acc[i][0]);
        acc[i][1] = fmaf(a[i], bf[1], acc[i][1]);
      }
    }
    __syncthreads();
  }
  float* p = part + (size_t)kz * BL * 96;
  #pragma unroll
  for (int i = 0; i < 4; i++) {
    const int m = m0 + tm + i;
    p[(size_t)m * 96 + n0 + tn]     = acc[i][0];
    p[(size_t)m * 96 + n0 + tn + 1] = acc[i][1];
  }
}

// fixed-order deterministic reduce of the KS partials -> xdbl
__global__ __launch_bounds__(256) void xproj_reduce_k(
    const float* __restrict__ part, float* __restrict__ out) {
  const int i = blockIdx.x * 256 + threadIdx.x;
  float s = 0.f;
  #pragma unroll
  for (int k = 0; k < KS; k++) s += part[(size_t)k * BL * 96 + i];
  out[i] = s;
}

// ------ causal depthwise conv + SiLU, bf16 in / bf16 out ----------------------
__global__ __launch_bounds__(256) void conv_silu_k(
    const unsigned short* __restrict__ xz,
    const float* __restrict__ cw, const float* __restrict__ cb,
    unsigned short* __restrict__ xc) {
  const int gid = blockIdx.x * 256 + threadIdx.x;
  const int c4 = (gid & (D_INNER / 4 - 1)) << 2;
  const int row = gid >> 9;
  const int l = row & (LL - 1);
  const unsigned short* base = xz + (size_t)row * (2 * D_INNER) + c4;
  const float4 w0 = *(const float4*)(cw + (c4 + 0) * 4);
  const float4 w1 = *(const float4*)(cw + (c4 + 1) * 4);
  const float4 w2 = *(const float4*)(cw + (c4 + 2) * 4);
  const float4 w3 = *(const float4*)(cw + (c4 + 3) * 4);
  float4 acc = *(const float4*)(cb + c4);
  ushort4 uv = *(const ushort4*)base;
  acc.x = fmaf(w0.w, b2f(uv.x), acc.x); acc.y = fmaf(w1.w, b2f(uv.y), acc.y);
  acc.z = fmaf(w2.w, b2f(uv.z), acc.z); acc.w = fmaf(w3.w, b2f(uv.w), acc.w);
  if (l >= 1) {
    uv = *(const ushort4*)(base - 2 * D_INNER);
    acc.x = fmaf(w0.z, b2f(uv.x), acc.x); acc.y = fmaf(w1.z, b2f(uv.y), acc.y);
    acc.z = fmaf(w2.z, b2f(uv.z), acc.z); acc.w = fmaf(w3.z, b2f(uv.w), acc.w);
  }
  if (l >= 2) {
    uv = *(const ushort4*)(base - 4 * D_INNER);
    acc.x = fmaf(w0.y, b2f(uv.x), acc.x); acc.y = fmaf(w1.y, b2f(uv.y), acc.y);
    acc.z = fmaf(w2.y, b2f(uv.z), acc.z); acc.w = fmaf(w3.y, b2f(uv.w), acc.w);
  }
  if (l >= 3) {
    uv = *(const ushort4*)(base - 6 * D_INNER);
    acc.x = fmaf(w0.x, b2f(uv.x), acc.x); acc.y = fmaf(w1.x, b2f(uv.y), acc.y);
    acc.z = fmaf(w2.x, b2f(uv.z), acc.z); acc.w = fmaf(w3.x, b2f(uv.w), acc.w);
  }
  ushort4 o4;
  o4.x = rnd_bf16(acc.x / (1.f + __expf(-acc.x)));
  o4.y = rnd_bf16(acc.y / (1.f + __expf(-acc.y)));
  o4.z = rnd_bf16(acc.z / (1.f + __expf(-acc.z)));
  o4.w = rnd_bf16(acc.w / (1.f + __expf(-acc.w)));
  *(ushort4*)(xc + (size_t)row * D_INNER + c4) = o4;
}

// ------- chunked selective scan, pass 1 (bf16 dt, bf16 xc) --------------------
__global__ __launch_bounds__(256) void scan_pass1_k(
    const unsigned short* __restrict__ dt, const unsigned short* __restrict__ xc,
    const float* __restrict__ xdbl, const float* __restrict__ A_log,
    float* __restrict__ hend, float* __restrict__ sumdt) {
  const int c = blockIdx.x * 256 + threadIdx.x;
  const int k = blockIdx.y;
  const int b = blockIdx.z;
  float Ac[D_STATE];
  #pragma unroll
  for (int n = 0; n < D_STATE; n++) Ac[n] = -__expf(A_log[c * D_STATE + n]);
  float h[D_STATE] = {};
  float sd = 0.f;
  const size_t r0 = (size_t)b * LL + (size_t)k * CLEN;
  const unsigned short* dtp = dt + r0 * D_INNER + c;
  const unsigned short* xcp = xc + r0 * D_INNER + c;
  const float* Bp  = xdbl + r0 * 96 + DT_RANK;

  float dtv = b2f(dtp[0]);
  float xv  = b2f(xcp[0]);
  float4 B0 = *(const float4*)(Bp + 0);
  float4 B1 = *(const float4*)(Bp + 4);
  float4 B2 = *(const float4*)(Bp + 8);
  float4 B3 = *(const float4*)(Bp + 12);
  for (int l = 0; l < CLEN; l++) {
    const int lp = (l + 1 < CLEN) ? l + 1 : l;
    const float dtv2 = b2f(dtp[(size_t)lp * D_INNER]);
    const float xv2  = b2f(xcp[(size_t)lp * D_INNER]);
    const float4 B0n = *(const float4*)(Bp + (size_t)lp * 96 + 0);
    const float4 B1n = *(const float4*)(Bp + (size_t)lp * 96 + 4);
    const float4 B2n = *(const float4*)(Bp + (size_t)lp * 96 + 8);
    const float4 B3n = *(const float4*)(Bp + (size_t)lp * 96 + 12);
    sd += dtv;
    const float dx = dtv * xv;
    const float Bv[D_STATE] = {B0.x,B0.y,B0.z,B0.w, B1.x,B1.y,B1.z,B1.w,
                               B2.x,B2.y,B2.z,B2.w, B3.x,B3.y,B3.z,B3.w};
    #pragma unroll
    for (int n = 0; n < D_STATE; n++)
      h[n] = fmaf(__expf(dtv * Ac[n]), h[n], dx * Bv[n]);
    dtv = dtv2; xv = xv2; B0 = B0n; B1 = B1n; B2 = B2n; B3 = B3n;
  }
  float* he = hend + (((size_t)(b * CH + k) * D_INNER + c) << 4);
  #pragma unroll
  for (int n = 0; n < D_STATE; n += 4)
    *(float4*)(he + n) = make_float4(h[n], h[n+1], h[n+2], h[n+3]);
  sumdt[(size_t)(b * CH + k) * D_INNER + c] = sd;
}

// ------- chunked scan fixup ---------------------------------------------------
__global__ __launch_bounds__(256) void scan_fix_k(
    float* __restrict__ hend, const float* __restrict__ sumdt,
    const float* __restrict__ A_log) {
  const int gid = blockIdx.x * 256 + threadIdx.x;
  const int n = gid & 15;
  const int c = (gid >> 4) & (D_INNER - 1);
  const int b = gid >> 15;
  const float Ac = -__expf(A_log[c * D_STATE + n]);
  float hrun = 0.f;
  for (int k = 0; k < CH; k++) {
    const size_t base = (size_t)(b * CH + k) * D_INNER + c;
    const float sd = sumdt[base];
    float* hp = hend + (base << 4) + n;
    const float tmp = *hp;
    *hp = hrun;
    hrun = fmaf(__expf(Ac * sd), hrun, tmp);
  }
}

// ------- chunked scan pass 3 ---------------------------------------------------
__global__ __launch_bounds__(256) void scan_pass3_k(
    const unsigned short* __restrict__ dt, const unsigned short* __restrict__ xc,
    const float* __restrict__ xdbl, const unsigned short* __restrict__ xz,
    const float* __restrict__ h0, const float* __restrict__ A_log,
    const float* __restrict__ Dp, unsigned short* __restrict__ yh) {
  const int c = blockIdx.x * 256 + threadIdx.x;
  const int k = blockIdx.y;
  const int b = blockIdx.z;
  float Ac[D_STATE];
  #pragma unroll
  for (int n = 0; n < D_STATE; n++) Ac[n] = -__expf(A_log[c * D_STATE + n]);
  const float Dv = Dp[c];
  float h[D_STATE];
  const float* hp = h0 + (((size_t)(b * CH + k) * D_INNER + c) << 4);
  #pragma unroll
  for (int n = 0; n < D_STATE; n += 4) {
    const float4 v = *(const float4*)(hp + n);
    h[n] = v.x; h[n+1] = v.y; h[n+2] = v.z; h[n+3] = v.w;
  }
  const size_t r0 = (size_t)b * LL + (size_t)k * CLEN;
  const unsigned short* dtp = dt + r0 * D_INNER + c;
  const unsigned short* xcp = xc + r0 * D_INNER + c;
  const float* Bp  = xdbl + r0 * 96 + DT_RANK;
  const unsigned short* zp = xz + r0 * (size_t)(2 * D_INNER) + D_INNER + c;
  unsigned short* yhp = yh + r0 * D_INNER + c;

  float dtv = b2f(dtp[0]);
  float xv  = b2f(xcp[0]);
  float zv  = b2f(zp[0]);
  float4 B0 = *(const float4*)(Bp + 0);
  float4 B1 = *(const float4*)(Bp + 4);
  float4 B2 = *(const float4*)(Bp + 8);
  float4 B3 = *(const float4*)(Bp + 12);
  float4 C0 = *(const float4*)(Bp + 16);
  float4 C1 = *(const float4*)(Bp + 20);
  float4 C2 = *(const float4*)(Bp + 24);
  float4 C3 = *(const float4*)(Bp + 28);
  for (int l = 0; l < CLEN; l++) {
    const int lp = (l + 1 < CLEN) ? l + 1 : l;
    const float dtv2 = b2f(dtp[(size_t)lp * D_INNER]);
    const float xv2  = b2f(xcp[(size_t)lp * D_INNER]);
    const float zv2  = b2f(zp[(size_t)lp * 2 * D_INNER]);
    const float4 B0n = *(const float4*)(Bp + (size_t)lp * 96 + 0);
    const float4 B1n = *(const float4*)(Bp + (size_t)lp * 96 + 4);
    const float4 B2n = *(const float4*)(Bp + (size_t)lp * 96 + 8);
    const float4 B3n = *(const float4*)(Bp + (size_t)lp * 96 + 12);
    const float4 C0n = *(const float4*)(Bp + (size_t)lp * 96 + 16);
    const float4 C1n = *(const float4*)(Bp + (size_t)lp * 96 + 20);
    const float4 C2n = *(const float4*)(Bp + (size_t)lp * 96 + 24);
    const float4 C3n = *(const float4*)(Bp + (size_t)lp * 96 + 28);
    const float dx = dtv * xv;
    const float Bv[D_STATE] = {B0.x,B0.y,B0.z,B0.w, B1.x,B1.y,B1.z,B1.w,
                               B2.x,B2.y,B2.z,B2.w, B3.x,B3.y,B3.z,B3.w};
    const float Cv[D_STATE] = {C0.x,C0.y,C0.z,C0.w, C1.x,C1.y,C1.z,C1.w,
                               C2.x,C2.y,C2.z,C2.w, C3.x,C3.y,C3.z,C3.w};
    float y = 0.f;
    #pragma unroll
    for (int n = 0; n < D_STATE; n++) {
      h[n] = fmaf(__expf(dtv * Ac[n]), h[n], dx * Bv[n]);
      y = fmaf(h[n], Cv[n], y);
    }
    y = fmaf(xv, Dv, y);
    y *= zv / (1.f + __expf(-zv));
    yhp[(size_t)l * D_INNER] = rnd_bf16(y);
    dtv = dtv2; xv = xv2; zv = zv2;
    B0 = B0n; B1 = B1n; B2 = B2n; B3 = B3n;
    C0 = C0n; C1 = C1n; C2 = C2n; C3 = C3n;
  }
}

// ---------------- mean pool over L, two-stage ---------------------------------
__global__ __launch_bounds__(256) void pool1_k(const float* __restrict__ h,
    float* __restrict__ pp) {
  const int d = blockIdx.x * 256 + threadIdx.x;
  const int b = blockIdx.y;
  const int seg = blockIdx.z;
  float s = 0.f;
  const size_t base = (size_t)b * LL + (size_t)seg * 64;
  for (int l = 0; l < 64; l++) s += h[(base + l) * D_MODEL + d];
  pp[((size_t)(b * 16 + seg)) * D_MODEL + d] = s;
}
__global__ __launch_bounds__(256) void pool2_k(const float* __restrict__ pp,
    float* __restrict__ pooled) {
  const int d = blockIdx.x * 256 + threadIdx.x;
  const int b = blockIdx.y;
  float s = 0.f;
  #pragma unroll
  for (int k = 0; k < 16; k++) s += pp[((size_t)(b * 16 + k)) * D_MODEL + d];
  pooled[b * D_MODEL + d] = s * (1.f / LL);
}

// ---------------- classifier head --------------------------------------------
__global__ __launch_bounds__(64) void head_k(const float* __restrict__ pooled,
    const float* __restrict__ hw, const float* __restrict__ hb,
    float* __restrict__ out) {
  const int b = blockIdx.x / N_CLASSES;
  const int j = blockIdx.x % N_CLASSES;
  float s = 0.f;
  for (int k = threadIdx.x; k < D_MODEL; k += 64)
    s = fmaf(pooled[b * D_MODEL + k], hw[j * D_MODEL + k], s);
  #pragma unroll
  for (int o = 32; o; o >>= 1) s += __shfl_down(s, o);
  if (threadIdx.x == 0) out[b * N_CLASSES + j] = s + hb[j];
}

extern "C" void kernel_launch(void* const* d_in, const int* in_sizes, int n_in,
                              void* d_out, int out_size, void* d_ws, size_t ws_size,
                              hipStream_t stream) {
  const float* x0    = (const float*)d_in[0];
  const float* ln1w  = (const float*)d_in[1];
  const float* ln1b  = (const float*)d_in[2];
  const float* inw   = (const float*)d_in[3];
  const float* convw = (const float*)d_in[4];
  const float* convb = (const float*)d_in[5];
  const float* xpw   = (const float*)d_in[6];
  const float* dtpw  = (const float*)d_in[7];
  const float* dtpb  = (const float*)d_in[8];
  const float* Alog  = (const float*)d_in[9];
  const float* Dp    = (const float*)d_in[10];
  const float* outw  = (const float*)d_in[11];
  const float* normw = (const float*)d_in[12];
  const float* normb = (const float*)d_in[13];
  const float* headw = (const float*)d_in[14];
  const float* headb = (const float*)d_in[15];

  float* ws = (float*)d_ws;
  size_t f = 0;
  float* X      = ws + f; f += (size_t)BL * D_MODEL;
  float* xzf    = ws + f; f += (size_t)BL * D_INNER;
  float* xdbl   = ws + f; f += (size_t)BL * 96;
  float* dty    = ws + f; f += (size_t)BL * D_INNER;
  float* pooled = ws + f; f += 4096;
  float* pooldp = ws + f; f += (size_t)16 * BB * D_MODEL;
  float* xpart  = ws + f; f += (size_t)KS * BL * 96;
  float* hend   = ws + f; f += (size_t)BB * CH * D_INNER * D_STATE;
  float* opart  = ws + f; f += (size_t)KSO * BL * D_MODEL;
  unsigned short* hh  = (unsigned short*)(ws + f); f += (size_t)BL * D_MODEL / 2;
  unsigned short* yh  = (unsigned short*)(ws + f); f += (size_t)BL * D_INNER / 2;
  unsigned short* xcb = (unsigned short*)(ws + f); f += (size_t)BL * D_INNER / 2;
  unsigned short* wih = (unsigned short*)(ws + f);
  f += (size_t)N_LAYERS * 2 * D_INNER * D_MODEL / 2;
  unsigned short* woh = (unsigned short*)(ws + f);
  f += (size_t)N_LAYERS * D_MODEL * D_INNER / 2;
  unsigned short* xz  = (unsigned short*)xzf;
  unsigned short* dtb = (unsigned short*)dty;
  float* sumdt = xpart;

  round_k<<<(N_LAYERS * 2 * D_INNER * D_MODEL) / 1024, 256, 0, stream>>>(inw, wih);
  round_k<<<(N_LAYERS * D_MODEL * D_INNER) / 1024, 256, 0, stream>>>(outw, woh);
  layernorm_bf16_k<<<BL, 256, 0, stream>>>(x0, ln1w, ln1b, hh);

  for (int layer = 0; layer < N_LAYERS; ++layer) {
    const unsigned short* wi = wih + (size_t)layer * 2 * D_INNER * D_MODEL;
    const unsigned short* wo = woh + (size_t)layer * D_MODEL * D_INNER;
    // xz = h @ in_w^T : 4096x4096x1024, 256² counted-vmcnt pipeline, bf16 out
    mfma_gemm256_nt<<<dim3(16, 16), 512, 0, stream>>>(
        hh, wi, xz, D_MODEL, 2 * D_INNER);
    conv_silu_k<<<(BL * D_INNER / 4) / 256, 256, 0, stream>>>(
        xz, convw + layer * D_INNER * D_CONV, convb + layer * D_INNER, xcb);
    sgemm_splitk_k<<<dim3(96 / 32, 4096 / 64, KS), 256, 0, stream>>>(
        xcb, xpw + (size_t)layer * 96 * D_INNER, xpart);
    xproj_reduce_k<<<(BL * 96) / 256, 256, 0, stream>>>(xpart, xdbl);
    sgemm_nt<64,64,64,4,4,1><<<dim3(2048 / 64, 4096 / 64), 256, 0, stream>>>(
        xdbl, dtpw + (size_t)layer * D_INNER * DT_RANK, dtb,
        BL, D_INNER, DT_RANK, 96, DT_RANK, D_INNER,
        dtpb + layer * D_INNER);
    scan_pass1_k<<<dim3(D_INNER / 256, CH, BB), 256, 0, stream>>>(
        dtb, xcb, xdbl, Alog + (size_t)layer * D_INNER * D_STATE, hend, sumdt);
    scan_fix_k<<<(BB * D_INNER * D_STATE) / 256, 256, 0, stream>>>(
        hend, sumdt, Alog + (size_t)layer * D_INNER * D_STATE);
    scan_pass3_k<<<dim3(D_INNER / 256, CH, BB), 256, 0, stream>>>(
        dtb, xcb, xdbl, xz, hend, Alog + (size_t)layer * D_INNER * D_STATE,
        Dp + layer * D_INNER, yh);
    mfma_gemm_nt<1, KSO><<<dim3(1024 / 128, 4096 / 128, KSO), 256, 0, stream>>>(
        yh, wo, opart, BL, D_MODEL, D_INNER, D_MODEL);
    const float* Xin = (layer == 0) ? x0 : X;
    if (layer + 1 < N_LAYERS) {
      oreduce_ln_k<0><<<BL, 256, 0, stream>>>(
          opart, Xin, X, ln1w + (layer + 1) * D_MODEL,
          ln1b + (layer + 1) * D_MODEL, hh);
    } else {
      oreduce_ln_k<1><<<BL, 256, 0, stream>>>(opart, Xin, X, normw, normb, dty);
    }
  }

  pool1_k<<<dim3(D_MODEL / 256, BB, 16), 256, 0, stream>>>(dty, pooldp);
  pool2_k<<<dim3(D_MODEL / 256, BB), 256, 0, stream>>>(pooldp, pooled);
  head_k<<<BB * N_CLASSES, 64, 0, stream>>>(pooled, headw, headb, (float*)d_out);
}

// Round 14
// 553.051 us; speedup vs baseline: 5.6926x; 1.0319x over previous
//
#include <hip/hip_runtime.h>
#include <hip/hip_bf16.h>

#define N_LAYERS 2
#define D_MODEL 1024
#define D_INNER 2048
#define D_STATE 16
#define D_CONV 4
#define DT_RANK 64
#define N_CLASSES 10
#define BB 4
#define LL 1024
#define BL (BB*LL)   // 4096 rows
#define CH 32        // scan chunks per sequence
#define CLEN (LL/CH) // 32 steps per chunk
#define KS 8         // split-K segments for x_proj
#define KSO 2        // split-K segments for out_proj

typedef __attribute__((ext_vector_type(8))) short bf16x8;
typedef __attribute__((ext_vector_type(8))) unsigned short us8;
typedef __attribute__((ext_vector_type(4))) float f32x4;

typedef const void __attribute__((address_space(1)))* gas_ptr;
typedef void __attribute__((address_space(3)))* las_ptr;
#define GLDS16(g, p) __builtin_amdgcn_global_load_lds((gas_ptr)(g), (las_ptr)(p), 16, 0, 0)

__device__ inline unsigned short rnd_bf16(float x) {
  unsigned u = __float_as_uint(x);
  return (unsigned short)((u + 0x7FFFu + ((u >> 16) & 1u)) >> 16);
}
__device__ inline float b2f(unsigned short u) {
  return __uint_as_float(((unsigned)u) << 16);
}

// round weights to bf16
__global__ __launch_bounds__(256) void round_k(const float* __restrict__ in,
    unsigned short* __restrict__ hi) {
  const int i = blockIdx.x * 256 + threadIdx.x;
  const float4 v = ((const float4*)in)[i];
  ushort4 h4;
  h4.x = rnd_bf16(v.x); h4.y = rnd_bf16(v.y);
  h4.z = rnd_bf16(v.z); h4.w = rnd_bf16(v.w);
  ((ushort4*)hi)[i] = h4;
}

// ---------------- LayerNorm -> bf16 out ---------------------------------------
__global__ __launch_bounds__(256) void layernorm_bf16_k(const float* __restrict__ x,
    const float* __restrict__ w, const float* __restrict__ b,
    unsigned short* __restrict__ oh) {
  const int row = blockIdx.x;
  const int t = threadIdx.x;
  const float4 v = *(const float4*)(x + (size_t)row * D_MODEL + t * 4);
  float s = v.x + v.y + v.z + v.w;
  float q = v.x*v.x + v.y*v.y + v.z*v.z + v.w*v.w;
  #pragma unroll
  for (int o = 32; o; o >>= 1) { s += __shfl_down(s, o); q += __shfl_down(q, o); }
  __shared__ float red[8];
  if ((t & 63) == 0) { red[t >> 6] = s; red[4 + (t >> 6)] = q; }
  __syncthreads();
  s = red[0] + red[1] + red[2] + red[3];
  q = red[4] + red[5] + red[6] + red[7];
  const float mean = s * (1.f / D_MODEL);
  const float var  = q * (1.f / D_MODEL) - mean * mean;
  const float rstd = rsqrtf(var + 1e-5f);
  const float4 wv = *(const float4*)(w + t * 4);
  const float4 bv = *(const float4*)(b + t * 4);
  ushort4 h4;
  h4.x = rnd_bf16((v.x - mean) * rstd * wv.x + bv.x);
  h4.y = rnd_bf16((v.y - mean) * rstd * wv.y + bv.y);
  h4.z = rnd_bf16((v.z - mean) * rstd * wv.z + bv.z);
  h4.w = rnd_bf16((v.w - mean) * rstd * wv.w + bv.w);
  ((ushort4*)(oh + (size_t)row * D_MODEL))[t] = h4;
}

// ---- fused: Xout = Xin + sum(out_proj partials); then LayerNorm -> operand ---
template<int OUT>
__global__ __launch_bounds__(256) void oreduce_ln_k(
    const float* __restrict__ part, const float* __restrict__ Xin,
    float* __restrict__ Xout,
    const float* __restrict__ w, const float* __restrict__ b,
    void* __restrict__ out) {
  const int row = blockIdx.x;
  const int t = threadIdx.x;
  float4 v = *(const float4*)(Xin + (size_t)row * D_MODEL + t * 4);
  #pragma unroll
  for (int k = 0; k < KSO; k++) {
    const float4 p = *(const float4*)(part + (size_t)k * BL * D_MODEL
                                      + (size_t)row * D_MODEL + t * 4);
    v.x += p.x; v.y += p.y; v.z += p.z; v.w += p.w;
  }
  *(float4*)(Xout + (size_t)row * D_MODEL + t * 4) = v;   // residual stream
  float s = v.x + v.y + v.z + v.w;
  float q = v.x*v.x + v.y*v.y + v.z*v.z + v.w*v.w;
  #pragma unroll
  for (int o = 32; o; o >>= 1) { s += __shfl_down(s, o); q += __shfl_down(q, o); }
  __shared__ float red[8];
  if ((t & 63) == 0) { red[t >> 6] = s; red[4 + (t >> 6)] = q; }
  __syncthreads();
  s = red[0] + red[1] + red[2] + red[3];
  q = red[4] + red[5] + red[6] + red[7];
  const float mean = s * (1.f / D_MODEL);
  const float var  = q * (1.f / D_MODEL) - mean * mean;
  const float rstd = rsqrtf(var + 1e-5f);
  const float4 wv = *(const float4*)(w + t * 4);
  const float4 bv = *(const float4*)(b + t * 4);
  float4 o4;
  o4.x = (v.x - mean) * rstd * wv.x + bv.x;
  o4.y = (v.y - mean) * rstd * wv.y + bv.y;
  o4.z = (v.z - mean) * rstd * wv.z + bv.z;
  o4.w = (v.w - mean) * rstd * wv.w + bv.w;
  if constexpr (OUT == 0) {
    ushort4 h4;
    h4.x = rnd_bf16(o4.x); h4.y = rnd_bf16(o4.y);
    h4.z = rnd_bf16(o4.z); h4.w = rnd_bf16(o4.w);
    ((ushort4*)((unsigned short*)out + (size_t)row * D_MODEL))[t] = h4;
  } else {
    *(float4*)((float*)out + (size_t)row * D_MODEL + t * 4) = o4;
  }
}

// ==== 256x256 bf16 MFMA GEMM NT — counted-vmcnt pipeline (in_proj only) ======
__global__ __launch_bounds__(512) void mfma_gemm256_nt(
    const unsigned short* __restrict__ A, const unsigned short* __restrict__ B,
    unsigned short* __restrict__ C, int K, int ldc) {
  __shared__ unsigned short S[65536];   // [buf:2][mat:2][256*64] bf16 = 128 KB
  const int tid = threadIdx.x;
  const int l = tid & 63;
  const int w = tid >> 6;
  const int wm = w >> 2, wn = w & 3;
  const int bid = blockIdx.y * 16 + blockIdx.x;
  const int x = bid & 7, v = bid >> 3;
  const int bx = (x & 1) * 8 + (v & 7);
  const int by = (x >> 1) * 4 + (v >> 3);
  const int m0 = by * 256, n0 = bx * 256;
  const int nkt = K >> 6;
  const int r8 = (tid >> 3) & 7;
  const int c16s = (tid & 7) ^ r8;

  auto stage1 = [&](int kt, int mat, int half) {
    const unsigned short* base = (mat == 0) ? (A + (size_t)m0 * K)
                                            : (B + (size_t)n0 * K);
    unsigned short* dst = S + ((kt & 1) * 32768 + mat * 16384 + half * 8192);
    #pragma unroll
    for (int e = 0; e < 2; ++e) {
      const int row = half * 128 + e * 64 + (tid >> 3);
      GLDS16(base + (size_t)row * K + kt * 64 + c16s * 8,
             dst + e * 4096 + tid * 8);
    }
  };
  auto stage_full = [&](int kt) {
    stage1(kt, 0, 0); stage1(kt, 0, 1); stage1(kt, 1, 0); stage1(kt, 1, 1);
  };

  stage_full(0);
  if (nkt > 1) stage_full(1);

  f32x4 acc[8][4] = {};
  const int fr = l & 15;
  const int fk8 = l >> 4;

  #pragma unroll 1
  for (int kt = 0; kt < nkt; ++kt) {
    if (kt + 1 < nkt) asm volatile("s_waitcnt vmcnt(8)" ::: "memory");
    else              asm volatile("s_waitcnt vmcnt(0)" ::: "memory");
    __builtin_amdgcn_s_barrier();
    __builtin_amdgcn_sched_barrier(0);
    const unsigned short* SA = S + (kt & 1) * 32768;
    const unsigned short* SB = SA + 16384;
    #pragma unroll
    for (int kk8 = 0; kk8 < 8; kk8 += 4) {
      bf16x8 av[8], bv[4];
      const int c8 = kk8 + fk8;
      #pragma unroll
      for (int i = 0; i < 8; ++i) {
        const int R = wm * 128 + i * 16 + fr;
        av[i] = *(const bf16x8*)&SA[R * 64 + ((c8 ^ (R & 7)) << 3)];
      }
      #pragma unroll
      for (int j = 0; j < 4; ++j) {
        const int R = wn * 64 + j * 16 + fr;
        bv[j] = *(const bf16x8*)&SB[R * 64 + ((c8 ^ (R & 7)) << 3)];
      }
      __builtin_amdgcn_s_setprio(1);
      #pragma unroll
      for (int i = 0; i < 8; ++i)
        #pragma unroll
        for (int j = 0; j < 4; ++j)
          acc[i][j] = __builtin_amdgcn_mfma_f32_16x16x32_bf16(
              av[i], bv[j], acc[i][j], 0, 0, 0);
      __builtin_amdgcn_s_setprio(0);
    }
    __builtin_amdgcn_s_barrier();
    __builtin_amdgcn_sched_barrier(0);
    if (kt + 2 < nkt) stage_full(kt + 2);
  }

  const int orow = (l >> 4) * 4, ocol = l & 15;
  #pragma unroll
  for (int i = 0; i < 8; ++i)
    #pragma unroll
    for (int j = 0; j < 4; ++j)
      #pragma unroll
      for (int r = 0; r < 4; ++r) {
        const int m = m0 + wm * 128 + i * 16 + orow + r;
        const int n = n0 + wn * 64 + j * 16 + ocol;
        C[(size_t)m * ldc + n] = rnd_bf16(acc[i][j][r]);
      }
}

// ---- bf16 MFMA GEMM NT 128² -------------------------------------------------
// EPI 0: bf16 store. EPI 1: fp32 partials at C+kz*M*ldc. EPI 2: softplus+bias
// -> bf16 store (dt GEMM).
template<int EPI, int KSEG>
__global__ __launch_bounds__(256) void mfma_gemm_nt(
    const unsigned short* __restrict__ Ah, const unsigned short* __restrict__ Bh,
    void* __restrict__ Cv, int M, int N, int K, int ldc,
    const float* __restrict__ bias) {
  __shared__ unsigned short As[128 * 64];
  __shared__ unsigned short Bs[128 * 64];
  const int tid = threadIdx.x;
  const int w = tid >> 6, l = tid & 63;
  const int wr = w >> 1, wc = w & 1;
  const int nbx = gridDim.x;
  const int nwg = nbx * gridDim.y;
  int bid = blockIdx.y * nbx + blockIdx.x;
  bid = (bid & 7) * (nwg >> 3) + (bid >> 3);
  const int st = bid >> 6, wi = bid & 63;
  const int stpr = (nbx >= 8) ? (nbx >> 3) : 1;
  int n0, m0;
  if (nbx >= 8) {
    n0 = ((st % stpr) * 8 + (wi & 7)) * 128;
    m0 = ((st / stpr) * 8 + (wi >> 3)) * 128;
  } else {
    n0 = (bid % nbx) * 128;
    m0 = (bid / nbx) * 128;
  }
  const int kz = (KSEG > 1) ? blockIdx.z : 0;
  const int kbeg = kz * (K / KSEG);
  const int kend = kbeg + K / KSEG;
  const int srow = l >> 3;
  const int scol = (l & 7) * 8;
  const int fr = l & 15;
  const int fk = (l >> 4) * 8;
  f32x4 acc[4][4] = {};

  #pragma unroll 1
  for (int k0 = kbeg; k0 < kend; k0 += 64) {
    __syncthreads();
    #pragma unroll
    for (int it = 0; it < 4; ++it) {
      const int bi = it * 4 + w;
      const int row = bi * 8 + srow;
      GLDS16(Ah + (size_t)(m0 + row) * K + k0 + scol, &As[bi * 512 + l * 8]);
      GLDS16(Bh + (size_t)(n0 + row) * K + k0 + scol, &Bs[bi * 512 + l * 8]);
    }
    __syncthreads();
    #pragma unroll
    for (int kk = 0; kk < 64; kk += 32) {
      bf16x8 a[4], b[4];
      #pragma unroll
      for (int f = 0; f < 4; ++f)
        b[f] = *(const bf16x8*)&Bs[(wc * 64 + f * 16 + fr) * 64 + kk + fk];
      #pragma unroll
      for (int f = 0; f < 4; ++f)
        a[f] = *(const bf16x8*)&As[(wr * 64 + f * 16 + fr) * 64 + kk + fk];
      #pragma unroll
      for (int i = 0; i < 4; ++i)
        #pragma unroll
        for (int j = 0; j < 4; ++j)
          acc[i][j] = __builtin_amdgcn_mfma_f32_16x16x32_bf16(
              a[i], b[j], acc[i][j], 0, 0, 0);
    }
  }
  const int orow = (l >> 4) * 4;
  const int ocol = l & 15;
  if constexpr (EPI == 0 || EPI == 2) {
    unsigned short* Cw = (unsigned short*)Cv;
    #pragma unroll
    for (int i = 0; i < 4; ++i)
      #pragma unroll
      for (int j = 0; j < 4; ++j)
        #pragma unroll
        for (int r = 0; r < 4; ++r) {
          const int m = m0 + wr * 64 + i * 16 + orow + r;
          const int n = n0 + wc * 64 + j * 16 + ocol;
          float vv = acc[i][j][r];
          if constexpr (EPI == 2) {
            vv += bias[n];
            vv = (vv > 20.f) ? vv : log1pf(__expf(vv));
          }
          Cw[(size_t)m * ldc + n] = rnd_bf16(vv);
        }
  } else {
    float* Cw = (float*)Cv + (size_t)kz * M * ldc;
    #pragma unroll
    for (int i = 0; i < 4; ++i)
      #pragma unroll
      for (int j = 0; j < 4; ++j)
        #pragma unroll
        for (int r = 0; r < 4; ++r) {
          const int m = m0 + wr * 64 + i * 16 + orow + r;
          const int n = n0 + wc * 64 + j * 16 + ocol;
          Cw[(size_t)m * ldc + n] = acc[i][j][r];
        }
  }
}

// ---- x_proj split-K (bf16 A) ------------------------------------------------
__global__ __launch_bounds__(256) void sgemm_splitk_k(
    const unsigned short* __restrict__ A, const float* __restrict__ B,
    float* __restrict__ part) {
  __shared__ float As[32][64 + 4];
  __shared__ float Bs[32][32 + 4];
  const int tid = threadIdx.x;
  const int n0 = blockIdx.x * 32;
  const int m0 = blockIdx.y * 64;
  const int kz = blockIdx.z;
  const int tn = (tid & 15) * 2;
  const int tm = (tid >> 4) * 4;
  float acc[4][2] = {};
  for (int kb = 0; kb < 256; kb += 32) {
    const int k0 = kz * 256 + kb;
    {
      int r = tid >> 2, c8 = (tid & 3) * 8;
      us8 u = *(const us8*)(A + (size_t)(m0 + r) * D_INNER + k0 + c8);
      #pragma unroll
      for (int j = 0; j < 8; j++) As[c8 + j][r] = b2f((unsigned short)u[j]);
    }
    {
      int r = tid >> 3, c4 = tid & 7;
      float4 v = *(const float4*)(B + (size_t)(n0 + r) * D_INNER + k0 + c4 * 4);
      Bs[c4*4+0][r] = v.x; Bs[c4*4+1][r] = v.y;
      Bs[c4*4+2][r] = v.z; Bs[c4*4+3][r] = v.w;
    }
    __syncthreads();
    #pragma unroll
    for (int k = 0; k < 32; k++) {
      float a[4], bf[2];
      #pragma unroll
      for (int i = 0; i < 4; i++) a[i] = As[k][tm + i];
      bf[0] = Bs[k][tn]; bf[1] = Bs[k][tn + 1];
      #pragma unroll
      for (int i = 0; i < 4; i++) {
        acc[i][0] = fmaf(a[i], bf[0], acc[i][0]);
        acc[i][1] = fmaf(a[i], bf[1], acc[i][1]);
      }
    }
    __syncthreads();
  }
  float* p = part + (size_t)kz * BL * 96;
  #pragma unroll
  for (int i = 0; i < 4; i++) {
    const int m = m0 + tm + i;
    p[(size_t)m * 96 + n0 + tn]     = acc[i][0];
    p[(size_t)m * 96 + n0 + tn + 1] = acc[i][1];
  }
}

// reduce KS partials; split: cols 0..63 -> bf16 dtr[BL][64], 64..95 -> fp32 bc[BL][32]
__global__ __launch_bounds__(256) void xproj_reduce_k(
    const float* __restrict__ part, unsigned short* __restrict__ dtr,
    float* __restrict__ bc) {
  const int i = blockIdx.x * 256 + threadIdx.x;   // over BL*96
  const int m = i / 96, col = i % 96;
  float s = 0.f;
  #pragma unroll
  for (int k = 0; k < KS; k++) s += part[(size_t)k * BL * 96 + i];
  if (col < DT_RANK) dtr[(size_t)m * DT_RANK + col] = rnd_bf16(s);
  else               bc[(size_t)m * 32 + (col - DT_RANK)] = s;
}

// ------ causal depthwise conv + SiLU, bf16 in / bf16 out ----------------------
__global__ __launch_bounds__(256) void conv_silu_k(
    const unsigned short* __restrict__ xz,
    const float* __restrict__ cw, const float* __restrict__ cb,
    unsigned short* __restrict__ xc) {
  const int gid = blockIdx.x * 256 + threadIdx.x;
  const int c4 = (gid & (D_INNER / 4 - 1)) << 2;
  const int row = gid >> 9;
  const int l = row & (LL - 1);
  const unsigned short* base = xz + (size_t)row * (2 * D_INNER) + c4;
  const float4 w0 = *(const float4*)(cw + (c4 + 0) * 4);
  const float4 w1 = *(const float4*)(cw + (c4 + 1) * 4);
  const float4 w2 = *(const float4*)(cw + (c4 + 2) * 4);
  const float4 w3 = *(const float4*)(cw + (c4 + 3) * 4);
  float4 acc = *(const float4*)(cb + c4);
  ushort4 uv = *(const ushort4*)base;
  acc.x = fmaf(w0.w, b2f(uv.x), acc.x); acc.y = fmaf(w1.w, b2f(uv.y), acc.y);
  acc.z = fmaf(w2.w, b2f(uv.z), acc.z); acc.w = fmaf(w3.w, b2f(uv.w), acc.w);
  if (l >= 1) {
    uv = *(const ushort4*)(base - 2 * D_INNER);
    acc.x = fmaf(w0.z, b2f(uv.x), acc.x); acc.y = fmaf(w1.z, b2f(uv.y), acc.y);
    acc.z = fmaf(w2.z, b2f(uv.z), acc.z); acc.w = fmaf(w3.z, b2f(uv.w), acc.w);
  }
  if (l >= 2) {
    uv = *(const ushort4*)(base - 4 * D_INNER);
    acc.x = fmaf(w0.y, b2f(uv.x), acc.x); acc.y = fmaf(w1.y, b2f(uv.y), acc.y);
    acc.z = fmaf(w2.y, b2f(uv.z), acc.z); acc.w = fmaf(w3.y, b2f(uv.w), acc.w);
  }
  if (l >= 3) {
    uv = *(const ushort4*)(base - 6 * D_INNER);
    acc.x = fmaf(w0.x, b2f(uv.x), acc.x); acc.y = fmaf(w1.x, b2f(uv.y), acc.y);
    acc.z = fmaf(w2.x, b2f(uv.z), acc.z); acc.w = fmaf(w3.x, b2f(uv.w), acc.w);
  }
  ushort4 o4;
  o4.x = rnd_bf16(acc.x / (1.f + __expf(-acc.x)));
  o4.y = rnd_bf16(acc.y / (1.f + __expf(-acc.y)));
  o4.z = rnd_bf16(acc.z / (1.f + __expf(-acc.z)));
  o4.w = rnd_bf16(acc.w / (1.f + __expf(-acc.w)));
  *(ushort4*)(xc + (size_t)row * D_INNER + c4) = o4;
}

// ------- chunked selective scan, pass 1 (bf16 dt/xc, bc stride 32) ------------
__global__ __launch_bounds__(256) void scan_pass1_k(
    const unsigned short* __restrict__ dt, const unsigned short* __restrict__ xc,
    const float* __restrict__ bc, const float* __restrict__ A_log,
    float* __restrict__ hend, float* __restrict__ sumdt) {
  const int c = blockIdx.x * 256 + threadIdx.x;
  const int k = blockIdx.y;
  const int b = blockIdx.z;
  float Ac[D_STATE];
  #pragma unroll
  for (int n = 0; n < D_STATE; n++) Ac[n] = -__expf(A_log[c * D_STATE + n]);
  float h[D_STATE] = {};
  float sd = 0.f;
  const size_t r0 = (size_t)b * LL + (size_t)k * CLEN;
  const unsigned short* dtp = dt + r0 * D_INNER + c;
  const unsigned short* xcp = xc + r0 * D_INNER + c;
  const float* Bp  = bc + r0 * 32;

  float dtv = b2f(dtp[0]);
  float xv  = b2f(xcp[0]);
  float4 B0 = *(const float4*)(Bp + 0);
  float4 B1 = *(const float4*)(Bp + 4);
  float4 B2 = *(const float4*)(Bp + 8);
  float4 B3 = *(const float4*)(Bp + 12);
  for (int l = 0; l < CLEN; l++) {
    const int lp = (l + 1 < CLEN) ? l + 1 : l;
    const float dtv2 = b2f(dtp[(size_t)lp * D_INNER]);
    const float xv2  = b2f(xcp[(size_t)lp * D_INNER]);
    const float4 B0n = *(const float4*)(Bp + (size_t)lp * 32 + 0);
    const float4 B1n = *(const float4*)(Bp + (size_t)lp * 32 + 4);
    const float4 B2n = *(const float4*)(Bp + (size_t)lp * 32 + 8);
    const float4 B3n = *(const float4*)(Bp + (size_t)lp * 32 + 12);
    sd += dtv;
    const float dx = dtv * xv;
    const float Bv[D_STATE] = {B0.x,B0.y,B0.z,B0.w, B1.x,B1.y,B1.z,B1.w,
                               B2.x,B2.y,B2.z,B2.w, B3.x,B3.y,B3.z,B3.w};
    #pragma unroll
    for (int n = 0; n < D_STATE; n++)
      h[n] = fmaf(__expf(dtv * Ac[n]), h[n], dx * Bv[n]);
    dtv = dtv2; xv = xv2; B0 = B0n; B1 = B1n; B2 = B2n; B3 = B3n;
  }
  float* he = hend + (((size_t)(b * CH + k) * D_INNER + c) << 4);
  #pragma unroll
  for (int n = 0; n < D_STATE; n += 4)
    *(float4*)(he + n) = make_float4(h[n], h[n+1], h[n+2], h[n+3]);
  sumdt[(size_t)(b * CH + k) * D_INNER + c] = sd;
}

// ------- chunked scan fixup ---------------------------------------------------
__global__ __launch_bounds__(256) void scan_fix_k(
    float* __restrict__ hend, const float* __restrict__ sumdt,
    const float* __restrict__ A_log) {
  const int gid = blockIdx.x * 256 + threadIdx.x;
  const int n = gid & 15;
  const int c = (gid >> 4) & (D_INNER - 1);
  const int b = gid >> 15;
  const float Ac = -__expf(A_log[c * D_STATE + n]);
  float hrun = 0.f;
  for (int k = 0; k < CH; k++) {
    const size_t base = (size_t)(b * CH + k) * D_INNER + c;
    const float sd = sumdt[base];
    float* hp = hend + (base << 4) + n;
    const float tmp = *hp;
    *hp = hrun;
    hrun = fmaf(__expf(Ac * sd), hrun, tmp);
  }
}

// ------- chunked scan pass 3 (bc stride 32) ------------------------------------
__global__ __launch_bounds__(256) void scan_pass3_k(
    const unsigned short* __restrict__ dt, const unsigned short* __restrict__ xc,
    const float* __restrict__ bc, const unsigned short* __restrict__ xz,
    const float* __restrict__ h0, const float* __restrict__ A_log,
    const float* __restrict__ Dp, unsigned short* __restrict__ yh) {
  const int c = blockIdx.x * 256 + threadIdx.x;
  const int k = blockIdx.y;
  const int b = blockIdx.z;
  float Ac[D_STATE];
  #pragma unroll
  for (int n = 0; n < D_STATE; n++) Ac[n] = -__expf(A_log[c * D_STATE + n]);
  const float Dv = Dp[c];
  float h[D_STATE];
  const float* hp = h0 + (((size_t)(b * CH + k) * D_INNER + c) << 4);
  #pragma unroll
  for (int n = 0; n < D_STATE; n += 4) {
    const float4 v = *(const float4*)(hp + n);
    h[n] = v.x; h[n+1] = v.y; h[n+2] = v.z; h[n+3] = v.w;
  }
  const size_t r0 = (size_t)b * LL + (size_t)k * CLEN;
  const unsigned short* dtp = dt + r0 * D_INNER + c;
  const unsigned short* xcp = xc + r0 * D_INNER + c;
  const float* Bp  = bc + r0 * 32;
  const unsigned short* zp = xz + r0 * (size_t)(2 * D_INNER) + D_INNER + c;
  unsigned short* yhp = yh + r0 * D_INNER + c;

  float dtv = b2f(dtp[0]);
  float xv  = b2f(xcp[0]);
  float zv  = b2f(zp[0]);
  float4 B0 = *(const float4*)(Bp + 0);
  float4 B1 = *(const float4*)(Bp + 4);
  float4 B2 = *(const float4*)(Bp + 8);
  float4 B3 = *(const float4*)(Bp + 12);
  float4 C0 = *(const float4*)(Bp + 16);
  float4 C1 = *(const float4*)(Bp + 20);
  float4 C2 = *(const float4*)(Bp + 24);
  float4 C3 = *(const float4*)(Bp + 28);
  for (int l = 0; l < CLEN; l++) {
    const int lp = (l + 1 < CLEN) ? l + 1 : l;
    const float dtv2 = b2f(dtp[(size_t)lp * D_INNER]);
    const float xv2  = b2f(xcp[(size_t)lp * D_INNER]);
    const float zv2  = b2f(zp[(size_t)lp * 2 * D_INNER]);
    const float4 B0n = *(const float4*)(Bp + (size_t)lp * 32 + 0);
    const float4 B1n = *(const float4*)(Bp + (size_t)lp * 32 + 4);
    const float4 B2n = *(const float4*)(Bp + (size_t)lp * 32 + 8);
    const float4 B3n = *(const float4*)(Bp + (size_t)lp * 32 + 12);
    const float4 C0n = *(const float4*)(Bp + (size_t)lp * 32 + 16);
    const float4 C1n = *(const float4*)(Bp + (size_t)lp * 32 + 20);
    const float4 C2n = *(const float4*)(Bp + (size_t)lp * 32 + 24);
    const float4 C3n = *(const float4*)(Bp + (size_t)lp * 32 + 28);
    const float dx = dtv * xv;
    const float Bv[D_STATE] = {B0.x,B0.y,B0.z,B0.w, B1.x,B1.y,B1.z,B1.w,
                               B2.x,B2.y,B2.z,B2.w, B3.x,B3.y,B3.z,B3.w};
    const float Cv[D_STATE] = {C0.x,C0.y,C0.z,C0.w, C1.x,C1.y,C1.z,C1.w,
                               C2.x,C2.y,C2.z,C2.w, C3.x,C3.y,C3.z,C3.w};
    float y = 0.f;
    #pragma unroll
    for (int n = 0; n < D_STATE; n++) {
      h[n] = fmaf(__expf(dtv * Ac[n]), h[n], dx * Bv[n]);
      y = fmaf(h[n], Cv[n], y);
    }
    y = fmaf(xv, Dv, y);
    y *= zv / (1.f + __expf(-zv));
    yhp[(size_t)l * D_INNER] = rnd_bf16(y);
    dtv = dtv2; xv = xv2; zv = zv2;
    B0 = B0n; B1 = B1n; B2 = B2n; B3 = B3n;
    C0 = C0n; C1 = C1n; C2 = C2n; C3 = C3n;
  }
}

// ---------------- mean pool over L, two-stage ---------------------------------
__global__ __launch_bounds__(256) void pool1_k(const float* __restrict__ h,
    float* __restrict__ pp) {
  const int d = blockIdx.x * 256 + threadIdx.x;
  const int b = blockIdx.y;
  const int seg = blockIdx.z;
  float s = 0.f;
  const size_t base = (size_t)b * LL + (size_t)seg * 64;
  for (int l = 0; l < 64; l++) s += h[(base + l) * D_MODEL + d];
  pp[((size_t)(b * 16 + seg)) * D_MODEL + d] = s;
}
__global__ __launch_bounds__(256) void pool2_k(const float* __restrict__ pp,
    float* __restrict__ pooled) {
  const int d = blockIdx.x * 256 + threadIdx.x;
  const int b = blockIdx.y;
  float s = 0.f;
  #pragma unroll
  for (int k = 0; k < 16; k++) s += pp[((size_t)(b * 16 + k)) * D_MODEL + d];
  pooled[b * D_MODEL + d] = s * (1.f / LL);
}

// ---------------- classifier head --------------------------------------------
__global__ __launch_bounds__(64) void head_k(const float* __restrict__ pooled,
    const float* __restrict__ hw, const float* __restrict__ hb,
    float* __restrict__ out) {
  const int b = blockIdx.x / N_CLASSES;
  const int j = blockIdx.x % N_CLASSES;
  float s = 0.f;
  for (int k = threadIdx.x; k < D_MODEL; k += 64)
    s = fmaf(pooled[b * D_MODEL + k], hw[j * D_MODEL + k], s);
  #pragma unroll
  for (int o = 32; o; o >>= 1) s += __shfl_down(s, o);
  if (threadIdx.x == 0) out[b * N_CLASSES + j] = s + hb[j];
}

extern "C" void kernel_launch(void* const* d_in, const int* in_sizes, int n_in,
                              void* d_out, int out_size, void* d_ws, size_t ws_size,
                              hipStream_t stream) {
  const float* x0    = (const float*)d_in[0];
  const float* ln1w  = (const float*)d_in[1];
  const float* ln1b  = (const float*)d_in[2];
  const float* inw   = (const float*)d_in[3];
  const float* convw = (const float*)d_in[4];
  const float* convb = (const float*)d_in[5];
  const float* xpw   = (const float*)d_in[6];
  const float* dtpw  = (const float*)d_in[7];
  const float* dtpb  = (const float*)d_in[8];
  const float* Alog  = (const float*)d_in[9];
  const float* Dp    = (const float*)d_in[10];
  const float* outw  = (const float*)d_in[11];
  const float* normw = (const float*)d_in[12];
  const float* normb = (const float*)d_in[13];
  const float* headw = (const float*)d_in[14];
  const float* headb = (const float*)d_in[15];

  float* ws = (float*)d_ws;
  size_t f = 0;
  float* X      = ws + f; f += (size_t)BL * D_MODEL;
  float* xzf    = ws + f; f += (size_t)BL * D_INNER;
  float* bc     = ws + f; f += (size_t)BL * 32;
  float* dty    = ws + f; f += (size_t)BL * D_INNER;
  float* pooled = ws + f; f += 4096;
  float* pooldp = ws + f; f += (size_t)16 * BB * D_MODEL;
  float* xpart  = ws + f; f += (size_t)KS * BL * 96;
  float* hend   = ws + f; f += (size_t)BB * CH * D_INNER * D_STATE;
  float* opart  = ws + f; f += (size_t)KSO * BL * D_MODEL;
  unsigned short* hh  = (unsigned short*)(ws + f); f += (size_t)BL * D_MODEL / 2;
  unsigned short* yh  = (unsigned short*)(ws + f); f += (size_t)BL * D_INNER / 2;
  unsigned short* xcb = (unsigned short*)(ws + f); f += (size_t)BL * D_INNER / 2;
  unsigned short* dtr = (unsigned short*)(ws + f); f += (size_t)BL * DT_RANK / 2;
  unsigned short* wih = (unsigned short*)(ws + f);
  f += (size_t)N_LAYERS * 2 * D_INNER * D_MODEL / 2;
  unsigned short* woh = (unsigned short*)(ws + f);
  f += (size_t)N_LAYERS * D_MODEL * D_INNER / 2;
  unsigned short* wdt = (unsigned short*)(ws + f);
  f += (size_t)N_LAYERS * D_INNER * DT_RANK / 2;
  unsigned short* xz  = (unsigned short*)xzf;
  unsigned short* dtb = (unsigned short*)dty;
  float* sumdt = xpart;

  round_k<<<(N_LAYERS * 2 * D_INNER * D_MODEL) / 1024, 256, 0, stream>>>(inw, wih);
  round_k<<<(N_LAYERS * D_MODEL * D_INNER) / 1024, 256, 0, stream>>>(outw, woh);
  round_k<<<(N_LAYERS * D_INNER * DT_RANK) / 1024, 256, 0, stream>>>(dtpw, wdt);
  layernorm_bf16_k<<<BL, 256, 0, stream>>>(x0, ln1w, ln1b, hh);

  for (int layer = 0; layer < N_LAYERS; ++layer) {
    const unsigned short* wi = wih + (size_t)layer * 2 * D_INNER * D_MODEL;
    const unsigned short* wo = woh + (size_t)layer * D_MODEL * D_INNER;
    const unsigned short* wd = wdt + (size_t)layer * D_INNER * DT_RANK;
    // xz = h @ in_w^T : 4096x4096x1024, 256² counted-vmcnt pipeline, bf16 out
    mfma_gemm256_nt<<<dim3(16, 16), 512, 0, stream>>>(
        hh, wi, xz, D_MODEL, 2 * D_INNER);
    conv_silu_k<<<(BL * D_INNER / 4) / 256, 256, 0, stream>>>(
        xz, convw + layer * D_INNER * D_CONV, convb + layer * D_INNER, xcb);
    // x_dbl = xc @ xp_w^T : split-K + split reduce -> dtr (bf16) + bc (fp32)
    sgemm_splitk_k<<<dim3(96 / 32, 4096 / 64, KS), 256, 0, stream>>>(
        xcb, xpw + (size_t)layer * 96 * D_INNER, xpart);
    xproj_reduce_k<<<(BL * 96) / 256, 256, 0, stream>>>(xpart, dtr, bc);
    // dt = softplus(dt_r @ dtp_w^T + b) : 4096x2048x64, bf16 MFMA, bf16 out
    mfma_gemm_nt<2, 1><<<dim3(2048 / 128, 4096 / 128), 256, 0, stream>>>(
        dtr, wd, dtb, BL, D_INNER, DT_RANK, D_INNER, dtpb + layer * D_INNER);
    // chunked scan (CH=32)
    scan_pass1_k<<<dim3(D_INNER / 256, CH, BB), 256, 0, stream>>>(
        dtb, xcb, bc, Alog + (size_t)layer * D_INNER * D_STATE, hend, sumdt);
    scan_fix_k<<<(BB * D_INNER * D_STATE) / 256, 256, 0, stream>>>(
        hend, sumdt, Alog + (size_t)layer * D_INNER * D_STATE);
    scan_pass3_k<<<dim3(D_INNER / 256, CH, BB), 256, 0, stream>>>(
        dtb, xcb, bc, xz, hend, Alog + (size_t)layer * D_INNER * D_STATE,
        Dp + layer * D_INNER, yh);
    // y @ out_w^T : split-K=2 partials
    mfma_gemm_nt<1, KSO><<<dim3(1024 / 128, 4096 / 128, KSO), 256, 0, stream>>>(
        yh, wo, opart, BL, D_MODEL, D_INNER, D_MODEL, nullptr);
    const float* Xin = (layer == 0) ? x0 : X;
    if (layer + 1 < N_LAYERS) {
      oreduce_ln_k<0><<<BL, 256, 0, stream>>>(
          opart, Xin, X, ln1w + (layer + 1) * D_MODEL,
          ln1b + (layer + 1) * D_MODEL, hh);
    } else {
      oreduce_ln_k<1><<<BL, 256, 0, stream>>>(opart, Xin, X, normw, normb, dty);
    }
  }

  pool1_k<<<dim3(D_MODEL / 256, BB, 16), 256, 0, stream>>>(dty, pooldp);
  pool2_k<<<dim3(D_MODEL / 256, BB), 256, 0, stream>>>(pooldp, pooled);
  head_k<<<BB * N_CLASSES, 64, 0, stream>>>(pooled, headw, headb, (float*)d_out);
}

// Round 15
// 504.901 us; speedup vs baseline: 6.2355x; 1.0954x over previous
//
#include <hip/hip_runtime.h>
#include <hip/hip_bf16.h>

#define N_LAYERS 2
#define D_MODEL 1024
#define D_INNER 2048
#define D_STATE 16
#define D_CONV 4
#define DT_RANK 64
#define N_CLASSES 10
#define BB 4
#define LL 1024
#define BL (BB*LL)   // 4096 rows
#define CH 32        // scan chunks per sequence
#define CLEN (LL/CH) // 32 steps per chunk
#define KS 8         // split-K segments for x_proj
#define KSO 2        // split-K segments for out_proj

typedef __attribute__((ext_vector_type(8))) short bf16x8;
typedef __attribute__((ext_vector_type(8))) unsigned short us8;
typedef __attribute__((ext_vector_type(4))) float f32x4;

typedef const void __attribute__((address_space(1)))* gas_ptr;
typedef void __attribute__((address_space(3)))* las_ptr;
#define GLDS16(g, p) __builtin_amdgcn_global_load_lds((gas_ptr)(g), (las_ptr)(p), 16, 0, 0)

__device__ inline unsigned short rnd_bf16(float x) {
  unsigned u = __float_as_uint(x);
  return (unsigned short)((u + 0x7FFFu + ((u >> 16) & 1u)) >> 16);
}
__device__ inline float b2f(unsigned short u) {
  return __uint_as_float(((unsigned)u) << 16);
}

// round weights to bf16
__global__ __launch_bounds__(256) void round_k(const float* __restrict__ in,
    unsigned short* __restrict__ hi) {
  const int i = blockIdx.x * 256 + threadIdx.x;
  const float4 v = ((const float4*)in)[i];
  ushort4 h4;
  h4.x = rnd_bf16(v.x); h4.y = rnd_bf16(v.y);
  h4.z = rnd_bf16(v.z); h4.w = rnd_bf16(v.w);
  ((ushort4*)hi)[i] = h4;
}

// ---------------- LayerNorm -> bf16 out ---------------------------------------
__global__ __launch_bounds__(256) void layernorm_bf16_k(const float* __restrict__ x,
    const float* __restrict__ w, const float* __restrict__ b,
    unsigned short* __restrict__ oh) {
  const int row = blockIdx.x;
  const int t = threadIdx.x;
  const float4 v = *(const float4*)(x + (size_t)row * D_MODEL + t * 4);
  float s = v.x + v.y + v.z + v.w;
  float q = v.x*v.x + v.y*v.y + v.z*v.z + v.w*v.w;
  #pragma unroll
  for (int o = 32; o; o >>= 1) { s += __shfl_down(s, o); q += __shfl_down(q, o); }
  __shared__ float red[8];
  if ((t & 63) == 0) { red[t >> 6] = s; red[4 + (t >> 6)] = q; }
  __syncthreads();
  s = red[0] + red[1] + red[2] + red[3];
  q = red[4] + red[5] + red[6] + red[7];
  const float mean = s * (1.f / D_MODEL);
  const float var  = q * (1.f / D_MODEL) - mean * mean;
  const float rstd = rsqrtf(var + 1e-5f);
  const float4 wv = *(const float4*)(w + t * 4);
  const float4 bv = *(const float4*)(b + t * 4);
  ushort4 h4;
  h4.x = rnd_bf16((v.x - mean) * rstd * wv.x + bv.x);
  h4.y = rnd_bf16((v.y - mean) * rstd * wv.y + bv.y);
  h4.z = rnd_bf16((v.z - mean) * rstd * wv.z + bv.z);
  h4.w = rnd_bf16((v.w - mean) * rstd * wv.w + bv.w);
  ((ushort4*)(oh + (size_t)row * D_MODEL))[t] = h4;
}

// ---- fused: Xout = Xin + sum(out_proj partials); then LayerNorm -> operand ---
template<int OUT>
__global__ __launch_bounds__(256) void oreduce_ln_k(
    const float* __restrict__ part, const float* __restrict__ Xin,
    float* __restrict__ Xout,
    const float* __restrict__ w, const float* __restrict__ b,
    void* __restrict__ out) {
  const int row = blockIdx.x;
  const int t = threadIdx.x;
  float4 v = *(const float4*)(Xin + (size_t)row * D_MODEL + t * 4);
  #pragma unroll
  for (int k = 0; k < KSO; k++) {
    const float4 p = *(const float4*)(part + (size_t)k * BL * D_MODEL
                                      + (size_t)row * D_MODEL + t * 4);
    v.x += p.x; v.y += p.y; v.z += p.z; v.w += p.w;
  }
  *(float4*)(Xout + (size_t)row * D_MODEL + t * 4) = v;   // residual stream
  float s = v.x + v.y + v.z + v.w;
  float q = v.x*v.x + v.y*v.y + v.z*v.z + v.w*v.w;
  #pragma unroll
  for (int o = 32; o; o >>= 1) { s += __shfl_down(s, o); q += __shfl_down(q, o); }
  __shared__ float red[8];
  if ((t & 63) == 0) { red[t >> 6] = s; red[4 + (t >> 6)] = q; }
  __syncthreads();
  s = red[0] + red[1] + red[2] + red[3];
  q = red[4] + red[5] + red[6] + red[7];
  const float mean = s * (1.f / D_MODEL);
  const float var  = q * (1.f / D_MODEL) - mean * mean;
  const float rstd = rsqrtf(var + 1e-5f);
  const float4 wv = *(const float4*)(w + t * 4);
  const float4 bv = *(const float4*)(b + t * 4);
  float4 o4;
  o4.x = (v.x - mean) * rstd * wv.x + bv.x;
  o4.y = (v.y - mean) * rstd * wv.y + bv.y;
  o4.z = (v.z - mean) * rstd * wv.z + bv.z;
  o4.w = (v.w - mean) * rstd * wv.w + bv.w;
  if constexpr (OUT == 0) {
    ushort4 h4;
    h4.x = rnd_bf16(o4.x); h4.y = rnd_bf16(o4.y);
    h4.z = rnd_bf16(o4.z); h4.w = rnd_bf16(o4.w);
    ((ushort4*)((unsigned short*)out + (size_t)row * D_MODEL))[t] = h4;
  } else {
    *(float4*)((float*)out + (size_t)row * D_MODEL + t * 4) = o4;
  }
}

// ==== 256x256 bf16 MFMA GEMM NT — counted-vmcnt pipeline (in_proj only) ======
__global__ __launch_bounds__(512) void mfma_gemm256_nt(
    const unsigned short* __restrict__ A, const unsigned short* __restrict__ B,
    unsigned short* __restrict__ C, int K, int ldc) {
  __shared__ unsigned short S[65536];   // [buf:2][mat:2][256*64] bf16 = 128 KB
  const int tid = threadIdx.x;
  const int l = tid & 63;
  const int w = tid >> 6;
  const int wm = w >> 2, wn = w & 3;
  const int bid = blockIdx.y * 16 + blockIdx.x;
  const int x = bid & 7, v = bid >> 3;
  const int bx = (x & 1) * 8 + (v & 7);
  const int by = (x >> 1) * 4 + (v >> 3);
  const int m0 = by * 256, n0 = bx * 256;
  const int nkt = K >> 6;
  const int r8 = (tid >> 3) & 7;
  const int c16s = (tid & 7) ^ r8;

  auto stage1 = [&](int kt, int mat, int half) {
    const unsigned short* base = (mat == 0) ? (A + (size_t)m0 * K)
                                            : (B + (size_t)n0 * K);
    unsigned short* dst = S + ((kt & 1) * 32768 + mat * 16384 + half * 8192);
    #pragma unroll
    for (int e = 0; e < 2; ++e) {
      const int row = half * 128 + e * 64 + (tid >> 3);
      GLDS16(base + (size_t)row * K + kt * 64 + c16s * 8,
             dst + e * 4096 + tid * 8);
    }
  };
  auto stage_full = [&](int kt) {
    stage1(kt, 0, 0); stage1(kt, 0, 1); stage1(kt, 1, 0); stage1(kt, 1, 1);
  };

  stage_full(0);
  if (nkt > 1) stage_full(1);

  f32x4 acc[8][4] = {};
  const int fr = l & 15;
  const int fk8 = l >> 4;

  #pragma unroll 1
  for (int kt = 0; kt < nkt; ++kt) {
    if (kt + 1 < nkt) asm volatile("s_waitcnt vmcnt(8)" ::: "memory");
    else              asm volatile("s_waitcnt vmcnt(0)" ::: "memory");
    __builtin_amdgcn_s_barrier();
    __builtin_amdgcn_sched_barrier(0);
    const unsigned short* SA = S + (kt & 1) * 32768;
    const unsigned short* SB = SA + 16384;
    #pragma unroll
    for (int kk8 = 0; kk8 < 8; kk8 += 4) {
      bf16x8 av[8], bv[4];
      const int c8 = kk8 + fk8;
      #pragma unroll
      for (int i = 0; i < 8; ++i) {
        const int R = wm * 128 + i * 16 + fr;
        av[i] = *(const bf16x8*)&SA[R * 64 + ((c8 ^ (R & 7)) << 3)];
      }
      #pragma unroll
      for (int j = 0; j < 4; ++j) {
        const int R = wn * 64 + j * 16 + fr;
        bv[j] = *(const bf16x8*)&SB[R * 64 + ((c8 ^ (R & 7)) << 3)];
      }
      __builtin_amdgcn_s_setprio(1);
      #pragma unroll
      for (int i = 0; i < 8; ++i)
        #pragma unroll
        for (int j = 0; j < 4; ++j)
          acc[i][j] = __builtin_amdgcn_mfma_f32_16x16x32_bf16(
              av[i], bv[j], acc[i][j], 0, 0, 0);
      __builtin_amdgcn_s_setprio(0);
    }
    __builtin_amdgcn_s_barrier();
    __builtin_amdgcn_sched_barrier(0);
    if (kt + 2 < nkt) stage_full(kt + 2);
  }

  const int orow = (l >> 4) * 4, ocol = l & 15;
  #pragma unroll
  for (int i = 0; i < 8; ++i)
    #pragma unroll
    for (int j = 0; j < 4; ++j)
      #pragma unroll
      for (int r = 0; r < 4; ++r) {
        const int m = m0 + wm * 128 + i * 16 + orow + r;
        const int n = n0 + wn * 64 + j * 16 + ocol;
        C[(size_t)m * ldc + n] = rnd_bf16(acc[i][j][r]);
      }
}

// ---- bf16 MFMA GEMM NT 128² -------------------------------------------------
// EPI 0: bf16 store. EPI 1: fp32 partials. EPI 2: softplus+bias -> bf16.
template<int EPI, int KSEG>
__global__ __launch_bounds__(256) void mfma_gemm_nt(
    const unsigned short* __restrict__ Ah, const unsigned short* __restrict__ Bh,
    void* __restrict__ Cv, int M, int N, int K, int ldc,
    const float* __restrict__ bias) {
  __shared__ unsigned short As[128 * 64];
  __shared__ unsigned short Bs[128 * 64];
  const int tid = threadIdx.x;
  const int w = tid >> 6, l = tid & 63;
  const int wr = w >> 1, wc = w & 1;
  const int nbx = gridDim.x;
  const int nwg = nbx * gridDim.y;
  int bid = blockIdx.y * nbx + blockIdx.x;
  bid = (bid & 7) * (nwg >> 3) + (bid >> 3);
  const int st = bid >> 6, wi = bid & 63;
  const int stpr = (nbx >= 8) ? (nbx >> 3) : 1;
  int n0, m0;
  if (nbx >= 8) {
    n0 = ((st % stpr) * 8 + (wi & 7)) * 128;
    m0 = ((st / stpr) * 8 + (wi >> 3)) * 128;
  } else {
    n0 = (bid % nbx) * 128;
    m0 = (bid / nbx) * 128;
  }
  const int kz = (KSEG > 1) ? blockIdx.z : 0;
  const int kbeg = kz * (K / KSEG);
  const int kend = kbeg + K / KSEG;
  const int srow = l >> 3;
  const int scol = (l & 7) * 8;
  const int fr = l & 15;
  const int fk = (l >> 4) * 8;
  f32x4 acc[4][4] = {};

  #pragma unroll 1
  for (int k0 = kbeg; k0 < kend; k0 += 64) {
    __syncthreads();
    #pragma unroll
    for (int it = 0; it < 4; ++it) {
      const int bi = it * 4 + w;
      const int row = bi * 8 + srow;
      GLDS16(Ah + (size_t)(m0 + row) * K + k0 + scol, &As[bi * 512 + l * 8]);
      GLDS16(Bh + (size_t)(n0 + row) * K + k0 + scol, &Bs[bi * 512 + l * 8]);
    }
    __syncthreads();
    #pragma unroll
    for (int kk = 0; kk < 64; kk += 32) {
      bf16x8 a[4], b[4];
      #pragma unroll
      for (int f = 0; f < 4; ++f)
        b[f] = *(const bf16x8*)&Bs[(wc * 64 + f * 16 + fr) * 64 + kk + fk];
      #pragma unroll
      for (int f = 0; f < 4; ++f)
        a[f] = *(const bf16x8*)&As[(wr * 64 + f * 16 + fr) * 64 + kk + fk];
      #pragma unroll
      for (int i = 0; i < 4; ++i)
        #pragma unroll
        for (int j = 0; j < 4; ++j)
          acc[i][j] = __builtin_amdgcn_mfma_f32_16x16x32_bf16(
              a[i], b[j], acc[i][j], 0, 0, 0);
    }
  }
  const int orow = (l >> 4) * 4;
  const int ocol = l & 15;
  if constexpr (EPI == 0 || EPI == 2) {
    unsigned short* Cw = (unsigned short*)Cv;
    #pragma unroll
    for (int i = 0; i < 4; ++i)
      #pragma unroll
      for (int j = 0; j < 4; ++j)
        #pragma unroll
        for (int r = 0; r < 4; ++r) {
          const int m = m0 + wr * 64 + i * 16 + orow + r;
          const int n = n0 + wc * 64 + j * 16 + ocol;
          float vv = acc[i][j][r];
          if constexpr (EPI == 2) {
            vv += bias[n];
            vv = (vv > 20.f) ? vv : log1pf(__expf(vv));
          }
          Cw[(size_t)m * ldc + n] = rnd_bf16(vv);
        }
  } else {
    float* Cw = (float*)Cv + (size_t)kz * M * ldc;
    #pragma unroll
    for (int i = 0; i < 4; ++i)
      #pragma unroll
      for (int j = 0; j < 4; ++j)
        #pragma unroll
        for (int r = 0; r < 4; ++r) {
          const int m = m0 + wr * 64 + i * 16 + orow + r;
          const int n = n0 + wc * 64 + j * 16 + ocol;
          Cw[(size_t)m * ldc + n] = acc[i][j][r];
        }
  }
}

// ---- x_proj split-K (bf16 A) ------------------------------------------------
__global__ __launch_bounds__(256) void sgemm_splitk_k(
    const unsigned short* __restrict__ A, const float* __restrict__ B,
    float* __restrict__ part) {
  __shared__ float As[32][64 + 4];
  __shared__ float Bs[32][32 + 4];
  const int tid = threadIdx.x;
  const int n0 = blockIdx.x * 32;
  const int m0 = blockIdx.y * 64;
  const int kz = blockIdx.z;
  const int tn = (tid & 15) * 2;
  const int tm = (tid >> 4) * 4;
  float acc[4][2] = {};
  for (int kb = 0; kb < 256; kb += 32) {
    const int k0 = kz * 256 + kb;
    {
      int r = tid >> 2, c8 = (tid & 3) * 8;
      us8 u = *(const us8*)(A + (size_t)(m0 + r) * D_INNER + k0 + c8);
      #pragma unroll
      for (int j = 0; j < 8; j++) As[c8 + j][r] = b2f((unsigned short)u[j]);
    }
    {
      int r = tid >> 3, c4 = tid & 7;
      float4 v = *(const float4*)(B + (size_t)(n0 + r) * D_INNER + k0 + c4 * 4);
      Bs[c4*4+0][r] = v.x; Bs[c4*4+1][r] = v.y;
      Bs[c4*4+2][r] = v.z; Bs[c4*4+3][r] = v.w;
    }
    __syncthreads();
    #pragma unroll
    for (int k = 0; k < 32; k++) {
      float a[4], bf[2];
      #pragma unroll
      for (int i = 0; i < 4; i++) a[i] = As[k][tm + i];
      bf[0] = Bs[k][tn]; bf[1] = Bs[k][tn + 1];
      #pragma unroll
      for (int i = 0; i < 4; i++) {
        acc[i][0] = fmaf(a[i], bf[0], acc[i][0]);
        acc[i][1] = fmaf(a[i], bf[1], acc[i][1]);
      }
    }
    __syncthreads();
  }
  float* p = part + (size_t)kz * BL * 96;
  #pragma unroll
  for (int i = 0; i < 4; i++) {
    const int m = m0 + tm + i;
    p[(size_t)m * 96 + n0 + tn]     = acc[i][0];
    p[(size_t)m * 96 + n0 + tn + 1] = acc[i][1];
  }
}

// reduce KS partials; split: cols 0..63 -> bf16 dtr, 64..95 -> fp32 bc[BL][32]
__global__ __launch_bounds__(256) void xproj_reduce_k(
    const float* __restrict__ part, unsigned short* __restrict__ dtr,
    float* __restrict__ bc) {
  const int i = blockIdx.x * 256 + threadIdx.x;   // over BL*96
  const int m = i / 96, col = i % 96;
  float s = 0.f;
  #pragma unroll
  for (int k = 0; k < KS; k++) s += part[(size_t)k * BL * 96 + i];
  if (col < DT_RANK) dtr[(size_t)m * DT_RANK + col] = rnd_bf16(s);
  else               bc[(size_t)m * 32 + (col - DT_RANK)] = s;
}

// ------ causal depthwise conv + SiLU, bf16 in / bf16 out ----------------------
__global__ __launch_bounds__(256) void conv_silu_k(
    const unsigned short* __restrict__ xz,
    const float* __restrict__ cw, const float* __restrict__ cb,
    unsigned short* __restrict__ xc) {
  const int gid = blockIdx.x * 256 + threadIdx.x;
  const int c4 = (gid & (D_INNER / 4 - 1)) << 2;
  const int row = gid >> 9;
  const int l = row & (LL - 1);
  const unsigned short* base = xz + (size_t)row * (2 * D_INNER) + c4;
  const float4 w0 = *(const float4*)(cw + (c4 + 0) * 4);
  const float4 w1 = *(const float4*)(cw + (c4 + 1) * 4);
  const float4 w2 = *(const float4*)(cw + (c4 + 2) * 4);
  const float4 w3 = *(const float4*)(cw + (c4 + 3) * 4);
  float4 acc = *(const float4*)(cb + c4);
  ushort4 uv = *(const ushort4*)base;
  acc.x = fmaf(w0.w, b2f(uv.x), acc.x); acc.y = fmaf(w1.w, b2f(uv.y), acc.y);
  acc.z = fmaf(w2.w, b2f(uv.z), acc.z); acc.w = fmaf(w3.w, b2f(uv.w), acc.w);
  if (l >= 1) {
    uv = *(const ushort4*)(base - 2 * D_INNER);
    acc.x = fmaf(w0.z, b2f(uv.x), acc.x); acc.y = fmaf(w1.z, b2f(uv.y), acc.y);
    acc.z = fmaf(w2.z, b2f(uv.z), acc.z); acc.w = fmaf(w3.z, b2f(uv.w), acc.w);
  }
  if (l >= 2) {
    uv = *(const ushort4*)(base - 4 * D_INNER);
    acc.x = fmaf(w0.y, b2f(uv.x), acc.x); acc.y = fmaf(w1.y, b2f(uv.y), acc.y);
    acc.z = fmaf(w2.y, b2f(uv.z), acc.z); acc.w = fmaf(w3.y, b2f(uv.w), acc.w);
  }
  if (l >= 3) {
    uv = *(const ushort4*)(base - 6 * D_INNER);
    acc.x = fmaf(w0.x, b2f(uv.x), acc.x); acc.y = fmaf(w1.x, b2f(uv.y), acc.y);
    acc.z = fmaf(w2.x, b2f(uv.z), acc.z); acc.w = fmaf(w3.x, b2f(uv.w), acc.w);
  }
  ushort4 o4;
  o4.x = rnd_bf16(acc.x / (1.f + __expf(-acc.x)));
  o4.y = rnd_bf16(acc.y / (1.f + __expf(-acc.y)));
  o4.z = rnd_bf16(acc.z / (1.f + __expf(-acc.z)));
  o4.w = rnd_bf16(acc.w / (1.f + __expf(-acc.w)));
  *(ushort4*)(xc + (size_t)row * D_INNER + c4) = o4;
}

// w-power helper: P[n] = w^(n+1), depth-4 multiply tree
__device__ inline void wpowers(float w1, float* P) {
  const float w2 = w1 * w1, w3 = w2 * w1, w4 = w2 * w2;
  const float w5 = w4 * w1, w6 = w4 * w2, w7 = w4 * w3, w8 = w4 * w4;
  P[0] = w1;  P[1] = w2;  P[2] = w3;  P[3] = w4;
  P[4] = w5;  P[5] = w6;  P[6] = w7;  P[7] = w8;
  P[8]  = w8 * w1;  P[9]  = w8 * w2;  P[10] = w8 * w3;  P[11] = w8 * w4;
  P[12] = w8 * w5;  P[13] = w8 * w6;  P[14] = w8 * w7;  P[15] = w8 * w8;
}

// ------- chunked selective scan, pass 1 (bf16 dt/xc, bc stride 32) ------------
// Fast path: Ac[n] ~= -(n+1) (checked at runtime) -> dA[n] = exp(-dt)^(n+1),
// 1 exp + 15 muls instead of 16 exps. Generic fallback otherwise.
__global__ __launch_bounds__(256) void scan_pass1_k(
    const unsigned short* __restrict__ dt, const unsigned short* __restrict__ xc,
    const float* __restrict__ bc, const float* __restrict__ A_log,
    float* __restrict__ hend, float* __restrict__ sumdt) {
  const int c = blockIdx.x * 256 + threadIdx.x;
  const int k = blockIdx.y;
  const int b = blockIdx.z;
  float Ac[D_STATE];
  bool fast = true;
  #pragma unroll
  for (int n = 0; n < D_STATE; n++) {
    Ac[n] = -__expf(A_log[c * D_STATE + n]);
    fast = fast && (fabsf(Ac[n] + (float)(n + 1)) <= 4e-6f * (float)(n + 1));
  }
  float h[D_STATE] = {};
  float sd = 0.f;
  const size_t r0 = (size_t)b * LL + (size_t)k * CLEN;
  const unsigned short* dtp = dt + r0 * D_INNER + c;
  const unsigned short* xcp = xc + r0 * D_INNER + c;
  const float* Bp  = bc + r0 * 32;

  float dtv = b2f(dtp[0]);
  float xv  = b2f(xcp[0]);
  float4 B0 = *(const float4*)(Bp + 0);
  float4 B1 = *(const float4*)(Bp + 4);
  float4 B2 = *(const float4*)(Bp + 8);
  float4 B3 = *(const float4*)(Bp + 12);
  if (fast) {
    for (int l = 0; l < CLEN; l++) {
      const int lp = (l + 1 < CLEN) ? l + 1 : l;
      const float dtv2 = b2f(dtp[(size_t)lp * D_INNER]);
      const float xv2  = b2f(xcp[(size_t)lp * D_INNER]);
      const float4 B0n = *(const float4*)(Bp + (size_t)lp * 32 + 0);
      const float4 B1n = *(const float4*)(Bp + (size_t)lp * 32 + 4);
      const float4 B2n = *(const float4*)(Bp + (size_t)lp * 32 + 8);
      const float4 B3n = *(const float4*)(Bp + (size_t)lp * 32 + 12);
      sd += dtv;
      const float dx = dtv * xv;
      float P[D_STATE];
      wpowers(__expf(-dtv), P);
      const float Bv[D_STATE] = {B0.x,B0.y,B0.z,B0.w, B1.x,B1.y,B1.z,B1.w,
                                 B2.x,B2.y,B2.z,B2.w, B3.x,B3.y,B3.z,B3.w};
      #pragma unroll
      for (int n = 0; n < D_STATE; n++)
        h[n] = fmaf(P[n], h[n], dx * Bv[n]);
      dtv = dtv2; xv = xv2; B0 = B0n; B1 = B1n; B2 = B2n; B3 = B3n;
    }
  } else {
    for (int l = 0; l < CLEN; l++) {
      const int lp = (l + 1 < CLEN) ? l + 1 : l;
      const float dtv2 = b2f(dtp[(size_t)lp * D_INNER]);
      const float xv2  = b2f(xcp[(size_t)lp * D_INNER]);
      const float4 B0n = *(const float4*)(Bp + (size_t)lp * 32 + 0);
      const float4 B1n = *(const float4*)(Bp + (size_t)lp * 32 + 4);
      const float4 B2n = *(const float4*)(Bp + (size_t)lp * 32 + 8);
      const float4 B3n = *(const float4*)(Bp + (size_t)lp * 32 + 12);
      sd += dtv;
      const float dx = dtv * xv;
      const float Bv[D_STATE] = {B0.x,B0.y,B0.z,B0.w, B1.x,B1.y,B1.z,B1.w,
                                 B2.x,B2.y,B2.z,B2.w, B3.x,B3.y,B3.z,B3.w};
      #pragma unroll
      for (int n = 0; n < D_STATE; n++)
        h[n] = fmaf(__expf(dtv * Ac[n]), h[n], dx * Bv[n]);
      dtv = dtv2; xv = xv2; B0 = B0n; B1 = B1n; B2 = B2n; B3 = B3n;
    }
  }
  float* he = hend + (((size_t)(b * CH + k) * D_INNER + c) << 4);
  #pragma unroll
  for (int n = 0; n < D_STATE; n += 4)
    *(float4*)(he + n) = make_float4(h[n], h[n+1], h[n+2], h[n+3]);
  sumdt[(size_t)(b * CH + k) * D_INNER + c] = sd;
}

// ------- chunked scan fixup ---------------------------------------------------
__global__ __launch_bounds__(256) void scan_fix_k(
    float* __restrict__ hend, const float* __restrict__ sumdt,
    const float* __restrict__ A_log) {
  const int gid = blockIdx.x * 256 + threadIdx.x;
  const int n = gid & 15;
  const int c = (gid >> 4) & (D_INNER - 1);
  const int b = gid >> 15;
  const float Ac = -__expf(A_log[c * D_STATE + n]);
  float hrun = 0.f;
  for (int k = 0; k < CH; k++) {
    const size_t base = (size_t)(b * CH + k) * D_INNER + c;
    const float sd = sumdt[base];
    float* hp = hend + (base << 4) + n;
    const float tmp = *hp;
    *hp = hrun;
    hrun = fmaf(__expf(Ac * sd), hrun, tmp);
  }
}

// ------- chunked scan pass 3 (bc stride 32, fast w-power path) -----------------
__global__ __launch_bounds__(256) void scan_pass3_k(
    const unsigned short* __restrict__ dt, const unsigned short* __restrict__ xc,
    const float* __restrict__ bc, const unsigned short* __restrict__ xz,
    const float* __restrict__ h0, const float* __restrict__ A_log,
    const float* __restrict__ Dp, unsigned short* __restrict__ yh) {
  const int c = blockIdx.x * 256 + threadIdx.x;
  const int k = blockIdx.y;
  const int b = blockIdx.z;
  float Ac[D_STATE];
  bool fast = true;
  #pragma unroll
  for (int n = 0; n < D_STATE; n++) {
    Ac[n] = -__expf(A_log[c * D_STATE + n]);
    fast = fast && (fabsf(Ac[n] + (float)(n + 1)) <= 4e-6f * (float)(n + 1));
  }
  const float Dv = Dp[c];
  float h[D_STATE];
  const float* hp = h0 + (((size_t)(b * CH + k) * D_INNER + c) << 4);
  #pragma unroll
  for (int n = 0; n < D_STATE; n += 4) {
    const float4 v = *(const float4*)(hp + n);
    h[n] = v.x; h[n+1] = v.y; h[n+2] = v.z; h[n+3] = v.w;
  }
  const size_t r0 = (size_t)b * LL + (size_t)k * CLEN;
  const unsigned short* dtp = dt + r0 * D_INNER + c;
  const unsigned short* xcp = xc + r0 * D_INNER + c;
  const float* Bp  = bc + r0 * 32;
  const unsigned short* zp = xz + r0 * (size_t)(2 * D_INNER) + D_INNER + c;
  unsigned short* yhp = yh + r0 * D_INNER + c;

  float dtv = b2f(dtp[0]);
  float xv  = b2f(xcp[0]);
  float zv  = b2f(zp[0]);
  float4 B0 = *(const float4*)(Bp + 0);
  float4 B1 = *(const float4*)(Bp + 4);
  float4 B2 = *(const float4*)(Bp + 8);
  float4 B3 = *(const float4*)(Bp + 12);
  float4 C0 = *(const float4*)(Bp + 16);
  float4 C1 = *(const float4*)(Bp + 20);
  float4 C2 = *(const float4*)(Bp + 24);
  float4 C3 = *(const float4*)(Bp + 28);
  if (fast) {
    for (int l = 0; l < CLEN; l++) {
      const int lp = (l + 1 < CLEN) ? l + 1 : l;
      const float dtv2 = b2f(dtp[(size_t)lp * D_INNER]);
      const float xv2  = b2f(xcp[(size_t)lp * D_INNER]);
      const float zv2  = b2f(zp[(size_t)lp * 2 * D_INNER]);
      const float4 B0n = *(const float4*)(Bp + (size_t)lp * 32 + 0);
      const float4 B1n = *(const float4*)(Bp + (size_t)lp * 32 + 4);
      const float4 B2n = *(const float4*)(Bp + (size_t)lp * 32 + 8);
      const float4 B3n = *(const float4*)(Bp + (size_t)lp * 32 + 12);
      const float4 C0n = *(const float4*)(Bp + (size_t)lp * 32 + 16);
      const float4 C1n = *(const float4*)(Bp + (size_t)lp * 32 + 20);
      const float4 C2n = *(const float4*)(Bp + (size_t)lp * 32 + 24);
      const float4 C3n = *(const float4*)(Bp + (size_t)lp * 32 + 28);
      const float dx = dtv * xv;
      float P[D_STATE];
      wpowers(__expf(-dtv), P);
      const float Bv[D_STATE] = {B0.x,B0.y,B0.z,B0.w, B1.x,B1.y,B1.z,B1.w,
                                 B2.x,B2.y,B2.z,B2.w, B3.x,B3.y,B3.z,B3.w};
      const float Cv[D_STATE] = {C0.x,C0.y,C0.z,C0.w, C1.x,C1.y,C1.z,C1.w,
                                 C2.x,C2.y,C2.z,C2.w, C3.x,C3.y,C3.z,C3.w};
      float y = 0.f;
      #pragma unroll
      for (int n = 0; n < D_STATE; n++) {
        h[n] = fmaf(P[n], h[n], dx * Bv[n]);
        y = fmaf(h[n], Cv[n], y);
      }
      y = fmaf(xv, Dv, y);
      y *= zv / (1.f + __expf(-zv));
      yhp[(size_t)l * D_INNER] = rnd_bf16(y);
      dtv = dtv2; xv = xv2; zv = zv2;
      B0 = B0n; B1 = B1n; B2 = B2n; B3 = B3n;
      C0 = C0n; C1 = C1n; C2 = C2n; C3 = C3n;
    }
  } else {
    for (int l = 0; l < CLEN; l++) {
      const int lp = (l + 1 < CLEN) ? l + 1 : l;
      const float dtv2 = b2f(dtp[(size_t)lp * D_INNER]);
      const float xv2  = b2f(xcp[(size_t)lp * D_INNER]);
      const float zv2  = b2f(zp[(size_t)lp * 2 * D_INNER]);
      const float4 B0n = *(const float4*)(Bp + (size_t)lp * 32 + 0);
      const float4 B1n = *(const float4*)(Bp + (size_t)lp * 32 + 4);
      const float4 B2n = *(const float4*)(Bp + (size_t)lp * 32 + 8);
      const float4 B3n = *(const float4*)(Bp + (size_t)lp * 32 + 12);
      const float4 C0n = *(const float4*)(Bp + (size_t)lp * 32 + 16);
      const float4 C1n = *(const float4*)(Bp + (size_t)lp * 32 + 20);
      const float4 C2n = *(const float4*)(Bp + (size_t)lp * 32 + 24);
      const float4 C3n = *(const float4*)(Bp + (size_t)lp * 32 + 28);
      const float dx = dtv * xv;
      const float Bv[D_STATE] = {B0.x,B0.y,B0.z,B0.w, B1.x,B1.y,B1.z,B1.w,
                                 B2.x,B2.y,B2.z,B2.w, B3.x,B3.y,B3.z,B3.w};
      const float Cv[D_STATE] = {C0.x,C0.y,C0.z,C0.w, C1.x,C1.y,C1.z,C1.w,
                                 C2.x,C2.y,C2.z,C2.w, C3.x,C3.y,C3.z,C3.w};
      float y = 0.f;
      #pragma unroll
      for (int n = 0; n < D_STATE; n++) {
        h[n] = fmaf(__expf(dtv * Ac[n]), h[n], dx * Bv[n]);
        y = fmaf(h[n], Cv[n], y);
      }
      y = fmaf(xv, Dv, y);
      y *= zv / (1.f + __expf(-zv));
      yhp[(size_t)l * D_INNER] = rnd_bf16(y);
      dtv = dtv2; xv = xv2; zv = zv2;
      B0 = B0n; B1 = B1n; B2 = B2n; B3 = B3n;
      C0 = C0n; C1 = C1n; C2 = C2n; C3 = C3n;
    }
  }
}

// ---------------- mean pool over L, two-stage ---------------------------------
__global__ __launch_bounds__(256) void pool1_k(const float* __restrict__ h,
    float* __restrict__ pp) {
  const int d = blockIdx.x * 256 + threadIdx.x;
  const int b = blockIdx.y;
  const int seg = blockIdx.z;
  float s = 0.f;
  const size_t base = (size_t)b * LL + (size_t)seg * 64;
  for (int l = 0; l < 64; l++) s += h[(base + l) * D_MODEL + d];
  pp[((size_t)(b * 16 + seg)) * D_MODEL + d] = s;
}
__global__ __launch_bounds__(256) void pool2_k(const float* __restrict__ pp,
    float* __restrict__ pooled) {
  const int d = blockIdx.x * 256 + threadIdx.x;
  const int b = blockIdx.y;
  float s = 0.f;
  #pragma unroll
  for (int k = 0; k < 16; k++) s += pp[((size_t)(b * 16 + k)) * D_MODEL + d];
  pooled[b * D_MODEL + d] = s * (1.f / LL);
}

// ---------------- classifier head --------------------------------------------
__global__ __launch_bounds__(64) void head_k(const float* __restrict__ pooled,
    const float* __restrict__ hw, const float* __restrict__ hb,
    float* __restrict__ out) {
  const int b = blockIdx.x / N_CLASSES;
  const int j = blockIdx.x % N_CLASSES;
  float s = 0.f;
  for (int k = threadIdx.x; k < D_MODEL; k += 64)
    s = fmaf(pooled[b * D_MODEL + k], hw[j * D_MODEL + k], s);
  #pragma unroll
  for (int o = 32; o; o >>= 1) s += __shfl_down(s, o);
  if (threadIdx.x == 0) out[b * N_CLASSES + j] = s + hb[j];
}

extern "C" void kernel_launch(void* const* d_in, const int* in_sizes, int n_in,
                              void* d_out, int out_size, void* d_ws, size_t ws_size,
                              hipStream_t stream) {
  const float* x0    = (const float*)d_in[0];
  const float* ln1w  = (const float*)d_in[1];
  const float* ln1b  = (const float*)d_in[2];
  const float* inw   = (const float*)d_in[3];
  const float* convw = (const float*)d_in[4];
  const float* convb = (const float*)d_in[5];
  const float* xpw   = (const float*)d_in[6];
  const float* dtpw  = (const float*)d_in[7];
  const float* dtpb  = (const float*)d_in[8];
  const float* Alog  = (const float*)d_in[9];
  const float* Dp    = (const float*)d_in[10];
  const float* outw  = (const float*)d_in[11];
  const float* normw = (const float*)d_in[12];
  const float* normb = (const float*)d_in[13];
  const float* headw = (const float*)d_in[14];
  const float* headb = (const float*)d_in[15];

  float* ws = (float*)d_ws;
  size_t f = 0;
  float* X      = ws + f; f += (size_t)BL * D_MODEL;
  float* xzf    = ws + f; f += (size_t)BL * D_INNER;
  float* bc     = ws + f; f += (size_t)BL * 32;
  float* dty    = ws + f; f += (size_t)BL * D_INNER;
  float* pooled = ws + f; f += 4096;
  float* pooldp = ws + f; f += (size_t)16 * BB * D_MODEL;
  float* xpart  = ws + f; f += (size_t)KS * BL * 96;
  float* hend   = ws + f; f += (size_t)BB * CH * D_INNER * D_STATE;
  float* opart  = ws + f; f += (size_t)KSO * BL * D_MODEL;
  unsigned short* hh  = (unsigned short*)(ws + f); f += (size_t)BL * D_MODEL / 2;
  unsigned short* yh  = (unsigned short*)(ws + f); f += (size_t)BL * D_INNER / 2;
  unsigned short* xcb = (unsigned short*)(ws + f); f += (size_t)BL * D_INNER / 2;
  unsigned short* dtr = (unsigned short*)(ws + f); f += (size_t)BL * DT_RANK / 2;
  unsigned short* wih = (unsigned short*)(ws + f);
  f += (size_t)N_LAYERS * 2 * D_INNER * D_MODEL / 2;
  unsigned short* woh = (unsigned short*)(ws + f);
  f += (size_t)N_LAYERS * D_MODEL * D_INNER / 2;
  unsigned short* wdt = (unsigned short*)(ws + f);
  f += (size_t)N_LAYERS * D_INNER * DT_RANK / 2;
  unsigned short* xz  = (unsigned short*)xzf;
  unsigned short* dtb = (unsigned short*)dty;
  float* sumdt = xpart;

  round_k<<<(N_LAYERS * 2 * D_INNER * D_MODEL) / 1024, 256, 0, stream>>>(inw, wih);
  round_k<<<(N_LAYERS * D_MODEL * D_INNER) / 1024, 256, 0, stream>>>(outw, woh);
  round_k<<<(N_LAYERS * D_INNER * DT_RANK) / 1024, 256, 0, stream>>>(dtpw, wdt);
  layernorm_bf16_k<<<BL, 256, 0, stream>>>(x0, ln1w, ln1b, hh);

  for (int layer = 0; layer < N_LAYERS; ++layer) {
    const unsigned short* wi = wih + (size_t)layer * 2 * D_INNER * D_MODEL;
    const unsigned short* wo = woh + (size_t)layer * D_MODEL * D_INNER;
    const unsigned short* wd = wdt + (size_t)layer * D_INNER * DT_RANK;
    mfma_gemm256_nt<<<dim3(16, 16), 512, 0, stream>>>(
        hh, wi, xz, D_MODEL, 2 * D_INNER);
    conv_silu_k<<<(BL * D_INNER / 4) / 256, 256, 0, stream>>>(
        xz, convw + layer * D_INNER * D_CONV, convb + layer * D_INNER, xcb);
    sgemm_splitk_k<<<dim3(96 / 32, 4096 / 64, KS), 256, 0, stream>>>(
        xcb, xpw + (size_t)layer * 96 * D_INNER, xpart);
    xproj_reduce_k<<<(BL * 96) / 256, 256, 0, stream>>>(xpart, dtr, bc);
    mfma_gemm_nt<2, 1><<<dim3(2048 / 128, 4096 / 128), 256, 0, stream>>>(
        dtr, wd, dtb, BL, D_INNER, DT_RANK, D_INNER, dtpb + layer * D_INNER);
    scan_pass1_k<<<dim3(D_INNER / 256, CH, BB), 256, 0, stream>>>(
        dtb, xcb, bc, Alog + (size_t)layer * D_INNER * D_STATE, hend, sumdt);
    scan_fix_k<<<(BB * D_INNER * D_STATE) / 256, 256, 0, stream>>>(
        hend, sumdt, Alog + (size_t)layer * D_INNER * D_STATE);
    scan_pass3_k<<<dim3(D_INNER / 256, CH, BB), 256, 0, stream>>>(
        dtb, xcb, bc, xz, hend, Alog + (size_t)layer * D_INNER * D_STATE,
        Dp + layer * D_INNER, yh);
    mfma_gemm_nt<1, KSO><<<dim3(1024 / 128, 4096 / 128, KSO), 256, 0, stream>>>(
        yh, wo, opart, BL, D_MODEL, D_INNER, D_MODEL, nullptr);
    const float* Xin = (layer == 0) ? x0 : X;
    if (layer + 1 < N_LAYERS) {
      oreduce_ln_k<0><<<BL, 256, 0, stream>>>(
          opart, Xin, X, ln1w + (layer + 1) * D_MODEL,
          ln1b + (layer + 1) * D_MODEL, hh);
    } else {
      oreduce_ln_k<1><<<BL, 256, 0, stream>>>(opart, Xin, X, normw, normb, dty);
    }
  }

  pool1_k<<<dim3(D_MODEL / 256, BB, 16), 256, 0, stream>>>(dty, pooldp);
  pool2_k<<<dim3(D_MODEL / 256, BB), 256, 0, stream>>>(pooldp, pooled);
  head_k<<<BB * N_CLASSES, 64, 0, stream>>>(pooled, headw, headb, (float*)d_out);
}